// Round 1
// baseline (2493.319 us; speedup 1.0000x reference)
//
#include <hip/hip_runtime.h>
#include <math.h>

static constexpr int NB = 16;
static constexpr int NC = 3;
static constexpr int IM = 224;
static constexpr int IMP = IM * IM;      // 50176
static constexpr int HPq = 14;
static constexpr int NPq = 196;
static constexpr int DIMq = 768;
static constexpr int OUTq = 1024;
static constexpr int DIq = 1536;
static constexpr int ROWS = NB * NPq;    // 3136

// ---------------- K1a: channel avg/max ----------------
__global__ __launch_bounds__(256) void k_avgmax(const float* __restrict__ img, float* __restrict__ am) {
    int idx = blockIdx.x * 256 + threadIdx.x;
    if (idx >= NB * IMP) return;
    int p = idx % IMP, b = idx / IMP;
    const float* ib = img + (size_t)b * NC * IMP + p;
    float c0 = ib[0], c1 = ib[IMP], c2 = ib[2 * IMP];
    am[(size_t)(b * 2 + 0) * IMP + p] = (c0 + c1 + c2) * (1.f / 3.f);
    am[(size_t)(b * 2 + 1) * IMP + p] = fmaxf(c0, fmaxf(c1, c2));
}

// ---------------- K1b: 7x7 conv gate + patchify ----------------
__global__ __launch_bounds__(256) void k_gatepatch(const float* __restrict__ img, const float* __restrict__ am,
                                                   const float* __restrict__ saw, float* __restrict__ G) {
    int idx = blockIdx.x * 256 + threadIdx.x;
    if (idx >= NB * IMP) return;
    int p = idx % IMP, b = idx / IMP;
    int y = p / IM, x = p % IM;
    float acc = 0.f;
    #pragma unroll
    for (int ci = 0; ci < 2; ci++) {
        const float* amc = am + (size_t)(b * 2 + ci) * IMP;
        const float* wc = saw + ci * 49;
        #pragma unroll
        for (int kh = 0; kh < 7; kh++) {
            int yy = y + kh - 3;
            if (yy < 0 || yy >= IM) continue;
            #pragma unroll
            for (int kw = 0; kw < 7; kw++) {
                int xx = x + kw - 3;
                if (xx < 0 || xx >= IM) continue;
                acc += amc[yy * IM + xx] * wc[kh * 7 + kw];
            }
        }
    }
    float s = 1.f / (1.f + expf(-acc));
    int hy = y >> 4, py = y & 15, hx = x >> 4, px = x & 15;
    size_t base = ((size_t)(b * NPq + hy * HPq + hx) * 768) + (size_t)(py * 16 + px) * 3;
    const float* ib = img + (size_t)b * NC * IMP + p;
    G[base + 0] = ib[0] * s;
    G[base + 1] = ib[IMP] * s;
    G[base + 2] = ib[2 * IMP] * s;
}

// ---------------- generic f32 GEMM: C = A(MxK) @ W(KxN) + bias, epilogues ----------------
enum { EPI_NONE = 0, EPI_POSEMB = 1, EPI_SOFTPLUS = 2 };

template<int EPI>
__global__ __launch_bounds__(256) void k_gemm(const float* __restrict__ A, int lda,
                                              const float* __restrict__ W, int ldw,
                                              const float* __restrict__ bias,
                                              float* __restrict__ C, int ldc,
                                              int M, int N, int K,
                                              const float* __restrict__ extra) {
    __shared__ __align__(16) float As[8][128];
    __shared__ __align__(16) float Bs[8][128];
    const int bm = blockIdx.y * 128, bn = blockIdx.x * 128;
    const int tid = threadIdx.x;
    const int ty = tid >> 4, tx = tid & 15;
    const int arow = tid >> 1, akk = (tid & 1) * 4;
    const int brow = tid >> 5, bcol = (tid & 31) * 4;
    float acc[8][8];
    #pragma unroll
    for (int i = 0; i < 8; i++)
        #pragma unroll
        for (int j = 0; j < 8; j++) acc[i][j] = 0.f;

    const int gr = bm + arow;
    const bool aok = gr < M;
    const int gn = bn + bcol;
    const bool bok = gn < N;

    for (int k0 = 0; k0 < K; k0 += 8) {
        float4 av = make_float4(0.f, 0.f, 0.f, 0.f);
        if (aok) av = *(const float4*)(A + (size_t)gr * lda + (k0 + akk));
        As[akk + 0][arow] = av.x; As[akk + 1][arow] = av.y;
        As[akk + 2][arow] = av.z; As[akk + 3][arow] = av.w;
        float4 bv = make_float4(0.f, 0.f, 0.f, 0.f);
        if (bok) bv = *(const float4*)(W + (size_t)(k0 + brow) * ldw + gn);
        *(float4*)&Bs[brow][bcol] = bv;
        __syncthreads();
        #pragma unroll
        for (int kk = 0; kk < 8; kk++) {
            float4 a0 = *(const float4*)&As[kk][ty * 4];
            float4 a1 = *(const float4*)&As[kk][64 + ty * 4];
            float4 b0 = *(const float4*)&Bs[kk][tx * 4];
            float4 b1 = *(const float4*)&Bs[kk][64 + tx * 4];
            float a[8] = {a0.x, a0.y, a0.z, a0.w, a1.x, a1.y, a1.z, a1.w};
            float b[8] = {b0.x, b0.y, b0.z, b0.w, b1.x, b1.y, b1.z, b1.w};
            #pragma unroll
            for (int i = 0; i < 8; i++)
                #pragma unroll
                for (int j = 0; j < 8; j++)
                    acc[i][j] = fmaf(a[i], b[j], acc[i][j]);
        }
        __syncthreads();
    }

    #pragma unroll
    for (int i = 0; i < 8; i++) {
        int r = bm + ((i < 4) ? (ty * 4 + i) : (64 + ty * 4 + i - 4));
        if (r >= M) continue;
        #pragma unroll
        for (int j = 0; j < 8; j++) {
            int c = bn + ((j < 4) ? (tx * 4 + j) : (64 + tx * 4 + j - 4));
            if (c >= N) continue;
            float v = acc[i][j];
            if (bias) v += bias[c];
            if (EPI == EPI_POSEMB) v += extra[(size_t)(r % NPq) * N + c];
            if (EPI == EPI_SOFTPLUS) v = (v > 20.f) ? v : log1pf(expf(v));
            C[(size_t)r * ldc + c] = v;
        }
    }
}

// ---------------- causal depthwise conv (DC=4) + silu ----------------
__global__ __launch_bounds__(256) void k_conv_silu(const float* __restrict__ xr, const float* __restrict__ cw,
                                                   const float* __restrict__ cb, float* __restrict__ xi2) {
    int idx = blockIdx.x * 256 + threadIdx.x;
    if (idx >= ROWS * DIq) return;
    int d = idx % DIq; int bt = idx / DIq; int t = bt % NPq; int b = bt / NPq;
    float w0 = cw[d * 4 + 0], w1 = cw[d * 4 + 1], w2 = cw[d * 4 + 2], w3 = cw[d * 4 + 3];
    float s = cb[d];
    const float* base = xr + (size_t)b * NPq * 3072 + d;
    if (t >= 3) s += base[(size_t)(t - 3) * 3072] * w0;
    if (t >= 2) s += base[(size_t)(t - 2) * 3072] * w1;
    if (t >= 1) s += base[(size_t)(t - 1) * 3072] * w2;
    s += base[(size_t)t * 3072] * w3;
    xi2[idx] = s / (1.f + expf(-s));
}

// ---------------- selective-scan: lane = (d, n), 196 sequential steps ----------------
__global__ __launch_bounds__(256) void k_scan(const float* __restrict__ delta, const float* __restrict__ xi2,
                                              const float* __restrict__ dbc, const float* __restrict__ xr,
                                              const float* __restrict__ Alog, const float* __restrict__ Dv,
                                              float* __restrict__ ys) {
    int b = blockIdx.x;
    int d = blockIdx.y * 16 + (threadIdx.x >> 4);
    int n = threadIdx.x & 15;
    float A = -expf(Alog[d * 16 + n]);
    float Dd = Dv[d];
    float h = 0.f;
    for (int t = 0; t < NPq; t++) {
        size_t bt = (size_t)b * NPq + t;
        float de = delta[bt * DIq + d];
        float u  = xi2[bt * DIq + d];
        float Bn = dbc[bt * 80 + 48 + n];
        float Cn = dbc[bt * 80 + 64 + n];
        h = expf(de * A) * h + de * Bn * u;
        float p = h * Cn;
        p += __shfl_xor(p, 1);
        p += __shfl_xor(p, 2);
        p += __shfl_xor(p, 4);
        p += __shfl_xor(p, 8);
        if (n == 0) {
            float r = xr[bt * 3072 + DIq + d];
            ys[bt * DIq + d] = (p + Dd * u) * (r / (1.f + expf(-r)));
        }
    }
}

// ---------------- row LayerNorm (1024) + exact gelu ----------------
__global__ __launch_bounds__(256) void k_ln_gelu(const float* __restrict__ in, const float* __restrict__ g,
                                                 const float* __restrict__ bt, float* __restrict__ out) {
    int row = blockIdx.x;
    const float* x = in + (size_t)row * OUTq;
    float4 v = ((const float4*)x)[threadIdx.x];
    float s = v.x + v.y + v.z + v.w;
    float ss = v.x * v.x + v.y * v.y + v.z * v.z + v.w * v.w;
    #pragma unroll
    for (int off = 32; off >= 1; off >>= 1) { s += __shfl_down(s, off); ss += __shfl_down(ss, off); }
    __shared__ float sh[10];
    int wid = threadIdx.x >> 6, lid = threadIdx.x & 63;
    if (lid == 0) { sh[wid] = s; sh[4 + wid] = ss; }
    __syncthreads();
    if (threadIdx.x == 0) {
        float S = sh[0] + sh[1] + sh[2] + sh[3], SS = sh[4] + sh[5] + sh[6] + sh[7];
        float m = S * (1.f / OUTq);
        float var = SS * (1.f / OUTq) - m * m;
        sh[8] = m; sh[9] = rsqrtf(var + 1e-5f);
    }
    __syncthreads();
    float m = sh[8], rst = sh[9];
    float4 gv = ((const float4*)g)[threadIdx.x];
    float4 bv = ((const float4*)bt)[threadIdx.x];
    float4 o;
    float y0 = (v.x - m) * rst * gv.x + bv.x; o.x = 0.5f * y0 * (1.f + erff(y0 * 0.70710678118f));
    float y1 = (v.y - m) * rst * gv.y + bv.y; o.y = 0.5f * y1 * (1.f + erff(y1 * 0.70710678118f));
    float y2 = (v.z - m) * rst * gv.z + bv.z; o.z = 0.5f * y2 * (1.f + erff(y2 * 0.70710678118f));
    float y3 = (v.w - m) * rst * gv.w + bv.w; o.w = 0.5f * y3 * (1.f + erff(y3 * 0.70710678118f));
    ((float4*)(out + (size_t)row * OUTq))[threadIdx.x] = o;
}

// ---------------- column softmax (over t) + weighted pool ----------------
__global__ __launch_bounds__(256) void k_softpool(const float* __restrict__ gm, const float* __restrict__ ym,
                                                  float* __restrict__ pooled) {
    int b = blockIdx.y;
    int j = blockIdx.x * 256 + threadIdx.x;
    const float* gb = gm + (size_t)b * NPq * OUTq + j;
    const float* yb = ym + (size_t)b * NPq * OUTq + j;
    float mx = -1e30f;
    for (int t = 0; t < NPq; t++) mx = fmaxf(mx, gb[(size_t)t * OUTq]);
    float s = 0.f, ps = 0.f;
    for (int t = 0; t < NPq; t++) {
        float e = expf(gb[(size_t)t * OUTq] - mx);
        s += e;
        ps += yb[(size_t)t * OUTq] * e;
    }
    pooled[b * OUTq + j] = ps / s;
}

// ---------------- final LayerNorm over 1024 per batch ----------------
__global__ __launch_bounds__(256) void k_final_ln(const float* __restrict__ p, const float* __restrict__ g,
                                                  const float* __restrict__ bt, float* __restrict__ out) {
    int row = blockIdx.x;
    const float* x = p + (size_t)row * OUTq;
    float4 v = ((const float4*)x)[threadIdx.x];
    float s = v.x + v.y + v.z + v.w;
    float ss = v.x * v.x + v.y * v.y + v.z * v.z + v.w * v.w;
    #pragma unroll
    for (int off = 32; off >= 1; off >>= 1) { s += __shfl_down(s, off); ss += __shfl_down(ss, off); }
    __shared__ float sh[10];
    int wid = threadIdx.x >> 6, lid = threadIdx.x & 63;
    if (lid == 0) { sh[wid] = s; sh[4 + wid] = ss; }
    __syncthreads();
    if (threadIdx.x == 0) {
        float S = sh[0] + sh[1] + sh[2] + sh[3], SS = sh[4] + sh[5] + sh[6] + sh[7];
        float m = S * (1.f / OUTq);
        float var = SS * (1.f / OUTq) - m * m;
        sh[8] = m; sh[9] = rsqrtf(var + 1e-5f);
    }
    __syncthreads();
    float m = sh[8], rst = sh[9];
    float4 gv = ((const float4*)g)[threadIdx.x];
    float4 bv = ((const float4*)bt)[threadIdx.x];
    float4 o;
    o.x = (v.x - m) * rst * gv.x + bv.x;
    o.y = (v.y - m) * rst * gv.y + bv.y;
    o.z = (v.z - m) * rst * gv.z + bv.z;
    o.w = (v.w - m) * rst * gv.w + bv.w;
    ((float4*)(out + (size_t)row * OUTq))[threadIdx.x] = o;
}

extern "C" void kernel_launch(void* const* d_in, const int* in_sizes, int n_in,
                              void* d_out, int out_size, void* d_ws, size_t ws_size,
                              hipStream_t stream) {
    const float* img   = (const float*)d_in[0];
    const float* sa_w  = (const float*)d_in[1];
    const float* pe_w  = (const float*)d_in[2];
    const float* pe_b  = (const float*)d_in[3];
    const float* pos   = (const float*)d_in[4];
    const float* in_w  = (const float*)d_in[5];
    const float* in_b  = (const float*)d_in[6];
    const float* cv_w  = (const float*)d_in[7];
    const float* cv_b  = (const float*)d_in[8];
    const float* xp_w  = (const float*)d_in[9];
    const float* dt_w  = (const float*)d_in[10];
    const float* dt_b  = (const float*)d_in[11];
    const float* Alog  = (const float*)d_in[12];
    const float* Dv    = (const float*)d_in[13];
    const float* ot_w  = (const float*)d_in[14];
    const float* ot_b  = (const float*)d_in[15];
    const float* em_w  = (const float*)d_in[16];
    const float* em_b  = (const float*)d_in[17];
    const float* em_g  = (const float*)d_in[18];
    const float* em_bt = (const float*)d_in[19];
    const float* at_w  = (const float*)d_in[20];
    const float* at_b  = (const float*)d_in[21];
    const float* at_g  = (const float*)d_in[22];
    const float* at_bt = (const float*)d_in[23];
    const float* la_g  = (const float*)d_in[24];
    const float* la_bt = (const float*)d_in[25];

    char* ws = (char*)d_ws;
    auto al = [](size_t x) { return (x + 255) & ~(size_t)255; };
    size_t SZ_am  = (size_t)NB * 2 * IMP * 4;      // 6.42 MB
    size_t SZ_G   = (size_t)ROWS * 768 * 4;        // 9.63 MB
    size_t SZ_x   = SZ_G;
    size_t SZ_xr  = (size_t)ROWS * 3072 * 4;       // 38.5 MB
    size_t SZ_xi2 = (size_t)ROWS * 1536 * 4;       // 19.3 MB
    size_t SZ_de  = SZ_xi2;
    size_t SZ_dbc = (size_t)ROWS * 80 * 4;         // 1.0 MB
    size_t SZ_ys  = SZ_xi2;
    size_t SZ_yem = (size_t)ROWS * 1024 * 4;       // 12.8 MB

    size_t o_am  = 0;
    size_t o_G   = al(o_am + SZ_am);
    size_t o_x   = al(o_G + SZ_G);
    size_t o_xr  = al(o_x + SZ_x);
    size_t o_xi2 = al(o_xr + SZ_xr);
    size_t o_de  = al(o_xi2 + SZ_xi2);
    size_t o_dbc = al(o_de + SZ_de);
    size_t o_ys  = al(o_dbc + SZ_dbc);
    size_t o_yem = al(o_ys + SZ_ys);
    size_t o_pool = al(o_yem + SZ_yem);

    float* am   = (float*)(ws + o_am);
    float* G    = (float*)(ws + o_G);
    float* x    = (float*)(ws + o_x);
    float* xr   = (float*)(ws + o_xr);
    float* xi2  = (float*)(ws + o_xi2);
    float* de   = (float*)(ws + o_de);
    float* dbc  = (float*)(ws + o_dbc);
    float* ys   = (float*)(ws + o_ys);
    float* yem  = (float*)(ws + o_yem);
    float* pool = (float*)(ws + o_pool);
    // reuse (dead regions): t1 over am∪G (16.0 MB >= 12.8 MB); t2 over xr; g_att over xr+16MB
    float* t1  = (float*)(ws + 0);
    float* t2  = (float*)(ws + o_xr);
    float* gat = (float*)(ws + o_xr + ((size_t)16 << 20));

    int npx = NB * IMP;  // 802816
    k_avgmax<<<(npx + 255) / 256, 256, 0, stream>>>(img, am);
    k_gatepatch<<<(npx + 255) / 256, 256, 0, stream>>>(img, am, sa_w, G);

    dim3 blk(256);
    // patch embed: x = G @ pe_w + pe_b + pos
    k_gemm<EPI_POSEMB><<<dim3(6, 25), blk, 0, stream>>>(G, 768, pe_w, 768, pe_b, x, 768, ROWS, 768, 768, pos);

    for (int l = 0; l < 2; l++) {
        // xr = x @ in_w + in_b   (N=3072)
        k_gemm<EPI_NONE><<<dim3(24, 25), blk, 0, stream>>>(x, 768, in_w + (size_t)l * 768 * 3072, 3072,
                                                           in_b + l * 3072, xr, 3072, ROWS, 3072, 768, nullptr);
        int ne = ROWS * DIq;
        k_conv_silu<<<(ne + 255) / 256, 256, 0, stream>>>(xr, cv_w + (size_t)l * DIq * 4, cv_b + l * DIq, xi2);
        // dbc = xi2 @ xproj_w (no bias), N=80
        k_gemm<EPI_NONE><<<dim3(1, 25), blk, 0, stream>>>(xi2, 1536, xp_w + (size_t)l * 1536 * 80, 80,
                                                          nullptr, dbc, 80, ROWS, 80, 1536, nullptr);
        // delta = softplus(dbc[:, :48] @ dt_w + dt_b), N=1536, K=48
        k_gemm<EPI_SOFTPLUS><<<dim3(12, 25), blk, 0, stream>>>(dbc, 80, dt_w + (size_t)l * 48 * 1536, 1536,
                                                               dt_b + l * 1536, de, 1536, ROWS, 1536, 48, nullptr);
        k_scan<<<dim3(16, 96), blk, 0, stream>>>(de, xi2, dbc, xr, Alog + (size_t)l * 1536 * 16, Dv + l * 1536, ys);
        // x = ys @ out_w + out_b
        k_gemm<EPI_NONE><<<dim3(6, 25), blk, 0, stream>>>(ys, 1536, ot_w + (size_t)l * 1536 * 768, 768,
                                                          ot_b + l * 768, x, 768, ROWS, 768, 1536, nullptr);
    }

    // head
    k_gemm<EPI_NONE><<<dim3(8, 25), blk, 0, stream>>>(x, 768, em_w, 1024, em_b, t1, 1024, ROWS, 1024, 768, nullptr);
    k_ln_gelu<<<ROWS, 256, 0, stream>>>(t1, em_g, em_bt, yem);
    k_gemm<EPI_NONE><<<dim3(8, 25), blk, 0, stream>>>(yem, 1024, at_w, 1024, at_b, t2, 1024, ROWS, 1024, 1024, nullptr);
    k_ln_gelu<<<ROWS, 256, 0, stream>>>(t2, at_g, at_bt, gat);
    k_softpool<<<dim3(4, NB), 256, 0, stream>>>(gat, yem, pool);
    k_final_ln<<<NB, 256, 0, stream>>>(pool, la_g, la_bt, (float*)d_out);
}

// Round 2
// 1679.476 us; speedup vs baseline: 1.4846x; 1.4846x over previous
//
#include <hip/hip_runtime.h>
#include <math.h>

static constexpr int NB = 16;
static constexpr int NC = 3;
static constexpr int IM = 224;
static constexpr int IMP = IM * IM;      // 50176
static constexpr int HPq = 14;
static constexpr int NPq = 196;
static constexpr int OUTq = 1024;
static constexpr int DIq = 1536;
static constexpr int ROWS = NB * NPq;    // 3136

typedef __bf16 bf8_t __attribute__((ext_vector_type(8)));
typedef float f4_t __attribute__((ext_vector_type(4)));
typedef unsigned short us8 __attribute__((ext_vector_type(8)));

__device__ inline unsigned short f2bf(float x) {
    unsigned u = __builtin_bit_cast(unsigned, x);
    unsigned r = (u + 0x7FFFu + ((u >> 16) & 1u)) >> 16;
    return (unsigned short)r;
}

// ---------------- K1a: channel avg/max ----------------
__global__ __launch_bounds__(256) void k_avgmax(const float* __restrict__ img, float* __restrict__ am) {
    int idx = blockIdx.x * 256 + threadIdx.x;
    if (idx >= NB * IMP) return;
    int p = idx % IMP, b = idx / IMP;
    const float* ib = img + (size_t)b * NC * IMP + p;
    float c0 = ib[0], c1 = ib[IMP], c2 = ib[2 * IMP];
    am[(size_t)(b * 2 + 0) * IMP + p] = (c0 + c1 + c2) * (1.f / 3.f);
    am[(size_t)(b * 2 + 1) * IMP + p] = fmaxf(c0, fmaxf(c1, c2));
}

// ---------------- K1b: 7x7 conv gate + patchify ----------------
__global__ __launch_bounds__(256) void k_gatepatch(const float* __restrict__ img, const float* __restrict__ am,
                                                   const float* __restrict__ saw, float* __restrict__ G) {
    int idx = blockIdx.x * 256 + threadIdx.x;
    if (idx >= NB * IMP) return;
    int p = idx % IMP, b = idx / IMP;
    int y = p / IM, x = p % IM;
    float acc = 0.f;
    #pragma unroll
    for (int ci = 0; ci < 2; ci++) {
        const float* amc = am + (size_t)(b * 2 + ci) * IMP;
        const float* wc = saw + ci * 49;
        #pragma unroll
        for (int kh = 0; kh < 7; kh++) {
            int yy = y + kh - 3;
            if (yy < 0 || yy >= IM) continue;
            #pragma unroll
            for (int kw = 0; kw < 7; kw++) {
                int xx = x + kw - 3;
                if (xx < 0 || xx >= IM) continue;
                acc += amc[yy * IM + xx] * wc[kh * 7 + kw];
            }
        }
    }
    float s = 1.f / (1.f + expf(-acc));
    int hy = y >> 4, py = y & 15, hx = x >> 4, px = x & 15;
    size_t base = ((size_t)(b * NPq + hy * HPq + hx) * 768) + (size_t)(py * 16 + px) * 3;
    const float* ib = img + (size_t)b * NC * IMP + p;
    G[base + 0] = ib[0] * s;
    G[base + 1] = ib[IMP] * s;
    G[base + 2] = ib[2 * IMP] * s;
}

// ---------------- weight transpose + f32->bf16: W[K][N] -> Wt[N][K] ----------------
__global__ __launch_bounds__(256) void k_transpose_bf(const float* __restrict__ W, unsigned short* __restrict__ Wt,
                                                      int K, int N) {
    __shared__ float t[32][33];
    int n0 = blockIdx.x * 32, k0 = blockIdx.y * 32;
    int c = threadIdx.x & 31, r8 = threadIdx.x >> 5;
    #pragma unroll
    for (int i = 0; i < 4; i++) {
        int r = r8 + i * 8;
        t[r][c] = W[(size_t)(k0 + r) * N + n0 + c];
    }
    __syncthreads();
    #pragma unroll
    for (int i = 0; i < 4; i++) {
        int r = r8 + i * 8;
        Wt[(size_t)(n0 + r) * K + k0 + c] = f2bf(t[c][r]);
    }
}

// ---------------- bf16 MFMA GEMM: C = A(f32, MxK) @ Wt^T (Wt is bf16 [N][K]) ----------------
enum { EPI_NONE = 0, EPI_POSEMB = 1, EPI_SOFTPLUS = 2 };

template<int EPI>
__global__ __launch_bounds__(256) void k_gemm_bf(const float* __restrict__ A, int lda,
                                                 const unsigned short* __restrict__ Wt,
                                                 const float* __restrict__ bias,
                                                 float* __restrict__ C, int ldc,
                                                 int M, int N, int K,
                                                 const float* __restrict__ extra) {
    __shared__ __align__(16) unsigned short As[128 * 64];
    __shared__ __align__(16) unsigned short Bs[128 * 64];
    const int bm = blockIdx.y * 128, bn = blockIdx.x * 128;
    const int tid = threadIdx.x;
    const int lane = tid & 63, wid = tid >> 6;
    const int wr = (wid >> 1) * 64, wc = (wid & 1) * 64;
    const int lr = lane & 15, lq = lane >> 4;

    f4_t acc[4][4] = {};

    for (int k0 = 0; k0 < K; k0 += 64) {
        #pragma unroll
        for (int i = 0; i < 4; i++) {
            int gid = tid + i * 256;          // 0..1023
            int r = gid >> 3, g = gid & 7;    // row 0..127, 8-elem group 0..7
            int soff = r * 64 + ((g ^ (r & 7)) * 8);
            us8 av = {};
            if (bm + r < M) {
                const float* ap = A + (size_t)(bm + r) * lda + k0 + g * 8;
                float4 f0 = *(const float4*)ap;
                float4 f1 = *(const float4*)(ap + 4);
                av[0] = f2bf(f0.x); av[1] = f2bf(f0.y); av[2] = f2bf(f0.z); av[3] = f2bf(f0.w);
                av[4] = f2bf(f1.x); av[5] = f2bf(f1.y); av[6] = f2bf(f1.z); av[7] = f2bf(f1.w);
            }
            *(us8*)&As[soff] = av;
            const unsigned short* bp = Wt + (size_t)(bn + r) * K + k0 + g * 8;
            *(us8*)&Bs[soff] = *(const us8*)bp;
        }
        __syncthreads();
        #pragma unroll
        for (int h = 0; h < 2; h++) {
            bf8_t af[4], bfr[4];
            #pragma unroll
            for (int mb = 0; mb < 4; mb++) {
                int row = wr + mb * 16 + lr;
                int g = h * 4 + lq;
                af[mb] = *(const bf8_t*)&As[row * 64 + ((g ^ (row & 7)) * 8)];
                int rn = wc + mb * 16 + lr;
                bfr[mb] = *(const bf8_t*)&Bs[rn * 64 + ((g ^ (rn & 7)) * 8)];
            }
            #pragma unroll
            for (int mb = 0; mb < 4; mb++)
                #pragma unroll
                for (int nb = 0; nb < 4; nb++)
                    acc[mb][nb] = __builtin_amdgcn_mfma_f32_16x16x32_bf16(af[mb], bfr[nb], acc[mb][nb], 0, 0, 0);
        }
        __syncthreads();
    }

    #pragma unroll
    for (int mb = 0; mb < 4; mb++) {
        #pragma unroll
        for (int nb = 0; nb < 4; nb++) {
            int col = bn + wc + nb * 16 + lr;
            #pragma unroll
            for (int q = 0; q < 4; q++) {
                int row = bm + wr + mb * 16 + lq * 4 + q;
                if (row < M) {
                    float v = acc[mb][nb][q];
                    if (bias) v += bias[col];
                    if (EPI == EPI_POSEMB) v += extra[(size_t)(row % NPq) * N + col];
                    C[(size_t)row * ldc + col] = v;
                }
            }
        }
    }
}

// ---------------- f32 GEMM (small/odd shapes): C = A(MxK) @ W(KxN) + bias ----------------
template<int EPI>
__global__ __launch_bounds__(256) void k_gemm(const float* __restrict__ A, int lda,
                                              const float* __restrict__ W, int ldw,
                                              const float* __restrict__ bias,
                                              float* __restrict__ C, int ldc,
                                              int M, int N, int K,
                                              const float* __restrict__ extra) {
    __shared__ __align__(16) float As[8][128];
    __shared__ __align__(16) float Bs[8][128];
    const int bm = blockIdx.y * 128, bn = blockIdx.x * 128;
    const int tid = threadIdx.x;
    const int ty = tid >> 4, tx = tid & 15;
    const int arow = tid >> 1, akk = (tid & 1) * 4;
    const int brow = tid >> 5, bcol = (tid & 31) * 4;
    float acc[8][8];
    #pragma unroll
    for (int i = 0; i < 8; i++)
        #pragma unroll
        for (int j = 0; j < 8; j++) acc[i][j] = 0.f;

    const int gr = bm + arow;
    const bool aok = gr < M;
    const int gn = bn + bcol;
    const bool bok = gn < N;

    for (int k0 = 0; k0 < K; k0 += 8) {
        float4 av = make_float4(0.f, 0.f, 0.f, 0.f);
        if (aok && k0 + akk < K) av = *(const float4*)(A + (size_t)gr * lda + (k0 + akk));
        As[akk + 0][arow] = av.x; As[akk + 1][arow] = av.y;
        As[akk + 2][arow] = av.z; As[akk + 3][arow] = av.w;
        float4 bv = make_float4(0.f, 0.f, 0.f, 0.f);
        if (bok && k0 + brow < K) bv = *(const float4*)(W + (size_t)(k0 + brow) * ldw + gn);
        *(float4*)&Bs[brow][bcol] = bv;
        __syncthreads();
        #pragma unroll
        for (int kk = 0; kk < 8; kk++) {
            float4 a0 = *(const float4*)&As[kk][ty * 4];
            float4 a1 = *(const float4*)&As[kk][64 + ty * 4];
            float4 b0 = *(const float4*)&Bs[kk][tx * 4];
            float4 b1 = *(const float4*)&Bs[kk][64 + tx * 4];
            float a[8] = {a0.x, a0.y, a0.z, a0.w, a1.x, a1.y, a1.z, a1.w};
            float b[8] = {b0.x, b0.y, b0.z, b0.w, b1.x, b1.y, b1.z, b1.w};
            #pragma unroll
            for (int i = 0; i < 8; i++)
                #pragma unroll
                for (int j = 0; j < 8; j++)
                    acc[i][j] = fmaf(a[i], b[j], acc[i][j]);
        }
        __syncthreads();
    }

    #pragma unroll
    for (int i = 0; i < 8; i++) {
        int r = bm + ((i < 4) ? (ty * 4 + i) : (64 + ty * 4 + i - 4));
        if (r >= M) continue;
        #pragma unroll
        for (int j = 0; j < 8; j++) {
            int c = bn + ((j < 4) ? (tx * 4 + j) : (64 + tx * 4 + j - 4));
            if (c >= N) continue;
            float v = acc[i][j];
            if (bias) v += bias[c];
            if (EPI == EPI_POSEMB) v += extra[(size_t)(r % NPq) * N + c];
            if (EPI == EPI_SOFTPLUS) v = (v > 20.f) ? v : log1pf(expf(v));
            C[(size_t)r * ldc + c] = v;
        }
    }
}

// ---------------- causal depthwise conv (DC=4) + silu ----------------
__global__ __launch_bounds__(256) void k_conv_silu(const float* __restrict__ xr, const float* __restrict__ cw,
                                                   const float* __restrict__ cb, float* __restrict__ xi2) {
    int idx = blockIdx.x * 256 + threadIdx.x;
    if (idx >= ROWS * DIq) return;
    int d = idx % DIq; int bt = idx / DIq; int t = bt % NPq; int b = bt / NPq;
    float w0 = cw[d * 4 + 0], w1 = cw[d * 4 + 1], w2 = cw[d * 4 + 2], w3 = cw[d * 4 + 3];
    float s = cb[d];
    const float* base = xr + (size_t)b * NPq * 3072 + d;
    if (t >= 3) s += base[(size_t)(t - 3) * 3072] * w0;
    if (t >= 2) s += base[(size_t)(t - 2) * 3072] * w1;
    if (t >= 1) s += base[(size_t)(t - 1) * 3072] * w2;
    s += base[(size_t)t * 3072] * w3;
    xi2[idx] = s / (1.f + expf(-s));
}

// ---------------- selective-scan: lane = (d, n), 196 sequential steps ----------------
__global__ __launch_bounds__(256) void k_scan(const float* __restrict__ delta, const float* __restrict__ xi2,
                                              const float* __restrict__ dbc, const float* __restrict__ xr,
                                              const float* __restrict__ Alog, const float* __restrict__ Dv,
                                              float* __restrict__ ys) {
    int b = blockIdx.x;
    int d = blockIdx.y * 16 + (threadIdx.x >> 4);
    int n = threadIdx.x & 15;
    float A = -expf(Alog[d * 16 + n]);
    float Dd = Dv[d];
    float h = 0.f;
    for (int t = 0; t < NPq; t++) {
        size_t bt = (size_t)b * NPq + t;
        float de = delta[bt * DIq + d];
        float u  = xi2[bt * DIq + d];
        float Bn = dbc[bt * 80 + 48 + n];
        float Cn = dbc[bt * 80 + 64 + n];
        h = expf(de * A) * h + de * Bn * u;
        float p = h * Cn;
        p += __shfl_xor(p, 1);
        p += __shfl_xor(p, 2);
        p += __shfl_xor(p, 4);
        p += __shfl_xor(p, 8);
        if (n == 0) {
            float r = xr[bt * 3072 + DIq + d];
            ys[bt * DIq + d] = (p + Dd * u) * (r / (1.f + expf(-r)));
        }
    }
}

// ---------------- row LayerNorm (1024) + exact gelu ----------------
__global__ __launch_bounds__(256) void k_ln_gelu(const float* __restrict__ in, const float* __restrict__ g,
                                                 const float* __restrict__ bt, float* __restrict__ out) {
    int row = blockIdx.x;
    const float* x = in + (size_t)row * OUTq;
    float4 v = ((const float4*)x)[threadIdx.x];
    float s = v.x + v.y + v.z + v.w;
    float ss = v.x * v.x + v.y * v.y + v.z * v.z + v.w * v.w;
    #pragma unroll
    for (int off = 32; off >= 1; off >>= 1) { s += __shfl_down(s, off); ss += __shfl_down(ss, off); }
    __shared__ float sh[10];
    int wid = threadIdx.x >> 6, lid = threadIdx.x & 63;
    if (lid == 0) { sh[wid] = s; sh[4 + wid] = ss; }
    __syncthreads();
    if (threadIdx.x == 0) {
        float S = sh[0] + sh[1] + sh[2] + sh[3], SS = sh[4] + sh[5] + sh[6] + sh[7];
        float m = S * (1.f / OUTq);
        float var = SS * (1.f / OUTq) - m * m;
        sh[8] = m; sh[9] = rsqrtf(var + 1e-5f);
    }
    __syncthreads();
    float m = sh[8], rst = sh[9];
    float4 gv = ((const float4*)g)[threadIdx.x];
    float4 bv = ((const float4*)bt)[threadIdx.x];
    float4 o;
    float y0 = (v.x - m) * rst * gv.x + bv.x; o.x = 0.5f * y0 * (1.f + erff(y0 * 0.70710678118f));
    float y1 = (v.y - m) * rst * gv.y + bv.y; o.y = 0.5f * y1 * (1.f + erff(y1 * 0.70710678118f));
    float y2 = (v.z - m) * rst * gv.z + bv.z; o.z = 0.5f * y2 * (1.f + erff(y2 * 0.70710678118f));
    float y3 = (v.w - m) * rst * gv.w + bv.w; o.w = 0.5f * y3 * (1.f + erff(y3 * 0.70710678118f));
    ((float4*)(out + (size_t)row * OUTq))[threadIdx.x] = o;
}

// ---------------- column softmax (over t) + weighted pool ----------------
__global__ __launch_bounds__(256) void k_softpool(const float* __restrict__ gm, const float* __restrict__ ym,
                                                  float* __restrict__ pooled) {
    int b = blockIdx.y;
    int j = blockIdx.x * 256 + threadIdx.x;
    const float* gb = gm + (size_t)b * NPq * OUTq + j;
    const float* yb = ym + (size_t)b * NPq * OUTq + j;
    float mx = -1e30f;
    for (int t = 0; t < NPq; t++) mx = fmaxf(mx, gb[(size_t)t * OUTq]);
    float s = 0.f, ps = 0.f;
    for (int t = 0; t < NPq; t++) {
        float e = expf(gb[(size_t)t * OUTq] - mx);
        s += e;
        ps += yb[(size_t)t * OUTq] * e;
    }
    pooled[b * OUTq + j] = ps / s;
}

// ---------------- final LayerNorm over 1024 per batch ----------------
__global__ __launch_bounds__(256) void k_final_ln(const float* __restrict__ p, const float* __restrict__ g,
                                                  const float* __restrict__ bt, float* __restrict__ out) {
    int row = blockIdx.x;
    const float* x = p + (size_t)row * OUTq;
    float4 v = ((const float4*)x)[threadIdx.x];
    float s = v.x + v.y + v.z + v.w;
    float ss = v.x * v.x + v.y * v.y + v.z * v.z + v.w * v.w;
    #pragma unroll
    for (int off = 32; off >= 1; off >>= 1) { s += __shfl_down(s, off); ss += __shfl_down(ss, off); }
    __shared__ float sh[10];
    int wid = threadIdx.x >> 6, lid = threadIdx.x & 63;
    if (lid == 0) { sh[wid] = s; sh[4 + wid] = ss; }
    __syncthreads();
    if (threadIdx.x == 0) {
        float S = sh[0] + sh[1] + sh[2] + sh[3], SS = sh[4] + sh[5] + sh[6] + sh[7];
        float m = S * (1.f / OUTq);
        float var = SS * (1.f / OUTq) - m * m;
        sh[8] = m; sh[9] = rsqrtf(var + 1e-5f);
    }
    __syncthreads();
    float m = sh[8], rst = sh[9];
    float4 gv = ((const float4*)g)[threadIdx.x];
    float4 bv = ((const float4*)bt)[threadIdx.x];
    float4 o;
    o.x = (v.x - m) * rst * gv.x + bv.x;
    o.y = (v.y - m) * rst * gv.y + bv.y;
    o.z = (v.z - m) * rst * gv.z + bv.z;
    o.w = (v.w - m) * rst * gv.w + bv.w;
    ((float4*)(out + (size_t)row * OUTq))[threadIdx.x] = o;
}

extern "C" void kernel_launch(void* const* d_in, const int* in_sizes, int n_in,
                              void* d_out, int out_size, void* d_ws, size_t ws_size,
                              hipStream_t stream) {
    const float* img   = (const float*)d_in[0];
    const float* sa_w  = (const float*)d_in[1];
    const float* pe_w  = (const float*)d_in[2];
    const float* pe_b  = (const float*)d_in[3];
    const float* pos   = (const float*)d_in[4];
    const float* in_w  = (const float*)d_in[5];
    const float* in_b  = (const float*)d_in[6];
    const float* cv_w  = (const float*)d_in[7];
    const float* cv_b  = (const float*)d_in[8];
    const float* xp_w  = (const float*)d_in[9];
    const float* dt_w  = (const float*)d_in[10];
    const float* dt_b  = (const float*)d_in[11];
    const float* Alog  = (const float*)d_in[12];
    const float* Dv    = (const float*)d_in[13];
    const float* ot_w  = (const float*)d_in[14];
    const float* ot_b  = (const float*)d_in[15];
    const float* em_w  = (const float*)d_in[16];
    const float* em_b  = (const float*)d_in[17];
    const float* em_g  = (const float*)d_in[18];
    const float* em_bt = (const float*)d_in[19];
    const float* at_w  = (const float*)d_in[20];
    const float* at_b  = (const float*)d_in[21];
    const float* at_g  = (const float*)d_in[22];
    const float* at_bt = (const float*)d_in[23];
    const float* la_g  = (const float*)d_in[24];
    const float* la_bt = (const float*)d_in[25];

    char* ws = (char*)d_ws;
    auto al = [](size_t x) { return (x + 255) & ~(size_t)255; };
    size_t SZ_am  = (size_t)NB * 2 * IMP * 4;
    size_t SZ_G   = (size_t)ROWS * 768 * 4;
    size_t SZ_x   = SZ_G;
    size_t SZ_xr  = (size_t)ROWS * 3072 * 4;
    size_t SZ_xi2 = (size_t)ROWS * 1536 * 4;
    size_t SZ_de  = SZ_xi2;
    size_t SZ_dbc = (size_t)ROWS * 80 * 4;
    size_t SZ_ys  = SZ_xi2;
    size_t SZ_yem = (size_t)ROWS * 1024 * 4;
    size_t SZ_pool = (size_t)NB * OUTq * 4;

    size_t o_am  = 0;
    size_t o_G   = al(o_am + SZ_am);
    size_t o_x   = al(o_G + SZ_G);
    size_t o_xr  = al(o_x + SZ_x);
    size_t o_xi2 = al(o_xr + SZ_xr);
    size_t o_de  = al(o_xi2 + SZ_xi2);
    size_t o_dbc = al(o_de + SZ_de);
    size_t o_ys  = al(o_dbc + SZ_dbc);
    size_t o_yem = al(o_ys + SZ_ys);
    size_t o_pool = al(o_yem + SZ_yem);

    // bf16 transposed weights (persist whole launch) at tail
    size_t o_wpe  = al(o_pool + SZ_pool);
    size_t o_win0 = al(o_wpe  + (size_t)768 * 768 * 2);
    size_t o_win1 = al(o_win0 + (size_t)3072 * 768 * 2);
    size_t o_wot0 = al(o_win1 + (size_t)3072 * 768 * 2);
    size_t o_wot1 = al(o_wot0 + (size_t)768 * 1536 * 2);
    size_t o_wem  = al(o_wot1 + (size_t)768 * 1536 * 2);
    size_t o_wat  = al(o_wem  + (size_t)1024 * 768 * 2);

    float* am   = (float*)(ws + o_am);
    float* G    = (float*)(ws + o_G);
    float* x    = (float*)(ws + o_x);
    float* xr   = (float*)(ws + o_xr);
    float* xi2  = (float*)(ws + o_xi2);
    float* de   = (float*)(ws + o_de);
    float* dbc  = (float*)(ws + o_dbc);
    float* ys   = (float*)(ws + o_ys);
    float* yem  = (float*)(ws + o_yem);
    float* pool = (float*)(ws + o_pool);
    unsigned short* wpe  = (unsigned short*)(ws + o_wpe);
    unsigned short* win0 = (unsigned short*)(ws + o_win0);
    unsigned short* win1 = (unsigned short*)(ws + o_win1);
    unsigned short* wot0 = (unsigned short*)(ws + o_wot0);
    unsigned short* wot1 = (unsigned short*)(ws + o_wot1);
    unsigned short* wem  = (unsigned short*)(ws + o_wem);
    unsigned short* wat  = (unsigned short*)(ws + o_wat);
    // reuse (dead regions): t1 over am∪G; t2 over xr; gat over xr+16MB
    float* t1  = (float*)(ws + 0);
    float* t2  = (float*)(ws + o_xr);
    float* gat = (float*)(ws + o_xr + ((size_t)16 << 20));

    // ---- weight conversion (W[K][N] -> bf16 [N][K]) ----
    k_transpose_bf<<<dim3(768 / 32, 768 / 32), 256, 0, stream>>>(pe_w, wpe, 768, 768);
    k_transpose_bf<<<dim3(3072 / 32, 768 / 32), 256, 0, stream>>>(in_w, win0, 768, 3072);
    k_transpose_bf<<<dim3(3072 / 32, 768 / 32), 256, 0, stream>>>(in_w + (size_t)768 * 3072, win1, 768, 3072);
    k_transpose_bf<<<dim3(768 / 32, 1536 / 32), 256, 0, stream>>>(ot_w, wot0, 1536, 768);
    k_transpose_bf<<<dim3(768 / 32, 1536 / 32), 256, 0, stream>>>(ot_w + (size_t)1536 * 768, wot1, 1536, 768);
    k_transpose_bf<<<dim3(1024 / 32, 768 / 32), 256, 0, stream>>>(em_w, wem, 768, 1024);
    k_transpose_bf<<<dim3(1024 / 32, 1024 / 32), 256, 0, stream>>>(at_w, wat, 1024, 1024);

    int npx = NB * IMP;
    k_avgmax<<<(npx + 255) / 256, 256, 0, stream>>>(img, am);
    k_gatepatch<<<(npx + 255) / 256, 256, 0, stream>>>(img, am, sa_w, G);

    dim3 blk(256);
    // patch embed: x = G @ pe_w + pe_b + pos
    k_gemm_bf<EPI_POSEMB><<<dim3(6, 25), blk, 0, stream>>>(G, 768, wpe, pe_b, x, 768, ROWS, 768, 768, pos);

    for (int l = 0; l < 2; l++) {
        const unsigned short* win = l ? win1 : win0;
        const unsigned short* wot = l ? wot1 : wot0;
        // xr = x @ in_w + in_b
        k_gemm_bf<EPI_NONE><<<dim3(24, 25), blk, 0, stream>>>(x, 768, win, in_b + l * 3072, xr, 3072,
                                                              ROWS, 3072, 768, nullptr);
        int ne = ROWS * DIq;
        k_conv_silu<<<(ne + 255) / 256, 256, 0, stream>>>(xr, cv_w + (size_t)l * DIq * 4, cv_b + l * DIq, xi2);
        // dbc = xi2 @ xproj_w (f32, N=80)
        k_gemm<EPI_NONE><<<dim3(1, 25), blk, 0, stream>>>(xi2, 1536, xp_w + (size_t)l * 1536 * 80, 80,
                                                          nullptr, dbc, 80, ROWS, 80, 1536, nullptr);
        // delta = softplus(dbc[:, :48] @ dt_w + dt_b) (f32, K=48)
        k_gemm<EPI_SOFTPLUS><<<dim3(12, 25), blk, 0, stream>>>(dbc, 80, dt_w + (size_t)l * 48 * 1536, 1536,
                                                               dt_b + l * 1536, de, 1536, ROWS, 1536, 48, nullptr);
        k_scan<<<dim3(16, 96), blk, 0, stream>>>(de, xi2, dbc, xr, Alog + (size_t)l * 1536 * 16, Dv + l * 1536, ys);
        // x = ys @ out_w + out_b
        k_gemm_bf<EPI_NONE><<<dim3(6, 25), blk, 0, stream>>>(ys, 1536, wot, ot_b + l * 768, x, 768,
                                                             ROWS, 768, 1536, nullptr);
    }

    // head
    k_gemm_bf<EPI_NONE><<<dim3(8, 25), blk, 0, stream>>>(x, 768, wem, em_b, t1, 1024, ROWS, 1024, 768, nullptr);
    k_ln_gelu<<<ROWS, 256, 0, stream>>>(t1, em_g, em_bt, yem);
    k_gemm_bf<EPI_NONE><<<dim3(8, 25), blk, 0, stream>>>(yem, 1024, wat, at_b, t2, 1024, ROWS, 1024, 1024, nullptr);
    k_ln_gelu<<<ROWS, 256, 0, stream>>>(t2, at_g, at_bt, gat);
    k_softpool<<<dim3(4, NB), 256, 0, stream>>>(gat, yem, pool);
    k_final_ln<<<NB, 256, 0, stream>>>(pool, la_g, la_bt, (float*)d_out);
}

// Round 3
// 1095.356 us; speedup vs baseline: 2.2763x; 1.5333x over previous
//
#include <hip/hip_runtime.h>
#include <math.h>

static constexpr int NB = 16;
static constexpr int NC = 3;
static constexpr int IM = 224;
static constexpr int IMP = IM * IM;      // 50176
static constexpr int HPq = 14;
static constexpr int NPq = 196;
static constexpr int OUTq = 1024;
static constexpr int DIq = 1536;
static constexpr int ROWS = NB * NPq;    // 3136

typedef __bf16 bf8_t __attribute__((ext_vector_type(8)));
typedef float f4_t __attribute__((ext_vector_type(4)));
typedef unsigned short us8 __attribute__((ext_vector_type(8)));

__device__ inline unsigned short f2bf(float x) {
    unsigned u = __builtin_bit_cast(unsigned, x);
    unsigned r = (u + 0x7FFFu + ((u >> 16) & 1u)) >> 16;
    return (unsigned short)r;
}

// ---------------- K1a: channel avg/max ----------------
__global__ __launch_bounds__(256) void k_avgmax(const float* __restrict__ img, float* __restrict__ am) {
    int idx = blockIdx.x * 256 + threadIdx.x;
    if (idx >= NB * IMP) return;
    int p = idx % IMP, b = idx / IMP;
    const float* ib = img + (size_t)b * NC * IMP + p;
    float c0 = ib[0], c1 = ib[IMP], c2 = ib[2 * IMP];
    am[(size_t)(b * 2 + 0) * IMP + p] = (c0 + c1 + c2) * (1.f / 3.f);
    am[(size_t)(b * 2 + 1) * IMP + p] = fmaxf(c0, fmaxf(c1, c2));
}

// ---------------- K1b: 7x7 conv gate + patchify ----------------
__global__ __launch_bounds__(256) void k_gatepatch(const float* __restrict__ img, const float* __restrict__ am,
                                                   const float* __restrict__ saw, float* __restrict__ G) {
    int idx = blockIdx.x * 256 + threadIdx.x;
    if (idx >= NB * IMP) return;
    int p = idx % IMP, b = idx / IMP;
    int y = p / IM, x = p % IM;
    float acc = 0.f;
    #pragma unroll
    for (int ci = 0; ci < 2; ci++) {
        const float* amc = am + (size_t)(b * 2 + ci) * IMP;
        const float* wc = saw + ci * 49;
        #pragma unroll
        for (int kh = 0; kh < 7; kh++) {
            int yy = y + kh - 3;
            if (yy < 0 || yy >= IM) continue;
            #pragma unroll
            for (int kw = 0; kw < 7; kw++) {
                int xx = x + kw - 3;
                if (xx < 0 || xx >= IM) continue;
                acc += amc[yy * IM + xx] * wc[kh * 7 + kw];
            }
        }
    }
    float s = 1.f / (1.f + expf(-acc));
    int hy = y >> 4, py = y & 15, hx = x >> 4, px = x & 15;
    size_t base = ((size_t)(b * NPq + hy * HPq + hx) * 768) + (size_t)(py * 16 + px) * 3;
    const float* ib = img + (size_t)b * NC * IMP + p;
    G[base + 0] = ib[0] * s;
    G[base + 1] = ib[IMP] * s;
    G[base + 2] = ib[2 * IMP] * s;
}

// ---------------- weight transpose + f32->bf16: W[K][N] -> Wt[N][K] ----------------
__global__ __launch_bounds__(256) void k_transpose_bf(const float* __restrict__ W, unsigned short* __restrict__ Wt,
                                                      int K, int N) {
    __shared__ float t[32][33];
    int n0 = blockIdx.x * 32, k0 = blockIdx.y * 32;
    int c = threadIdx.x & 31, r8 = threadIdx.x >> 5;
    #pragma unroll
    for (int i = 0; i < 4; i++) {
        int r = r8 + i * 8;
        t[r][c] = W[(size_t)(k0 + r) * N + n0 + c];
    }
    __syncthreads();
    #pragma unroll
    for (int i = 0; i < 4; i++) {
        int r = r8 + i * 8;
        Wt[(size_t)(n0 + r) * K + k0 + c] = f2bf(t[c][r]);
    }
}

// ---------------- bf16 MFMA GEMM: C = A(f32, MxK) @ Wt^T (Wt is bf16 [N][K]) ----------------
enum { EPI_NONE = 0, EPI_POSEMB = 1 };

template<int EPI>
__global__ __launch_bounds__(256) void k_gemm_bf(const float* __restrict__ A, int lda,
                                                 const unsigned short* __restrict__ Wt,
                                                 const float* __restrict__ bias,
                                                 float* __restrict__ C, int ldc,
                                                 int M, int N, int K,
                                                 const float* __restrict__ extra) {
    __shared__ __align__(16) unsigned short As[128 * 64];
    __shared__ __align__(16) unsigned short Bs[128 * 64];
    const int bm = blockIdx.y * 128, bn = blockIdx.x * 128;
    const int tid = threadIdx.x;
    const int lane = tid & 63, wid = tid >> 6;
    const int wr = (wid >> 1) * 64, wc = (wid & 1) * 64;
    const int lr = lane & 15, lq = lane >> 4;

    f4_t acc[4][4] = {};

    for (int k0 = 0; k0 < K; k0 += 64) {
        #pragma unroll
        for (int i = 0; i < 4; i++) {
            int gid = tid + i * 256;          // 0..1023
            int r = gid >> 3, g = gid & 7;    // row 0..127, 8-elem group 0..7
            int soff = r * 64 + ((g ^ (r & 7)) * 8);
            us8 av = {};
            if (bm + r < M) {
                const float* ap = A + (size_t)(bm + r) * lda + k0 + g * 8;
                float4 f0 = *(const float4*)ap;
                float4 f1 = *(const float4*)(ap + 4);
                av[0] = f2bf(f0.x); av[1] = f2bf(f0.y); av[2] = f2bf(f0.z); av[3] = f2bf(f0.w);
                av[4] = f2bf(f1.x); av[5] = f2bf(f1.y); av[6] = f2bf(f1.z); av[7] = f2bf(f1.w);
            }
            *(us8*)&As[soff] = av;
            const unsigned short* bp = Wt + (size_t)(bn + r) * K + k0 + g * 8;
            *(us8*)&Bs[soff] = *(const us8*)bp;
        }
        __syncthreads();
        #pragma unroll
        for (int h = 0; h < 2; h++) {
            bf8_t af[4], bfr[4];
            #pragma unroll
            for (int mb = 0; mb < 4; mb++) {
                int row = wr + mb * 16 + lr;
                int g = h * 4 + lq;
                af[mb] = *(const bf8_t*)&As[row * 64 + ((g ^ (row & 7)) * 8)];
                int rn = wc + mb * 16 + lr;
                bfr[mb] = *(const bf8_t*)&Bs[rn * 64 + ((g ^ (rn & 7)) * 8)];
            }
            #pragma unroll
            for (int mb = 0; mb < 4; mb++)
                #pragma unroll
                for (int nb = 0; nb < 4; nb++)
                    acc[mb][nb] = __builtin_amdgcn_mfma_f32_16x16x32_bf16(af[mb], bfr[nb], acc[mb][nb], 0, 0, 0);
        }
        __syncthreads();
    }

    #pragma unroll
    for (int mb = 0; mb < 4; mb++) {
        #pragma unroll
        for (int nb = 0; nb < 4; nb++) {
            int col = bn + wc + nb * 16 + lr;
            #pragma unroll
            for (int q = 0; q < 4; q++) {
                int row = bm + wr + mb * 16 + lq * 4 + q;
                if (row < M) {
                    float v = acc[mb][nb][q];
                    if (bias) v += bias[col];
                    if (EPI == EPI_POSEMB) v += extra[(size_t)(row % NPq) * N + col];
                    C[(size_t)row * ldc + col] = v;
                }
            }
        }
    }
}

// ---------------- xproj split-K f32 GEMM: part[kc] = xi2[:, kc] @ W[kc, :80] ----------------
static constexpr int XP_KS = 4;
static constexpr int XP_KC = 1536 / XP_KS;   // 384

__global__ __launch_bounds__(256) void k_xproj_part(const float* __restrict__ xi2, const float* __restrict__ W,
                                                    float* __restrict__ part) {
    __shared__ float As[32][65];
    __shared__ __align__(16) float Bs[64][80];
    int m0 = blockIdx.x * 32;
    int kc0 = blockIdx.y * XP_KC;
    int tid = threadIdx.x;
    int row = tid >> 3, cg = (tid & 7) * 10;
    float acc[10] = {};
    for (int k0 = 0; k0 < XP_KC; k0 += 64) {
        #pragma unroll
        for (int i = 0; i < 2; i++) {
            int id = tid + i * 256;           // 0..511
            int r = id >> 4, c4 = (id & 15) * 4;
            float4 v = *(const float4*)(xi2 + (size_t)(m0 + r) * 1536 + kc0 + k0 + c4);
            As[r][c4] = v.x; As[r][c4 + 1] = v.y; As[r][c4 + 2] = v.z; As[r][c4 + 3] = v.w;
        }
        #pragma unroll
        for (int i = 0; i < 5; i++) {
            int id = tid + i * 256;           // 0..1279
            int r = id / 20, c4 = (id % 20) * 4;
            *(float4*)&Bs[r][c4] = *(const float4*)(W + (size_t)(kc0 + k0 + r) * 80 + c4);
        }
        __syncthreads();
        #pragma unroll
        for (int kk = 0; kk < 64; kk++) {
            float a = As[row][kk];
            #pragma unroll
            for (int j = 0; j < 10; j++)
                acc[j] = fmaf(a, Bs[kk][cg + j], acc[j]);
        }
        __syncthreads();
    }
    float* p = part + ((size_t)blockIdx.y * ROWS + m0 + row) * 80 + cg;
    #pragma unroll
    for (int j = 0; j < 10; j++) p[j] = acc[j];
}

__global__ __launch_bounds__(256) void k_xreduce(const float* __restrict__ part, float* __restrict__ dbc) {
    int idx = (blockIdx.x * 256 + threadIdx.x) * 4;
    if (idx >= ROWS * 80) return;
    const int S = ROWS * 80;
    float4 a = *(const float4*)(part + idx);
    float4 b = *(const float4*)(part + S + idx);
    float4 c = *(const float4*)(part + 2 * S + idx);
    float4 d = *(const float4*)(part + 3 * S + idx);
    float4 o;
    o.x = a.x + b.x + c.x + d.x;
    o.y = a.y + b.y + c.y + d.y;
    o.z = a.z + b.z + c.z + d.z;
    o.w = a.w + b.w + c.w + d.w;
    *(float4*)(dbc + idx) = o;
}

// ---------------- dt GEMM (K=48) + softplus: de = softplus(dbc[:, :48] @ dt_w + dt_b) ----------------
static constexpr int DT_RPB = 4;
__global__ __launch_bounds__(384) void k_dt(const float* __restrict__ dbc, const float* __restrict__ W,
                                            const float* __restrict__ bias, float* __restrict__ de) {
    int r0 = blockIdx.x * DT_RPB;
    int j = threadIdx.x * 4;
    __shared__ float ds[DT_RPB][48];
    if (threadIdx.x < DT_RPB * 48)
        ds[threadIdx.x / 48][threadIdx.x % 48] = dbc[(size_t)(r0 + threadIdx.x / 48) * 80 + threadIdx.x % 48];
    __syncthreads();
    float4 b = *(const float4*)(bias + j);
    float4 a0 = b, a1 = b, a2 = b, a3 = b;
    for (int k = 0; k < 48; k++) {
        float4 w = *(const float4*)(W + (size_t)k * 1536 + j);
        float d0 = ds[0][k], d1 = ds[1][k], d2 = ds[2][k], d3 = ds[3][k];
        a0.x = fmaf(d0, w.x, a0.x); a0.y = fmaf(d0, w.y, a0.y); a0.z = fmaf(d0, w.z, a0.z); a0.w = fmaf(d0, w.w, a0.w);
        a1.x = fmaf(d1, w.x, a1.x); a1.y = fmaf(d1, w.y, a1.y); a1.z = fmaf(d1, w.z, a1.z); a1.w = fmaf(d1, w.w, a1.w);
        a2.x = fmaf(d2, w.x, a2.x); a2.y = fmaf(d2, w.y, a2.y); a2.z = fmaf(d2, w.z, a2.z); a2.w = fmaf(d2, w.w, a2.w);
        a3.x = fmaf(d3, w.x, a3.x); a3.y = fmaf(d3, w.y, a3.y); a3.z = fmaf(d3, w.z, a3.z); a3.w = fmaf(d3, w.w, a3.w);
    }
    auto sp = [](float v) { return (v > 20.f) ? v : log1pf(expf(v)); };
    float4 o;
    o.x = sp(a0.x); o.y = sp(a0.y); o.z = sp(a0.z); o.w = sp(a0.w);
    *(float4*)(de + (size_t)(r0 + 0) * 1536 + j) = o;
    o.x = sp(a1.x); o.y = sp(a1.y); o.z = sp(a1.z); o.w = sp(a1.w);
    *(float4*)(de + (size_t)(r0 + 1) * 1536 + j) = o;
    o.x = sp(a2.x); o.y = sp(a2.y); o.z = sp(a2.z); o.w = sp(a2.w);
    *(float4*)(de + (size_t)(r0 + 2) * 1536 + j) = o;
    o.x = sp(a3.x); o.y = sp(a3.y); o.z = sp(a3.z); o.w = sp(a3.w);
    *(float4*)(de + (size_t)(r0 + 3) * 1536 + j) = o;
}

// ---------------- causal depthwise conv (DC=4) + silu ----------------
__global__ __launch_bounds__(256) void k_conv_silu(const float* __restrict__ xr, const float* __restrict__ cw,
                                                   const float* __restrict__ cb, float* __restrict__ xi2) {
    int idx = blockIdx.x * 256 + threadIdx.x;
    if (idx >= ROWS * DIq) return;
    int d = idx % DIq; int bt = idx / DIq; int t = bt % NPq; int b = bt / NPq;
    float w0 = cw[d * 4 + 0], w1 = cw[d * 4 + 1], w2 = cw[d * 4 + 2], w3 = cw[d * 4 + 3];
    float s = cb[d];
    const float* base = xr + (size_t)b * NPq * 3072 + d;
    if (t >= 3) s += base[(size_t)(t - 3) * 3072] * w0;
    if (t >= 2) s += base[(size_t)(t - 2) * 3072] * w1;
    if (t >= 1) s += base[(size_t)(t - 1) * 3072] * w2;
    s += base[(size_t)t * 3072] * w3;
    xi2[idx] = s / (1.f + expf(-s));
}

// ---------------- selective-scan: lane = (d, n), 196 sequential steps ----------------
__global__ __launch_bounds__(256) void k_scan(const float* __restrict__ delta, const float* __restrict__ xi2,
                                              const float* __restrict__ dbc, const float* __restrict__ xr,
                                              const float* __restrict__ Alog, const float* __restrict__ Dv,
                                              float* __restrict__ ys) {
    int b = blockIdx.x;
    int d = blockIdx.y * 16 + (threadIdx.x >> 4);
    int n = threadIdx.x & 15;
    float A = -expf(Alog[d * 16 + n]);
    float Dd = Dv[d];
    float h = 0.f;
    for (int t = 0; t < NPq; t++) {
        size_t bt = (size_t)b * NPq + t;
        float de = delta[bt * DIq + d];
        float u  = xi2[bt * DIq + d];
        float Bn = dbc[bt * 80 + 48 + n];
        float Cn = dbc[bt * 80 + 64 + n];
        h = expf(de * A) * h + de * Bn * u;
        float p = h * Cn;
        p += __shfl_xor(p, 1);
        p += __shfl_xor(p, 2);
        p += __shfl_xor(p, 4);
        p += __shfl_xor(p, 8);
        if (n == 0) {
            float r = xr[bt * 3072 + DIq + d];
            ys[bt * DIq + d] = (p + Dd * u) * (r / (1.f + expf(-r)));
        }
    }
}

// ---------------- row LayerNorm (1024) + exact gelu ----------------
__global__ __launch_bounds__(256) void k_ln_gelu(const float* __restrict__ in, const float* __restrict__ g,
                                                 const float* __restrict__ bt, float* __restrict__ out) {
    int row = blockIdx.x;
    const float* x = in + (size_t)row * OUTq;
    float4 v = ((const float4*)x)[threadIdx.x];
    float s = v.x + v.y + v.z + v.w;
    float ss = v.x * v.x + v.y * v.y + v.z * v.z + v.w * v.w;
    #pragma unroll
    for (int off = 32; off >= 1; off >>= 1) { s += __shfl_down(s, off); ss += __shfl_down(ss, off); }
    __shared__ float sh[10];
    int wid = threadIdx.x >> 6, lid = threadIdx.x & 63;
    if (lid == 0) { sh[wid] = s; sh[4 + wid] = ss; }
    __syncthreads();
    if (threadIdx.x == 0) {
        float S = sh[0] + sh[1] + sh[2] + sh[3], SS = sh[4] + sh[5] + sh[6] + sh[7];
        float m = S * (1.f / OUTq);
        float var = SS * (1.f / OUTq) - m * m;
        sh[8] = m; sh[9] = rsqrtf(var + 1e-5f);
    }
    __syncthreads();
    float m = sh[8], rst = sh[9];
    float4 gv = ((const float4*)g)[threadIdx.x];
    float4 bv = ((const float4*)bt)[threadIdx.x];
    float4 o;
    float y0 = (v.x - m) * rst * gv.x + bv.x; o.x = 0.5f * y0 * (1.f + erff(y0 * 0.70710678118f));
    float y1 = (v.y - m) * rst * gv.y + bv.y; o.y = 0.5f * y1 * (1.f + erff(y1 * 0.70710678118f));
    float y2 = (v.z - m) * rst * gv.z + bv.z; o.z = 0.5f * y2 * (1.f + erff(y2 * 0.70710678118f));
    float y3 = (v.w - m) * rst * gv.w + bv.w; o.w = 0.5f * y3 * (1.f + erff(y3 * 0.70710678118f));
    ((float4*)(out + (size_t)row * OUTq))[threadIdx.x] = o;
}

// ---------------- column softmax (over t) + weighted pool ----------------
__global__ __launch_bounds__(256) void k_softpool(const float* __restrict__ gm, const float* __restrict__ ym,
                                                  float* __restrict__ pooled) {
    int b = blockIdx.y;
    int j = blockIdx.x * 256 + threadIdx.x;
    const float* gb = gm + (size_t)b * NPq * OUTq + j;
    const float* yb = ym + (size_t)b * NPq * OUTq + j;
    float mx = -1e30f;
    for (int t = 0; t < NPq; t++) mx = fmaxf(mx, gb[(size_t)t * OUTq]);
    float s = 0.f, ps = 0.f;
    for (int t = 0; t < NPq; t++) {
        float e = expf(gb[(size_t)t * OUTq] - mx);
        s += e;
        ps += yb[(size_t)t * OUTq] * e;
    }
    pooled[b * OUTq + j] = ps / s;
}

// ---------------- final LayerNorm over 1024 per batch ----------------
__global__ __launch_bounds__(256) void k_final_ln(const float* __restrict__ p, const float* __restrict__ g,
                                                  const float* __restrict__ bt, float* __restrict__ out) {
    int row = blockIdx.x;
    const float* x = p + (size_t)row * OUTq;
    float4 v = ((const float4*)x)[threadIdx.x];
    float s = v.x + v.y + v.z + v.w;
    float ss = v.x * v.x + v.y * v.y + v.z * v.z + v.w * v.w;
    #pragma unroll
    for (int off = 32; off >= 1; off >>= 1) { s += __shfl_down(s, off); ss += __shfl_down(ss, off); }
    __shared__ float sh[10];
    int wid = threadIdx.x >> 6, lid = threadIdx.x & 63;
    if (lid == 0) { sh[wid] = s; sh[4 + wid] = ss; }
    __syncthreads();
    if (threadIdx.x == 0) {
        float S = sh[0] + sh[1] + sh[2] + sh[3], SS = sh[4] + sh[5] + sh[6] + sh[7];
        float m = S * (1.f / OUTq);
        float var = SS * (1.f / OUTq) - m * m;
        sh[8] = m; sh[9] = rsqrtf(var + 1e-5f);
    }
    __syncthreads();
    float m = sh[8], rst = sh[9];
    float4 gv = ((const float4*)g)[threadIdx.x];
    float4 bv = ((const float4*)bt)[threadIdx.x];
    float4 o;
    o.x = (v.x - m) * rst * gv.x + bv.x;
    o.y = (v.y - m) * rst * gv.y + bv.y;
    o.z = (v.z - m) * rst * gv.z + bv.z;
    o.w = (v.w - m) * rst * gv.w + bv.w;
    ((float4*)(out + (size_t)row * OUTq))[threadIdx.x] = o;
}

extern "C" void kernel_launch(void* const* d_in, const int* in_sizes, int n_in,
                              void* d_out, int out_size, void* d_ws, size_t ws_size,
                              hipStream_t stream) {
    const float* img   = (const float*)d_in[0];
    const float* sa_w  = (const float*)d_in[1];
    const float* pe_w  = (const float*)d_in[2];
    const float* pe_b  = (const float*)d_in[3];
    const float* pos   = (const float*)d_in[4];
    const float* in_w  = (const float*)d_in[5];
    const float* in_b  = (const float*)d_in[6];
    const float* cv_w  = (const float*)d_in[7];
    const float* cv_b  = (const float*)d_in[8];
    const float* xp_w  = (const float*)d_in[9];
    const float* dt_w  = (const float*)d_in[10];
    const float* dt_b  = (const float*)d_in[11];
    const float* Alog  = (const float*)d_in[12];
    const float* Dv    = (const float*)d_in[13];
    const float* ot_w  = (const float*)d_in[14];
    const float* ot_b  = (const float*)d_in[15];
    const float* em_w  = (const float*)d_in[16];
    const float* em_b  = (const float*)d_in[17];
    const float* em_g  = (const float*)d_in[18];
    const float* em_bt = (const float*)d_in[19];
    const float* at_w  = (const float*)d_in[20];
    const float* at_b  = (const float*)d_in[21];
    const float* at_g  = (const float*)d_in[22];
    const float* at_bt = (const float*)d_in[23];
    const float* la_g  = (const float*)d_in[24];
    const float* la_bt = (const float*)d_in[25];

    char* ws = (char*)d_ws;
    auto al = [](size_t x) { return (x + 255) & ~(size_t)255; };
    size_t SZ_am  = (size_t)NB * 2 * IMP * 4;
    size_t SZ_G   = (size_t)ROWS * 768 * 4;
    size_t SZ_x   = SZ_G;
    size_t SZ_xr  = (size_t)ROWS * 3072 * 4;
    size_t SZ_xi2 = (size_t)ROWS * 1536 * 4;
    size_t SZ_de  = SZ_xi2;
    size_t SZ_dbc = (size_t)ROWS * 80 * 4;
    size_t SZ_ys  = SZ_xi2;
    size_t SZ_yem = (size_t)ROWS * 1024 * 4;
    size_t SZ_pool = (size_t)NB * OUTq * 4;
    size_t SZ_part = (size_t)XP_KS * ROWS * 80 * 4;   // 4 MB

    size_t o_am  = 0;
    size_t o_G   = al(o_am + SZ_am);
    size_t o_x   = al(o_G + SZ_G);
    size_t o_xr  = al(o_x + SZ_x);
    size_t o_xi2 = al(o_xr + SZ_xr);
    size_t o_de  = al(o_xi2 + SZ_xi2);
    size_t o_dbc = al(o_de + SZ_de);
    size_t o_ys  = al(o_dbc + SZ_dbc);
    size_t o_yem = al(o_ys + SZ_ys);
    size_t o_pool = al(o_yem + SZ_yem);
    size_t o_part = al(o_pool + SZ_pool);

    // bf16 transposed weights (persist whole launch) at tail
    size_t o_wpe  = al(o_part + SZ_part);
    size_t o_win0 = al(o_wpe  + (size_t)768 * 768 * 2);
    size_t o_win1 = al(o_win0 + (size_t)3072 * 768 * 2);
    size_t o_wot0 = al(o_win1 + (size_t)3072 * 768 * 2);
    size_t o_wot1 = al(o_wot0 + (size_t)768 * 1536 * 2);
    size_t o_wem  = al(o_wot1 + (size_t)768 * 1536 * 2);
    size_t o_wat  = al(o_wem  + (size_t)1024 * 768 * 2);

    float* am   = (float*)(ws + o_am);
    float* G    = (float*)(ws + o_G);
    float* x    = (float*)(ws + o_x);
    float* xr   = (float*)(ws + o_xr);
    float* xi2  = (float*)(ws + o_xi2);
    float* de   = (float*)(ws + o_de);
    float* dbc  = (float*)(ws + o_dbc);
    float* ys   = (float*)(ws + o_ys);
    float* yem  = (float*)(ws + o_yem);
    float* pool = (float*)(ws + o_pool);
    float* part = (float*)(ws + o_part);
    unsigned short* wpe  = (unsigned short*)(ws + o_wpe);
    unsigned short* win0 = (unsigned short*)(ws + o_win0);
    unsigned short* win1 = (unsigned short*)(ws + o_win1);
    unsigned short* wot0 = (unsigned short*)(ws + o_wot0);
    unsigned short* wot1 = (unsigned short*)(ws + o_wot1);
    unsigned short* wem  = (unsigned short*)(ws + o_wem);
    unsigned short* wat  = (unsigned short*)(ws + o_wat);
    // reuse (dead regions): t1 over am∪G; t2 over xr; gat over xr+16MB
    float* t1  = (float*)(ws + 0);
    float* t2  = (float*)(ws + o_xr);
    float* gat = (float*)(ws + o_xr + ((size_t)16 << 20));

    // ---- weight conversion (W[K][N] -> bf16 [N][K]) ----
    k_transpose_bf<<<dim3(768 / 32, 768 / 32), 256, 0, stream>>>(pe_w, wpe, 768, 768);
    k_transpose_bf<<<dim3(3072 / 32, 768 / 32), 256, 0, stream>>>(in_w, win0, 768, 3072);
    k_transpose_bf<<<dim3(3072 / 32, 768 / 32), 256, 0, stream>>>(in_w + (size_t)768 * 3072, win1, 768, 3072);
    k_transpose_bf<<<dim3(768 / 32, 1536 / 32), 256, 0, stream>>>(ot_w, wot0, 1536, 768);
    k_transpose_bf<<<dim3(768 / 32, 1536 / 32), 256, 0, stream>>>(ot_w + (size_t)1536 * 768, wot1, 1536, 768);
    k_transpose_bf<<<dim3(1024 / 32, 768 / 32), 256, 0, stream>>>(em_w, wem, 768, 1024);
    k_transpose_bf<<<dim3(1024 / 32, 1024 / 32), 256, 0, stream>>>(at_w, wat, 1024, 1024);

    int npx = NB * IMP;
    k_avgmax<<<(npx + 255) / 256, 256, 0, stream>>>(img, am);
    k_gatepatch<<<(npx + 255) / 256, 256, 0, stream>>>(img, am, sa_w, G);

    dim3 blk(256);
    // patch embed: x = G @ pe_w + pe_b + pos
    k_gemm_bf<EPI_POSEMB><<<dim3(6, 25), blk, 0, stream>>>(G, 768, wpe, pe_b, x, 768, ROWS, 768, 768, pos);

    for (int l = 0; l < 2; l++) {
        const unsigned short* win = l ? win1 : win0;
        const unsigned short* wot = l ? wot1 : wot0;
        // xr = x @ in_w + in_b
        k_gemm_bf<EPI_NONE><<<dim3(24, 25), blk, 0, stream>>>(x, 768, win, in_b + l * 3072, xr, 3072,
                                                              ROWS, 3072, 768, nullptr);
        int ne = ROWS * DIq;
        k_conv_silu<<<(ne + 255) / 256, 256, 0, stream>>>(xr, cv_w + (size_t)l * DIq * 4, cv_b + l * DIq, xi2);
        // dbc = xi2 @ xproj_w (f32 split-K + reduce)
        k_xproj_part<<<dim3(ROWS / 32, XP_KS), blk, 0, stream>>>(xi2, xp_w + (size_t)l * 1536 * 80, part);
        k_xreduce<<<(ROWS * 80 / 4 + 255) / 256, 256, 0, stream>>>(part, dbc);
        // delta = softplus(dbc[:, :48] @ dt_w + dt_b)
        k_dt<<<ROWS / DT_RPB, 384, 0, stream>>>(dbc, dt_w + (size_t)l * 48 * 1536, dt_b + l * 1536, de);
        k_scan<<<dim3(16, 96), blk, 0, stream>>>(de, xi2, dbc, xr, Alog + (size_t)l * 1536 * 16, Dv + l * 1536, ys);
        // x = ys @ out_w + out_b
        k_gemm_bf<EPI_NONE><<<dim3(6, 25), blk, 0, stream>>>(ys, 1536, wot, ot_b + l * 768, x, 768,
                                                             ROWS, 768, 1536, nullptr);
    }

    // head
    k_gemm_bf<EPI_NONE><<<dim3(8, 25), blk, 0, stream>>>(x, 768, wem, em_b, t1, 1024, ROWS, 1024, 768, nullptr);
    k_ln_gelu<<<ROWS, 256, 0, stream>>>(t1, em_g, em_bt, yem);
    k_gemm_bf<EPI_NONE><<<dim3(8, 25), blk, 0, stream>>>(yem, 1024, wat, at_b, t2, 1024, ROWS, 1024, 1024, nullptr);
    k_ln_gelu<<<ROWS, 256, 0, stream>>>(t2, at_g, at_bt, gat);
    k_softpool<<<dim3(4, NB), 256, 0, stream>>>(gat, yem, pool);
    k_final_ln<<<NB, 256, 0, stream>>>(pool, la_g, la_bt, (float*)d_out);
}

// Round 4
// 969.985 us; speedup vs baseline: 2.5705x; 1.1293x over previous
//
#include <hip/hip_runtime.h>
#include <math.h>

static constexpr int NB = 16;
static constexpr int NC = 3;
static constexpr int IM = 224;
static constexpr int IMP = IM * IM;      // 50176
static constexpr int HPq = 14;
static constexpr int NPq = 196;
static constexpr int OUTq = 1024;
static constexpr int DIq = 1536;
static constexpr int ROWS = NB * NPq;    // 3136

typedef __bf16 bf8_t __attribute__((ext_vector_type(8)));
typedef float f4_t __attribute__((ext_vector_type(4)));
typedef unsigned short us8 __attribute__((ext_vector_type(8)));

__device__ inline unsigned short f2bf(float x) {
    unsigned u = __builtin_bit_cast(unsigned, x);
    unsigned r = (u + 0x7FFFu + ((u >> 16) & 1u)) >> 16;
    return (unsigned short)r;
}

__device__ inline float fast_sig(float x) {
    return __builtin_amdgcn_rcpf(1.f + __expf(-x));
}

// ---------------- K1a: channel avg/max ----------------
__global__ __launch_bounds__(256) void k_avgmax(const float* __restrict__ img, float* __restrict__ am) {
    int idx = blockIdx.x * 256 + threadIdx.x;
    if (idx >= NB * IMP) return;
    int p = idx % IMP, b = idx / IMP;
    const float* ib = img + (size_t)b * NC * IMP + p;
    float c0 = ib[0], c1 = ib[IMP], c2 = ib[2 * IMP];
    am[(size_t)(b * 2 + 0) * IMP + p] = (c0 + c1 + c2) * (1.f / 3.f);
    am[(size_t)(b * 2 + 1) * IMP + p] = fmaxf(c0, fmaxf(c1, c2));
}

// ---------------- K1b: 7x7 conv gate + patchify ----------------
__global__ __launch_bounds__(256) void k_gatepatch(const float* __restrict__ img, const float* __restrict__ am,
                                                   const float* __restrict__ saw, float* __restrict__ G) {
    int idx = blockIdx.x * 256 + threadIdx.x;
    if (idx >= NB * IMP) return;
    int p = idx % IMP, b = idx / IMP;
    int y = p / IM, x = p % IM;
    float acc = 0.f;
    #pragma unroll
    for (int ci = 0; ci < 2; ci++) {
        const float* amc = am + (size_t)(b * 2 + ci) * IMP;
        const float* wc = saw + ci * 49;
        #pragma unroll
        for (int kh = 0; kh < 7; kh++) {
            int yy = y + kh - 3;
            if (yy < 0 || yy >= IM) continue;
            #pragma unroll
            for (int kw = 0; kw < 7; kw++) {
                int xx = x + kw - 3;
                if (xx < 0 || xx >= IM) continue;
                acc += amc[yy * IM + xx] * wc[kh * 7 + kw];
            }
        }
    }
    float s = fast_sig(acc);
    int hy = y >> 4, py = y & 15, hx = x >> 4, px = x & 15;
    size_t base = ((size_t)(b * NPq + hy * HPq + hx) * 768) + (size_t)(py * 16 + px) * 3;
    const float* ib = img + (size_t)b * NC * IMP + p;
    G[base + 0] = ib[0] * s;
    G[base + 1] = ib[IMP] * s;
    G[base + 2] = ib[2 * IMP] * s;
}

// ---------------- weight transpose + f32->bf16: W[K][N] -> Wt[N][K] ----------------
__global__ __launch_bounds__(256) void k_transpose_bf(const float* __restrict__ W, unsigned short* __restrict__ Wt,
                                                      int K, int N) {
    __shared__ float t[32][33];
    int n0 = blockIdx.x * 32, k0 = blockIdx.y * 32;
    int c = threadIdx.x & 31, r8 = threadIdx.x >> 5;
    #pragma unroll
    for (int i = 0; i < 4; i++) {
        int r = r8 + i * 8;
        t[r][c] = W[(size_t)(k0 + r) * N + n0 + c];
    }
    __syncthreads();
    #pragma unroll
    for (int i = 0; i < 4; i++) {
        int r = r8 + i * 8;
        Wt[(size_t)(n0 + r) * K + k0 + c] = f2bf(t[c][r]);
    }
}

// ---------------- bf16 MFMA GEMM: C = A(f32, MxK) @ Wt^T (Wt is bf16 [N][K]) ----------------
enum { EPI_NONE = 0, EPI_POSEMB = 1 };

template<int EPI>
__global__ __launch_bounds__(256) void k_gemm_bf(const float* __restrict__ A, int lda,
                                                 const unsigned short* __restrict__ Wt,
                                                 const float* __restrict__ bias,
                                                 float* __restrict__ C, int ldc,
                                                 int M, int N, int K,
                                                 const float* __restrict__ extra) {
    __shared__ __align__(16) unsigned short As[128 * 64];
    __shared__ __align__(16) unsigned short Bs[128 * 64];
    const int bm = blockIdx.y * 128, bn = blockIdx.x * 128;
    const int tid = threadIdx.x;
    const int lane = tid & 63, wid = tid >> 6;
    const int wr = (wid >> 1) * 64, wc = (wid & 1) * 64;
    const int lr = lane & 15, lq = lane >> 4;

    f4_t acc[4][4] = {};

    for (int k0 = 0; k0 < K; k0 += 64) {
        #pragma unroll
        for (int i = 0; i < 4; i++) {
            int gid = tid + i * 256;          // 0..1023
            int r = gid >> 3, g = gid & 7;    // row 0..127, 8-elem group 0..7
            int soff = r * 64 + ((g ^ (r & 7)) * 8);
            us8 av = {};
            if (bm + r < M) {
                const float* ap = A + (size_t)(bm + r) * lda + k0 + g * 8;
                float4 f0 = *(const float4*)ap;
                float4 f1 = *(const float4*)(ap + 4);
                av[0] = f2bf(f0.x); av[1] = f2bf(f0.y); av[2] = f2bf(f0.z); av[3] = f2bf(f0.w);
                av[4] = f2bf(f1.x); av[5] = f2bf(f1.y); av[6] = f2bf(f1.z); av[7] = f2bf(f1.w);
            }
            *(us8*)&As[soff] = av;
            const unsigned short* bp = Wt + (size_t)(bn + r) * K + k0 + g * 8;
            *(us8*)&Bs[soff] = *(const us8*)bp;
        }
        __syncthreads();
        #pragma unroll
        for (int h = 0; h < 2; h++) {
            bf8_t af[4], bfr[4];
            #pragma unroll
            for (int mb = 0; mb < 4; mb++) {
                int row = wr + mb * 16 + lr;
                int g = h * 4 + lq;
                af[mb] = *(const bf8_t*)&As[row * 64 + ((g ^ (row & 7)) * 8)];
                int rn = wc + mb * 16 + lr;
                bfr[mb] = *(const bf8_t*)&Bs[rn * 64 + ((g ^ (rn & 7)) * 8)];
            }
            #pragma unroll
            for (int mb = 0; mb < 4; mb++)
                #pragma unroll
                for (int nb = 0; nb < 4; nb++)
                    acc[mb][nb] = __builtin_amdgcn_mfma_f32_16x16x32_bf16(af[mb], bfr[nb], acc[mb][nb], 0, 0, 0);
        }
        __syncthreads();
    }

    #pragma unroll
    for (int mb = 0; mb < 4; mb++) {
        #pragma unroll
        for (int nb = 0; nb < 4; nb++) {
            int col = bn + wc + nb * 16 + lr;
            #pragma unroll
            for (int q = 0; q < 4; q++) {
                int row = bm + wr + mb * 16 + lq * 4 + q;
                if (row < M) {
                    float v = acc[mb][nb][q];
                    if (bias) v += bias[col];
                    if (EPI == EPI_POSEMB) v += extra[(size_t)(row % NPq) * N + col];
                    C[(size_t)row * ldc + col] = v;
                }
            }
        }
    }
}

// ---------------- xproj split-K f32 GEMM: part[kc] = xi2[:, kc] @ W[kc, :80] ----------------
static constexpr int XP_KS = 4;
static constexpr int XP_KC = 1536 / XP_KS;   // 384

__global__ __launch_bounds__(256) void k_xproj_part(const float* __restrict__ xi2, const float* __restrict__ W,
                                                    float* __restrict__ part) {
    __shared__ float As[32][65];
    __shared__ __align__(16) float Bs[64][80];
    int m0 = blockIdx.x * 32;
    int kc0 = blockIdx.y * XP_KC;
    int tid = threadIdx.x;
    int row = tid >> 3, cg = (tid & 7) * 10;
    float acc[10] = {};
    for (int k0 = 0; k0 < XP_KC; k0 += 64) {
        #pragma unroll
        for (int i = 0; i < 2; i++) {
            int id = tid + i * 256;           // 0..511
            int r = id >> 4, c4 = (id & 15) * 4;
            float4 v = *(const float4*)(xi2 + (size_t)(m0 + r) * 1536 + kc0 + k0 + c4);
            As[r][c4] = v.x; As[r][c4 + 1] = v.y; As[r][c4 + 2] = v.z; As[r][c4 + 3] = v.w;
        }
        #pragma unroll
        for (int i = 0; i < 5; i++) {
            int id = tid + i * 256;           // 0..1279
            int r = id / 20, c4 = (id % 20) * 4;
            *(float4*)&Bs[r][c4] = *(const float4*)(W + (size_t)(kc0 + k0 + r) * 80 + c4);
        }
        __syncthreads();
        #pragma unroll
        for (int kk = 0; kk < 64; kk++) {
            float a = As[row][kk];
            #pragma unroll
            for (int j = 0; j < 10; j++)
                acc[j] = fmaf(a, Bs[kk][cg + j], acc[j]);
        }
        __syncthreads();
    }
    float* p = part + ((size_t)blockIdx.y * ROWS + m0 + row) * 80 + cg;
    #pragma unroll
    for (int j = 0; j < 10; j++) p[j] = acc[j];
}

__global__ __launch_bounds__(256) void k_xreduce(const float* __restrict__ part, float* __restrict__ dbc) {
    int idx = (blockIdx.x * 256 + threadIdx.x) * 4;
    if (idx >= ROWS * 80) return;
    const int S = ROWS * 80;
    float4 a = *(const float4*)(part + idx);
    float4 b = *(const float4*)(part + S + idx);
    float4 c = *(const float4*)(part + 2 * S + idx);
    float4 d = *(const float4*)(part + 3 * S + idx);
    float4 o;
    o.x = a.x + b.x + c.x + d.x;
    o.y = a.y + b.y + c.y + d.y;
    o.z = a.z + b.z + c.z + d.z;
    o.w = a.w + b.w + c.w + d.w;
    *(float4*)(dbc + idx) = o;
}

// ---------------- dt GEMM (K=48) + softplus: de = softplus(dbc[:, :48] @ dt_w + dt_b) ----------------
static constexpr int DT_RPB = 4;
__global__ __launch_bounds__(384) void k_dt(const float* __restrict__ dbc, const float* __restrict__ W,
                                            const float* __restrict__ bias, float* __restrict__ de) {
    int r0 = blockIdx.x * DT_RPB;
    int j = threadIdx.x * 4;
    __shared__ float ds[DT_RPB][48];
    if (threadIdx.x < DT_RPB * 48)
        ds[threadIdx.x / 48][threadIdx.x % 48] = dbc[(size_t)(r0 + threadIdx.x / 48) * 80 + threadIdx.x % 48];
    __syncthreads();
    float4 b = *(const float4*)(bias + j);
    float4 a0 = b, a1 = b, a2 = b, a3 = b;
    for (int k = 0; k < 48; k++) {
        float4 w = *(const float4*)(W + (size_t)k * 1536 + j);
        float d0 = ds[0][k], d1 = ds[1][k], d2 = ds[2][k], d3 = ds[3][k];
        a0.x = fmaf(d0, w.x, a0.x); a0.y = fmaf(d0, w.y, a0.y); a0.z = fmaf(d0, w.z, a0.z); a0.w = fmaf(d0, w.w, a0.w);
        a1.x = fmaf(d1, w.x, a1.x); a1.y = fmaf(d1, w.y, a1.y); a1.z = fmaf(d1, w.z, a1.z); a1.w = fmaf(d1, w.w, a1.w);
        a2.x = fmaf(d2, w.x, a2.x); a2.y = fmaf(d2, w.y, a2.y); a2.z = fmaf(d2, w.z, a2.z); a2.w = fmaf(d2, w.w, a2.w);
        a3.x = fmaf(d3, w.x, a3.x); a3.y = fmaf(d3, w.y, a3.y); a3.z = fmaf(d3, w.z, a3.z); a3.w = fmaf(d3, w.w, a3.w);
    }
    auto sp = [](float v) { return (v > 20.f) ? v : log1pf(expf(v)); };
    float4 o;
    o.x = sp(a0.x); o.y = sp(a0.y); o.z = sp(a0.z); o.w = sp(a0.w);
    *(float4*)(de + (size_t)(r0 + 0) * 1536 + j) = o;
    o.x = sp(a1.x); o.y = sp(a1.y); o.z = sp(a1.z); o.w = sp(a1.w);
    *(float4*)(de + (size_t)(r0 + 1) * 1536 + j) = o;
    o.x = sp(a2.x); o.y = sp(a2.y); o.z = sp(a2.z); o.w = sp(a2.w);
    *(float4*)(de + (size_t)(r0 + 2) * 1536 + j) = o;
    o.x = sp(a3.x); o.y = sp(a3.y); o.z = sp(a3.z); o.w = sp(a3.w);
    *(float4*)(de + (size_t)(r0 + 3) * 1536 + j) = o;
}

// ---------------- causal depthwise conv (DC=4) + silu; also sres = silu(res) ----------------
__global__ __launch_bounds__(256) void k_conv_silu(const float* __restrict__ xr, const float* __restrict__ cw,
                                                   const float* __restrict__ cb, float* __restrict__ xi2,
                                                   float* __restrict__ sres) {
    int idx = blockIdx.x * 256 + threadIdx.x;
    if (idx >= ROWS * DIq) return;
    int d = idx % DIq; int bt = idx / DIq; int t = bt % NPq; int b = bt / NPq;
    float w0 = cw[d * 4 + 0], w1 = cw[d * 4 + 1], w2 = cw[d * 4 + 2], w3 = cw[d * 4 + 3];
    float s = cb[d];
    const float* base = xr + (size_t)b * NPq * 3072 + d;
    if (t >= 3) s += base[(size_t)(t - 3) * 3072] * w0;
    if (t >= 2) s += base[(size_t)(t - 2) * 3072] * w1;
    if (t >= 1) s += base[(size_t)(t - 1) * 3072] * w2;
    s += base[(size_t)t * 3072] * w3;
    xi2[idx] = s * fast_sig(s);
    float r = xr[(size_t)bt * 3072 + 1536 + d];
    sres[idx] = r * fast_sig(r);
}

// ---------------- selective-scan: lane = (d, n'∈0..7), 2 states/lane ----------------
__global__ __launch_bounds__(256) void k_scan(const float* __restrict__ delta, const float* __restrict__ xi2,
                                              const float* __restrict__ dbc, const float* __restrict__ sres,
                                              const float* __restrict__ Alog, const float* __restrict__ Dv,
                                              float* __restrict__ ys) {
    int b = blockIdx.x;
    int d = blockIdx.y * 32 + (threadIdx.x >> 3);
    int np = threadIdx.x & 7;
    float A0 = -__expf(Alog[d * 16 + np]);
    float A1 = -__expf(Alog[d * 16 + np + 8]);
    float Dd = Dv[d];
    const float* pd  = delta + (size_t)b * NPq * DIq + d;
    const float* pu  = xi2   + (size_t)b * NPq * DIq + d;
    const float* pbc = dbc   + (size_t)b * NPq * 80;
    const float* psr = sres  + (size_t)b * NPq * DIq + d;
    float* py        = ys    + (size_t)b * NPq * DIq + d;
    float h0 = 0.f, h1 = 0.f;
    float de = pd[0], u = pu[0];
    float B0 = pbc[48 + np], B1 = pbc[56 + np], C0 = pbc[64 + np], C1 = pbc[72 + np];
    for (int t = 0; t < NPq; t++) {
        float dc = de, uc = u, B0c = B0, B1c = B1, C0c = C0, C1c = C1;
        if (t + 1 < NPq) {
            pd += DIq; pu += DIq; pbc += 80;
            de = pd[0]; u = pu[0];
            B0 = pbc[48 + np]; B1 = pbc[56 + np]; C0 = pbc[64 + np]; C1 = pbc[72 + np];
        }
        float a0 = __expf(dc * A0), a1 = __expf(dc * A1);
        float deu = dc * uc;
        h0 = fmaf(a0, h0, deu * B0c);
        h1 = fmaf(a1, h1, deu * B1c);
        float p = fmaf(h1, C1c, h0 * C0c);
        p += __shfl_xor(p, 1);
        p += __shfl_xor(p, 2);
        p += __shfl_xor(p, 4);
        if (np == 0) py[0] = fmaf(Dd, uc, p) * psr[0];
        py += DIq; psr += DIq;
    }
}

// ---------------- row LayerNorm (1024) + exact gelu ----------------
__global__ __launch_bounds__(256) void k_ln_gelu(const float* __restrict__ in, const float* __restrict__ g,
                                                 const float* __restrict__ bt, float* __restrict__ out) {
    int row = blockIdx.x;
    const float* x = in + (size_t)row * OUTq;
    float4 v = ((const float4*)x)[threadIdx.x];
    float s = v.x + v.y + v.z + v.w;
    float ss = v.x * v.x + v.y * v.y + v.z * v.z + v.w * v.w;
    #pragma unroll
    for (int off = 32; off >= 1; off >>= 1) { s += __shfl_down(s, off); ss += __shfl_down(ss, off); }
    __shared__ float sh[10];
    int wid = threadIdx.x >> 6, lid = threadIdx.x & 63;
    if (lid == 0) { sh[wid] = s; sh[4 + wid] = ss; }
    __syncthreads();
    if (threadIdx.x == 0) {
        float S = sh[0] + sh[1] + sh[2] + sh[3], SS = sh[4] + sh[5] + sh[6] + sh[7];
        float m = S * (1.f / OUTq);
        float var = SS * (1.f / OUTq) - m * m;
        sh[8] = m; sh[9] = rsqrtf(var + 1e-5f);
    }
    __syncthreads();
    float m = sh[8], rst = sh[9];
    float4 gv = ((const float4*)g)[threadIdx.x];
    float4 bv = ((const float4*)bt)[threadIdx.x];
    float4 o;
    float y0 = (v.x - m) * rst * gv.x + bv.x; o.x = 0.5f * y0 * (1.f + erff(y0 * 0.70710678118f));
    float y1 = (v.y - m) * rst * gv.y + bv.y; o.y = 0.5f * y1 * (1.f + erff(y1 * 0.70710678118f));
    float y2 = (v.z - m) * rst * gv.z + bv.z; o.z = 0.5f * y2 * (1.f + erff(y2 * 0.70710678118f));
    float y3 = (v.w - m) * rst * gv.w + bv.w; o.w = 0.5f * y3 * (1.f + erff(y3 * 0.70710678118f));
    ((float4*)(out + (size_t)row * OUTq))[threadIdx.x] = o;
}

// ---------------- column softmax (over t) + weighted pool ----------------
__global__ __launch_bounds__(256) void k_softpool(const float* __restrict__ gm, const float* __restrict__ ym,
                                                  float* __restrict__ pooled) {
    int b = blockIdx.y;
    int j = blockIdx.x * 256 + threadIdx.x;
    const float* gb = gm + (size_t)b * NPq * OUTq + j;
    const float* yb = ym + (size_t)b * NPq * OUTq + j;
    float mx = -1e30f;
    for (int t = 0; t < NPq; t++) mx = fmaxf(mx, gb[(size_t)t * OUTq]);
    float s = 0.f, ps = 0.f;
    for (int t = 0; t < NPq; t++) {
        float e = __expf(gb[(size_t)t * OUTq] - mx);
        s += e;
        ps += yb[(size_t)t * OUTq] * e;
    }
    pooled[b * OUTq + j] = ps / s;
}

// ---------------- final LayerNorm over 1024 per batch ----------------
__global__ __launch_bounds__(256) void k_final_ln(const float* __restrict__ p, const float* __restrict__ g,
                                                  const float* __restrict__ bt, float* __restrict__ out) {
    int row = blockIdx.x;
    const float* x = p + (size_t)row * OUTq;
    float4 v = ((const float4*)x)[threadIdx.x];
    float s = v.x + v.y + v.z + v.w;
    float ss = v.x * v.x + v.y * v.y + v.z * v.z + v.w * v.w;
    #pragma unroll
    for (int off = 32; off >= 1; off >>= 1) { s += __shfl_down(s, off); ss += __shfl_down(ss, off); }
    __shared__ float sh[10];
    int wid = threadIdx.x >> 6, lid = threadIdx.x & 63;
    if (lid == 0) { sh[wid] = s; sh[4 + wid] = ss; }
    __syncthreads();
    if (threadIdx.x == 0) {
        float S = sh[0] + sh[1] + sh[2] + sh[3], SS = sh[4] + sh[5] + sh[6] + sh[7];
        float m = S * (1.f / OUTq);
        float var = SS * (1.f / OUTq) - m * m;
        sh[8] = m; sh[9] = rsqrtf(var + 1e-5f);
    }
    __syncthreads();
    float m = sh[8], rst = sh[9];
    float4 gv = ((const float4*)g)[threadIdx.x];
    float4 bv = ((const float4*)bt)[threadIdx.x];
    float4 o;
    o.x = (v.x - m) * rst * gv.x + bv.x;
    o.y = (v.y - m) * rst * gv.y + bv.y;
    o.z = (v.z - m) * rst * gv.z + bv.z;
    o.w = (v.w - m) * rst * gv.w + bv.w;
    ((float4*)(out + (size_t)row * OUTq))[threadIdx.x] = o;
}

extern "C" void kernel_launch(void* const* d_in, const int* in_sizes, int n_in,
                              void* d_out, int out_size, void* d_ws, size_t ws_size,
                              hipStream_t stream) {
    const float* img   = (const float*)d_in[0];
    const float* sa_w  = (const float*)d_in[1];
    const float* pe_w  = (const float*)d_in[2];
    const float* pe_b  = (const float*)d_in[3];
    const float* pos   = (const float*)d_in[4];
    const float* in_w  = (const float*)d_in[5];
    const float* in_b  = (const float*)d_in[6];
    const float* cv_w  = (const float*)d_in[7];
    const float* cv_b  = (const float*)d_in[8];
    const float* xp_w  = (const float*)d_in[9];
    const float* dt_w  = (const float*)d_in[10];
    const float* dt_b  = (const float*)d_in[11];
    const float* Alog  = (const float*)d_in[12];
    const float* Dv    = (const float*)d_in[13];
    const float* ot_w  = (const float*)d_in[14];
    const float* ot_b  = (const float*)d_in[15];
    const float* em_w  = (const float*)d_in[16];
    const float* em_b  = (const float*)d_in[17];
    const float* em_g  = (const float*)d_in[18];
    const float* em_bt = (const float*)d_in[19];
    const float* at_w  = (const float*)d_in[20];
    const float* at_b  = (const float*)d_in[21];
    const float* at_g  = (const float*)d_in[22];
    const float* at_bt = (const float*)d_in[23];
    const float* la_g  = (const float*)d_in[24];
    const float* la_bt = (const float*)d_in[25];

    char* ws = (char*)d_ws;
    auto al = [](size_t x) { return (x + 255) & ~(size_t)255; };
    size_t SZ_am  = (size_t)NB * 2 * IMP * 4;
    size_t SZ_G   = (size_t)ROWS * 768 * 4;
    size_t SZ_x   = SZ_G;
    size_t SZ_xr  = (size_t)ROWS * 3072 * 4;
    size_t SZ_xi2 = (size_t)ROWS * 1536 * 4;
    size_t SZ_de  = SZ_xi2;
    size_t SZ_dbc = (size_t)ROWS * 80 * 4;
    size_t SZ_ys  = SZ_xi2;
    size_t SZ_yem = (size_t)ROWS * 1024 * 4;
    size_t SZ_pool = (size_t)NB * OUTq * 4;
    size_t SZ_part = (size_t)XP_KS * ROWS * 80 * 4;   // 4 MB

    size_t o_am  = 0;
    size_t o_G   = al(o_am + SZ_am);
    size_t o_x   = al(o_G + SZ_G);
    size_t o_xr  = al(o_x + SZ_x);
    size_t o_xi2 = al(o_xr + SZ_xr);
    size_t o_de  = al(o_xi2 + SZ_xi2);
    size_t o_dbc = al(o_de + SZ_de);
    size_t o_ys  = al(o_dbc + SZ_dbc);
    size_t o_yem = al(o_ys + SZ_ys);
    size_t o_pool = al(o_yem + SZ_yem);
    size_t o_part = al(o_pool + SZ_pool);

    // bf16 transposed weights (persist whole launch) at tail
    size_t o_wpe  = al(o_part + SZ_part);
    size_t o_win0 = al(o_wpe  + (size_t)768 * 768 * 2);
    size_t o_win1 = al(o_win0 + (size_t)3072 * 768 * 2);
    size_t o_wot0 = al(o_win1 + (size_t)3072 * 768 * 2);
    size_t o_wot1 = al(o_wot0 + (size_t)768 * 1536 * 2);
    size_t o_wem  = al(o_wot1 + (size_t)768 * 1536 * 2);
    size_t o_wat  = al(o_wem  + (size_t)1024 * 768 * 2);

    float* am   = (float*)(ws + o_am);
    float* G    = (float*)(ws + o_G);
    float* x    = (float*)(ws + o_x);
    float* xr   = (float*)(ws + o_xr);
    float* xi2  = (float*)(ws + o_xi2);
    float* de   = (float*)(ws + o_de);
    float* dbc  = (float*)(ws + o_dbc);
    float* ys   = (float*)(ws + o_ys);
    float* yem  = (float*)(ws + o_yem);
    float* pool = (float*)(ws + o_pool);
    float* part = (float*)(ws + o_part);
    unsigned short* wpe  = (unsigned short*)(ws + o_wpe);
    unsigned short* win0 = (unsigned short*)(ws + o_win0);
    unsigned short* win1 = (unsigned short*)(ws + o_win1);
    unsigned short* wot0 = (unsigned short*)(ws + o_wot0);
    unsigned short* wot1 = (unsigned short*)(ws + o_wot1);
    unsigned short* wem  = (unsigned short*)(ws + o_wem);
    unsigned short* wat  = (unsigned short*)(ws + o_wat);
    // sres overlays am+G+x (dead between in-proj and out-GEMM of each layer);
    // t1 overlays same region during head; t2/gat overlay xr during head.
    float* sres = (float*)(ws + 0);                  // 19.3 MB < am+G+x (25.7 MB)
    float* t1  = (float*)(ws + 0);
    float* t2  = (float*)(ws + o_xr);
    float* gat = (float*)(ws + o_xr + ((size_t)16 << 20));

    // ---- weight conversion (W[K][N] -> bf16 [N][K]) ----
    k_transpose_bf<<<dim3(768 / 32, 768 / 32), 256, 0, stream>>>(pe_w, wpe, 768, 768);
    k_transpose_bf<<<dim3(3072 / 32, 768 / 32), 256, 0, stream>>>(in_w, win0, 768, 3072);
    k_transpose_bf<<<dim3(3072 / 32, 768 / 32), 256, 0, stream>>>(in_w + (size_t)768 * 3072, win1, 768, 3072);
    k_transpose_bf<<<dim3(768 / 32, 1536 / 32), 256, 0, stream>>>(ot_w, wot0, 1536, 768);
    k_transpose_bf<<<dim3(768 / 32, 1536 / 32), 256, 0, stream>>>(ot_w + (size_t)1536 * 768, wot1, 1536, 768);
    k_transpose_bf<<<dim3(1024 / 32, 768 / 32), 256, 0, stream>>>(em_w, wem, 768, 1024);
    k_transpose_bf<<<dim3(1024 / 32, 1024 / 32), 256, 0, stream>>>(at_w, wat, 1024, 1024);

    int npx = NB * IMP;
    k_avgmax<<<(npx + 255) / 256, 256, 0, stream>>>(img, am);
    k_gatepatch<<<(npx + 255) / 256, 256, 0, stream>>>(img, am, sa_w, G);

    dim3 blk(256);
    // patch embed: x = G @ pe_w + pe_b + pos
    k_gemm_bf<EPI_POSEMB><<<dim3(6, 25), blk, 0, stream>>>(G, 768, wpe, pe_b, x, 768, ROWS, 768, 768, pos);

    for (int l = 0; l < 2; l++) {
        const unsigned short* win = l ? win1 : win0;
        const unsigned short* wot = l ? wot1 : wot0;
        // xr = x @ in_w + in_b
        k_gemm_bf<EPI_NONE><<<dim3(24, 25), blk, 0, stream>>>(x, 768, win, in_b + l * 3072, xr, 3072,
                                                              ROWS, 3072, 768, nullptr);
        int ne = ROWS * DIq;
        k_conv_silu<<<(ne + 255) / 256, 256, 0, stream>>>(xr, cv_w + (size_t)l * DIq * 4, cv_b + l * DIq,
                                                          xi2, sres);
        // dbc = xi2 @ xproj_w (f32 split-K + reduce)
        k_xproj_part<<<dim3(ROWS / 32, XP_KS), blk, 0, stream>>>(xi2, xp_w + (size_t)l * 1536 * 80, part);
        k_xreduce<<<(ROWS * 80 / 4 + 255) / 256, 256, 0, stream>>>(part, dbc);
        // delta = softplus(dbc[:, :48] @ dt_w + dt_b)
        k_dt<<<ROWS / DT_RPB, 384, 0, stream>>>(dbc, dt_w + (size_t)l * 48 * 1536, dt_b + l * 1536, de);
        k_scan<<<dim3(16, 48), blk, 0, stream>>>(de, xi2, dbc, sres, Alog + (size_t)l * 1536 * 16,
                                                 Dv + l * 1536, ys);
        // x = ys @ out_w + out_b
        k_gemm_bf<EPI_NONE><<<dim3(6, 25), blk, 0, stream>>>(ys, 1536, wot, ot_b + l * 768, x, 768,
                                                             ROWS, 768, 1536, nullptr);
    }

    // head
    k_gemm_bf<EPI_NONE><<<dim3(8, 25), blk, 0, stream>>>(x, 768, wem, em_b, t1, 1024, ROWS, 1024, 768, nullptr);
    k_ln_gelu<<<ROWS, 256, 0, stream>>>(t1, em_g, em_bt, yem);
    k_gemm_bf<EPI_NONE><<<dim3(8, 25), blk, 0, stream>>>(yem, 1024, wat, at_b, t2, 1024, ROWS, 1024, 1024, nullptr);
    k_ln_gelu<<<ROWS, 256, 0, stream>>>(t2, at_g, at_bt, gat);
    k_softpool<<<dim3(4, NB), 256, 0, stream>>>(gat, yem, pool);
    k_final_ln<<<NB, 256, 0, stream>>>(pool, la_g, la_bt, (float*)d_out);
}

// Round 5
// 845.621 us; speedup vs baseline: 2.9485x; 1.1471x over previous
//
#include <hip/hip_runtime.h>
#include <math.h>

static constexpr int NB = 16;
static constexpr int NC = 3;
static constexpr int IM = 224;
static constexpr int IMP = IM * IM;      // 50176
static constexpr int HPq = 14;
static constexpr int NPq = 196;
static constexpr int OUTq = 1024;
static constexpr int DIq = 1536;
static constexpr int ROWS = NB * NPq;    // 3136

typedef __bf16 bf8_t __attribute__((ext_vector_type(8)));
typedef float f4_t __attribute__((ext_vector_type(4)));
typedef unsigned short us8 __attribute__((ext_vector_type(8)));

__device__ inline unsigned short f2bf(float x) {
    unsigned u = __builtin_bit_cast(unsigned, x);
    unsigned r = (u + 0x7FFFu + ((u >> 16) & 1u)) >> 16;
    return (unsigned short)r;
}

__device__ inline float fast_sig(float x) {
    return __builtin_amdgcn_rcpf(1.f + __expf(-x));
}

// ---------------- K1a: channel avg/max ----------------
__global__ __launch_bounds__(256) void k_avgmax(const float* __restrict__ img, float* __restrict__ am) {
    int idx = blockIdx.x * 256 + threadIdx.x;
    if (idx >= NB * IMP) return;
    int p = idx % IMP, b = idx / IMP;
    const float* ib = img + (size_t)b * NC * IMP + p;
    float c0 = ib[0], c1 = ib[IMP], c2 = ib[2 * IMP];
    am[(size_t)(b * 2 + 0) * IMP + p] = (c0 + c1 + c2) * (1.f / 3.f);
    am[(size_t)(b * 2 + 1) * IMP + p] = fmaxf(c0, fmaxf(c1, c2));
}

// ---------------- K1b: 7x7 conv gate + patchify ----------------
__global__ __launch_bounds__(256) void k_gatepatch(const float* __restrict__ img, const float* __restrict__ am,
                                                   const float* __restrict__ saw, float* __restrict__ G) {
    int idx = blockIdx.x * 256 + threadIdx.x;
    if (idx >= NB * IMP) return;
    int p = idx % IMP, b = idx / IMP;
    int y = p / IM, x = p % IM;
    float acc = 0.f;
    #pragma unroll
    for (int ci = 0; ci < 2; ci++) {
        const float* amc = am + (size_t)(b * 2 + ci) * IMP;
        const float* wc = saw + ci * 49;
        #pragma unroll
        for (int kh = 0; kh < 7; kh++) {
            int yy = y + kh - 3;
            if (yy < 0 || yy >= IM) continue;
            #pragma unroll
            for (int kw = 0; kw < 7; kw++) {
                int xx = x + kw - 3;
                if (xx < 0 || xx >= IM) continue;
                acc += amc[yy * IM + xx] * wc[kh * 7 + kw];
            }
        }
    }
    float s = fast_sig(acc);
    int hy = y >> 4, py = y & 15, hx = x >> 4, px = x & 15;
    size_t base = ((size_t)(b * NPq + hy * HPq + hx) * 768) + (size_t)(py * 16 + px) * 3;
    const float* ib = img + (size_t)b * NC * IMP + p;
    G[base + 0] = ib[0] * s;
    G[base + 1] = ib[IMP] * s;
    G[base + 2] = ib[2 * IMP] * s;
}

// ---------------- weight transpose + f32->bf16: W[K][N] -> Wt[N][K] ----------------
__global__ __launch_bounds__(256) void k_transpose_bf(const float* __restrict__ W, unsigned short* __restrict__ Wt,
                                                      int K, int N) {
    __shared__ float t[32][33];
    int n0 = blockIdx.x * 32, k0 = blockIdx.y * 32;
    int c = threadIdx.x & 31, r8 = threadIdx.x >> 5;
    #pragma unroll
    for (int i = 0; i < 4; i++) {
        int r = r8 + i * 8;
        t[r][c] = W[(size_t)(k0 + r) * N + n0 + c];
    }
    __syncthreads();
    #pragma unroll
    for (int i = 0; i < 4; i++) {
        int r = r8 + i * 8;
        Wt[(size_t)(n0 + r) * K + k0 + c] = f2bf(t[c][r]);
    }
}

// ---------------- bf16 MFMA GEMM: C = A(f32, MxK) @ Wt^T (Wt is bf16 [N][K]) ----------------
enum { EPI_NONE = 0, EPI_POSEMB = 1 };

template<int EPI>
__global__ __launch_bounds__(256) void k_gemm_bf(const float* __restrict__ A, int lda,
                                                 const unsigned short* __restrict__ Wt,
                                                 const float* __restrict__ bias,
                                                 float* __restrict__ C, int ldc,
                                                 int M, int N, int K,
                                                 const float* __restrict__ extra) {
    __shared__ __align__(16) unsigned short As[128 * 64];
    __shared__ __align__(16) unsigned short Bs[128 * 64];
    const int bm = blockIdx.y * 128, bn = blockIdx.x * 128;
    const int tid = threadIdx.x;
    const int lane = tid & 63, wid = tid >> 6;
    const int wr = (wid >> 1) * 64, wc = (wid & 1) * 64;
    const int lr = lane & 15, lq = lane >> 4;

    f4_t acc[4][4] = {};

    for (int k0 = 0; k0 < K; k0 += 64) {
        #pragma unroll
        for (int i = 0; i < 4; i++) {
            int gid = tid + i * 256;          // 0..1023
            int r = gid >> 3, g = gid & 7;    // row 0..127, 8-elem group 0..7
            int soff = r * 64 + ((g ^ (r & 7)) * 8);
            us8 av = {};
            if (bm + r < M) {
                const float* ap = A + (size_t)(bm + r) * lda + k0 + g * 8;
                float4 f0 = *(const float4*)ap;
                float4 f1 = *(const float4*)(ap + 4);
                av[0] = f2bf(f0.x); av[1] = f2bf(f0.y); av[2] = f2bf(f0.z); av[3] = f2bf(f0.w);
                av[4] = f2bf(f1.x); av[5] = f2bf(f1.y); av[6] = f2bf(f1.z); av[7] = f2bf(f1.w);
            }
            *(us8*)&As[soff] = av;
            const unsigned short* bp = Wt + (size_t)(bn + r) * K + k0 + g * 8;
            *(us8*)&Bs[soff] = *(const us8*)bp;
        }
        __syncthreads();
        #pragma unroll
        for (int h = 0; h < 2; h++) {
            bf8_t af[4], bfr[4];
            #pragma unroll
            for (int mb = 0; mb < 4; mb++) {
                int row = wr + mb * 16 + lr;
                int g = h * 4 + lq;
                af[mb] = *(const bf8_t*)&As[row * 64 + ((g ^ (row & 7)) * 8)];
                int rn = wc + mb * 16 + lr;
                bfr[mb] = *(const bf8_t*)&Bs[rn * 64 + ((g ^ (rn & 7)) * 8)];
            }
            #pragma unroll
            for (int mb = 0; mb < 4; mb++)
                #pragma unroll
                for (int nb = 0; nb < 4; nb++)
                    acc[mb][nb] = __builtin_amdgcn_mfma_f32_16x16x32_bf16(af[mb], bfr[nb], acc[mb][nb], 0, 0, 0);
        }
        __syncthreads();
    }

    #pragma unroll
    for (int mb = 0; mb < 4; mb++) {
        #pragma unroll
        for (int nb = 0; nb < 4; nb++) {
            int col = bn + wc + nb * 16 + lr;
            #pragma unroll
            for (int q = 0; q < 4; q++) {
                int row = bm + wr + mb * 16 + lq * 4 + q;
                if (row < M) {
                    float v = acc[mb][nb][q];
                    if (bias) v += bias[col];
                    if (EPI == EPI_POSEMB) v += extra[(size_t)(row % NPq) * N + col];
                    C[(size_t)row * ldc + col] = v;
                }
            }
        }
    }
}

// ---------------- xproj split-K f32 GEMM: part[kc] = xi2[:, kc] @ W[kc, :80] ----------------
static constexpr int XP_KS = 4;
static constexpr int XP_KC = 1536 / XP_KS;   // 384

__global__ __launch_bounds__(256) void k_xproj_part(const float* __restrict__ xi2, const float* __restrict__ W,
                                                    float* __restrict__ part) {
    __shared__ float As[32][65];
    __shared__ __align__(16) float Bs[64][80];
    int m0 = blockIdx.x * 32;
    int kc0 = blockIdx.y * XP_KC;
    int tid = threadIdx.x;
    int row = tid >> 3, cg = (tid & 7) * 10;
    float acc[10] = {};
    for (int k0 = 0; k0 < XP_KC; k0 += 64) {
        #pragma unroll
        for (int i = 0; i < 2; i++) {
            int id = tid + i * 256;           // 0..511
            int r = id >> 4, c4 = (id & 15) * 4;
            float4 v = *(const float4*)(xi2 + (size_t)(m0 + r) * 1536 + kc0 + k0 + c4);
            As[r][c4] = v.x; As[r][c4 + 1] = v.y; As[r][c4 + 2] = v.z; As[r][c4 + 3] = v.w;
        }
        #pragma unroll
        for (int i = 0; i < 5; i++) {
            int id = tid + i * 256;           // 0..1279
            int r = id / 20, c4 = (id % 20) * 4;
            *(float4*)&Bs[r][c4] = *(const float4*)(W + (size_t)(kc0 + k0 + r) * 80 + c4);
        }
        __syncthreads();
        #pragma unroll
        for (int kk = 0; kk < 64; kk++) {
            float a = As[row][kk];
            #pragma unroll
            for (int j = 0; j < 10; j++)
                acc[j] = fmaf(a, Bs[kk][cg + j], acc[j]);
        }
        __syncthreads();
    }
    float* p = part + ((size_t)blockIdx.y * ROWS + m0 + row) * 80 + cg;
    #pragma unroll
    for (int j = 0; j < 10; j++) p[j] = acc[j];
}

__global__ __launch_bounds__(256) void k_xreduce(const float* __restrict__ part, float* __restrict__ dbc) {
    int idx = (blockIdx.x * 256 + threadIdx.x) * 4;
    if (idx >= ROWS * 80) return;
    const int S = ROWS * 80;
    float4 a = *(const float4*)(part + idx);
    float4 b = *(const float4*)(part + S + idx);
    float4 c = *(const float4*)(part + 2 * S + idx);
    float4 d = *(const float4*)(part + 3 * S + idx);
    float4 o;
    o.x = a.x + b.x + c.x + d.x;
    o.y = a.y + b.y + c.y + d.y;
    o.z = a.z + b.z + c.z + d.z;
    o.w = a.w + b.w + c.w + d.w;
    *(float4*)(dbc + idx) = o;
}

// ---------------- dt GEMM (K=48) + softplus: de = softplus(dbc[:, :48] @ dt_w + dt_b) ----------------
static constexpr int DT_RPB = 4;
__global__ __launch_bounds__(384) void k_dt(const float* __restrict__ dbc, const float* __restrict__ W,
                                            const float* __restrict__ bias, float* __restrict__ de) {
    int r0 = blockIdx.x * DT_RPB;
    int j = threadIdx.x * 4;
    __shared__ float ds[DT_RPB][48];
    if (threadIdx.x < DT_RPB * 48)
        ds[threadIdx.x / 48][threadIdx.x % 48] = dbc[(size_t)(r0 + threadIdx.x / 48) * 80 + threadIdx.x % 48];
    __syncthreads();
    float4 b = *(const float4*)(bias + j);
    float4 a0 = b, a1 = b, a2 = b, a3 = b;
    for (int k = 0; k < 48; k++) {
        float4 w = *(const float4*)(W + (size_t)k * 1536 + j);
        float d0 = ds[0][k], d1 = ds[1][k], d2 = ds[2][k], d3 = ds[3][k];
        a0.x = fmaf(d0, w.x, a0.x); a0.y = fmaf(d0, w.y, a0.y); a0.z = fmaf(d0, w.z, a0.z); a0.w = fmaf(d0, w.w, a0.w);
        a1.x = fmaf(d1, w.x, a1.x); a1.y = fmaf(d1, w.y, a1.y); a1.z = fmaf(d1, w.z, a1.z); a1.w = fmaf(d1, w.w, a1.w);
        a2.x = fmaf(d2, w.x, a2.x); a2.y = fmaf(d2, w.y, a2.y); a2.z = fmaf(d2, w.z, a2.z); a2.w = fmaf(d2, w.w, a2.w);
        a3.x = fmaf(d3, w.x, a3.x); a3.y = fmaf(d3, w.y, a3.y); a3.z = fmaf(d3, w.z, a3.z); a3.w = fmaf(d3, w.w, a3.w);
    }
    auto sp = [](float v) { return (v > 20.f) ? v : log1pf(expf(v)); };
    float4 o;
    o.x = sp(a0.x); o.y = sp(a0.y); o.z = sp(a0.z); o.w = sp(a0.w);
    *(float4*)(de + (size_t)(r0 + 0) * 1536 + j) = o;
    o.x = sp(a1.x); o.y = sp(a1.y); o.z = sp(a1.z); o.w = sp(a1.w);
    *(float4*)(de + (size_t)(r0 + 1) * 1536 + j) = o;
    o.x = sp(a2.x); o.y = sp(a2.y); o.z = sp(a2.z); o.w = sp(a2.w);
    *(float4*)(de + (size_t)(r0 + 2) * 1536 + j) = o;
    o.x = sp(a3.x); o.y = sp(a3.y); o.z = sp(a3.z); o.w = sp(a3.w);
    *(float4*)(de + (size_t)(r0 + 3) * 1536 + j) = o;
}

// ---------------- causal depthwise conv (DC=4) + silu; also sres = silu(res) ----------------
__global__ __launch_bounds__(256) void k_conv_silu(const float* __restrict__ xr, const float* __restrict__ cw,
                                                   const float* __restrict__ cb, float* __restrict__ xi2,
                                                   float* __restrict__ sres) {
    int idx = blockIdx.x * 256 + threadIdx.x;
    if (idx >= ROWS * DIq) return;
    int d = idx % DIq; int bt = idx / DIq; int t = bt % NPq; int b = bt / NPq;
    float w0 = cw[d * 4 + 0], w1 = cw[d * 4 + 1], w2 = cw[d * 4 + 2], w3 = cw[d * 4 + 3];
    float s = cb[d];
    const float* base = xr + (size_t)b * NPq * 3072 + d;
    if (t >= 3) s += base[(size_t)(t - 3) * 3072] * w0;
    if (t >= 2) s += base[(size_t)(t - 2) * 3072] * w1;
    if (t >= 1) s += base[(size_t)(t - 1) * 3072] * w2;
    s += base[(size_t)t * 3072] * w3;
    xi2[idx] = s * fast_sig(s);
    float r = xr[(size_t)bt * 3072 + 1536 + d];
    sres[idx] = r * fast_sig(r);
}

// ---------------- selective-scan, LDS-tiled: block = (b, 32 d's), 7 tiles of 28 steps ----------------
static constexpr int STB = 28;   // t-tile size (196 = 7*28)

__global__ __launch_bounds__(256) void k_scan(const float* __restrict__ delta, const float* __restrict__ xi2,
                                              const float* __restrict__ dbc, const float* __restrict__ sres,
                                              const float* __restrict__ Alog, const float* __restrict__ Dv,
                                              float* __restrict__ ys) {
    const int b = blockIdx.x;
    const int d0 = blockIdx.y * 32;
    const int tid = threadIdx.x;
    // compute-phase mapping
    const int dl = tid >> 3;          // 0..31
    const int np = tid & 7;           // 0..7 (2 states each)
    const int d = d0 + dl;
    const float A0 = -__expf(Alog[d * 16 + np]);
    const float A1 = -__expf(Alog[d * 16 + np + 8]);
    const float Dd = Dv[d];
    // stage-phase mapping: idx = tid + j*256 -> t = (tid>>5) + 8j, lane col = tid&31
    const int tr = tid >> 5;          // 0..7
    const int dls = tid & 31;

    __shared__ float sdu[STB][64];    // [t][dl*2 + {0:de, 1:u}]
    __shared__ float sbc[STB][32];    // [t][np*4 + {B0,B1,C0,C1}]
    __shared__ float ssr[STB][32];    // [t][dl]

    const float* gde = delta + ((size_t)b * NPq + tr) * DIq + d0 + dls;
    const float* gu  = xi2   + ((size_t)b * NPq + tr) * DIq + d0 + dls;
    const float* gsr = sres  + ((size_t)b * NPq + tr) * DIq + d0 + dls;
    const float* gbc = dbc   + ((size_t)b * NPq + tr) * 80 + 48 + dls;
    float* gy = ys + (size_t)b * NPq * DIq + d;

    float rde[4], ru[4], rsr[4], rbc[4];

    // stage loads for tile c into registers (issued early; vmcnt waited at write)
    auto stageLoad = [&](int c) {
        const int t0 = c * STB;
        #pragma unroll
        for (int j = 0; j < 3; j++) {
            int off = (t0 + 8 * j) * DIq;
            rde[j] = gde[off];
            ru[j]  = gu[off];
            rsr[j] = gsr[off];
            rbc[j] = gbc[(t0 + 8 * j) * 80];
        }
        if (tid < 128) {   // idx = tid + 768 < 896
            int off = (t0 + 24) * DIq;
            rde[3] = gde[off];
            ru[3]  = gu[off];
            rsr[3] = gsr[off];
            rbc[3] = gbc[(t0 + 24) * 80];
        }
    };
    auto stageWrite = [&]() {
        // perm for bc: global i in 0..31 -> (i&7)*4 + (i>>3)
        const int pi = (dls & 7) * 4 + (dls >> 3);
        #pragma unroll
        for (int j = 0; j < 3; j++) {
            int t = tr + 8 * j;
            sdu[t][dls * 2 + 0] = rde[j];
            sdu[t][dls * 2 + 1] = ru[j];
            ssr[t][dls] = rsr[j];
            sbc[t][pi] = rbc[j];
        }
        if (tid < 128) {
            int t = tr + 24;
            sdu[t][dls * 2 + 0] = rde[3];
            sdu[t][dls * 2 + 1] = ru[3];
            ssr[t][dls] = rsr[3];
            sbc[t][pi] = rbc[3];
        }
    };

    stageLoad(0);
    stageWrite();
    __syncthreads();

    float h0 = 0.f, h1 = 0.f;
    for (int c = 0; c < 7; c++) {
        if (c < 6) stageLoad(c + 1);      // overlap HBM latency with compute below
        #pragma unroll 4
        for (int t = 0; t < STB; t++) {
            float2 du = *(const float2*)&sdu[t][dl * 2];
            float4 bc = *(const float4*)&sbc[t][np * 4];
            float sr = ssr[t][dl];
            float a0 = __expf(du.x * A0), a1 = __expf(du.x * A1);
            float deu = du.x * du.y;
            h0 = fmaf(a0, h0, deu * bc.x);
            h1 = fmaf(a1, h1, deu * bc.y);
            float p = fmaf(h1, bc.w, h0 * bc.z);
            p += __shfl_xor(p, 1);
            p += __shfl_xor(p, 2);
            p += __shfl_xor(p, 4);
            if (np == 0) gy[(size_t)(c * STB + t) * DIq] = fmaf(Dd, du.y, p) * sr;
        }
        __syncthreads();                  // everyone done reading LDS
        if (c < 6) {
            stageWrite();
            __syncthreads();
        }
    }
}

// ---------------- row LayerNorm (1024) + exact gelu ----------------
__global__ __launch_bounds__(256) void k_ln_gelu(const float* __restrict__ in, const float* __restrict__ g,
                                                 const float* __restrict__ bt, float* __restrict__ out) {
    int row = blockIdx.x;
    const float* x = in + (size_t)row * OUTq;
    float4 v = ((const float4*)x)[threadIdx.x];
    float s = v.x + v.y + v.z + v.w;
    float ss = v.x * v.x + v.y * v.y + v.z * v.z + v.w * v.w;
    #pragma unroll
    for (int off = 32; off >= 1; off >>= 1) { s += __shfl_down(s, off); ss += __shfl_down(ss, off); }
    __shared__ float sh[10];
    int wid = threadIdx.x >> 6, lid = threadIdx.x & 63;
    if (lid == 0) { sh[wid] = s; sh[4 + wid] = ss; }
    __syncthreads();
    if (threadIdx.x == 0) {
        float S = sh[0] + sh[1] + sh[2] + sh[3], SS = sh[4] + sh[5] + sh[6] + sh[7];
        float m = S * (1.f / OUTq);
        float var = SS * (1.f / OUTq) - m * m;
        sh[8] = m; sh[9] = rsqrtf(var + 1e-5f);
    }
    __syncthreads();
    float m = sh[8], rst = sh[9];
    float4 gv = ((const float4*)g)[threadIdx.x];
    float4 bv = ((const float4*)bt)[threadIdx.x];
    float4 o;
    float y0 = (v.x - m) * rst * gv.x + bv.x; o.x = 0.5f * y0 * (1.f + erff(y0 * 0.70710678118f));
    float y1 = (v.y - m) * rst * gv.y + bv.y; o.y = 0.5f * y1 * (1.f + erff(y1 * 0.70710678118f));
    float y2 = (v.z - m) * rst * gv.z + bv.z; o.z = 0.5f * y2 * (1.f + erff(y2 * 0.70710678118f));
    float y3 = (v.w - m) * rst * gv.w + bv.w; o.w = 0.5f * y3 * (1.f + erff(y3 * 0.70710678118f));
    ((float4*)(out + (size_t)row * OUTq))[threadIdx.x] = o;
}

// ---------------- column softmax (over t) + weighted pool ----------------
__global__ __launch_bounds__(256) void k_softpool(const float* __restrict__ gm, const float* __restrict__ ym,
                                                  float* __restrict__ pooled) {
    int b = blockIdx.y;
    int j = blockIdx.x * 256 + threadIdx.x;
    const float* gb = gm + (size_t)b * NPq * OUTq + j;
    const float* yb = ym + (size_t)b * NPq * OUTq + j;
    float mx = -1e30f;
    for (int t = 0; t < NPq; t++) mx = fmaxf(mx, gb[(size_t)t * OUTq]);
    float s = 0.f, ps = 0.f;
    for (int t = 0; t < NPq; t++) {
        float e = __expf(gb[(size_t)t * OUTq] - mx);
        s += e;
        ps += yb[(size_t)t * OUTq] * e;
    }
    pooled[b * OUTq + j] = ps / s;
}

// ---------------- final LayerNorm over 1024 per batch ----------------
__global__ __launch_bounds__(256) void k_final_ln(const float* __restrict__ p, const float* __restrict__ g,
                                                  const float* __restrict__ bt, float* __restrict__ out) {
    int row = blockIdx.x;
    const float* x = p + (size_t)row * OUTq;
    float4 v = ((const float4*)x)[threadIdx.x];
    float s = v.x + v.y + v.z + v.w;
    float ss = v.x * v.x + v.y * v.y + v.z * v.z + v.w * v.w;
    #pragma unroll
    for (int off = 32; off >= 1; off >>= 1) { s += __shfl_down(s, off); ss += __shfl_down(ss, off); }
    __shared__ float sh[10];
    int wid = threadIdx.x >> 6, lid = threadIdx.x & 63;
    if (lid == 0) { sh[wid] = s; sh[4 + wid] = ss; }
    __syncthreads();
    if (threadIdx.x == 0) {
        float S = sh[0] + sh[1] + sh[2] + sh[3], SS = sh[4] + sh[5] + sh[6] + sh[7];
        float m = S * (1.f / OUTq);
        float var = SS * (1.f / OUTq) - m * m;
        sh[8] = m; sh[9] = rsqrtf(var + 1e-5f);
    }
    __syncthreads();
    float m = sh[8], rst = sh[9];
    float4 gv = ((const float4*)g)[threadIdx.x];
    float4 bv = ((const float4*)bt)[threadIdx.x];
    float4 o;
    o.x = (v.x - m) * rst * gv.x + bv.x;
    o.y = (v.y - m) * rst * gv.y + bv.y;
    o.z = (v.z - m) * rst * gv.z + bv.z;
    o.w = (v.w - m) * rst * gv.w + bv.w;
    ((float4*)(out + (size_t)row * OUTq))[threadIdx.x] = o;
}

extern "C" void kernel_launch(void* const* d_in, const int* in_sizes, int n_in,
                              void* d_out, int out_size, void* d_ws, size_t ws_size,
                              hipStream_t stream) {
    const float* img   = (const float*)d_in[0];
    const float* sa_w  = (const float*)d_in[1];
    const float* pe_w  = (const float*)d_in[2];
    const float* pe_b  = (const float*)d_in[3];
    const float* pos   = (const float*)d_in[4];
    const float* in_w  = (const float*)d_in[5];
    const float* in_b  = (const float*)d_in[6];
    const float* cv_w  = (const float*)d_in[7];
    const float* cv_b  = (const float*)d_in[8];
    const float* xp_w  = (const float*)d_in[9];
    const float* dt_w  = (const float*)d_in[10];
    const float* dt_b  = (const float*)d_in[11];
    const float* Alog  = (const float*)d_in[12];
    const float* Dv    = (const float*)d_in[13];
    const float* ot_w  = (const float*)d_in[14];
    const float* ot_b  = (const float*)d_in[15];
    const float* em_w  = (const float*)d_in[16];
    const float* em_b  = (const float*)d_in[17];
    const float* em_g  = (const float*)d_in[18];
    const float* em_bt = (const float*)d_in[19];
    const float* at_w  = (const float*)d_in[20];
    const float* at_b  = (const float*)d_in[21];
    const float* at_g  = (const float*)d_in[22];
    const float* at_bt = (const float*)d_in[23];
    const float* la_g  = (const float*)d_in[24];
    const float* la_bt = (const float*)d_in[25];

    char* ws = (char*)d_ws;
    auto al = [](size_t x) { return (x + 255) & ~(size_t)255; };
    size_t SZ_am  = (size_t)NB * 2 * IMP * 4;
    size_t SZ_G   = (size_t)ROWS * 768 * 4;
    size_t SZ_x   = SZ_G;
    size_t SZ_xr  = (size_t)ROWS * 3072 * 4;
    size_t SZ_xi2 = (size_t)ROWS * 1536 * 4;
    size_t SZ_de  = SZ_xi2;
    size_t SZ_dbc = (size_t)ROWS * 80 * 4;
    size_t SZ_ys  = SZ_xi2;
    size_t SZ_yem = (size_t)ROWS * 1024 * 4;
    size_t SZ_pool = (size_t)NB * OUTq * 4;
    size_t SZ_part = (size_t)XP_KS * ROWS * 80 * 4;   // 4 MB

    size_t o_am  = 0;
    size_t o_G   = al(o_am + SZ_am);
    size_t o_x   = al(o_G + SZ_G);
    size_t o_xr  = al(o_x + SZ_x);
    size_t o_xi2 = al(o_xr + SZ_xr);
    size_t o_de  = al(o_xi2 + SZ_xi2);
    size_t o_dbc = al(o_de + SZ_de);
    size_t o_ys  = al(o_dbc + SZ_dbc);
    size_t o_yem = al(o_ys + SZ_ys);
    size_t o_pool = al(o_yem + SZ_yem);
    size_t o_part = al(o_pool + SZ_pool);

    // bf16 transposed weights (persist whole launch) at tail
    size_t o_wpe  = al(o_part + SZ_part);
    size_t o_win0 = al(o_wpe  + (size_t)768 * 768 * 2);
    size_t o_win1 = al(o_win0 + (size_t)3072 * 768 * 2);
    size_t o_wot0 = al(o_win1 + (size_t)3072 * 768 * 2);
    size_t o_wot1 = al(o_wot0 + (size_t)768 * 1536 * 2);
    size_t o_wem  = al(o_wot1 + (size_t)768 * 1536 * 2);
    size_t o_wat  = al(o_wem  + (size_t)1024 * 768 * 2);

    float* am   = (float*)(ws + o_am);
    float* G    = (float*)(ws + o_G);
    float* x    = (float*)(ws + o_x);
    float* xr   = (float*)(ws + o_xr);
    float* xi2  = (float*)(ws + o_xi2);
    float* de   = (float*)(ws + o_de);
    float* dbc  = (float*)(ws + o_dbc);
    float* ys   = (float*)(ws + o_ys);
    float* yem  = (float*)(ws + o_yem);
    float* pool = (float*)(ws + o_pool);
    float* part = (float*)(ws + o_part);
    unsigned short* wpe  = (unsigned short*)(ws + o_wpe);
    unsigned short* win0 = (unsigned short*)(ws + o_win0);
    unsigned short* win1 = (unsigned short*)(ws + o_win1);
    unsigned short* wot0 = (unsigned short*)(ws + o_wot0);
    unsigned short* wot1 = (unsigned short*)(ws + o_wot1);
    unsigned short* wem  = (unsigned short*)(ws + o_wem);
    unsigned short* wat  = (unsigned short*)(ws + o_wat);
    // sres overlays am+G+x (dead between in-proj and out-GEMM of each layer);
    // t1 overlays same region during head; t2/gat overlay xr during head.
    float* sres = (float*)(ws + 0);                  // 19.3 MB < am+G+x (25.7 MB)
    float* t1  = (float*)(ws + 0);
    float* t2  = (float*)(ws + o_xr);
    float* gat = (float*)(ws + o_xr + ((size_t)16 << 20));

    // ---- weight conversion (W[K][N] -> bf16 [N][K]) ----
    k_transpose_bf<<<dim3(768 / 32, 768 / 32), 256, 0, stream>>>(pe_w, wpe, 768, 768);
    k_transpose_bf<<<dim3(3072 / 32, 768 / 32), 256, 0, stream>>>(in_w, win0, 768, 3072);
    k_transpose_bf<<<dim3(3072 / 32, 768 / 32), 256, 0, stream>>>(in_w + (size_t)768 * 3072, win1, 768, 3072);
    k_transpose_bf<<<dim3(768 / 32, 1536 / 32), 256, 0, stream>>>(ot_w, wot0, 1536, 768);
    k_transpose_bf<<<dim3(768 / 32, 1536 / 32), 256, 0, stream>>>(ot_w + (size_t)1536 * 768, wot1, 1536, 768);
    k_transpose_bf<<<dim3(1024 / 32, 768 / 32), 256, 0, stream>>>(em_w, wem, 768, 1024);
    k_transpose_bf<<<dim3(1024 / 32, 1024 / 32), 256, 0, stream>>>(at_w, wat, 1024, 1024);

    int npx = NB * IMP;
    k_avgmax<<<(npx + 255) / 256, 256, 0, stream>>>(img, am);
    k_gatepatch<<<(npx + 255) / 256, 256, 0, stream>>>(img, am, sa_w, G);

    dim3 blk(256);
    // patch embed: x = G @ pe_w + pe_b + pos
    k_gemm_bf<EPI_POSEMB><<<dim3(6, 25), blk, 0, stream>>>(G, 768, wpe, pe_b, x, 768, ROWS, 768, 768, pos);

    for (int l = 0; l < 2; l++) {
        const unsigned short* win = l ? win1 : win0;
        const unsigned short* wot = l ? wot1 : wot0;
        // xr = x @ in_w + in_b
        k_gemm_bf<EPI_NONE><<<dim3(24, 25), blk, 0, stream>>>(x, 768, win, in_b + l * 3072, xr, 3072,
                                                              ROWS, 3072, 768, nullptr);
        int ne = ROWS * DIq;
        k_conv_silu<<<(ne + 255) / 256, 256, 0, stream>>>(xr, cv_w + (size_t)l * DIq * 4, cv_b + l * DIq,
                                                          xi2, sres);
        // dbc = xi2 @ xproj_w (f32 split-K + reduce)
        k_xproj_part<<<dim3(ROWS / 32, XP_KS), blk, 0, stream>>>(xi2, xp_w + (size_t)l * 1536 * 80, part);
        k_xreduce<<<(ROWS * 80 / 4 + 255) / 256, 256, 0, stream>>>(part, dbc);
        // delta = softplus(dbc[:, :48] @ dt_w + dt_b)
        k_dt<<<ROWS / DT_RPB, 384, 0, stream>>>(dbc, dt_w + (size_t)l * 48 * 1536, dt_b + l * 1536, de);
        k_scan<<<dim3(16, 48), blk, 0, stream>>>(de, xi2, dbc, sres, Alog + (size_t)l * 1536 * 16,
                                                 Dv + l * 1536, ys);
        // x = ys @ out_w + out_b
        k_gemm_bf<EPI_NONE><<<dim3(6, 25), blk, 0, stream>>>(ys, 1536, wot, ot_b + l * 768, x, 768,
                                                             ROWS, 768, 1536, nullptr);
    }

    // head
    k_gemm_bf<EPI_NONE><<<dim3(8, 25), blk, 0, stream>>>(x, 768, wem, em_b, t1, 1024, ROWS, 1024, 768, nullptr);
    k_ln_gelu<<<ROWS, 256, 0, stream>>>(t1, em_g, em_bt, yem);
    k_gemm_bf<EPI_NONE><<<dim3(8, 25), blk, 0, stream>>>(yem, 1024, wat, at_b, t2, 1024, ROWS, 1024, 1024, nullptr);
    k_ln_gelu<<<ROWS, 256, 0, stream>>>(t2, at_g, at_bt, gat);
    k_softpool<<<dim3(4, NB), 256, 0, stream>>>(gat, yem, pool);
    k_final_ln<<<NB, 256, 0, stream>>>(pool, la_g, la_bt, (float*)d_out);
}

// Round 6
// 607.980 us; speedup vs baseline: 4.1010x; 1.3909x over previous
//
#include <hip/hip_runtime.h>
#include <math.h>

static constexpr int NB = 16;
static constexpr int NC = 3;
static constexpr int IM = 224;
static constexpr int IMP = IM * IM;      // 50176
static constexpr int HPq = 14;
static constexpr int NPq = 196;
static constexpr int OUTq = 1024;
static constexpr int DIq = 1536;
static constexpr int ROWS = NB * NPq;    // 3136
static constexpr int MPAD = 3200;        // 25*128, A-operand row padding

typedef __bf16 bf8_t __attribute__((ext_vector_type(8)));
typedef float f4_t __attribute__((ext_vector_type(4)));
typedef const __attribute__((address_space(1))) unsigned int cgu32;
typedef __attribute__((address_space(3))) unsigned int lu32;

__device__ inline unsigned short f2bf(float x) {
    unsigned u = __builtin_bit_cast(unsigned, x);
    unsigned r = (u + 0x7FFFu + ((u >> 16) & 1u)) >> 16;
    return (unsigned short)r;
}
__device__ inline float bf2f(unsigned short v) {
    return __builtin_bit_cast(float, (unsigned)v << 16);
}
__device__ inline float fast_sig(float x) {
    return __builtin_amdgcn_rcpf(1.f + __expf(-x));
}

// ---------------- K1a: channel avg/max ----------------
__global__ __launch_bounds__(256) void k_avgmax(const float* __restrict__ img, float* __restrict__ am) {
    int idx = blockIdx.x * 256 + threadIdx.x;
    if (idx >= NB * IMP) return;
    int p = idx % IMP, b = idx / IMP;
    const float* ib = img + (size_t)b * NC * IMP + p;
    float c0 = ib[0], c1 = ib[IMP], c2 = ib[2 * IMP];
    am[(size_t)(b * 2 + 0) * IMP + p] = (c0 + c1 + c2) * (1.f / 3.f);
    am[(size_t)(b * 2 + 1) * IMP + p] = fmaxf(c0, fmaxf(c1, c2));
}

// ---------------- K1b: 7x7 conv gate + patchify (G is bf16 now) ----------------
__global__ __launch_bounds__(256) void k_gatepatch(const float* __restrict__ img, const float* __restrict__ am,
                                                   const float* __restrict__ saw, unsigned short* __restrict__ G) {
    int idx = blockIdx.x * 256 + threadIdx.x;
    if (idx >= NB * IMP) return;
    int p = idx % IMP, b = idx / IMP;
    int y = p / IM, x = p % IM;
    float acc = 0.f;
    #pragma unroll
    for (int ci = 0; ci < 2; ci++) {
        const float* amc = am + (size_t)(b * 2 + ci) * IMP;
        const float* wc = saw + ci * 49;
        #pragma unroll
        for (int kh = 0; kh < 7; kh++) {
            int yy = y + kh - 3;
            if (yy < 0 || yy >= IM) continue;
            #pragma unroll
            for (int kw = 0; kw < 7; kw++) {
                int xx = x + kw - 3;
                if (xx < 0 || xx >= IM) continue;
                acc += amc[yy * IM + xx] * wc[kh * 7 + kw];
            }
        }
    }
    float s = fast_sig(acc);
    int hy = y >> 4, py = y & 15, hx = x >> 4, px = x & 15;
    size_t base = ((size_t)(b * NPq + hy * HPq + hx) * 768) + (size_t)(py * 16 + px) * 3;
    const float* ib = img + (size_t)b * NC * IMP + p;
    G[base + 0] = f2bf(ib[0] * s);
    G[base + 1] = f2bf(ib[IMP] * s);
    G[base + 2] = f2bf(ib[2 * IMP] * s);
}

// ---------------- weight transpose + f32->bf16: W[K][N] -> Wt[N][K] ----------------
__global__ __launch_bounds__(256) void k_transpose_bf(const float* __restrict__ W, unsigned short* __restrict__ Wt,
                                                      int K, int N) {
    __shared__ float t[32][33];
    int n0 = blockIdx.x * 32, k0 = blockIdx.y * 32;
    int c = threadIdx.x & 31, r8 = threadIdx.x >> 5;
    #pragma unroll
    for (int i = 0; i < 4; i++) {
        int r = r8 + i * 8;
        t[r][c] = W[(size_t)(k0 + r) * N + n0 + c];
    }
    __syncthreads();
    #pragma unroll
    for (int i = 0; i < 4; i++) {
        int r = r8 + i * 8;
        Wt[(size_t)(n0 + r) * K + k0 + c] = f2bf(t[c][r]);
    }
}

// ---------------- bf16 MFMA GEMM, gload_lds + double-buffer ----------------
// A: bf16 [MPAD][K]; Wt: bf16 [N][K]; C: f32 or bf16 [M][ldc]
enum { EPI_NONE = 0, EPI_POSEMB = 1 };

template<int EPI, bool CBF>
__global__ __launch_bounds__(256) void k_gemm_bf(const unsigned short* __restrict__ A,
                                                 const unsigned short* __restrict__ Wt,
                                                 const float* __restrict__ bias,
                                                 void* __restrict__ Cv, int ldc,
                                                 int M, int N, int K,
                                                 const float* __restrict__ extra) {
    constexpr int BM = 128, BN = 64;
    __shared__ __align__(16) unsigned short As[2][BM * 64];
    __shared__ __align__(16) unsigned short Bs[2][BN * 64];
    const int bm = blockIdx.y * BM, bn = blockIdx.x * BN;
    const int tid = threadIdx.x;
    const int lane = tid & 63;
    const int wbase = tid & ~63;                 // wid*64
    const int wr = ((tid >> 7) & 1) * 64;        // wave row offset (wid>>1)*64
    const int wc = ((tid >> 6) & 1) * 32;        // wave col offset (wid&1)*32
    const int lr = lane & 15, lq = lane >> 4;

    f4_t acc[4][2] = {};

    auto stage = [&](int buf, int k0) {
        #pragma unroll
        for (int i = 0; i < 4; i++) {            // A: 1024 groups of 8 bf16
            int gid2 = i * 256 + tid;
            int r = gid2 >> 3, g = gid2 & 7;
            const unsigned short* src = A + (size_t)(bm + r) * K + k0 + ((g ^ (r & 7)) * 8);
            __builtin_amdgcn_global_load_lds((cgu32*)src,
                (lu32*)&As[buf][(i * 256 + wbase) * 8], 16, 0, 0);
        }
        #pragma unroll
        for (int i = 0; i < 2; i++) {            // B: 512 groups
            int gid2 = i * 256 + tid;
            int r = gid2 >> 3, g = gid2 & 7;
            const unsigned short* src = Wt + (size_t)(bn + r) * K + k0 + ((g ^ (r & 7)) * 8);
            __builtin_amdgcn_global_load_lds((cgu32*)src,
                (lu32*)&Bs[buf][(i * 256 + wbase) * 8], 16, 0, 0);
        }
    };

    stage(0, 0);
    __syncthreads();
    int cur = 0;
    for (int k0 = 0; k0 < K; k0 += 64) {
        if (k0 + 64 < K) stage(cur ^ 1, k0 + 64);
        #pragma unroll
        for (int h = 0; h < 2; h++) {
            bf8_t af[4], bfr[2];
            #pragma unroll
            for (int mb = 0; mb < 4; mb++) {
                int row = wr + mb * 16 + lr;
                int g = h * 4 + lq;
                af[mb] = *(const bf8_t*)&As[cur][row * 64 + ((g ^ (row & 7)) * 8)];
            }
            #pragma unroll
            for (int nb = 0; nb < 2; nb++) {
                int rn = wc + nb * 16 + lr;
                int g = h * 4 + lq;
                bfr[nb] = *(const bf8_t*)&Bs[cur][rn * 64 + ((g ^ (rn & 7)) * 8)];
            }
            #pragma unroll
            for (int mb = 0; mb < 4; mb++)
                #pragma unroll
                for (int nb = 0; nb < 2; nb++)
                    acc[mb][nb] = __builtin_amdgcn_mfma_f32_16x16x32_bf16(af[mb], bfr[nb], acc[mb][nb], 0, 0, 0);
        }
        __syncthreads();                         // drains in-flight stage + protects LDS reuse
        cur ^= 1;
    }

    #pragma unroll
    for (int mb = 0; mb < 4; mb++) {
        #pragma unroll
        for (int nb = 0; nb < 2; nb++) {
            int col = bn + wc + nb * 16 + lr;
            #pragma unroll
            for (int q = 0; q < 4; q++) {
                int row = bm + wr + mb * 16 + lq * 4 + q;
                if (row < M) {
                    float v = acc[mb][nb][q];
                    if (bias) v += bias[col];
                    if (EPI == EPI_POSEMB) v += extra[(size_t)(row % NPq) * N + col];
                    if (CBF) ((unsigned short*)Cv)[(size_t)row * ldc + col] = f2bf(v);
                    else     ((float*)Cv)[(size_t)row * ldc + col] = v;
                }
            }
        }
    }
}

// ---------------- xproj split-K f32 GEMM ----------------
static constexpr int XP_KS = 4;
static constexpr int XP_KC = 1536 / XP_KS;   // 384

__global__ __launch_bounds__(256) void k_xproj_part(const float* __restrict__ xi2, const float* __restrict__ W,
                                                    float* __restrict__ part) {
    __shared__ float As[32][65];
    __shared__ __align__(16) float Bs[64][80];
    int m0 = blockIdx.x * 32;
    int kc0 = blockIdx.y * XP_KC;
    int tid = threadIdx.x;
    int row = tid >> 3, cg = (tid & 7) * 10;
    float acc[10] = {};
    for (int k0 = 0; k0 < XP_KC; k0 += 64) {
        #pragma unroll
        for (int i = 0; i < 2; i++) {
            int id = tid + i * 256;
            int r = id >> 4, c4 = (id & 15) * 4;
            float4 v = *(const float4*)(xi2 + (size_t)(m0 + r) * 1536 + kc0 + k0 + c4);
            As[r][c4] = v.x; As[r][c4 + 1] = v.y; As[r][c4 + 2] = v.z; As[r][c4 + 3] = v.w;
        }
        #pragma unroll
        for (int i = 0; i < 5; i++) {
            int id = tid + i * 256;
            int r = id / 20, c4 = (id % 20) * 4;
            *(float4*)&Bs[r][c4] = *(const float4*)(W + (size_t)(kc0 + k0 + r) * 80 + c4);
        }
        __syncthreads();
        #pragma unroll
        for (int kk = 0; kk < 64; kk++) {
            float a = As[row][kk];
            #pragma unroll
            for (int j = 0; j < 10; j++)
                acc[j] = fmaf(a, Bs[kk][cg + j], acc[j]);
        }
        __syncthreads();
    }
    float* p = part + ((size_t)blockIdx.y * ROWS + m0 + row) * 80 + cg;
    #pragma unroll
    for (int j = 0; j < 10; j++) p[j] = acc[j];
}

__global__ __launch_bounds__(256) void k_xreduce(const float* __restrict__ part, float* __restrict__ dbc) {
    int idx = (blockIdx.x * 256 + threadIdx.x) * 4;
    if (idx >= ROWS * 80) return;
    const int S = ROWS * 80;
    float4 a = *(const float4*)(part + idx);
    float4 b = *(const float4*)(part + S + idx);
    float4 c = *(const float4*)(part + 2 * S + idx);
    float4 d = *(const float4*)(part + 3 * S + idx);
    float4 o;
    o.x = a.x + b.x + c.x + d.x;
    o.y = a.y + b.y + c.y + d.y;
    o.z = a.z + b.z + c.z + d.z;
    o.w = a.w + b.w + c.w + d.w;
    *(float4*)(dbc + idx) = o;
}

// ---------------- dt GEMM (K=48) + softplus ----------------
static constexpr int DT_RPB = 4;
__global__ __launch_bounds__(384) void k_dt(const float* __restrict__ dbc, const float* __restrict__ W,
                                            const float* __restrict__ bias, float* __restrict__ de) {
    int r0 = blockIdx.x * DT_RPB;
    int j = threadIdx.x * 4;
    __shared__ float ds[DT_RPB][48];
    if (threadIdx.x < DT_RPB * 48)
        ds[threadIdx.x / 48][threadIdx.x % 48] = dbc[(size_t)(r0 + threadIdx.x / 48) * 80 + threadIdx.x % 48];
    __syncthreads();
    float4 b = *(const float4*)(bias + j);
    float4 a0 = b, a1 = b, a2 = b, a3 = b;
    for (int k = 0; k < 48; k++) {
        float4 w = *(const float4*)(W + (size_t)k * 1536 + j);
        float d0 = ds[0][k], d1 = ds[1][k], d2 = ds[2][k], d3 = ds[3][k];
        a0.x = fmaf(d0, w.x, a0.x); a0.y = fmaf(d0, w.y, a0.y); a0.z = fmaf(d0, w.z, a0.z); a0.w = fmaf(d0, w.w, a0.w);
        a1.x = fmaf(d1, w.x, a1.x); a1.y = fmaf(d1, w.y, a1.y); a1.z = fmaf(d1, w.z, a1.z); a1.w = fmaf(d1, w.w, a1.w);
        a2.x = fmaf(d2, w.x, a2.x); a2.y = fmaf(d2, w.y, a2.y); a2.z = fmaf(d2, w.z, a2.z); a2.w = fmaf(d2, w.w, a2.w);
        a3.x = fmaf(d3, w.x, a3.x); a3.y = fmaf(d3, w.y, a3.y); a3.z = fmaf(d3, w.z, a3.z); a3.w = fmaf(d3, w.w, a3.w);
    }
    auto sp = [](float v) { return (v > 20.f) ? v : log1pf(expf(v)); };
    float4 o;
    o.x = sp(a0.x); o.y = sp(a0.y); o.z = sp(a0.z); o.w = sp(a0.w);
    *(float4*)(de + (size_t)(r0 + 0) * 1536 + j) = o;
    o.x = sp(a1.x); o.y = sp(a1.y); o.z = sp(a1.z); o.w = sp(a1.w);
    *(float4*)(de + (size_t)(r0 + 1) * 1536 + j) = o;
    o.x = sp(a2.x); o.y = sp(a2.y); o.z = sp(a2.z); o.w = sp(a2.w);
    *(float4*)(de + (size_t)(r0 + 2) * 1536 + j) = o;
    o.x = sp(a3.x); o.y = sp(a3.y); o.z = sp(a3.z); o.w = sp(a3.w);
    *(float4*)(de + (size_t)(r0 + 3) * 1536 + j) = o;
}

// ---------------- causal depthwise conv (DC=4) + silu; also sres = silu(res) ----------------
__global__ __launch_bounds__(256) void k_conv_silu(const float* __restrict__ xr, const float* __restrict__ cw,
                                                   const float* __restrict__ cb, float* __restrict__ xi2,
                                                   float* __restrict__ sres) {
    int idx = blockIdx.x * 256 + threadIdx.x;
    if (idx >= ROWS * DIq) return;
    int d = idx % DIq; int bt = idx / DIq; int t = bt % NPq; int b = bt / NPq;
    float w0 = cw[d * 4 + 0], w1 = cw[d * 4 + 1], w2 = cw[d * 4 + 2], w3 = cw[d * 4 + 3];
    float s = cb[d];
    const float* base = xr + (size_t)b * NPq * 3072 + d;
    if (t >= 3) s += base[(size_t)(t - 3) * 3072] * w0;
    if (t >= 2) s += base[(size_t)(t - 2) * 3072] * w1;
    if (t >= 1) s += base[(size_t)(t - 1) * 3072] * w2;
    s += base[(size_t)t * 3072] * w3;
    xi2[idx] = s * fast_sig(s);
    float r = xr[(size_t)bt * 3072 + 1536 + d];
    sres[idx] = r * fast_sig(r);
}

// ---------------- selective-scan, LDS-tiled; ys out is bf16 ----------------
static constexpr int STB = 28;

__global__ __launch_bounds__(256) void k_scan(const float* __restrict__ delta, const float* __restrict__ xi2,
                                              const float* __restrict__ dbc, const float* __restrict__ sres,
                                              const float* __restrict__ Alog, const float* __restrict__ Dv,
                                              unsigned short* __restrict__ ys) {
    const int b = blockIdx.x;
    const int d0 = blockIdx.y * 32;
    const int tid = threadIdx.x;
    const int dl = tid >> 3;
    const int np = tid & 7;
    const int d = d0 + dl;
    const float A0 = -__expf(Alog[d * 16 + np]);
    const float A1 = -__expf(Alog[d * 16 + np + 8]);
    const float Dd = Dv[d];
    const int tr = tid >> 5;
    const int dls = tid & 31;

    __shared__ float sdu[STB][64];
    __shared__ float sbc[STB][32];
    __shared__ float ssr[STB][32];

    const float* gde = delta + ((size_t)b * NPq + tr) * DIq + d0 + dls;
    const float* gu  = xi2   + ((size_t)b * NPq + tr) * DIq + d0 + dls;
    const float* gsr = sres  + ((size_t)b * NPq + tr) * DIq + d0 + dls;
    const float* gbc = dbc   + ((size_t)b * NPq + tr) * 80 + 48 + dls;
    unsigned short* gy = ys + (size_t)b * NPq * DIq + d;

    float rde[4], ru[4], rsr[4], rbc[4];

    auto stageLoad = [&](int c) {
        const int t0 = c * STB;
        #pragma unroll
        for (int j = 0; j < 3; j++) {
            int off = (t0 + 8 * j) * DIq;
            rde[j] = gde[off];
            ru[j]  = gu[off];
            rsr[j] = gsr[off];
            rbc[j] = gbc[(t0 + 8 * j) * 80];
        }
        if (tid < 128) {
            int off = (t0 + 24) * DIq;
            rde[3] = gde[off];
            ru[3]  = gu[off];
            rsr[3] = gsr[off];
            rbc[3] = gbc[(t0 + 24) * 80];
        }
    };
    auto stageWrite = [&]() {
        const int pi = (dls & 7) * 4 + (dls >> 3);
        #pragma unroll
        for (int j = 0; j < 3; j++) {
            int t = tr + 8 * j;
            sdu[t][dls * 2 + 0] = rde[j];
            sdu[t][dls * 2 + 1] = ru[j];
            ssr[t][dls] = rsr[j];
            sbc[t][pi] = rbc[j];
        }
        if (tid < 128) {
            int t = tr + 24;
            sdu[t][dls * 2 + 0] = rde[3];
            sdu[t][dls * 2 + 1] = ru[3];
            ssr[t][dls] = rsr[3];
            sbc[t][pi] = rbc[3];
        }
    };

    stageLoad(0);
    stageWrite();
    __syncthreads();

    float h0 = 0.f, h1 = 0.f;
    for (int c = 0; c < 7; c++) {
        if (c < 6) stageLoad(c + 1);
        #pragma unroll 4
        for (int t = 0; t < STB; t++) {
            float2 du = *(const float2*)&sdu[t][dl * 2];
            float4 bc = *(const float4*)&sbc[t][np * 4];
            float sr = ssr[t][dl];
            float a0 = __expf(du.x * A0), a1 = __expf(du.x * A1);
            float deu = du.x * du.y;
            h0 = fmaf(a0, h0, deu * bc.x);
            h1 = fmaf(a1, h1, deu * bc.y);
            float p = fmaf(h1, bc.w, h0 * bc.z);
            p += __shfl_xor(p, 1);
            p += __shfl_xor(p, 2);
            p += __shfl_xor(p, 4);
            if (np == 0) gy[(size_t)(c * STB + t) * DIq] = f2bf(fmaf(Dd, du.y, p) * sr);
        }
        __syncthreads();
        if (c < 6) {
            stageWrite();
            __syncthreads();
        }
    }
}

// ---------------- row LayerNorm (1024) + exact gelu; out f32 or bf16 ----------------
template<bool OBF>
__global__ __launch_bounds__(256) void k_ln_gelu(const float* __restrict__ in, const float* __restrict__ g,
                                                 const float* __restrict__ bt, void* __restrict__ outv) {
    int row = blockIdx.x;
    const float* x = in + (size_t)row * OUTq;
    float4 v = ((const float4*)x)[threadIdx.x];
    float s = v.x + v.y + v.z + v.w;
    float ss = v.x * v.x + v.y * v.y + v.z * v.z + v.w * v.w;
    #pragma unroll
    for (int off = 32; off >= 1; off >>= 1) { s += __shfl_down(s, off); ss += __shfl_down(ss, off); }
    __shared__ float sh[10];
    int wid = threadIdx.x >> 6, lid = threadIdx.x & 63;
    if (lid == 0) { sh[wid] = s; sh[4 + wid] = ss; }
    __syncthreads();
    if (threadIdx.x == 0) {
        float S = sh[0] + sh[1] + sh[2] + sh[3], SS = sh[4] + sh[5] + sh[6] + sh[7];
        float m = S * (1.f / OUTq);
        float var = SS * (1.f / OUTq) - m * m;
        sh[8] = m; sh[9] = rsqrtf(var + 1e-5f);
    }
    __syncthreads();
    float m = sh[8], rst = sh[9];
    float4 gv = ((const float4*)g)[threadIdx.x];
    float4 bv = ((const float4*)bt)[threadIdx.x];
    float4 o;
    float y0 = (v.x - m) * rst * gv.x + bv.x; o.x = 0.5f * y0 * (1.f + erff(y0 * 0.70710678118f));
    float y1 = (v.y - m) * rst * gv.y + bv.y; o.y = 0.5f * y1 * (1.f + erff(y1 * 0.70710678118f));
    float y2 = (v.z - m) * rst * gv.z + bv.z; o.z = 0.5f * y2 * (1.f + erff(y2 * 0.70710678118f));
    float y3 = (v.w - m) * rst * gv.w + bv.w; o.w = 0.5f * y3 * (1.f + erff(y3 * 0.70710678118f));
    if (OBF) {
        ushort4 o4;
        o4.x = f2bf(o.x); o4.y = f2bf(o.y); o4.z = f2bf(o.z); o4.w = f2bf(o.w);
        ((ushort4*)((unsigned short*)outv + (size_t)row * OUTq))[threadIdx.x] = o4;
    } else {
        ((float4*)((float*)outv + (size_t)row * OUTq))[threadIdx.x] = o;
    }
}

// ---------------- column softmax (over t) + weighted pool; ym is bf16 ----------------
__global__ __launch_bounds__(256) void k_softpool(const float* __restrict__ gm, const unsigned short* __restrict__ ym,
                                                  float* __restrict__ pooled) {
    int b = blockIdx.y;
    int j = blockIdx.x * 256 + threadIdx.x;
    const float* gb = gm + (size_t)b * NPq * OUTq + j;
    const unsigned short* yb = ym + (size_t)b * NPq * OUTq + j;
    float mx = -1e30f;
    for (int t = 0; t < NPq; t++) mx = fmaxf(mx, gb[(size_t)t * OUTq]);
    float s = 0.f, ps = 0.f;
    for (int t = 0; t < NPq; t++) {
        float e = __expf(gb[(size_t)t * OUTq] - mx);
        s += e;
        ps += bf2f(yb[(size_t)t * OUTq]) * e;
    }
    pooled[b * OUTq + j] = ps / s;
}

// ---------------- final LayerNorm over 1024 per batch ----------------
__global__ __launch_bounds__(256) void k_final_ln(const float* __restrict__ p, const float* __restrict__ g,
                                                  const float* __restrict__ bt, float* __restrict__ out) {
    int row = blockIdx.x;
    const float* x = p + (size_t)row * OUTq;
    float4 v = ((const float4*)x)[threadIdx.x];
    float s = v.x + v.y + v.z + v.w;
    float ss = v.x * v.x + v.y * v.y + v.z * v.z + v.w * v.w;
    #pragma unroll
    for (int off = 32; off >= 1; off >>= 1) { s += __shfl_down(s, off); ss += __shfl_down(ss, off); }
    __shared__ float sh[10];
    int wid = threadIdx.x >> 6, lid = threadIdx.x & 63;
    if (lid == 0) { sh[wid] = s; sh[4 + wid] = ss; }
    __syncthreads();
    if (threadIdx.x == 0) {
        float S = sh[0] + sh[1] + sh[2] + sh[3], SS = sh[4] + sh[5] + sh[6] + sh[7];
        float m = S * (1.f / OUTq);
        float var = SS * (1.f / OUTq) - m * m;
        sh[8] = m; sh[9] = rsqrtf(var + 1e-5f);
    }
    __syncthreads();
    float m = sh[8], rst = sh[9];
    float4 gv = ((const float4*)g)[threadIdx.x];
    float4 bv = ((const float4*)bt)[threadIdx.x];
    float4 o;
    o.x = (v.x - m) * rst * gv.x + bv.x;
    o.y = (v.y - m) * rst * gv.y + bv.y;
    o.z = (v.z - m) * rst * gv.z + bv.z;
    o.w = (v.w - m) * rst * gv.w + bv.w;
    ((float4*)(out + (size_t)row * OUTq))[threadIdx.x] = o;
}

extern "C" void kernel_launch(void* const* d_in, const int* in_sizes, int n_in,
                              void* d_out, int out_size, void* d_ws, size_t ws_size,
                              hipStream_t stream) {
    const float* img   = (const float*)d_in[0];
    const float* sa_w  = (const float*)d_in[1];
    const float* pe_w  = (const float*)d_in[2];
    const float* pe_b  = (const float*)d_in[3];
    const float* pos   = (const float*)d_in[4];
    const float* in_w  = (const float*)d_in[5];
    const float* in_b  = (const float*)d_in[6];
    const float* cv_w  = (const float*)d_in[7];
    const float* cv_b  = (const float*)d_in[8];
    const float* xp_w  = (const float*)d_in[9];
    const float* dt_w  = (const float*)d_in[10];
    const float* dt_b  = (const float*)d_in[11];
    const float* Alog  = (const float*)d_in[12];
    const float* Dv    = (const float*)d_in[13];
    const float* ot_w  = (const float*)d_in[14];
    const float* ot_b  = (const float*)d_in[15];
    const float* em_w  = (const float*)d_in[16];
    const float* em_b  = (const float*)d_in[17];
    const float* em_g  = (const float*)d_in[18];
    const float* em_bt = (const float*)d_in[19];
    const float* at_w  = (const float*)d_in[20];
    const float* at_b  = (const float*)d_in[21];
    const float* at_g  = (const float*)d_in[22];
    const float* at_bt = (const float*)d_in[23];
    const float* la_g  = (const float*)d_in[24];
    const float* la_bt = (const float*)d_in[25];

    char* ws = (char*)d_ws;
    auto al = [](size_t x) { return (x + 255) & ~(size_t)255; };
    size_t SZ_am   = (size_t)NB * 2 * IMP * 4;        // 6.42 MB
    size_t SZ_G    = (size_t)MPAD * 768 * 2;          // 4.92 MB (bf16, padded)
    size_t SZ_x    = (size_t)MPAD * 768 * 2;          // bf16, padded
    size_t SZ_xr   = (size_t)ROWS * 3072 * 4;         // 38.5 MB
    size_t SZ_xi2  = (size_t)ROWS * 1536 * 4;         // 19.3 MB
    size_t SZ_de   = SZ_xi2;
    size_t SZ_dbc  = (size_t)ROWS * 80 * 4;
    size_t SZ_ys   = (size_t)MPAD * 1536 * 2;         // bf16, padded
    size_t SZ_sres = SZ_xi2;
    size_t SZ_yem  = (size_t)MPAD * 1024 * 2;         // bf16, padded
    size_t SZ_pool = (size_t)NB * OUTq * 4;
    size_t SZ_part = (size_t)XP_KS * ROWS * 80 * 4;

    size_t o_am   = 0;
    size_t o_G    = al(o_am + SZ_am);
    size_t o_x    = al(o_G + SZ_G);
    size_t o_xr   = al(o_x + SZ_x);
    size_t o_xi2  = al(o_xr + SZ_xr);
    size_t o_de   = al(o_xi2 + SZ_xi2);
    size_t o_dbc  = al(o_de + SZ_de);
    size_t o_ys   = al(o_dbc + SZ_dbc);
    size_t o_sres = al(o_ys + SZ_ys);
    size_t o_yem  = al(o_sres + SZ_sres);
    size_t o_pool = al(o_yem + SZ_yem);
    size_t o_part = al(o_pool + SZ_pool);

    size_t o_wpe  = al(o_part + SZ_part);
    size_t o_win0 = al(o_wpe  + (size_t)768 * 768 * 2);
    size_t o_win1 = al(o_win0 + (size_t)3072 * 768 * 2);
    size_t o_wot0 = al(o_win1 + (size_t)3072 * 768 * 2);
    size_t o_wot1 = al(o_wot0 + (size_t)768 * 1536 * 2);
    size_t o_wem  = al(o_wot1 + (size_t)768 * 1536 * 2);
    size_t o_wat  = al(o_wem  + (size_t)1024 * 768 * 2);

    float* am    = (float*)(ws + o_am);
    unsigned short* G  = (unsigned short*)(ws + o_G);
    unsigned short* x  = (unsigned short*)(ws + o_x);
    float* xr    = (float*)(ws + o_xr);
    float* xi2   = (float*)(ws + o_xi2);
    float* de    = (float*)(ws + o_de);
    float* dbc   = (float*)(ws + o_dbc);
    unsigned short* ys = (unsigned short*)(ws + o_ys);
    float* sres  = (float*)(ws + o_sres);
    unsigned short* yem = (unsigned short*)(ws + o_yem);
    float* pool  = (float*)(ws + o_pool);
    float* part  = (float*)(ws + o_part);
    unsigned short* wpe  = (unsigned short*)(ws + o_wpe);
    unsigned short* win0 = (unsigned short*)(ws + o_win0);
    unsigned short* win1 = (unsigned short*)(ws + o_win1);
    unsigned short* wot0 = (unsigned short*)(ws + o_wot0);
    unsigned short* wot1 = (unsigned short*)(ws + o_wot1);
    unsigned short* wem  = (unsigned short*)(ws + o_wem);
    unsigned short* wat  = (unsigned short*)(ws + o_wat);
    // head-phase overlays (xr/de/xi2 dead once layers finish)
    float* t1  = (float*)(ws + o_xr);
    float* t2  = (float*)(ws + o_de);
    float* gat = (float*)(ws + o_xi2);

    // ---- weight conversion (W[K][N] -> bf16 [N][K]) ----
    k_transpose_bf<<<dim3(768 / 32, 768 / 32), 256, 0, stream>>>(pe_w, wpe, 768, 768);
    k_transpose_bf<<<dim3(3072 / 32, 768 / 32), 256, 0, stream>>>(in_w, win0, 768, 3072);
    k_transpose_bf<<<dim3(3072 / 32, 768 / 32), 256, 0, stream>>>(in_w + (size_t)768 * 3072, win1, 768, 3072);
    k_transpose_bf<<<dim3(768 / 32, 1536 / 32), 256, 0, stream>>>(ot_w, wot0, 1536, 768);
    k_transpose_bf<<<dim3(768 / 32, 1536 / 32), 256, 0, stream>>>(ot_w + (size_t)1536 * 768, wot1, 1536, 768);
    k_transpose_bf<<<dim3(1024 / 32, 768 / 32), 256, 0, stream>>>(em_w, wem, 768, 1024);
    k_transpose_bf<<<dim3(1024 / 32, 1024 / 32), 256, 0, stream>>>(at_w, wat, 1024, 1024);

    int npx = NB * IMP;
    k_avgmax<<<(npx + 255) / 256, 256, 0, stream>>>(img, am);
    k_gatepatch<<<(npx + 255) / 256, 256, 0, stream>>>(img, am, sa_w, G);

    dim3 blk(256);
    // patch embed: x(bf16) = G @ pe_w + pe_b + pos
    k_gemm_bf<EPI_POSEMB, true><<<dim3(12, 25), blk, 0, stream>>>(G, wpe, pe_b, x, 768, ROWS, 768, 768, pos);

    for (int l = 0; l < 2; l++) {
        const unsigned short* win = l ? win1 : win0;
        const unsigned short* wot = l ? wot1 : wot0;
        // xr(f32) = x @ in_w + in_b
        k_gemm_bf<EPI_NONE, false><<<dim3(48, 25), blk, 0, stream>>>(x, win, in_b + l * 3072, xr, 3072,
                                                                     ROWS, 3072, 768, nullptr);
        int ne = ROWS * DIq;
        k_conv_silu<<<(ne + 255) / 256, 256, 0, stream>>>(xr, cv_w + (size_t)l * DIq * 4, cv_b + l * DIq,
                                                          xi2, sres);
        k_xproj_part<<<dim3(ROWS / 32, XP_KS), blk, 0, stream>>>(xi2, xp_w + (size_t)l * 1536 * 80, part);
        k_xreduce<<<(ROWS * 80 / 4 + 255) / 256, 256, 0, stream>>>(part, dbc);
        k_dt<<<ROWS / DT_RPB, 384, 0, stream>>>(dbc, dt_w + (size_t)l * 48 * 1536, dt_b + l * 1536, de);
        k_scan<<<dim3(16, 48), blk, 0, stream>>>(de, xi2, dbc, sres, Alog + (size_t)l * 1536 * 16,
                                                 Dv + l * 1536, ys);
        // x(bf16) = ys @ out_w + out_b
        k_gemm_bf<EPI_NONE, true><<<dim3(12, 25), blk, 0, stream>>>(ys, wot, ot_b + l * 768, x, 768,
                                                                    ROWS, 768, 1536, nullptr);
    }

    // head
    k_gemm_bf<EPI_NONE, false><<<dim3(16, 25), blk, 0, stream>>>(x, wem, em_b, t1, 1024, ROWS, 1024, 768, nullptr);
    k_ln_gelu<true><<<ROWS, 256, 0, stream>>>(t1, em_g, em_bt, yem);
    k_gemm_bf<EPI_NONE, false><<<dim3(16, 25), blk, 0, stream>>>(yem, wat, at_b, t2, 1024, ROWS, 1024, 1024, nullptr);
    k_ln_gelu<false><<<ROWS, 256, 0, stream>>>(t2, at_g, at_bt, gat);
    k_softpool<<<dim3(4, NB), 256, 0, stream>>>(gat, yem, pool);
    k_final_ln<<<NB, 256, 0, stream>>>(pool, la_g, la_bt, (float*)d_out);
}

// Round 7
// 563.580 us; speedup vs baseline: 4.4241x; 1.0788x over previous
//
#include <hip/hip_runtime.h>
#include <math.h>

static constexpr int NB = 16;
static constexpr int NC = 3;
static constexpr int IM = 224;
static constexpr int IMP = IM * IM;      // 50176
static constexpr int HPq = 14;
static constexpr int NPq = 196;
static constexpr int OUTq = 1024;
static constexpr int DIq = 1536;
static constexpr int ROWS = NB * NPq;    // 3136
static constexpr int MPAD = 3200;        // 25*128, A-operand row padding

typedef __bf16 bf8_t __attribute__((ext_vector_type(8)));
typedef float f4_t __attribute__((ext_vector_type(4)));
typedef const __attribute__((address_space(1))) unsigned int cgu32;
typedef __attribute__((address_space(3))) unsigned int lu32;

__device__ inline unsigned short f2bf(float x) {
    unsigned u = __builtin_bit_cast(unsigned, x);
    unsigned r = (u + 0x7FFFu + ((u >> 16) & 1u)) >> 16;
    return (unsigned short)r;
}
__device__ inline float bf2f(unsigned short v) {
    return __builtin_bit_cast(float, (unsigned)v << 16);
}
__device__ inline float fast_sig(float x) {
    return __builtin_amdgcn_rcpf(1.f + __expf(-x));
}

// ---------------- K1a: channel avg/max (float4, 4 px/thread) ----------------
__global__ __launch_bounds__(256) void k_avgmax(const float* __restrict__ img, float* __restrict__ am) {
    int idx = blockIdx.x * 256 + threadIdx.x;
    if (idx >= NB * IMP / 4) return;
    int p4 = (idx % (IMP / 4)) * 4, b = idx / (IMP / 4);
    const float* ib = img + (size_t)b * NC * IMP + p4;
    float4 c0 = *(const float4*)ib;
    float4 c1 = *(const float4*)(ib + IMP);
    float4 c2 = *(const float4*)(ib + 2 * IMP);
    float4 av, mx;
    av.x = (c0.x + c1.x + c2.x) * (1.f / 3.f); mx.x = fmaxf(c0.x, fmaxf(c1.x, c2.x));
    av.y = (c0.y + c1.y + c2.y) * (1.f / 3.f); mx.y = fmaxf(c0.y, fmaxf(c1.y, c2.y));
    av.z = (c0.z + c1.z + c2.z) * (1.f / 3.f); mx.z = fmaxf(c0.z, fmaxf(c1.z, c2.z));
    av.w = (c0.w + c1.w + c2.w) * (1.f / 3.f); mx.w = fmaxf(c0.w, fmaxf(c1.w, c2.w));
    *(float4*)(am + (size_t)(b * 2 + 0) * IMP + p4) = av;
    *(float4*)(am + (size_t)(b * 2 + 1) * IMP + p4) = mx;
}

// ---------------- K1b: 7x7 conv gate + patchify, 4 px/thread, float4 windows ----------------
__global__ __launch_bounds__(256) void k_gatepatch(const float* __restrict__ img, const float* __restrict__ am,
                                                   const float* __restrict__ saw, unsigned short* __restrict__ G) {
    int quad = blockIdx.x * 256 + threadIdx.x;
    if (quad >= NB * IMP / 4) return;
    int pq = quad % (IMP / 4), b = quad / (IMP / 4);
    int x0 = (pq % 56) * 4;
    int y = pq / 56;
    float acc0 = 0.f, acc1 = 0.f, acc2 = 0.f, acc3 = 0.f;
    const bool lok = (x0 >= 4), rok = (x0 <= IM - 8);
    #pragma unroll
    for (int ci = 0; ci < 2; ci++) {
        const float* amc = am + (size_t)(b * 2 + ci) * IMP;
        const float* wc = saw + ci * 49;
        #pragma unroll
        for (int kh = 0; kh < 7; kh++) {
            int yy = y + kh - 3;
            if (yy < 0 || yy >= IM) continue;
            const float* rowp = amc + yy * IM;
            float4 lv = lok ? *(const float4*)(rowp + x0 - 4) : make_float4(0.f, 0.f, 0.f, 0.f);
            float4 mv = *(const float4*)(rowp + x0);
            float4 rv = rok ? *(const float4*)(rowp + x0 + 4) : make_float4(0.f, 0.f, 0.f, 0.f);
            float f[12] = {lv.x, lv.y, lv.z, lv.w, mv.x, mv.y, mv.z, mv.w, rv.x, rv.y, rv.z, rv.w};
            #pragma unroll
            for (int kw = 0; kw < 7; kw++) {
                float w = wc[kh * 7 + kw];
                acc0 = fmaf(w, f[kw + 1], acc0);
                acc1 = fmaf(w, f[kw + 2], acc1);
                acc2 = fmaf(w, f[kw + 3], acc2);
                acc3 = fmaf(w, f[kw + 4], acc3);
            }
        }
    }
    float s0 = fast_sig(acc0), s1 = fast_sig(acc1), s2 = fast_sig(acc2), s3 = fast_sig(acc3);
    const float* ib = img + (size_t)b * NC * IMP + y * IM + x0;
    float4 c0 = *(const float4*)ib;
    float4 c1 = *(const float4*)(ib + IMP);
    float4 c2 = *(const float4*)(ib + 2 * IMP);
    int hy = y >> 4, py = y & 15, hx = x0 >> 4, px0 = x0 & 15;
    size_t base = ((size_t)(b * NPq + hy * HPq + hx) * 768) + (size_t)(py * 16 + px0) * 3;
    ushort4 o0, o1, o2;
    o0.x = f2bf(c0.x * s0); o0.y = f2bf(c1.x * s0); o0.z = f2bf(c2.x * s0);
    o0.w = f2bf(c0.y * s1);
    o1.x = f2bf(c1.y * s1); o1.y = f2bf(c2.y * s1);
    o1.z = f2bf(c0.z * s2); o1.w = f2bf(c1.z * s2);
    o2.x = f2bf(c2.z * s2);
    o2.y = f2bf(c0.w * s3); o2.z = f2bf(c1.w * s3); o2.w = f2bf(c2.w * s3);
    *(ushort4*)(G + base + 0) = o0;
    *(ushort4*)(G + base + 4) = o1;
    *(ushort4*)(G + base + 8) = o2;
}

// ---------------- weight transpose + f32->bf16: W[K][N] -> Wt[N][K] ----------------
__global__ __launch_bounds__(256) void k_transpose_bf(const float* __restrict__ W, unsigned short* __restrict__ Wt,
                                                      int K, int N) {
    __shared__ float t[32][33];
    int n0 = blockIdx.x * 32, k0 = blockIdx.y * 32;
    int c = threadIdx.x & 31, r8 = threadIdx.x >> 5;
    #pragma unroll
    for (int i = 0; i < 4; i++) {
        int r = r8 + i * 8;
        t[r][c] = W[(size_t)(k0 + r) * N + n0 + c];
    }
    __syncthreads();
    #pragma unroll
    for (int i = 0; i < 4; i++) {
        int r = r8 + i * 8;
        Wt[(size_t)(n0 + r) * K + k0 + c] = f2bf(t[c][r]);
    }
}

// ---------------- bf16 MFMA GEMM, gload_lds + double-buffer ----------------
enum { EPI_NONE = 0, EPI_POSEMB = 1 };

template<int EPI, bool CBF>
__global__ __launch_bounds__(256) void k_gemm_bf(const unsigned short* __restrict__ A,
                                                 const unsigned short* __restrict__ Wt,
                                                 const float* __restrict__ bias,
                                                 void* __restrict__ Cv, int ldc,
                                                 int M, int N, int K,
                                                 const float* __restrict__ extra) {
    constexpr int BM = 128, BN = 64;
    __shared__ __align__(16) unsigned short As[2][BM * 64];
    __shared__ __align__(16) unsigned short Bs[2][BN * 64];
    const int bm = blockIdx.y * BM, bn = blockIdx.x * BN;
    const int tid = threadIdx.x;
    const int lane = tid & 63;
    const int wbase = tid & ~63;
    const int wr = ((tid >> 7) & 1) * 64;
    const int wc = ((tid >> 6) & 1) * 32;
    const int lr = lane & 15, lq = lane >> 4;

    f4_t acc[4][2] = {};

    auto stage = [&](int buf, int k0) {
        #pragma unroll
        for (int i = 0; i < 4; i++) {
            int gid2 = i * 256 + tid;
            int r = gid2 >> 3, g = gid2 & 7;
            const unsigned short* src = A + (size_t)(bm + r) * K + k0 + ((g ^ (r & 7)) * 8);
            __builtin_amdgcn_global_load_lds((cgu32*)src,
                (lu32*)&As[buf][(i * 256 + wbase) * 8], 16, 0, 0);
        }
        #pragma unroll
        for (int i = 0; i < 2; i++) {
            int gid2 = i * 256 + tid;
            int r = gid2 >> 3, g = gid2 & 7;
            const unsigned short* src = Wt + (size_t)(bn + r) * K + k0 + ((g ^ (r & 7)) * 8);
            __builtin_amdgcn_global_load_lds((cgu32*)src,
                (lu32*)&Bs[buf][(i * 256 + wbase) * 8], 16, 0, 0);
        }
    };

    stage(0, 0);
    __syncthreads();
    int cur = 0;
    for (int k0 = 0; k0 < K; k0 += 64) {
        if (k0 + 64 < K) stage(cur ^ 1, k0 + 64);
        #pragma unroll
        for (int h = 0; h < 2; h++) {
            bf8_t af[4], bfr[2];
            #pragma unroll
            for (int mb = 0; mb < 4; mb++) {
                int row = wr + mb * 16 + lr;
                int g = h * 4 + lq;
                af[mb] = *(const bf8_t*)&As[cur][row * 64 + ((g ^ (row & 7)) * 8)];
            }
            #pragma unroll
            for (int nb = 0; nb < 2; nb++) {
                int rn = wc + nb * 16 + lr;
                int g = h * 4 + lq;
                bfr[nb] = *(const bf8_t*)&Bs[cur][rn * 64 + ((g ^ (rn & 7)) * 8)];
            }
            #pragma unroll
            for (int mb = 0; mb < 4; mb++)
                #pragma unroll
                for (int nb = 0; nb < 2; nb++)
                    acc[mb][nb] = __builtin_amdgcn_mfma_f32_16x16x32_bf16(af[mb], bfr[nb], acc[mb][nb], 0, 0, 0);
        }
        __syncthreads();
        cur ^= 1;
    }

    #pragma unroll
    for (int mb = 0; mb < 4; mb++) {
        #pragma unroll
        for (int nb = 0; nb < 2; nb++) {
            int col = bn + wc + nb * 16 + lr;
            #pragma unroll
            for (int q = 0; q < 4; q++) {
                int row = bm + wr + mb * 16 + lq * 4 + q;
                if (row < M) {
                    float v = acc[mb][nb][q];
                    if (bias) v += bias[col];
                    if (EPI == EPI_POSEMB) v += extra[(size_t)(row % NPq) * N + col];
                    if (CBF) ((unsigned short*)Cv)[(size_t)row * ldc + col] = f2bf(v);
                    else     ((float*)Cv)[(size_t)row * ldc + col] = v;
                }
            }
        }
    }
}

// ---------------- xproj split-K f32 GEMM ----------------
static constexpr int XP_KS = 4;
static constexpr int XP_KC = 1536 / XP_KS;   // 384

__global__ __launch_bounds__(256) void k_xproj_part(const float* __restrict__ xi2, const float* __restrict__ W,
                                                    float* __restrict__ part) {
    __shared__ float As[32][65];
    __shared__ __align__(16) float Bs[64][80];
    int m0 = blockIdx.x * 32;
    int kc0 = blockIdx.y * XP_KC;
    int tid = threadIdx.x;
    int row = tid >> 3, cg = (tid & 7) * 10;
    float acc[10] = {};
    for (int k0 = 0; k0 < XP_KC; k0 += 64) {
        #pragma unroll
        for (int i = 0; i < 2; i++) {
            int id = tid + i * 256;
            int r = id >> 4, c4 = (id & 15) * 4;
            float4 v = *(const float4*)(xi2 + (size_t)(m0 + r) * 1536 + kc0 + k0 + c4);
            As[r][c4] = v.x; As[r][c4 + 1] = v.y; As[r][c4 + 2] = v.z; As[r][c4 + 3] = v.w;
        }
        #pragma unroll
        for (int i = 0; i < 5; i++) {
            int id = tid + i * 256;
            int r = id / 20, c4 = (id % 20) * 4;
            *(float4*)&Bs[r][c4] = *(const float4*)(W + (size_t)(kc0 + k0 + r) * 80 + c4);
        }
        __syncthreads();
        #pragma unroll
        for (int kk = 0; kk < 64; kk++) {
            float a = As[row][kk];
            #pragma unroll
            for (int j = 0; j < 10; j++)
                acc[j] = fmaf(a, Bs[kk][cg + j], acc[j]);
        }
        __syncthreads();
    }
    float* p = part + ((size_t)blockIdx.y * ROWS + m0 + row) * 80 + cg;
    #pragma unroll
    for (int j = 0; j < 10; j++) p[j] = acc[j];
}

__global__ __launch_bounds__(256) void k_xreduce(const float* __restrict__ part, float* __restrict__ dbc) {
    int idx = (blockIdx.x * 256 + threadIdx.x) * 4;
    if (idx >= ROWS * 80) return;
    const int S = ROWS * 80;
    float4 a = *(const float4*)(part + idx);
    float4 b = *(const float4*)(part + S + idx);
    float4 c = *(const float4*)(part + 2 * S + idx);
    float4 d = *(const float4*)(part + 3 * S + idx);
    float4 o;
    o.x = a.x + b.x + c.x + d.x;
    o.y = a.y + b.y + c.y + d.y;
    o.z = a.z + b.z + c.z + d.z;
    o.w = a.w + b.w + c.w + d.w;
    *(float4*)(dbc + idx) = o;
}

// ---------------- dt GEMM (K=48) + softplus ----------------
static constexpr int DT_RPB = 4;
__global__ __launch_bounds__(384) void k_dt(const float* __restrict__ dbc, const float* __restrict__ W,
                                            const float* __restrict__ bias, float* __restrict__ de) {
    int r0 = blockIdx.x * DT_RPB;
    int j = threadIdx.x * 4;
    __shared__ float ds[DT_RPB][48];
    if (threadIdx.x < DT_RPB * 48)
        ds[threadIdx.x / 48][threadIdx.x % 48] = dbc[(size_t)(r0 + threadIdx.x / 48) * 80 + threadIdx.x % 48];
    __syncthreads();
    float4 b = *(const float4*)(bias + j);
    float4 a0 = b, a1 = b, a2 = b, a3 = b;
    for (int k = 0; k < 48; k++) {
        float4 w = *(const float4*)(W + (size_t)k * 1536 + j);
        float d0 = ds[0][k], d1 = ds[1][k], d2 = ds[2][k], d3 = ds[3][k];
        a0.x = fmaf(d0, w.x, a0.x); a0.y = fmaf(d0, w.y, a0.y); a0.z = fmaf(d0, w.z, a0.z); a0.w = fmaf(d0, w.w, a0.w);
        a1.x = fmaf(d1, w.x, a1.x); a1.y = fmaf(d1, w.y, a1.y); a1.z = fmaf(d1, w.z, a1.z); a1.w = fmaf(d1, w.w, a1.w);
        a2.x = fmaf(d2, w.x, a2.x); a2.y = fmaf(d2, w.y, a2.y); a2.z = fmaf(d2, w.z, a2.z); a2.w = fmaf(d2, w.w, a2.w);
        a3.x = fmaf(d3, w.x, a3.x); a3.y = fmaf(d3, w.y, a3.y); a3.z = fmaf(d3, w.z, a3.z); a3.w = fmaf(d3, w.w, a3.w);
    }
    auto sp = [](float v) { return (v > 20.f) ? v : log1pf(expf(v)); };
    float4 o;
    o.x = sp(a0.x); o.y = sp(a0.y); o.z = sp(a0.z); o.w = sp(a0.w);
    *(float4*)(de + (size_t)(r0 + 0) * 1536 + j) = o;
    o.x = sp(a1.x); o.y = sp(a1.y); o.z = sp(a1.z); o.w = sp(a1.w);
    *(float4*)(de + (size_t)(r0 + 1) * 1536 + j) = o;
    o.x = sp(a2.x); o.y = sp(a2.y); o.z = sp(a2.z); o.w = sp(a2.w);
    *(float4*)(de + (size_t)(r0 + 2) * 1536 + j) = o;
    o.x = sp(a3.x); o.y = sp(a3.y); o.z = sp(a3.z); o.w = sp(a3.w);
    *(float4*)(de + (size_t)(r0 + 3) * 1536 + j) = o;
}

// ---------------- causal depthwise conv (DC=4) + silu, 4 d's/thread, float4 ----------------
__global__ __launch_bounds__(256) void k_conv_silu(const float* __restrict__ xr, const float* __restrict__ cw,
                                                   const float* __restrict__ cb, float* __restrict__ xi2,
                                                   float* __restrict__ sres) {
    int idx4 = blockIdx.x * 256 + threadIdx.x;
    if (idx4 >= ROWS * DIq / 4) return;
    int d4 = (idx4 % (DIq / 4)) * 4;
    int bt = idx4 / (DIq / 4);
    int t = bt % NPq, b = bt / NPq;
    const float* base = xr + (size_t)b * NPq * 3072 + d4;
    float4 s = *(const float4*)(cb + d4);
    float4 w0 = *(const float4*)(cw + (d4 + 0) * 4);
    float4 w1 = *(const float4*)(cw + (d4 + 1) * 4);
    float4 w2 = *(const float4*)(cw + (d4 + 2) * 4);
    float4 w3 = *(const float4*)(cw + (d4 + 3) * 4);
    if (t >= 3) {
        float4 v = *(const float4*)(base + (size_t)(t - 3) * 3072);
        s.x = fmaf(v.x, w0.x, s.x); s.y = fmaf(v.y, w1.x, s.y);
        s.z = fmaf(v.z, w2.x, s.z); s.w = fmaf(v.w, w3.x, s.w);
    }
    if (t >= 2) {
        float4 v = *(const float4*)(base + (size_t)(t - 2) * 3072);
        s.x = fmaf(v.x, w0.y, s.x); s.y = fmaf(v.y, w1.y, s.y);
        s.z = fmaf(v.z, w2.y, s.z); s.w = fmaf(v.w, w3.y, s.w);
    }
    if (t >= 1) {
        float4 v = *(const float4*)(base + (size_t)(t - 1) * 3072);
        s.x = fmaf(v.x, w0.z, s.x); s.y = fmaf(v.y, w1.z, s.y);
        s.z = fmaf(v.z, w2.z, s.z); s.w = fmaf(v.w, w3.z, s.w);
    }
    {
        float4 v = *(const float4*)(base + (size_t)t * 3072);
        s.x = fmaf(v.x, w0.w, s.x); s.y = fmaf(v.y, w1.w, s.y);
        s.z = fmaf(v.z, w2.w, s.z); s.w = fmaf(v.w, w3.w, s.w);
    }
    float4 xo;
    xo.x = s.x * fast_sig(s.x); xo.y = s.y * fast_sig(s.y);
    xo.z = s.z * fast_sig(s.z); xo.w = s.w * fast_sig(s.w);
    *(float4*)(xi2 + (size_t)bt * DIq + d4) = xo;
    float4 r = *(const float4*)(xr + (size_t)bt * 3072 + 1536 + d4);
    float4 ro;
    ro.x = r.x * fast_sig(r.x); ro.y = r.y * fast_sig(r.y);
    ro.z = r.z * fast_sig(r.z); ro.w = r.w * fast_sig(r.w);
    *(float4*)(sres + (size_t)bt * DIq + d4) = ro;
}

// ---------------- selective-scan, LDS-tiled; ys out is bf16 ----------------
static constexpr int STB = 28;

__global__ __launch_bounds__(256) void k_scan(const float* __restrict__ delta, const float* __restrict__ xi2,
                                              const float* __restrict__ dbc, const float* __restrict__ sres,
                                              const float* __restrict__ Alog, const float* __restrict__ Dv,
                                              unsigned short* __restrict__ ys) {
    const int b = blockIdx.x;
    const int d0 = blockIdx.y * 32;
    const int tid = threadIdx.x;
    const int dl = tid >> 3;
    const int np = tid & 7;
    const int d = d0 + dl;
    const float A0 = -__expf(Alog[d * 16 + np]);
    const float A1 = -__expf(Alog[d * 16 + np + 8]);
    const float Dd = Dv[d];
    const int tr = tid >> 5;
    const int dls = tid & 31;

    __shared__ float sdu[STB][64];
    __shared__ float sbc[STB][32];
    __shared__ float ssr[STB][32];

    const float* gde = delta + ((size_t)b * NPq + tr) * DIq + d0 + dls;
    const float* gu  = xi2   + ((size_t)b * NPq + tr) * DIq + d0 + dls;
    const float* gsr = sres  + ((size_t)b * NPq + tr) * DIq + d0 + dls;
    const float* gbc = dbc   + ((size_t)b * NPq + tr) * 80 + 48 + dls;
    unsigned short* gy = ys + (size_t)b * NPq * DIq + d;

    float rde[4], ru[4], rsr[4], rbc[4];

    auto stageLoad = [&](int c) {
        const int t0 = c * STB;
        #pragma unroll
        for (int j = 0; j < 3; j++) {
            int off = (t0 + 8 * j) * DIq;
            rde[j] = gde[off];
            ru[j]  = gu[off];
            rsr[j] = gsr[off];
            rbc[j] = gbc[(t0 + 8 * j) * 80];
        }
        if (tid < 128) {
            int off = (t0 + 24) * DIq;
            rde[3] = gde[off];
            ru[3]  = gu[off];
            rsr[3] = gsr[off];
            rbc[3] = gbc[(t0 + 24) * 80];
        }
    };
    auto stageWrite = [&]() {
        const int pi = (dls & 7) * 4 + (dls >> 3);
        #pragma unroll
        for (int j = 0; j < 3; j++) {
            int t = tr + 8 * j;
            sdu[t][dls * 2 + 0] = rde[j];
            sdu[t][dls * 2 + 1] = ru[j];
            ssr[t][dls] = rsr[j];
            sbc[t][pi] = rbc[j];
        }
        if (tid < 128) {
            int t = tr + 24;
            sdu[t][dls * 2 + 0] = rde[3];
            sdu[t][dls * 2 + 1] = ru[3];
            ssr[t][dls] = rsr[3];
            sbc[t][pi] = rbc[3];
        }
    };

    stageLoad(0);
    stageWrite();
    __syncthreads();

    float h0 = 0.f, h1 = 0.f;
    for (int c = 0; c < 7; c++) {
        if (c < 6) stageLoad(c + 1);
        #pragma unroll 4
        for (int t = 0; t < STB; t++) {
            float2 du = *(const float2*)&sdu[t][dl * 2];
            float4 bc = *(const float4*)&sbc[t][np * 4];
            float sr = ssr[t][dl];
            float a0 = __expf(du.x * A0), a1 = __expf(du.x * A1);
            float deu = du.x * du.y;
            h0 = fmaf(a0, h0, deu * bc.x);
            h1 = fmaf(a1, h1, deu * bc.y);
            float p = fmaf(h1, bc.w, h0 * bc.z);
            p += __shfl_xor(p, 1);
            p += __shfl_xor(p, 2);
            p += __shfl_xor(p, 4);
            if (np == 0) gy[(size_t)(c * STB + t) * DIq] = f2bf(fmaf(Dd, du.y, p) * sr);
        }
        __syncthreads();
        if (c < 6) {
            stageWrite();
            __syncthreads();
        }
    }
}

// ---------------- row LayerNorm (1024) + exact gelu; out f32 or bf16 ----------------
template<bool OBF>
__global__ __launch_bounds__(256) void k_ln_gelu(const float* __restrict__ in, const float* __restrict__ g,
                                                 const float* __restrict__ bt, void* __restrict__ outv) {
    int row = blockIdx.x;
    const float* x = in + (size_t)row * OUTq;
    float4 v = ((const float4*)x)[threadIdx.x];
    float s = v.x + v.y + v.z + v.w;
    float ss = v.x * v.x + v.y * v.y + v.z * v.z + v.w * v.w;
    #pragma unroll
    for (int off = 32; off >= 1; off >>= 1) { s += __shfl_down(s, off); ss += __shfl_down(ss, off); }
    __shared__ float sh[10];
    int wid = threadIdx.x >> 6, lid = threadIdx.x & 63;
    if (lid == 0) { sh[wid] = s; sh[4 + wid] = ss; }
    __syncthreads();
    if (threadIdx.x == 0) {
        float S = sh[0] + sh[1] + sh[2] + sh[3], SS = sh[4] + sh[5] + sh[6] + sh[7];
        float m = S * (1.f / OUTq);
        float var = SS * (1.f / OUTq) - m * m;
        sh[8] = m; sh[9] = rsqrtf(var + 1e-5f);
    }
    __syncthreads();
    float m = sh[8], rst = sh[9];
    float4 gv = ((const float4*)g)[threadIdx.x];
    float4 bv = ((const float4*)bt)[threadIdx.x];
    float4 o;
    float y0 = (v.x - m) * rst * gv.x + bv.x; o.x = 0.5f * y0 * (1.f + erff(y0 * 0.70710678118f));
    float y1 = (v.y - m) * rst * gv.y + bv.y; o.y = 0.5f * y1 * (1.f + erff(y1 * 0.70710678118f));
    float y2 = (v.z - m) * rst * gv.z + bv.z; o.z = 0.5f * y2 * (1.f + erff(y2 * 0.70710678118f));
    float y3 = (v.w - m) * rst * gv.w + bv.w; o.w = 0.5f * y3 * (1.f + erff(y3 * 0.70710678118f));
    if (OBF) {
        ushort4 o4;
        o4.x = f2bf(o.x); o4.y = f2bf(o.y); o4.z = f2bf(o.z); o4.w = f2bf(o.w);
        ((ushort4*)((unsigned short*)outv + (size_t)row * OUTq))[threadIdx.x] = o4;
    } else {
        ((float4*)((float*)outv + (size_t)row * OUTq))[threadIdx.x] = o;
    }
}

// ---------------- column softmax (over t) + weighted pool; ym is bf16 ----------------
__global__ __launch_bounds__(256) void k_softpool(const float* __restrict__ gm, const unsigned short* __restrict__ ym,
                                                  float* __restrict__ pooled) {
    int b = blockIdx.y;
    int j = blockIdx.x * 256 + threadIdx.x;
    const float* gb = gm + (size_t)b * NPq * OUTq + j;
    const unsigned short* yb = ym + (size_t)b * NPq * OUTq + j;
    float mx = -1e30f;
    for (int t = 0; t < NPq; t++) mx = fmaxf(mx, gb[(size_t)t * OUTq]);
    float s = 0.f, ps = 0.f;
    for (int t = 0; t < NPq; t++) {
        float e = __expf(gb[(size_t)t * OUTq] - mx);
        s += e;
        ps += bf2f(yb[(size_t)t * OUTq]) * e;
    }
    pooled[b * OUTq + j] = ps / s;
}

// ---------------- final LayerNorm over 1024 per batch ----------------
__global__ __launch_bounds__(256) void k_final_ln(const float* __restrict__ p, const float* __restrict__ g,
                                                  const float* __restrict__ bt, float* __restrict__ out) {
    int row = blockIdx.x;
    const float* x = p + (size_t)row * OUTq;
    float4 v = ((const float4*)x)[threadIdx.x];
    float s = v.x + v.y + v.z + v.w;
    float ss = v.x * v.x + v.y * v.y + v.z * v.z + v.w * v.w;
    #pragma unroll
    for (int off = 32; off >= 1; off >>= 1) { s += __shfl_down(s, off); ss += __shfl_down(ss, off); }
    __shared__ float sh[10];
    int wid = threadIdx.x >> 6, lid = threadIdx.x & 63;
    if (lid == 0) { sh[wid] = s; sh[4 + wid] = ss; }
    __syncthreads();
    if (threadIdx.x == 0) {
        float S = sh[0] + sh[1] + sh[2] + sh[3], SS = sh[4] + sh[5] + sh[6] + sh[7];
        float m = S * (1.f / OUTq);
        float var = SS * (1.f / OUTq) - m * m;
        sh[8] = m; sh[9] = rsqrtf(var + 1e-5f);
    }
    __syncthreads();
    float m = sh[8], rst = sh[9];
    float4 gv = ((const float4*)g)[threadIdx.x];
    float4 bv = ((const float4*)bt)[threadIdx.x];
    float4 o;
    o.x = (v.x - m) * rst * gv.x + bv.x;
    o.y = (v.y - m) * rst * gv.y + bv.y;
    o.z = (v.z - m) * rst * gv.z + bv.z;
    o.w = (v.w - m) * rst * gv.w + bv.w;
    ((float4*)(out + (size_t)row * OUTq))[threadIdx.x] = o;
}

extern "C" void kernel_launch(void* const* d_in, const int* in_sizes, int n_in,
                              void* d_out, int out_size, void* d_ws, size_t ws_size,
                              hipStream_t stream) {
    const float* img   = (const float*)d_in[0];
    const float* sa_w  = (const float*)d_in[1];
    const float* pe_w  = (const float*)d_in[2];
    const float* pe_b  = (const float*)d_in[3];
    const float* pos   = (const float*)d_in[4];
    const float* in_w  = (const float*)d_in[5];
    const float* in_b  = (const float*)d_in[6];
    const float* cv_w  = (const float*)d_in[7];
    const float* cv_b  = (const float*)d_in[8];
    const float* xp_w  = (const float*)d_in[9];
    const float* dt_w  = (const float*)d_in[10];
    const float* dt_b  = (const float*)d_in[11];
    const float* Alog  = (const float*)d_in[12];
    const float* Dv    = (const float*)d_in[13];
    const float* ot_w  = (const float*)d_in[14];
    const float* ot_b  = (const float*)d_in[15];
    const float* em_w  = (const float*)d_in[16];
    const float* em_b  = (const float*)d_in[17];
    const float* em_g  = (const float*)d_in[18];
    const float* em_bt = (const float*)d_in[19];
    const float* at_w  = (const float*)d_in[20];
    const float* at_b  = (const float*)d_in[21];
    const float* at_g  = (const float*)d_in[22];
    const float* at_bt = (const float*)d_in[23];
    const float* la_g  = (const float*)d_in[24];
    const float* la_bt = (const float*)d_in[25];

    char* ws = (char*)d_ws;
    auto al = [](size_t x) { return (x + 255) & ~(size_t)255; };
    size_t SZ_am   = (size_t)NB * 2 * IMP * 4;
    size_t SZ_G    = (size_t)MPAD * 768 * 2;
    size_t SZ_x    = (size_t)MPAD * 768 * 2;
    size_t SZ_xr   = (size_t)ROWS * 3072 * 4;
    size_t SZ_xi2  = (size_t)ROWS * 1536 * 4;
    size_t SZ_de   = SZ_xi2;
    size_t SZ_dbc  = (size_t)ROWS * 80 * 4;
    size_t SZ_ys   = (size_t)MPAD * 1536 * 2;
    size_t SZ_sres = SZ_xi2;
    size_t SZ_yem  = (size_t)MPAD * 1024 * 2;
    size_t SZ_pool = (size_t)NB * OUTq * 4;
    size_t SZ_part = (size_t)XP_KS * ROWS * 80 * 4;

    size_t o_am   = 0;
    size_t o_G    = al(o_am + SZ_am);
    size_t o_x    = al(o_G + SZ_G);
    size_t o_xr   = al(o_x + SZ_x);
    size_t o_xi2  = al(o_xr + SZ_xr);
    size_t o_de   = al(o_xi2 + SZ_xi2);
    size_t o_dbc  = al(o_de + SZ_de);
    size_t o_ys   = al(o_dbc + SZ_dbc);
    size_t o_sres = al(o_ys + SZ_ys);
    size_t o_yem  = al(o_sres + SZ_sres);
    size_t o_pool = al(o_yem + SZ_yem);
    size_t o_part = al(o_pool + SZ_pool);

    size_t o_wpe  = al(o_part + SZ_part);
    size_t o_win0 = al(o_wpe  + (size_t)768 * 768 * 2);
    size_t o_win1 = al(o_win0 + (size_t)3072 * 768 * 2);
    size_t o_wot0 = al(o_win1 + (size_t)3072 * 768 * 2);
    size_t o_wot1 = al(o_wot0 + (size_t)768 * 1536 * 2);
    size_t o_wem  = al(o_wot1 + (size_t)768 * 1536 * 2);
    size_t o_wat  = al(o_wem  + (size_t)1024 * 768 * 2);

    float* am    = (float*)(ws + o_am);
    unsigned short* G  = (unsigned short*)(ws + o_G);
    unsigned short* x  = (unsigned short*)(ws + o_x);
    float* xr    = (float*)(ws + o_xr);
    float* xi2   = (float*)(ws + o_xi2);
    float* de    = (float*)(ws + o_de);
    float* dbc   = (float*)(ws + o_dbc);
    unsigned short* ys = (unsigned short*)(ws + o_ys);
    float* sres  = (float*)(ws + o_sres);
    unsigned short* yem = (unsigned short*)(ws + o_yem);
    float* pool  = (float*)(ws + o_pool);
    float* part  = (float*)(ws + o_part);
    unsigned short* wpe  = (unsigned short*)(ws + o_wpe);
    unsigned short* win0 = (unsigned short*)(ws + o_win0);
    unsigned short* win1 = (unsigned short*)(ws + o_win1);
    unsigned short* wot0 = (unsigned short*)(ws + o_wot0);
    unsigned short* wot1 = (unsigned short*)(ws + o_wot1);
    unsigned short* wem  = (unsigned short*)(ws + o_wem);
    unsigned short* wat  = (unsigned short*)(ws + o_wat);
    float* t1  = (float*)(ws + o_xr);
    float* t2  = (float*)(ws + o_de);
    float* gat = (float*)(ws + o_xi2);

    // ---- weight conversion (W[K][N] -> bf16 [N][K]) ----
    k_transpose_bf<<<dim3(768 / 32, 768 / 32), 256, 0, stream>>>(pe_w, wpe, 768, 768);
    k_transpose_bf<<<dim3(3072 / 32, 768 / 32), 256, 0, stream>>>(in_w, win0, 768, 3072);
    k_transpose_bf<<<dim3(3072 / 32, 768 / 32), 256, 0, stream>>>(in_w + (size_t)768 * 3072, win1, 768, 3072);
    k_transpose_bf<<<dim3(768 / 32, 1536 / 32), 256, 0, stream>>>(ot_w, wot0, 1536, 768);
    k_transpose_bf<<<dim3(768 / 32, 1536 / 32), 256, 0, stream>>>(ot_w + (size_t)1536 * 768, wot1, 1536, 768);
    k_transpose_bf<<<dim3(1024 / 32, 768 / 32), 256, 0, stream>>>(em_w, wem, 768, 1024);
    k_transpose_bf<<<dim3(1024 / 32, 1024 / 32), 256, 0, stream>>>(at_w, wat, 1024, 1024);

    int nq = NB * IMP / 4;   // 200704
    k_avgmax<<<(nq + 255) / 256, 256, 0, stream>>>(img, am);
    k_gatepatch<<<(nq + 255) / 256, 256, 0, stream>>>(img, am, sa_w, G);

    dim3 blk(256);
    // patch embed: x(bf16) = G @ pe_w + pe_b + pos
    k_gemm_bf<EPI_POSEMB, true><<<dim3(12, 25), blk, 0, stream>>>(G, wpe, pe_b, x, 768, ROWS, 768, 768, pos);

    for (int l = 0; l < 2; l++) {
        const unsigned short* win = l ? win1 : win0;
        const unsigned short* wot = l ? wot1 : wot0;
        // xr(f32) = x @ in_w + in_b
        k_gemm_bf<EPI_NONE, false><<<dim3(48, 25), blk, 0, stream>>>(x, win, in_b + l * 3072, xr, 3072,
                                                                     ROWS, 3072, 768, nullptr);
        int nc4 = ROWS * DIq / 4;
        k_conv_silu<<<(nc4 + 255) / 256, 256, 0, stream>>>(xr, cv_w + (size_t)l * DIq * 4, cv_b + l * DIq,
                                                           xi2, sres);
        k_xproj_part<<<dim3(ROWS / 32, XP_KS), blk, 0, stream>>>(xi2, xp_w + (size_t)l * 1536 * 80, part);
        k_xreduce<<<(ROWS * 80 / 4 + 255) / 256, 256, 0, stream>>>(part, dbc);
        k_dt<<<ROWS / DT_RPB, 384, 0, stream>>>(dbc, dt_w + (size_t)l * 48 * 1536, dt_b + l * 1536, de);
        k_scan<<<dim3(16, 48), blk, 0, stream>>>(de, xi2, dbc, sres, Alog + (size_t)l * 1536 * 16,
                                                 Dv + l * 1536, ys);
        // x(bf16) = ys @ out_w + out_b
        k_gemm_bf<EPI_NONE, true><<<dim3(12, 25), blk, 0, stream>>>(ys, wot, ot_b + l * 768, x, 768,
                                                                    ROWS, 768, 1536, nullptr);
    }

    // head
    k_gemm_bf<EPI_NONE, false><<<dim3(16, 25), blk, 0, stream>>>(x, wem, em_b, t1, 1024, ROWS, 1024, 768, nullptr);
    k_ln_gelu<true><<<ROWS, 256, 0, stream>>>(t1, em_g, em_bt, yem);
    k_gemm_bf<EPI_NONE, false><<<dim3(16, 25), blk, 0, stream>>>(yem, wat, at_b, t2, 1024, ROWS, 1024, 1024, nullptr);
    k_ln_gelu<false><<<ROWS, 256, 0, stream>>>(t2, at_g, at_bt, gat);
    k_softpool<<<dim3(4, NB), 256, 0, stream>>>(gat, yem, pool);
    k_final_ln<<<NB, 256, 0, stream>>>(pool, la_g, la_bt, (float*)d_out);
}

// Round 8
// 507.482 us; speedup vs baseline: 4.9131x; 1.1105x over previous
//
#include <hip/hip_runtime.h>
#include <math.h>

static constexpr int NB = 16;
static constexpr int NC = 3;
static constexpr int IM = 224;
static constexpr int IMP = IM * IM;      // 50176
static constexpr int HPq = 14;
static constexpr int NPq = 196;
static constexpr int OUTq = 1024;
static constexpr int DIq = 1536;
static constexpr int ROWS = NB * NPq;    // 3136
static constexpr int MPAD = 3200;        // 25*128, A-operand row padding

typedef __bf16 bf8_t __attribute__((ext_vector_type(8)));
typedef float f4_t __attribute__((ext_vector_type(4)));
typedef const __attribute__((address_space(1))) unsigned int cgu32;
typedef __attribute__((address_space(3))) unsigned int lu32;

__device__ inline unsigned short f2bf(float x) {
    unsigned u = __builtin_bit_cast(unsigned, x);
    unsigned r = (u + 0x7FFFu + ((u >> 16) & 1u)) >> 16;
    return (unsigned short)r;
}
__device__ inline float bf2f(unsigned short v) {
    return __builtin_bit_cast(float, (unsigned)v << 16);
}
__device__ inline float fast_sig(float x) {
    return __builtin_amdgcn_rcpf(1.f + __expf(-x));
}

// VALU-pipe cross-lane add via DPP (replaces ds_permute shfl_xor)
template<int CTRL>
__device__ inline float dpp_add(float x) {
    int v = __builtin_amdgcn_update_dpp(0, __builtin_bit_cast(int, x), CTRL, 0xF, 0xF, true);
    return x + __builtin_bit_cast(float, v);
}

// ---------------- K1a: channel avg/max (float4, 4 px/thread) ----------------
__global__ __launch_bounds__(256) void k_avgmax(const float* __restrict__ img, float* __restrict__ am) {
    int idx = blockIdx.x * 256 + threadIdx.x;
    if (idx >= NB * IMP / 4) return;
    int p4 = (idx % (IMP / 4)) * 4, b = idx / (IMP / 4);
    const float* ib = img + (size_t)b * NC * IMP + p4;
    float4 c0 = *(const float4*)ib;
    float4 c1 = *(const float4*)(ib + IMP);
    float4 c2 = *(const float4*)(ib + 2 * IMP);
    float4 av, mx;
    av.x = (c0.x + c1.x + c2.x) * (1.f / 3.f); mx.x = fmaxf(c0.x, fmaxf(c1.x, c2.x));
    av.y = (c0.y + c1.y + c2.y) * (1.f / 3.f); mx.y = fmaxf(c0.y, fmaxf(c1.y, c2.y));
    av.z = (c0.z + c1.z + c2.z) * (1.f / 3.f); mx.z = fmaxf(c0.z, fmaxf(c1.z, c2.z));
    av.w = (c0.w + c1.w + c2.w) * (1.f / 3.f); mx.w = fmaxf(c0.w, fmaxf(c1.w, c2.w));
    *(float4*)(am + (size_t)(b * 2 + 0) * IMP + p4) = av;
    *(float4*)(am + (size_t)(b * 2 + 1) * IMP + p4) = mx;
}

// ---------------- K1b: 7x7 conv gate + patchify, 4 px/thread, float4 windows ----------------
__global__ __launch_bounds__(256) void k_gatepatch(const float* __restrict__ img, const float* __restrict__ am,
                                                   const float* __restrict__ saw, unsigned short* __restrict__ G) {
    int quad = blockIdx.x * 256 + threadIdx.x;
    if (quad >= NB * IMP / 4) return;
    int pq = quad % (IMP / 4), b = quad / (IMP / 4);
    int x0 = (pq % 56) * 4;
    int y = pq / 56;
    float acc0 = 0.f, acc1 = 0.f, acc2 = 0.f, acc3 = 0.f;
    const bool lok = (x0 >= 4), rok = (x0 <= IM - 8);
    #pragma unroll
    for (int ci = 0; ci < 2; ci++) {
        const float* amc = am + (size_t)(b * 2 + ci) * IMP;
        const float* wc = saw + ci * 49;
        #pragma unroll
        for (int kh = 0; kh < 7; kh++) {
            int yy = y + kh - 3;
            if (yy < 0 || yy >= IM) continue;
            const float* rowp = amc + yy * IM;
            float4 lv = lok ? *(const float4*)(rowp + x0 - 4) : make_float4(0.f, 0.f, 0.f, 0.f);
            float4 mv = *(const float4*)(rowp + x0);
            float4 rv = rok ? *(const float4*)(rowp + x0 + 4) : make_float4(0.f, 0.f, 0.f, 0.f);
            float f[12] = {lv.x, lv.y, lv.z, lv.w, mv.x, mv.y, mv.z, mv.w, rv.x, rv.y, rv.z, rv.w};
            #pragma unroll
            for (int kw = 0; kw < 7; kw++) {
                float w = wc[kh * 7 + kw];
                acc0 = fmaf(w, f[kw + 1], acc0);
                acc1 = fmaf(w, f[kw + 2], acc1);
                acc2 = fmaf(w, f[kw + 3], acc2);
                acc3 = fmaf(w, f[kw + 4], acc3);
            }
        }
    }
    float s0 = fast_sig(acc0), s1 = fast_sig(acc1), s2 = fast_sig(acc2), s3 = fast_sig(acc3);
    const float* ib = img + (size_t)b * NC * IMP + y * IM + x0;
    float4 c0 = *(const float4*)ib;
    float4 c1 = *(const float4*)(ib + IMP);
    float4 c2 = *(const float4*)(ib + 2 * IMP);
    int hy = y >> 4, py = y & 15, hx = x0 >> 4, px0 = x0 & 15;
    size_t base = ((size_t)(b * NPq + hy * HPq + hx) * 768) + (size_t)(py * 16 + px0) * 3;
    ushort4 o0, o1, o2;
    o0.x = f2bf(c0.x * s0); o0.y = f2bf(c1.x * s0); o0.z = f2bf(c2.x * s0);
    o0.w = f2bf(c0.y * s1);
    o1.x = f2bf(c1.y * s1); o1.y = f2bf(c2.y * s1);
    o1.z = f2bf(c0.z * s2); o1.w = f2bf(c1.z * s2);
    o2.x = f2bf(c2.z * s2);
    o2.y = f2bf(c0.w * s3); o2.z = f2bf(c1.w * s3); o2.w = f2bf(c2.w * s3);
    *(ushort4*)(G + base + 0) = o0;
    *(ushort4*)(G + base + 4) = o1;
    *(ushort4*)(G + base + 8) = o2;
}

// ---------------- weight transpose + f32->bf16: W[K][N] -> Wt[N][K] ----------------
__global__ __launch_bounds__(256) void k_transpose_bf(const float* __restrict__ W, unsigned short* __restrict__ Wt,
                                                      int K, int N) {
    __shared__ float t[32][33];
    int n0 = blockIdx.x * 32, k0 = blockIdx.y * 32;
    int c = threadIdx.x & 31, r8 = threadIdx.x >> 5;
    #pragma unroll
    for (int i = 0; i < 4; i++) {
        int r = r8 + i * 8;
        t[r][c] = W[(size_t)(k0 + r) * N + n0 + c];
    }
    __syncthreads();
    #pragma unroll
    for (int i = 0; i < 4; i++) {
        int r = r8 + i * 8;
        Wt[(size_t)(n0 + r) * K + k0 + c] = f2bf(t[c][r]);
    }
}

// ---------------- bf16 MFMA GEMM, gload_lds + double-buffer ----------------
enum { EPI_NONE = 0, EPI_POSEMB = 1 };

template<int EPI, bool CBF>
__global__ __launch_bounds__(256) void k_gemm_bf(const unsigned short* __restrict__ A,
                                                 const unsigned short* __restrict__ Wt,
                                                 const float* __restrict__ bias,
                                                 void* __restrict__ Cv, int ldc,
                                                 int M, int N, int K,
                                                 const float* __restrict__ extra) {
    constexpr int BM = 128, BN = 64;
    __shared__ __align__(16) unsigned short As[2][BM * 64];
    __shared__ __align__(16) unsigned short Bs[2][BN * 64];
    const int bm = blockIdx.y * BM, bn = blockIdx.x * BN;
    const int tid = threadIdx.x;
    const int lane = tid & 63;
    const int wbase = tid & ~63;
    const int wr = ((tid >> 7) & 1) * 64;
    const int wc = ((tid >> 6) & 1) * 32;
    const int lr = lane & 15, lq = lane >> 4;

    f4_t acc[4][2] = {};

    auto stage = [&](int buf, int k0) {
        #pragma unroll
        for (int i = 0; i < 4; i++) {
            int gid2 = i * 256 + tid;
            int r = gid2 >> 3, g = gid2 & 7;
            const unsigned short* src = A + (size_t)(bm + r) * K + k0 + ((g ^ (r & 7)) * 8);
            __builtin_amdgcn_global_load_lds((cgu32*)src,
                (lu32*)&As[buf][(i * 256 + wbase) * 8], 16, 0, 0);
        }
        #pragma unroll
        for (int i = 0; i < 2; i++) {
            int gid2 = i * 256 + tid;
            int r = gid2 >> 3, g = gid2 & 7;
            const unsigned short* src = Wt + (size_t)(bn + r) * K + k0 + ((g ^ (r & 7)) * 8);
            __builtin_amdgcn_global_load_lds((cgu32*)src,
                (lu32*)&Bs[buf][(i * 256 + wbase) * 8], 16, 0, 0);
        }
    };

    stage(0, 0);
    __syncthreads();
    int cur = 0;
    for (int k0 = 0; k0 < K; k0 += 64) {
        if (k0 + 64 < K) stage(cur ^ 1, k0 + 64);
        #pragma unroll
        for (int h = 0; h < 2; h++) {
            bf8_t af[4], bfr[2];
            #pragma unroll
            for (int mb = 0; mb < 4; mb++) {
                int row = wr + mb * 16 + lr;
                int g = h * 4 + lq;
                af[mb] = *(const bf8_t*)&As[cur][row * 64 + ((g ^ (row & 7)) * 8)];
            }
            #pragma unroll
            for (int nb = 0; nb < 2; nb++) {
                int rn = wc + nb * 16 + lr;
                int g = h * 4 + lq;
                bfr[nb] = *(const bf8_t*)&Bs[cur][rn * 64 + ((g ^ (rn & 7)) * 8)];
            }
            #pragma unroll
            for (int mb = 0; mb < 4; mb++)
                #pragma unroll
                for (int nb = 0; nb < 2; nb++)
                    acc[mb][nb] = __builtin_amdgcn_mfma_f32_16x16x32_bf16(af[mb], bfr[nb], acc[mb][nb], 0, 0, 0);
        }
        __syncthreads();
        cur ^= 1;
    }

    #pragma unroll
    for (int mb = 0; mb < 4; mb++) {
        #pragma unroll
        for (int nb = 0; nb < 2; nb++) {
            int col = bn + wc + nb * 16 + lr;
            #pragma unroll
            for (int q = 0; q < 4; q++) {
                int row = bm + wr + mb * 16 + lq * 4 + q;
                if (row < M) {
                    float v = acc[mb][nb][q];
                    if (bias) v += bias[col];
                    if (EPI == EPI_POSEMB) v += extra[(size_t)(row % NPq) * N + col];
                    if (CBF) ((unsigned short*)Cv)[(size_t)row * ldc + col] = f2bf(v);
                    else     ((float*)Cv)[(size_t)row * ldc + col] = v;
                }
            }
        }
    }
}

// ---------------- xproj split-K f32 GEMM ----------------
static constexpr int XP_KS = 4;
static constexpr int XP_KC = 1536 / XP_KS;   // 384

__global__ __launch_bounds__(256) void k_xproj_part(const float* __restrict__ xi2, const float* __restrict__ W,
                                                    float* __restrict__ part) {
    __shared__ float As[32][65];
    __shared__ __align__(16) float Bs[64][80];
    int m0 = blockIdx.x * 32;
    int kc0 = blockIdx.y * XP_KC;
    int tid = threadIdx.x;
    int row = tid >> 3, cg = (tid & 7) * 10;
    float acc[10] = {};
    for (int k0 = 0; k0 < XP_KC; k0 += 64) {
        #pragma unroll
        for (int i = 0; i < 2; i++) {
            int id = tid + i * 256;
            int r = id >> 4, c4 = (id & 15) * 4;
            float4 v = *(const float4*)(xi2 + (size_t)(m0 + r) * 1536 + kc0 + k0 + c4);
            As[r][c4] = v.x; As[r][c4 + 1] = v.y; As[r][c4 + 2] = v.z; As[r][c4 + 3] = v.w;
        }
        #pragma unroll
        for (int i = 0; i < 5; i++) {
            int id = tid + i * 256;
            int r = id / 20, c4 = (id % 20) * 4;
            *(float4*)&Bs[r][c4] = *(const float4*)(W + (size_t)(kc0 + k0 + r) * 80 + c4);
        }
        __syncthreads();
        #pragma unroll
        for (int kk = 0; kk < 64; kk++) {
            float a = As[row][kk];
            #pragma unroll
            for (int j = 0; j < 10; j++)
                acc[j] = fmaf(a, Bs[kk][cg + j], acc[j]);
        }
        __syncthreads();
    }
    float* p = part + ((size_t)blockIdx.y * ROWS + m0 + row) * 80 + cg;
    #pragma unroll
    for (int j = 0; j < 10; j++) p[j] = acc[j];
}

__global__ __launch_bounds__(256) void k_xreduce(const float* __restrict__ part, float* __restrict__ dbc) {
    int idx = (blockIdx.x * 256 + threadIdx.x) * 4;
    if (idx >= ROWS * 80) return;
    const int S = ROWS * 80;
    float4 a = *(const float4*)(part + idx);
    float4 b = *(const float4*)(part + S + idx);
    float4 c = *(const float4*)(part + 2 * S + idx);
    float4 d = *(const float4*)(part + 3 * S + idx);
    float4 o;
    o.x = a.x + b.x + c.x + d.x;
    o.y = a.y + b.y + c.y + d.y;
    o.z = a.z + b.z + c.z + d.z;
    o.w = a.w + b.w + c.w + d.w;
    *(float4*)(dbc + idx) = o;
}

// ---------------- dt GEMM (K=48) + softplus ----------------
static constexpr int DT_RPB = 4;
__global__ __launch_bounds__(384) void k_dt(const float* __restrict__ dbc, const float* __restrict__ W,
                                            const float* __restrict__ bias, float* __restrict__ de) {
    int r0 = blockIdx.x * DT_RPB;
    int j = threadIdx.x * 4;
    __shared__ float ds[DT_RPB][48];
    if (threadIdx.x < DT_RPB * 48)
        ds[threadIdx.x / 48][threadIdx.x % 48] = dbc[(size_t)(r0 + threadIdx.x / 48) * 80 + threadIdx.x % 48];
    __syncthreads();
    float4 b = *(const float4*)(bias + j);
    float4 a0 = b, a1 = b, a2 = b, a3 = b;
    for (int k = 0; k < 48; k++) {
        float4 w = *(const float4*)(W + (size_t)k * 1536 + j);
        float d0 = ds[0][k], d1 = ds[1][k], d2 = ds[2][k], d3 = ds[3][k];
        a0.x = fmaf(d0, w.x, a0.x); a0.y = fmaf(d0, w.y, a0.y); a0.z = fmaf(d0, w.z, a0.z); a0.w = fmaf(d0, w.w, a0.w);
        a1.x = fmaf(d1, w.x, a1.x); a1.y = fmaf(d1, w.y, a1.y); a1.z = fmaf(d1, w.z, a1.z); a1.w = fmaf(d1, w.w, a1.w);
        a2.x = fmaf(d2, w.x, a2.x); a2.y = fmaf(d2, w.y, a2.y); a2.z = fmaf(d2, w.z, a2.z); a2.w = fmaf(d2, w.w, a2.w);
        a3.x = fmaf(d3, w.x, a3.x); a3.y = fmaf(d3, w.y, a3.y); a3.z = fmaf(d3, w.z, a3.z); a3.w = fmaf(d3, w.w, a3.w);
    }
    auto sp = [](float v) { return (v > 20.f) ? v : log1pf(expf(v)); };
    float4 o;
    o.x = sp(a0.x); o.y = sp(a0.y); o.z = sp(a0.z); o.w = sp(a0.w);
    *(float4*)(de + (size_t)(r0 + 0) * 1536 + j) = o;
    o.x = sp(a1.x); o.y = sp(a1.y); o.z = sp(a1.z); o.w = sp(a1.w);
    *(float4*)(de + (size_t)(r0 + 1) * 1536 + j) = o;
    o.x = sp(a2.x); o.y = sp(a2.y); o.z = sp(a2.z); o.w = sp(a2.w);
    *(float4*)(de + (size_t)(r0 + 2) * 1536 + j) = o;
    o.x = sp(a3.x); o.y = sp(a3.y); o.z = sp(a3.z); o.w = sp(a3.w);
    *(float4*)(de + (size_t)(r0 + 3) * 1536 + j) = o;
}

// ---------------- causal depthwise conv (DC=4) + silu, 4 d's/thread, float4 ----------------
__global__ __launch_bounds__(256) void k_conv_silu(const float* __restrict__ xr, const float* __restrict__ cw,
                                                   const float* __restrict__ cb, float* __restrict__ xi2,
                                                   float* __restrict__ sres) {
    int idx4 = blockIdx.x * 256 + threadIdx.x;
    if (idx4 >= ROWS * DIq / 4) return;
    int d4 = (idx4 % (DIq / 4)) * 4;
    int bt = idx4 / (DIq / 4);
    int t = bt % NPq, b = bt / NPq;
    const float* base = xr + (size_t)b * NPq * 3072 + d4;
    float4 s = *(const float4*)(cb + d4);
    float4 w0 = *(const float4*)(cw + (d4 + 0) * 4);
    float4 w1 = *(const float4*)(cw + (d4 + 1) * 4);
    float4 w2 = *(const float4*)(cw + (d4 + 2) * 4);
    float4 w3 = *(const float4*)(cw + (d4 + 3) * 4);
    if (t >= 3) {
        float4 v = *(const float4*)(base + (size_t)(t - 3) * 3072);
        s.x = fmaf(v.x, w0.x, s.x); s.y = fmaf(v.y, w1.x, s.y);
        s.z = fmaf(v.z, w2.x, s.z); s.w = fmaf(v.w, w3.x, s.w);
    }
    if (t >= 2) {
        float4 v = *(const float4*)(base + (size_t)(t - 2) * 3072);
        s.x = fmaf(v.x, w0.y, s.x); s.y = fmaf(v.y, w1.y, s.y);
        s.z = fmaf(v.z, w2.y, s.z); s.w = fmaf(v.w, w3.y, s.w);
    }
    if (t >= 1) {
        float4 v = *(const float4*)(base + (size_t)(t - 1) * 3072);
        s.x = fmaf(v.x, w0.z, s.x); s.y = fmaf(v.y, w1.z, s.y);
        s.z = fmaf(v.z, w2.z, s.z); s.w = fmaf(v.w, w3.z, s.w);
    }
    {
        float4 v = *(const float4*)(base + (size_t)t * 3072);
        s.x = fmaf(v.x, w0.w, s.x); s.y = fmaf(v.y, w1.w, s.y);
        s.z = fmaf(v.z, w2.w, s.z); s.w = fmaf(v.w, w3.w, s.w);
    }
    float4 xo;
    xo.x = s.x * fast_sig(s.x); xo.y = s.y * fast_sig(s.y);
    xo.z = s.z * fast_sig(s.z); xo.w = s.w * fast_sig(s.w);
    *(float4*)(xi2 + (size_t)bt * DIq + d4) = xo;
    float4 r = *(const float4*)(xr + (size_t)bt * 3072 + 1536 + d4);
    float4 ro;
    ro.x = r.x * fast_sig(r.x); ro.y = r.y * fast_sig(r.y);
    ro.z = r.z * fast_sig(r.z); ro.w = r.w * fast_sig(r.w);
    *(float4*)(sres + (size_t)bt * DIq + d4) = ro;
}

// ---------------- selective-scan, LDS-tiled, 2 DS ops/step + DPP reduce ----------------
static constexpr int STB = 28;

__global__ __launch_bounds__(256) void k_scan(const float* __restrict__ delta, const float* __restrict__ xi2,
                                              const float* __restrict__ dbc, const float* __restrict__ sres,
                                              const float* __restrict__ Alog, const float* __restrict__ Dv,
                                              unsigned short* __restrict__ ys) {
    const int b = blockIdx.x;
    const int d0 = blockIdx.y * 32;
    const int tid = threadIdx.x;
    const int dl = tid >> 3;
    const int np = tid & 7;
    const int d = d0 + dl;
    const float A0 = -__expf(Alog[d * 16 + np]);
    const float A1 = -__expf(Alog[d * 16 + np + 8]);
    const float Dd = Dv[d];
    const int tr = tid >> 5;
    const int dls = tid & 31;

    __shared__ float4 sdu[STB][32];   // {de, u, sres, pad} per d
    __shared__ float sbc[STB][32];    // [np*4 + {B0,B1,C0,C1}]

    const float* gde = delta + ((size_t)b * NPq + tr) * DIq + d0 + dls;
    const float* gu  = xi2   + ((size_t)b * NPq + tr) * DIq + d0 + dls;
    const float* gsr = sres  + ((size_t)b * NPq + tr) * DIq + d0 + dls;
    const float* gbc = dbc   + ((size_t)b * NPq + tr) * 80 + 48 + dls;
    unsigned short* gy = ys + (size_t)b * NPq * DIq + d;

    float rde[4], ru[4], rsr[4], rbc[4];

    auto stageLoad = [&](int c) {
        const int t0 = c * STB;
        #pragma unroll
        for (int j = 0; j < 3; j++) {
            int off = (t0 + 8 * j) * DIq;
            rde[j] = gde[off];
            ru[j]  = gu[off];
            rsr[j] = gsr[off];
            rbc[j] = gbc[(t0 + 8 * j) * 80];
        }
        if (tid < 128) {
            int off = (t0 + 24) * DIq;
            rde[3] = gde[off];
            ru[3]  = gu[off];
            rsr[3] = gsr[off];
            rbc[3] = gbc[(t0 + 24) * 80];
        }
    };
    auto stageWrite = [&]() {
        const int pi = (dls & 7) * 4 + (dls >> 3);
        #pragma unroll
        for (int j = 0; j < 3; j++) {
            int t = tr + 8 * j;
            sdu[t][dls] = make_float4(rde[j], ru[j], rsr[j], 0.f);
            sbc[t][pi] = rbc[j];
        }
        if (tid < 128) {
            int t = tr + 24;
            sdu[t][dls] = make_float4(rde[3], ru[3], rsr[3], 0.f);
            sbc[t][pi] = rbc[3];
        }
    };

    stageLoad(0);
    stageWrite();
    __syncthreads();

    float h0 = 0.f, h1 = 0.f;
    for (int c = 0; c < 7; c++) {
        if (c < 6) stageLoad(c + 1);
        #pragma unroll 4
        for (int t = 0; t < STB; t++) {
            float4 du = sdu[t][dl];
            float4 bc = *(const float4*)&sbc[t][np * 4];
            float a0 = __expf(du.x * A0), a1 = __expf(du.x * A1);
            float deu = du.x * du.y;
            h0 = fmaf(a0, h0, deu * bc.x);
            h1 = fmaf(a1, h1, deu * bc.y);
            float p = fmaf(h1, bc.w, h0 * bc.z);
            p = dpp_add<0xB1>(p);    // += lane^1 (quad_perm [1,0,3,2])
            p = dpp_add<0x4E>(p);    // += lane^2 (quad_perm [2,3,0,1])
            p = dpp_add<0x141>(p);   // += other quad (row_half_mirror)
            if (np == 0) gy[(size_t)(c * STB + t) * DIq] = f2bf(fmaf(Dd, du.y, p) * du.z);
        }
        __syncthreads();
        if (c < 6) {
            stageWrite();
            __syncthreads();
        }
    }
}

// ---------------- row LayerNorm (1024) + exact gelu; out f32 or bf16 ----------------
template<bool OBF>
__global__ __launch_bounds__(256) void k_ln_gelu(const float* __restrict__ in, const float* __restrict__ g,
                                                 const float* __restrict__ bt, void* __restrict__ outv) {
    int row = blockIdx.x;
    const float* x = in + (size_t)row * OUTq;
    float4 v = ((const float4*)x)[threadIdx.x];
    float s = v.x + v.y + v.z + v.w;
    float ss = v.x * v.x + v.y * v.y + v.z * v.z + v.w * v.w;
    #pragma unroll
    for (int off = 32; off >= 1; off >>= 1) { s += __shfl_down(s, off); ss += __shfl_down(ss, off); }
    __shared__ float sh[10];
    int wid = threadIdx.x >> 6, lid = threadIdx.x & 63;
    if (lid == 0) { sh[wid] = s; sh[4 + wid] = ss; }
    __syncthreads();
    if (threadIdx.x == 0) {
        float S = sh[0] + sh[1] + sh[2] + sh[3], SS = sh[4] + sh[5] + sh[6] + sh[7];
        float m = S * (1.f / OUTq);
        float var = SS * (1.f / OUTq) - m * m;
        sh[8] = m; sh[9] = rsqrtf(var + 1e-5f);
    }
    __syncthreads();
    float m = sh[8], rst = sh[9];
    float4 gv = ((const float4*)g)[threadIdx.x];
    float4 bv = ((const float4*)bt)[threadIdx.x];
    float4 o;
    float y0 = (v.x - m) * rst * gv.x + bv.x; o.x = 0.5f * y0 * (1.f + erff(y0 * 0.70710678118f));
    float y1 = (v.y - m) * rst * gv.y + bv.y; o.y = 0.5f * y1 * (1.f + erff(y1 * 0.70710678118f));
    float y2 = (v.z - m) * rst * gv.z + bv.z; o.z = 0.5f * y2 * (1.f + erff(y2 * 0.70710678118f));
    float y3 = (v.w - m) * rst * gv.w + bv.w; o.w = 0.5f * y3 * (1.f + erff(y3 * 0.70710678118f));
    if (OBF) {
        ushort4 o4;
        o4.x = f2bf(o.x); o4.y = f2bf(o.y); o4.z = f2bf(o.z); o4.w = f2bf(o.w);
        ((ushort4*)((unsigned short*)outv + (size_t)row * OUTq))[threadIdx.x] = o4;
    } else {
        ((float4*)((float*)outv + (size_t)row * OUTq))[threadIdx.x] = o;
    }
}

// ---------------- column softmax + pool, 4-way t-split, online rescale ----------------
__global__ __launch_bounds__(256) void k_softpool(const float* __restrict__ gm, const unsigned short* __restrict__ ym,
                                                  float* __restrict__ pooled) {
    int b = blockIdx.y;
    int jl = threadIdx.x & 63;
    int j = blockIdx.x * 64 + jl;
    int tc = threadIdx.x >> 6;              // 0..3, 49 t's each
    const float* gb = gm + (size_t)b * NPq * OUTq + j;
    const unsigned short* yb = ym + (size_t)b * NPq * OUTq + j;
    int t0 = tc * 49;
    float m = -1e30f, s = 0.f, ps = 0.f;
    for (int t = t0; t < t0 + 49; t++) {
        float g = gb[(size_t)t * OUTq];
        float y = bf2f(yb[(size_t)t * OUTq]);
        float mn = fmaxf(m, g);
        float sc = __expf(m - mn);
        float e = __expf(g - mn);
        s = fmaf(s, sc, e);
        ps = fmaf(ps, sc, y * e);
        m = mn;
    }
    __shared__ float sm[4][64], ssum[4][64], sps[4][64];
    sm[tc][jl] = m; ssum[tc][jl] = s; sps[tc][jl] = ps;
    __syncthreads();
    if (tc == 0) {
        float m0 = sm[0][jl], m1 = sm[1][jl], m2 = sm[2][jl], m3 = sm[3][jl];
        float mt = fmaxf(fmaxf(m0, m1), fmaxf(m2, m3));
        float e0 = __expf(m0 - mt), e1 = __expf(m1 - mt);
        float e2 = __expf(m2 - mt), e3 = __expf(m3 - mt);
        float st = ssum[0][jl] * e0 + ssum[1][jl] * e1 + ssum[2][jl] * e2 + ssum[3][jl] * e3;
        float pt = sps[0][jl] * e0 + sps[1][jl] * e1 + sps[2][jl] * e2 + sps[3][jl] * e3;
        pooled[b * OUTq + j] = pt / st;
    }
}

// ---------------- final LayerNorm over 1024 per batch ----------------
__global__ __launch_bounds__(256) void k_final_ln(const float* __restrict__ p, const float* __restrict__ g,
                                                  const float* __restrict__ bt, float* __restrict__ out) {
    int row = blockIdx.x;
    const float* x = p + (size_t)row * OUTq;
    float4 v = ((const float4*)x)[threadIdx.x];
    float s = v.x + v.y + v.z + v.w;
    float ss = v.x * v.x + v.y * v.y + v.z * v.z + v.w * v.w;
    #pragma unroll
    for (int off = 32; off >= 1; off >>= 1) { s += __shfl_down(s, off); ss += __shfl_down(ss, off); }
    __shared__ float sh[10];
    int wid = threadIdx.x >> 6, lid = threadIdx.x & 63;
    if (lid == 0) { sh[wid] = s; sh[4 + wid] = ss; }
    __syncthreads();
    if (threadIdx.x == 0) {
        float S = sh[0] + sh[1] + sh[2] + sh[3], SS = sh[4] + sh[5] + sh[6] + sh[7];
        float m = S * (1.f / OUTq);
        float var = SS * (1.f / OUTq) - m * m;
        sh[8] = m; sh[9] = rsqrtf(var + 1e-5f);
    }
    __syncthreads();
    float m = sh[8], rst = sh[9];
    float4 gv = ((const float4*)g)[threadIdx.x];
    float4 bv = ((const float4*)bt)[threadIdx.x];
    float4 o;
    o.x = (v.x - m) * rst * gv.x + bv.x;
    o.y = (v.y - m) * rst * gv.y + bv.y;
    o.z = (v.z - m) * rst * gv.z + bv.z;
    o.w = (v.w - m) * rst * gv.w + bv.w;
    ((float4*)(out + (size_t)row * OUTq))[threadIdx.x] = o;
}

extern "C" void kernel_launch(void* const* d_in, const int* in_sizes, int n_in,
                              void* d_out, int out_size, void* d_ws, size_t ws_size,
                              hipStream_t stream) {
    const float* img   = (const float*)d_in[0];
    const float* sa_w  = (const float*)d_in[1];
    const float* pe_w  = (const float*)d_in[2];
    const float* pe_b  = (const float*)d_in[3];
    const float* pos   = (const float*)d_in[4];
    const float* in_w  = (const float*)d_in[5];
    const float* in_b  = (const float*)d_in[6];
    const float* cv_w  = (const float*)d_in[7];
    const float* cv_b  = (const float*)d_in[8];
    const float* xp_w  = (const float*)d_in[9];
    const float* dt_w  = (const float*)d_in[10];
    const float* dt_b  = (const float*)d_in[11];
    const float* Alog  = (const float*)d_in[12];
    const float* Dv    = (const float*)d_in[13];
    const float* ot_w  = (const float*)d_in[14];
    const float* ot_b  = (const float*)d_in[15];
    const float* em_w  = (const float*)d_in[16];
    const float* em_b  = (const float*)d_in[17];
    const float* em_g  = (const float*)d_in[18];
    const float* em_bt = (const float*)d_in[19];
    const float* at_w  = (const float*)d_in[20];
    const float* at_b  = (const float*)d_in[21];
    const float* at_g  = (const float*)d_in[22];
    const float* at_bt = (const float*)d_in[23];
    const float* la_g  = (const float*)d_in[24];
    const float* la_bt = (const float*)d_in[25];

    char* ws = (char*)d_ws;
    auto al = [](size_t x) { return (x + 255) & ~(size_t)255; };
    size_t SZ_am   = (size_t)NB * 2 * IMP * 4;
    size_t SZ_G    = (size_t)MPAD * 768 * 2;
    size_t SZ_x    = (size_t)MPAD * 768 * 2;
    size_t SZ_xr   = (size_t)ROWS * 3072 * 4;
    size_t SZ_xi2  = (size_t)ROWS * 1536 * 4;
    size_t SZ_de   = SZ_xi2;
    size_t SZ_dbc  = (size_t)ROWS * 80 * 4;
    size_t SZ_ys   = (size_t)MPAD * 1536 * 2;
    size_t SZ_sres = SZ_xi2;
    size_t SZ_yem  = (size_t)MPAD * 1024 * 2;
    size_t SZ_pool = (size_t)NB * OUTq * 4;
    size_t SZ_part = (size_t)XP_KS * ROWS * 80 * 4;

    size_t o_am   = 0;
    size_t o_G    = al(o_am + SZ_am);
    size_t o_x    = al(o_G + SZ_G);
    size_t o_xr   = al(o_x + SZ_x);
    size_t o_xi2  = al(o_xr + SZ_xr);
    size_t o_de   = al(o_xi2 + SZ_xi2);
    size_t o_dbc  = al(o_de + SZ_de);
    size_t o_ys   = al(o_dbc + SZ_dbc);
    size_t o_sres = al(o_ys + SZ_ys);
    size_t o_yem  = al(o_sres + SZ_sres);
    size_t o_pool = al(o_yem + SZ_yem);
    size_t o_part = al(o_pool + SZ_pool);

    size_t o_wpe  = al(o_part + SZ_part);
    size_t o_win0 = al(o_wpe  + (size_t)768 * 768 * 2);
    size_t o_win1 = al(o_win0 + (size_t)3072 * 768 * 2);
    size_t o_wot0 = al(o_win1 + (size_t)3072 * 768 * 2);
    size_t o_wot1 = al(o_wot0 + (size_t)768 * 1536 * 2);
    size_t o_wem  = al(o_wot1 + (size_t)768 * 1536 * 2);
    size_t o_wat  = al(o_wem  + (size_t)1024 * 768 * 2);

    float* am    = (float*)(ws + o_am);
    unsigned short* G  = (unsigned short*)(ws + o_G);
    unsigned short* x  = (unsigned short*)(ws + o_x);
    float* xr    = (float*)(ws + o_xr);
    float* xi2   = (float*)(ws + o_xi2);
    float* de    = (float*)(ws + o_de);
    float* dbc   = (float*)(ws + o_dbc);
    unsigned short* ys = (unsigned short*)(ws + o_ys);
    float* sres  = (float*)(ws + o_sres);
    unsigned short* yem = (unsigned short*)(ws + o_yem);
    float* pool  = (float*)(ws + o_pool);
    float* part  = (float*)(ws + o_part);
    unsigned short* wpe  = (unsigned short*)(ws + o_wpe);
    unsigned short* win0 = (unsigned short*)(ws + o_win0);
    unsigned short* win1 = (unsigned short*)(ws + o_win1);
    unsigned short* wot0 = (unsigned short*)(ws + o_wot0);
    unsigned short* wot1 = (unsigned short*)(ws + o_wot1);
    unsigned short* wem  = (unsigned short*)(ws + o_wem);
    unsigned short* wat  = (unsigned short*)(ws + o_wat);
    float* t1  = (float*)(ws + o_xr);
    float* t2  = (float*)(ws + o_de);
    float* gat = (float*)(ws + o_xi2);

    // ---- weight conversion (W[K][N] -> bf16 [N][K]) ----
    k_transpose_bf<<<dim3(768 / 32, 768 / 32), 256, 0, stream>>>(pe_w, wpe, 768, 768);
    k_transpose_bf<<<dim3(3072 / 32, 768 / 32), 256, 0, stream>>>(in_w, win0, 768, 3072);
    k_transpose_bf<<<dim3(3072 / 32, 768 / 32), 256, 0, stream>>>(in_w + (size_t)768 * 3072, win1, 768, 3072);
    k_transpose_bf<<<dim3(768 / 32, 1536 / 32), 256, 0, stream>>>(ot_w, wot0, 1536, 768);
    k_transpose_bf<<<dim3(768 / 32, 1536 / 32), 256, 0, stream>>>(ot_w + (size_t)1536 * 768, wot1, 1536, 768);
    k_transpose_bf<<<dim3(1024 / 32, 768 / 32), 256, 0, stream>>>(em_w, wem, 768, 1024);
    k_transpose_bf<<<dim3(1024 / 32, 1024 / 32), 256, 0, stream>>>(at_w, wat, 1024, 1024);

    int nq = NB * IMP / 4;   // 200704
    k_avgmax<<<(nq + 255) / 256, 256, 0, stream>>>(img, am);
    k_gatepatch<<<(nq + 255) / 256, 256, 0, stream>>>(img, am, sa_w, G);

    dim3 blk(256);
    // patch embed: x(bf16) = G @ pe_w + pe_b + pos
    k_gemm_bf<EPI_POSEMB, true><<<dim3(12, 25), blk, 0, stream>>>(G, wpe, pe_b, x, 768, ROWS, 768, 768, pos);

    for (int l = 0; l < 2; l++) {
        const unsigned short* win = l ? win1 : win0;
        const unsigned short* wot = l ? wot1 : wot0;
        // xr(f32) = x @ in_w + in_b
        k_gemm_bf<EPI_NONE, false><<<dim3(48, 25), blk, 0, stream>>>(x, win, in_b + l * 3072, xr, 3072,
                                                                     ROWS, 3072, 768, nullptr);
        int nc4 = ROWS * DIq / 4;
        k_conv_silu<<<(nc4 + 255) / 256, 256, 0, stream>>>(xr, cv_w + (size_t)l * DIq * 4, cv_b + l * DIq,
                                                           xi2, sres);
        k_xproj_part<<<dim3(ROWS / 32, XP_KS), blk, 0, stream>>>(xi2, xp_w + (size_t)l * 1536 * 80, part);
        k_xreduce<<<(ROWS * 80 / 4 + 255) / 256, 256, 0, stream>>>(part, dbc);
        k_dt<<<ROWS / DT_RPB, 384, 0, stream>>>(dbc, dt_w + (size_t)l * 48 * 1536, dt_b + l * 1536, de);
        k_scan<<<dim3(16, 48), blk, 0, stream>>>(de, xi2, dbc, sres, Alog + (size_t)l * 1536 * 16,
                                                 Dv + l * 1536, ys);
        // x(bf16) = ys @ out_w + out_b
        k_gemm_bf<EPI_NONE, true><<<dim3(12, 25), blk, 0, stream>>>(ys, wot, ot_b + l * 768, x, 768,
                                                                    ROWS, 768, 1536, nullptr);
    }

    // head
    k_gemm_bf<EPI_NONE, false><<<dim3(16, 25), blk, 0, stream>>>(x, wem, em_b, t1, 1024, ROWS, 1024, 768, nullptr);
    k_ln_gelu<true><<<ROWS, 256, 0, stream>>>(t1, em_g, em_bt, yem);
    k_gemm_bf<EPI_NONE, false><<<dim3(16, 25), blk, 0, stream>>>(yem, wat, at_b, t2, 1024, ROWS, 1024, 1024, nullptr);
    k_ln_gelu<false><<<ROWS, 256, 0, stream>>>(t2, at_g, at_bt, gat);
    k_softpool<<<dim3(16, NB), 256, 0, stream>>>(gat, yem, pool);
    k_final_ln<<<NB, 256, 0, stream>>>(pool, la_g, la_bt, (float*)d_out);
}

// Round 9
// 503.691 us; speedup vs baseline: 4.9501x; 1.0075x over previous
//
#include <hip/hip_runtime.h>
#include <math.h>

static constexpr int NB = 16;
static constexpr int NC = 3;
static constexpr int IM = 224;
static constexpr int IMP = IM * IM;      // 50176
static constexpr int HPq = 14;
static constexpr int NPq = 196;
static constexpr int OUTq = 1024;
static constexpr int DIq = 1536;
static constexpr int ROWS = NB * NPq;    // 3136
static constexpr int MPAD = 3200;        // 25*128, GEMM A-operand row padding

typedef __bf16 bf8_t __attribute__((ext_vector_type(8)));
typedef float f4_t __attribute__((ext_vector_type(4)));
typedef const __attribute__((address_space(1))) unsigned int cgu32;
typedef __attribute__((address_space(3))) unsigned int lu32;

__device__ inline unsigned short f2bf(float x) {
    unsigned u = __builtin_bit_cast(unsigned, x);
    unsigned r = (u + 0x7FFFu + ((u >> 16) & 1u)) >> 16;
    return (unsigned short)r;
}
__device__ inline float bf2f(unsigned short v) {
    return __builtin_bit_cast(float, (unsigned)v << 16);
}
__device__ inline float fast_sig(float x) {
    return __builtin_amdgcn_rcpf(1.f + __expf(-x));
}

// VALU-pipe cross-lane add via DPP
template<int CTRL>
__device__ inline float dpp_add(float x) {
    int v = __builtin_amdgcn_update_dpp(0, __builtin_bit_cast(int, x), CTRL, 0xF, 0xF, true);
    return x + __builtin_bit_cast(float, v);
}

// ---------------- K1a: channel avg/max (float4, 4 px/thread) ----------------
__global__ __launch_bounds__(256) void k_avgmax(const float* __restrict__ img, float* __restrict__ am) {
    int idx = blockIdx.x * 256 + threadIdx.x;
    if (idx >= NB * IMP / 4) return;
    int p4 = (idx % (IMP / 4)) * 4, b = idx / (IMP / 4);
    const float* ib = img + (size_t)b * NC * IMP + p4;
    float4 c0 = *(const float4*)ib;
    float4 c1 = *(const float4*)(ib + IMP);
    float4 c2 = *(const float4*)(ib + 2 * IMP);
    float4 av, mx;
    av.x = (c0.x + c1.x + c2.x) * (1.f / 3.f); mx.x = fmaxf(c0.x, fmaxf(c1.x, c2.x));
    av.y = (c0.y + c1.y + c2.y) * (1.f / 3.f); mx.y = fmaxf(c0.y, fmaxf(c1.y, c2.y));
    av.z = (c0.z + c1.z + c2.z) * (1.f / 3.f); mx.z = fmaxf(c0.z, fmaxf(c1.z, c2.z));
    av.w = (c0.w + c1.w + c2.w) * (1.f / 3.f); mx.w = fmaxf(c0.w, fmaxf(c1.w, c2.w));
    *(float4*)(am + (size_t)(b * 2 + 0) * IMP + p4) = av;
    *(float4*)(am + (size_t)(b * 2 + 1) * IMP + p4) = mx;
}

// ---------------- K1b: 7x7 conv gate + patchify, 4 px/thread ----------------
__global__ __launch_bounds__(256) void k_gatepatch(const float* __restrict__ img, const float* __restrict__ am,
                                                   const float* __restrict__ saw, unsigned short* __restrict__ G) {
    int quad = blockIdx.x * 256 + threadIdx.x;
    if (quad >= NB * IMP / 4) return;
    int pq = quad % (IMP / 4), b = quad / (IMP / 4);
    int x0 = (pq % 56) * 4;
    int y = pq / 56;
    float acc0 = 0.f, acc1 = 0.f, acc2 = 0.f, acc3 = 0.f;
    const bool lok = (x0 >= 4), rok = (x0 <= IM - 8);
    #pragma unroll
    for (int ci = 0; ci < 2; ci++) {
        const float* amc = am + (size_t)(b * 2 + ci) * IMP;
        const float* wc = saw + ci * 49;
        #pragma unroll
        for (int kh = 0; kh < 7; kh++) {
            int yy = y + kh - 3;
            if (yy < 0 || yy >= IM) continue;
            const float* rowp = amc + yy * IM;
            float4 lv = lok ? *(const float4*)(rowp + x0 - 4) : make_float4(0.f, 0.f, 0.f, 0.f);
            float4 mv = *(const float4*)(rowp + x0);
            float4 rv = rok ? *(const float4*)(rowp + x0 + 4) : make_float4(0.f, 0.f, 0.f, 0.f);
            float f[12] = {lv.x, lv.y, lv.z, lv.w, mv.x, mv.y, mv.z, mv.w, rv.x, rv.y, rv.z, rv.w};
            #pragma unroll
            for (int kw = 0; kw < 7; kw++) {
                float w = wc[kh * 7 + kw];
                acc0 = fmaf(w, f[kw + 1], acc0);
                acc1 = fmaf(w, f[kw + 2], acc1);
                acc2 = fmaf(w, f[kw + 3], acc2);
                acc3 = fmaf(w, f[kw + 4], acc3);
            }
        }
    }
    float s0 = fast_sig(acc0), s1 = fast_sig(acc1), s2 = fast_sig(acc2), s3 = fast_sig(acc3);
    const float* ib = img + (size_t)b * NC * IMP + y * IM + x0;
    float4 c0 = *(const float4*)ib;
    float4 c1 = *(const float4*)(ib + IMP);
    float4 c2 = *(const float4*)(ib + 2 * IMP);
    int hy = y >> 4, py = y & 15, hx = x0 >> 4, px0 = x0 & 15;
    size_t base = ((size_t)(b * NPq + hy * HPq + hx) * 768) + (size_t)(py * 16 + px0) * 3;
    ushort4 o0, o1, o2;
    o0.x = f2bf(c0.x * s0); o0.y = f2bf(c1.x * s0); o0.z = f2bf(c2.x * s0);
    o0.w = f2bf(c0.y * s1);
    o1.x = f2bf(c1.y * s1); o1.y = f2bf(c2.y * s1);
    o1.z = f2bf(c0.z * s2); o1.w = f2bf(c1.z * s2);
    o2.x = f2bf(c2.z * s2);
    o2.y = f2bf(c0.w * s3); o2.z = f2bf(c1.w * s3); o2.w = f2bf(c2.w * s3);
    *(ushort4*)(G + base + 0) = o0;
    *(ushort4*)(G + base + 4) = o1;
    *(ushort4*)(G + base + 8) = o2;
}

// ---------------- weight transpose + f32->bf16: W[K][N] -> Wt[N][K] ----------------
__global__ __launch_bounds__(256) void k_transpose_bf(const float* __restrict__ W, unsigned short* __restrict__ Wt,
                                                      int K, int N) {
    __shared__ float t[32][33];
    int n0 = blockIdx.x * 32, k0 = blockIdx.y * 32;
    int c = threadIdx.x & 31, r8 = threadIdx.x >> 5;
    #pragma unroll
    for (int i = 0; i < 4; i++) {
        int r = r8 + i * 8;
        t[r][c] = W[(size_t)(k0 + r) * N + n0 + c];
    }
    __syncthreads();
    #pragma unroll
    for (int i = 0; i < 4; i++) {
        int r = r8 + i * 8;
        Wt[(size_t)(n0 + r) * K + k0 + c] = f2bf(t[c][r]);
    }
}

// ---------------- bf16 MFMA GEMM, gload_lds + double-buffer ----------------
enum { EPI_NONE = 0, EPI_POSEMB = 1, EPI_SPLIT = 2 };

template<int EPI, bool CBF>
__global__ __launch_bounds__(256) void k_gemm_bf(const unsigned short* __restrict__ A,
                                                 const unsigned short* __restrict__ Wt,
                                                 const float* __restrict__ bias,
                                                 void* __restrict__ Cv, int ldc,
                                                 int M, int N, int K,
                                                 const float* __restrict__ extra,
                                                 float* __restrict__ C2) {
    constexpr int BM = 128, BN = 64;
    __shared__ __align__(16) unsigned short As[2][BM * 64];
    __shared__ __align__(16) unsigned short Bs[2][BN * 64];
    const int bm = blockIdx.y * BM, bn = blockIdx.x * BN;
    const int tid = threadIdx.x;
    const int lane = tid & 63;
    const int wbase = tid & ~63;
    const int wr = ((tid >> 7) & 1) * 64;
    const int wc = ((tid >> 6) & 1) * 32;
    const int lr = lane & 15, lq = lane >> 4;

    f4_t acc[4][2] = {};

    auto stage = [&](int buf, int k0) {
        #pragma unroll
        for (int i = 0; i < 4; i++) {
            int gid2 = i * 256 + tid;
            int r = gid2 >> 3, g = gid2 & 7;
            const unsigned short* src = A + (size_t)(bm + r) * K + k0 + ((g ^ (r & 7)) * 8);
            __builtin_amdgcn_global_load_lds((cgu32*)src,
                (lu32*)&As[buf][(i * 256 + wbase) * 8], 16, 0, 0);
        }
        #pragma unroll
        for (int i = 0; i < 2; i++) {
            int gid2 = i * 256 + tid;
            int r = gid2 >> 3, g = gid2 & 7;
            const unsigned short* src = Wt + (size_t)(bn + r) * K + k0 + ((g ^ (r & 7)) * 8);
            __builtin_amdgcn_global_load_lds((cgu32*)src,
                (lu32*)&Bs[buf][(i * 256 + wbase) * 8], 16, 0, 0);
        }
    };

    stage(0, 0);
    __syncthreads();
    int cur = 0;
    for (int k0 = 0; k0 < K; k0 += 64) {
        if (k0 + 64 < K) stage(cur ^ 1, k0 + 64);
        #pragma unroll
        for (int h = 0; h < 2; h++) {
            bf8_t af[4], bfr[2];
            #pragma unroll
            for (int mb = 0; mb < 4; mb++) {
                int row = wr + mb * 16 + lr;
                int g = h * 4 + lq;
                af[mb] = *(const bf8_t*)&As[cur][row * 64 + ((g ^ (row & 7)) * 8)];
            }
            #pragma unroll
            for (int nb = 0; nb < 2; nb++) {
                int rn = wc + nb * 16 + lr;
                int g = h * 4 + lq;
                bfr[nb] = *(const bf8_t*)&Bs[cur][rn * 64 + ((g ^ (rn & 7)) * 8)];
            }
            #pragma unroll
            for (int mb = 0; mb < 4; mb++)
                #pragma unroll
                for (int nb = 0; nb < 2; nb++)
                    acc[mb][nb] = __builtin_amdgcn_mfma_f32_16x16x32_bf16(af[mb], bfr[nb], acc[mb][nb], 0, 0, 0);
        }
        __syncthreads();
        cur ^= 1;
    }

    #pragma unroll
    for (int mb = 0; mb < 4; mb++) {
        #pragma unroll
        for (int nb = 0; nb < 2; nb++) {
            int col = bn + wc + nb * 16 + lr;
            #pragma unroll
            for (int q = 0; q < 4; q++) {
                int row = bm + wr + mb * 16 + lq * 4 + q;
                if (row < M) {
                    float v = acc[mb][nb][q];
                    if (bias) v += bias[col];
                    if (EPI == EPI_SPLIT) {
                        // xi half -> bf16 xr2; res half -> silu f32 sres
                        if (col < DIq) ((unsigned short*)Cv)[(size_t)row * DIq + col] = f2bf(v);
                        else           C2[(size_t)row * DIq + (col - DIq)] = v * fast_sig(v);
                    } else {
                        if (EPI == EPI_POSEMB) v += extra[(size_t)(row % NPq) * N + col];
                        if (CBF) ((unsigned short*)Cv)[(size_t)row * ldc + col] = f2bf(v);
                        else     ((float*)Cv)[(size_t)row * ldc + col] = v;
                    }
                }
            }
        }
    }
}

// ---------------- xproj split-K f32 GEMM ----------------
static constexpr int XP_KS = 4;
static constexpr int XP_KC = 1536 / XP_KS;   // 384

__global__ __launch_bounds__(256) void k_xproj_part(const float* __restrict__ xi2, const float* __restrict__ W,
                                                    float* __restrict__ part) {
    __shared__ float As[32][65];
    __shared__ __align__(16) float Bs[64][80];
    int m0 = blockIdx.x * 32;
    int kc0 = blockIdx.y * XP_KC;
    int tid = threadIdx.x;
    int row = tid >> 3, cg = (tid & 7) * 10;
    float acc[10] = {};
    for (int k0 = 0; k0 < XP_KC; k0 += 64) {
        #pragma unroll
        for (int i = 0; i < 2; i++) {
            int id = tid + i * 256;
            int r = id >> 4, c4 = (id & 15) * 4;
            float4 v = *(const float4*)(xi2 + (size_t)(m0 + r) * 1536 + kc0 + k0 + c4);
            As[r][c4] = v.x; As[r][c4 + 1] = v.y; As[r][c4 + 2] = v.z; As[r][c4 + 3] = v.w;
        }
        #pragma unroll
        for (int i = 0; i < 5; i++) {
            int id = tid + i * 256;
            int r = id / 20, c4 = (id % 20) * 4;
            *(float4*)&Bs[r][c4] = *(const float4*)(W + (size_t)(kc0 + k0 + r) * 80 + c4);
        }
        __syncthreads();
        #pragma unroll
        for (int kk = 0; kk < 64; kk++) {
            float a = As[row][kk];
            #pragma unroll
            for (int j = 0; j < 10; j++)
                acc[j] = fmaf(a, Bs[kk][cg + j], acc[j]);
        }
        __syncthreads();
    }
    float* p = part + ((size_t)blockIdx.y * ROWS + m0 + row) * 80 + cg;
    #pragma unroll
    for (int j = 0; j < 10; j++) p[j] = acc[j];
}

// ---------------- merged xreduce + dt GEMM (K=48) + softplus ----------------
// reduces 4 split-K partials; writes dbc cols 48..79 (B/C for scan); computes de.
static constexpr int DT_RPB = 4;
__global__ __launch_bounds__(384) void k_dtred(const float* __restrict__ part, const float* __restrict__ W,
                                               const float* __restrict__ bias, float* __restrict__ de,
                                               float* __restrict__ dbc) {
    int r0 = blockIdx.x * DT_RPB;
    int tid = threadIdx.x;
    __shared__ float ds[DT_RPB][80];
    if (tid < DT_RPB * 80) {
        int row = tid / 80, col = tid % 80;
        const int S = ROWS * 80;
        const float* p = part + (size_t)(r0 + row) * 80 + col;
        float s = p[0] + p[S] + p[2 * S] + p[3 * S];
        ds[row][col] = s;
        if (col >= 48) dbc[(size_t)(r0 + row) * 80 + col] = s;
    }
    __syncthreads();
    int j = tid * 4;
    float4 b = *(const float4*)(bias + j);
    float4 a0 = b, a1 = b, a2 = b, a3 = b;
    for (int k = 0; k < 48; k++) {
        float4 w = *(const float4*)(W + (size_t)k * 1536 + j);
        float d0 = ds[0][k], d1 = ds[1][k], d2 = ds[2][k], d3 = ds[3][k];
        a0.x = fmaf(d0, w.x, a0.x); a0.y = fmaf(d0, w.y, a0.y); a0.z = fmaf(d0, w.z, a0.z); a0.w = fmaf(d0, w.w, a0.w);
        a1.x = fmaf(d1, w.x, a1.x); a1.y = fmaf(d1, w.y, a1.y); a1.z = fmaf(d1, w.z, a1.z); a1.w = fmaf(d1, w.w, a1.w);
        a2.x = fmaf(d2, w.x, a2.x); a2.y = fmaf(d2, w.y, a2.y); a2.z = fmaf(d2, w.z, a2.z); a2.w = fmaf(d2, w.w, a2.w);
        a3.x = fmaf(d3, w.x, a3.x); a3.y = fmaf(d3, w.y, a3.y); a3.z = fmaf(d3, w.z, a3.z); a3.w = fmaf(d3, w.w, a3.w);
    }
    auto sp = [](float v) { return (v > 20.f) ? v : log1pf(expf(v)); };
    float4 o;
    o.x = sp(a0.x); o.y = sp(a0.y); o.z = sp(a0.z); o.w = sp(a0.w);
    *(float4*)(de + (size_t)(r0 + 0) * 1536 + j) = o;
    o.x = sp(a1.x); o.y = sp(a1.y); o.z = sp(a1.z); o.w = sp(a1.w);
    *(float4*)(de + (size_t)(r0 + 1) * 1536 + j) = o;
    o.x = sp(a2.x); o.y = sp(a2.y); o.z = sp(a2.z); o.w = sp(a2.w);
    *(float4*)(de + (size_t)(r0 + 2) * 1536 + j) = o;
    o.x = sp(a3.x); o.y = sp(a3.y); o.z = sp(a3.z); o.w = sp(a3.w);
    *(float4*)(de + (size_t)(r0 + 3) * 1536 + j) = o;
}

// ---------------- causal depthwise conv (DC=4) + silu, bf16 taps, 4 d's/thread ----------------
__global__ __launch_bounds__(256) void k_conv_silu(const unsigned short* __restrict__ xr2, const float* __restrict__ cw,
                                                   const float* __restrict__ cb, float* __restrict__ xi2) {
    int idx4 = blockIdx.x * 256 + threadIdx.x;
    if (idx4 >= ROWS * DIq / 4) return;
    int d4 = (idx4 % (DIq / 4)) * 4;
    int bt = idx4 / (DIq / 4);
    int t = bt % NPq, b = bt / NPq;
    const unsigned short* base = xr2 + (size_t)b * NPq * DIq + d4;
    float4 s = *(const float4*)(cb + d4);
    float4 w0 = *(const float4*)(cw + (d4 + 0) * 4);
    float4 w1 = *(const float4*)(cw + (d4 + 1) * 4);
    float4 w2 = *(const float4*)(cw + (d4 + 2) * 4);
    float4 w3 = *(const float4*)(cw + (d4 + 3) * 4);
    if (t >= 3) {
        ushort4 v = *(const ushort4*)(base + (size_t)(t - 3) * DIq);
        s.x = fmaf(bf2f(v.x), w0.x, s.x); s.y = fmaf(bf2f(v.y), w1.x, s.y);
        s.z = fmaf(bf2f(v.z), w2.x, s.z); s.w = fmaf(bf2f(v.w), w3.x, s.w);
    }
    if (t >= 2) {
        ushort4 v = *(const ushort4*)(base + (size_t)(t - 2) * DIq);
        s.x = fmaf(bf2f(v.x), w0.y, s.x); s.y = fmaf(bf2f(v.y), w1.y, s.y);
        s.z = fmaf(bf2f(v.z), w2.y, s.z); s.w = fmaf(bf2f(v.w), w3.y, s.w);
    }
    if (t >= 1) {
        ushort4 v = *(const ushort4*)(base + (size_t)(t - 1) * DIq);
        s.x = fmaf(bf2f(v.x), w0.z, s.x); s.y = fmaf(bf2f(v.y), w1.z, s.y);
        s.z = fmaf(bf2f(v.z), w2.z, s.z); s.w = fmaf(bf2f(v.w), w3.z, s.w);
    }
    {
        ushort4 v = *(const ushort4*)(base + (size_t)t * DIq);
        s.x = fmaf(bf2f(v.x), w0.w, s.x); s.y = fmaf(bf2f(v.y), w1.w, s.y);
        s.z = fmaf(bf2f(v.z), w2.w, s.z); s.w = fmaf(bf2f(v.w), w3.w, s.w);
    }
    float4 xo;
    xo.x = s.x * fast_sig(s.x); xo.y = s.y * fast_sig(s.y);
    xo.z = s.z * fast_sig(s.z); xo.w = s.w * fast_sig(s.w);
    *(float4*)(xi2 + (size_t)bt * DIq + d4) = xo;
}

// ---------------- selective-scan, LDS double-buffered, 1 barrier/tile ----------------
static constexpr int STB = 28;

__global__ __launch_bounds__(256) void k_scan(const float* __restrict__ delta, const float* __restrict__ xi2,
                                              const float* __restrict__ dbc, const float* __restrict__ sres,
                                              const float* __restrict__ Alog, const float* __restrict__ Dv,
                                              unsigned short* __restrict__ ys) {
    const int b = blockIdx.x;
    const int d0 = blockIdx.y * 32;
    const int tid = threadIdx.x;
    const int dl = tid >> 3;
    const int np = tid & 7;
    const int d = d0 + dl;
    const float A0 = -__expf(Alog[d * 16 + np]);
    const float A1 = -__expf(Alog[d * 16 + np + 8]);
    const float Dd = Dv[d];
    const int tr = tid >> 5;
    const int dls = tid & 31;

    __shared__ float4 sdu[2][STB][32];   // {de, u, sres, pad} per d
    __shared__ float sbc[2][STB][32];    // [np*4 + {B0,B1,C0,C1}]

    const float* gde = delta + ((size_t)b * NPq + tr) * DIq + d0 + dls;
    const float* gu  = xi2   + ((size_t)b * NPq + tr) * DIq + d0 + dls;
    const float* gsr = sres  + ((size_t)b * NPq + tr) * DIq + d0 + dls;
    const float* gbc = dbc   + ((size_t)b * NPq + tr) * 80 + 48 + dls;
    unsigned short* gy = ys + (size_t)b * NPq * DIq + d;

    float rde[4], ru[4], rsr[4], rbc[4];

    auto stageLoad = [&](int c) {
        const int t0 = c * STB;
        #pragma unroll
        for (int j = 0; j < 3; j++) {
            int off = (t0 + 8 * j) * DIq;
            rde[j] = gde[off];
            ru[j]  = gu[off];
            rsr[j] = gsr[off];
            rbc[j] = gbc[(t0 + 8 * j) * 80];
        }
        if (tid < 128) {
            int off = (t0 + 24) * DIq;
            rde[3] = gde[off];
            ru[3]  = gu[off];
            rsr[3] = gsr[off];
            rbc[3] = gbc[(t0 + 24) * 80];
        }
    };
    auto stageWrite = [&](int buf) {
        const int pi = (dls & 7) * 4 + (dls >> 3);
        #pragma unroll
        for (int j = 0; j < 3; j++) {
            int t = tr + 8 * j;
            sdu[buf][t][dls] = make_float4(rde[j], ru[j], rsr[j], 0.f);
            sbc[buf][t][pi] = rbc[j];
        }
        if (tid < 128) {
            int t = tr + 24;
            sdu[buf][t][dls] = make_float4(rde[3], ru[3], rsr[3], 0.f);
            sbc[buf][t][pi] = rbc[3];
        }
    };

    stageLoad(0);
    stageWrite(0);
    __syncthreads();

    float h0 = 0.f, h1 = 0.f;
    int cur = 0;
    for (int c = 0; c < 7; c++) {
        if (c < 6) stageLoad(c + 1);
        #pragma unroll 4
        for (int t = 0; t < STB; t++) {
            float4 du = sdu[cur][t][dl];
            float4 bc = *(const float4*)&sbc[cur][t][np * 4];
            float a0 = __expf(du.x * A0), a1 = __expf(du.x * A1);
            float deu = du.x * du.y;
            h0 = fmaf(a0, h0, deu * bc.x);
            h1 = fmaf(a1, h1, deu * bc.y);
            float p = fmaf(h1, bc.w, h0 * bc.z);
            p = dpp_add<0xB1>(p);    // += lane^1
            p = dpp_add<0x4E>(p);    // += lane^2
            p = dpp_add<0x141>(p);   // += other quad (row_half_mirror)
            if (np == 0) gy[(size_t)(c * STB + t) * DIq] = f2bf(fmaf(Dd, du.y, p) * du.z);
        }
        if (c < 6) stageWrite(cur ^ 1);   // writes the idle buffer — no race with readers of cur
        __syncthreads();
        cur ^= 1;
    }
}

// ---------------- row LayerNorm (1024) + exact gelu; out f32 or bf16 ----------------
template<bool OBF>
__global__ __launch_bounds__(256) void k_ln_gelu(const float* __restrict__ in, const float* __restrict__ g,
                                                 const float* __restrict__ bt, void* __restrict__ outv) {
    int row = blockIdx.x;
    const float* x = in + (size_t)row * OUTq;
    float4 v = ((const float4*)x)[threadIdx.x];
    float s = v.x + v.y + v.z + v.w;
    float ss = v.x * v.x + v.y * v.y + v.z * v.z + v.w * v.w;
    #pragma unroll
    for (int off = 32; off >= 1; off >>= 1) { s += __shfl_down(s, off); ss += __shfl_down(ss, off); }
    __shared__ float sh[10];
    int wid = threadIdx.x >> 6, lid = threadIdx.x & 63;
    if (lid == 0) { sh[wid] = s; sh[4 + wid] = ss; }
    __syncthreads();
    if (threadIdx.x == 0) {
        float S = sh[0] + sh[1] + sh[2] + sh[3], SS = sh[4] + sh[5] + sh[6] + sh[7];
        float m = S * (1.f / OUTq);
        float var = SS * (1.f / OUTq) - m * m;
        sh[8] = m; sh[9] = rsqrtf(var + 1e-5f);
    }
    __syncthreads();
    float m = sh[8], rst = sh[9];
    float4 gv = ((const float4*)g)[threadIdx.x];
    float4 bv = ((const float4*)bt)[threadIdx.x];
    float4 o;
    float y0 = (v.x - m) * rst * gv.x + bv.x; o.x = 0.5f * y0 * (1.f + erff(y0 * 0.70710678118f));
    float y1 = (v.y - m) * rst * gv.y + bv.y; o.y = 0.5f * y1 * (1.f + erff(y1 * 0.70710678118f));
    float y2 = (v.z - m) * rst * gv.z + bv.z; o.z = 0.5f * y2 * (1.f + erff(y2 * 0.70710678118f));
    float y3 = (v.w - m) * rst * gv.w + bv.w; o.w = 0.5f * y3 * (1.f + erff(y3 * 0.70710678118f));
    if (OBF) {
        ushort4 o4;
        o4.x = f2bf(o.x); o4.y = f2bf(o.y); o4.z = f2bf(o.z); o4.w = f2bf(o.w);
        ((ushort4*)((unsigned short*)outv + (size_t)row * OUTq))[threadIdx.x] = o4;
    } else {
        ((float4*)((float*)outv + (size_t)row * OUTq))[threadIdx.x] = o;
    }
}

// ---------------- column softmax + pool, 4-way t-split, online rescale ----------------
__global__ __launch_bounds__(256) void k_softpool(const float* __restrict__ gm, const unsigned short* __restrict__ ym,
                                                  float* __restrict__ pooled) {
    int b = blockIdx.y;
    int jl = threadIdx.x & 63;
    int j = blockIdx.x * 64 + jl;
    int tc = threadIdx.x >> 6;
    const float* gb = gm + (size_t)b * NPq * OUTq + j;
    const unsigned short* yb = ym + (size_t)b * NPq * OUTq + j;
    int t0 = tc * 49;
    float m = -1e30f, s = 0.f, ps = 0.f;
    for (int t = t0; t < t0 + 49; t++) {
        float g = gb[(size_t)t * OUTq];
        float y = bf2f(yb[(size_t)t * OUTq]);
        float mn = fmaxf(m, g);
        float sc = __expf(m - mn);
        float e = __expf(g - mn);
        s = fmaf(s, sc, e);
        ps = fmaf(ps, sc, y * e);
        m = mn;
    }
    __shared__ float sm[4][64], ssum[4][64], sps[4][64];
    sm[tc][jl] = m; ssum[tc][jl] = s; sps[tc][jl] = ps;
    __syncthreads();
    if (tc == 0) {
        float m0 = sm[0][jl], m1 = sm[1][jl], m2 = sm[2][jl], m3 = sm[3][jl];
        float mt = fmaxf(fmaxf(m0, m1), fmaxf(m2, m3));
        float e0 = __expf(m0 - mt), e1 = __expf(m1 - mt);
        float e2 = __expf(m2 - mt), e3 = __expf(m3 - mt);
        float st = ssum[0][jl] * e0 + ssum[1][jl] * e1 + ssum[2][jl] * e2 + ssum[3][jl] * e3;
        float pt = sps[0][jl] * e0 + sps[1][jl] * e1 + sps[2][jl] * e2 + sps[3][jl] * e3;
        pooled[b * OUTq + j] = pt / st;
    }
}

// ---------------- final LayerNorm over 1024 per batch ----------------
__global__ __launch_bounds__(256) void k_final_ln(const float* __restrict__ p, const float* __restrict__ g,
                                                  const float* __restrict__ bt, float* __restrict__ out) {
    int row = blockIdx.x;
    const float* x = p + (size_t)row * OUTq;
    float4 v = ((const float4*)x)[threadIdx.x];
    float s = v.x + v.y + v.z + v.w;
    float ss = v.x * v.x + v.y * v.y + v.z * v.z + v.w * v.w;
    #pragma unroll
    for (int off = 32; off >= 1; off >>= 1) { s += __shfl_down(s, off); ss += __shfl_down(ss, off); }
    __shared__ float sh[10];
    int wid = threadIdx.x >> 6, lid = threadIdx.x & 63;
    if (lid == 0) { sh[wid] = s; sh[4 + wid] = ss; }
    __syncthreads();
    if (threadIdx.x == 0) {
        float S = sh[0] + sh[1] + sh[2] + sh[3], SS = sh[4] + sh[5] + sh[6] + sh[7];
        float m = S * (1.f / OUTq);
        float var = SS * (1.f / OUTq) - m * m;
        sh[8] = m; sh[9] = rsqrtf(var + 1e-5f);
    }
    __syncthreads();
    float m = sh[8], rst = sh[9];
    float4 gv = ((const float4*)g)[threadIdx.x];
    float4 bv = ((const float4*)bt)[threadIdx.x];
    float4 o;
    o.x = (v.x - m) * rst * gv.x + bv.x;
    o.y = (v.y - m) * rst * gv.y + bv.y;
    o.z = (v.z - m) * rst * gv.z + bv.z;
    o.w = (v.w - m) * rst * gv.w + bv.w;
    ((float4*)(out + (size_t)row * OUTq))[threadIdx.x] = o;
}

extern "C" void kernel_launch(void* const* d_in, const int* in_sizes, int n_in,
                              void* d_out, int out_size, void* d_ws, size_t ws_size,
                              hipStream_t stream) {
    const float* img   = (const float*)d_in[0];
    const float* sa_w  = (const float*)d_in[1];
    const float* pe_w  = (const float*)d_in[2];
    const float* pe_b  = (const float*)d_in[3];
    const float* pos   = (const float*)d_in[4];
    const float* in_w  = (const float*)d_in[5];
    const float* in_b  = (const float*)d_in[6];
    const float* cv_w  = (const float*)d_in[7];
    const float* cv_b  = (const float*)d_in[8];
    const float* xp_w  = (const float*)d_in[9];
    const float* dt_w  = (const float*)d_in[10];
    const float* dt_b  = (const float*)d_in[11];
    const float* Alog  = (const float*)d_in[12];
    const float* Dv    = (const float*)d_in[13];
    const float* ot_w  = (const float*)d_in[14];
    const float* ot_b  = (const float*)d_in[15];
    const float* em_w  = (const float*)d_in[16];
    const float* em_b  = (const float*)d_in[17];
    const float* em_g  = (const float*)d_in[18];
    const float* em_bt = (const float*)d_in[19];
    const float* at_w  = (const float*)d_in[20];
    const float* at_b  = (const float*)d_in[21];
    const float* at_g  = (const float*)d_in[22];
    const float* at_bt = (const float*)d_in[23];
    const float* la_g  = (const float*)d_in[24];
    const float* la_bt = (const float*)d_in[25];

    char* ws = (char*)d_ws;
    auto al = [](size_t x) { return (x + 255) & ~(size_t)255; };
    size_t SZ_am   = (size_t)NB * 2 * IMP * 4;
    size_t SZ_G    = (size_t)MPAD * 768 * 2;
    size_t SZ_x    = (size_t)MPAD * 768 * 2;
    size_t SZ_xr2  = (size_t)ROWS * DIq * 2;          // bf16 xi-half
    size_t SZ_xi2  = (size_t)ROWS * DIq * 4;
    size_t SZ_de   = SZ_xi2;
    size_t SZ_dbc  = (size_t)ROWS * 80 * 4;
    size_t SZ_ys   = (size_t)MPAD * DIq * 2;
    size_t SZ_sres = SZ_xi2;
    size_t SZ_yem  = (size_t)MPAD * 1024 * 2;
    size_t SZ_pool = (size_t)NB * OUTq * 4;
    size_t SZ_part = (size_t)XP_KS * ROWS * 80 * 4;

    size_t o_am   = 0;
    size_t o_G    = al(o_am + SZ_am);
    size_t o_x    = al(o_G + SZ_G);
    size_t o_xr2  = al(o_x + SZ_x);
    size_t o_xi2  = al(o_xr2 + SZ_xr2);
    size_t o_de   = al(o_xi2 + SZ_xi2);
    size_t o_dbc  = al(o_de + SZ_de);
    size_t o_ys   = al(o_dbc + SZ_dbc);
    size_t o_sres = al(o_ys + SZ_ys);
    size_t o_yem  = al(o_sres + SZ_sres);
    size_t o_pool = al(o_yem + SZ_yem);
    size_t o_part = al(o_pool + SZ_pool);

    size_t o_wpe  = al(o_part + SZ_part);
    size_t o_win0 = al(o_wpe  + (size_t)768 * 768 * 2);
    size_t o_win1 = al(o_win0 + (size_t)3072 * 768 * 2);
    size_t o_wot0 = al(o_win1 + (size_t)3072 * 768 * 2);
    size_t o_wot1 = al(o_wot0 + (size_t)768 * 1536 * 2);
    size_t o_wem  = al(o_wot1 + (size_t)768 * 1536 * 2);
    size_t o_wat  = al(o_wem  + (size_t)1024 * 768 * 2);

    float* am    = (float*)(ws + o_am);
    unsigned short* G   = (unsigned short*)(ws + o_G);
    unsigned short* x   = (unsigned short*)(ws + o_x);
    unsigned short* xr2 = (unsigned short*)(ws + o_xr2);
    float* xi2   = (float*)(ws + o_xi2);
    float* de    = (float*)(ws + o_de);
    float* dbc   = (float*)(ws + o_dbc);
    unsigned short* ys = (unsigned short*)(ws + o_ys);
    float* sres  = (float*)(ws + o_sres);
    unsigned short* yem = (unsigned short*)(ws + o_yem);
    float* pool  = (float*)(ws + o_pool);
    float* part  = (float*)(ws + o_part);
    unsigned short* wpe  = (unsigned short*)(ws + o_wpe);
    unsigned short* win0 = (unsigned short*)(ws + o_win0);
    unsigned short* win1 = (unsigned short*)(ws + o_win1);
    unsigned short* wot0 = (unsigned short*)(ws + o_wot0);
    unsigned short* wot1 = (unsigned short*)(ws + o_wot1);
    unsigned short* wem  = (unsigned short*)(ws + o_wem);
    unsigned short* wat  = (unsigned short*)(ws + o_wat);
    // head-phase overlays (layer buffers dead once layers finish)
    float* t1  = (float*)(ws + o_de);
    float* t2  = (float*)(ws + o_xi2);
    float* gat = (float*)(ws + o_sres);

    // ---- weight conversion (W[K][N] -> bf16 [N][K]) ----
    k_transpose_bf<<<dim3(768 / 32, 768 / 32), 256, 0, stream>>>(pe_w, wpe, 768, 768);
    k_transpose_bf<<<dim3(3072 / 32, 768 / 32), 256, 0, stream>>>(in_w, win0, 768, 3072);
    k_transpose_bf<<<dim3(3072 / 32, 768 / 32), 256, 0, stream>>>(in_w + (size_t)768 * 3072, win1, 768, 3072);
    k_transpose_bf<<<dim3(768 / 32, 1536 / 32), 256, 0, stream>>>(ot_w, wot0, 1536, 768);
    k_transpose_bf<<<dim3(768 / 32, 1536 / 32), 256, 0, stream>>>(ot_w + (size_t)1536 * 768, wot1, 1536, 768);
    k_transpose_bf<<<dim3(1024 / 32, 768 / 32), 256, 0, stream>>>(em_w, wem, 768, 1024);
    k_transpose_bf<<<dim3(1024 / 32, 1024 / 32), 256, 0, stream>>>(at_w, wat, 1024, 1024);

    int nq = NB * IMP / 4;
    k_avgmax<<<(nq + 255) / 256, 256, 0, stream>>>(img, am);
    k_gatepatch<<<(nq + 255) / 256, 256, 0, stream>>>(img, am, sa_w, G);

    dim3 blk(256);
    // patch embed: x(bf16) = G @ pe_w + pe_b + pos
    k_gemm_bf<EPI_POSEMB, true><<<dim3(12, 25), blk, 0, stream>>>(G, wpe, pe_b, x, 768, ROWS, 768, 768,
                                                                  pos, nullptr);

    for (int l = 0; l < 2; l++) {
        const unsigned short* win = l ? win1 : win0;
        const unsigned short* wot = l ? wot1 : wot0;
        // split epilogue: xi half -> bf16 xr2; res half -> silu f32 sres
        k_gemm_bf<EPI_SPLIT, true><<<dim3(48, 25), blk, 0, stream>>>(x, win, in_b + l * 3072, xr2, DIq,
                                                                     ROWS, 3072, 768, nullptr, sres);
        int nc4 = ROWS * DIq / 4;
        k_conv_silu<<<(nc4 + 255) / 256, 256, 0, stream>>>(xr2, cv_w + (size_t)l * DIq * 4, cv_b + l * DIq, xi2);
        k_xproj_part<<<dim3(ROWS / 32, XP_KS), blk, 0, stream>>>(xi2, xp_w + (size_t)l * 1536 * 80, part);
        k_dtred<<<ROWS / DT_RPB, 384, 0, stream>>>(part, dt_w + (size_t)l * 48 * 1536, dt_b + l * 1536, de, dbc);
        k_scan<<<dim3(16, 48), blk, 0, stream>>>(de, xi2, dbc, sres, Alog + (size_t)l * 1536 * 16,
                                                 Dv + l * 1536, ys);
        // x(bf16) = ys @ out_w + out_b
        k_gemm_bf<EPI_NONE, true><<<dim3(12, 25), blk, 0, stream>>>(ys, wot, ot_b + l * 768, x, 768,
                                                                    ROWS, 768, 1536, nullptr, nullptr);
    }

    // head
    k_gemm_bf<EPI_NONE, false><<<dim3(16, 25), blk, 0, stream>>>(x, wem, em_b, t1, 1024, ROWS, 1024, 768,
                                                                 nullptr, nullptr);
    k_ln_gelu<true><<<ROWS, 256, 0, stream>>>(t1, em_g, em_bt, yem);
    k_gemm_bf<EPI_NONE, false><<<dim3(16, 25), blk, 0, stream>>>(yem, wat, at_b, t2, 1024, ROWS, 1024, 1024,
                                                                 nullptr, nullptr);
    k_ln_gelu<false><<<ROWS, 256, 0, stream>>>(t2, at_g, at_bt, gat);
    k_softpool<<<dim3(16, NB), 256, 0, stream>>>(gat, yem, pool);
    k_final_ln<<<NB, 256, 0, stream>>>(pool, la_g, la_bt, (float*)d_out);
}

// Round 10
// 467.117 us; speedup vs baseline: 5.3377x; 1.0783x over previous
//
#include <hip/hip_runtime.h>
#include <math.h>

static constexpr int NB = 16;
static constexpr int NC = 3;
static constexpr int IM = 224;
static constexpr int IMP = IM * IM;      // 50176
static constexpr int HPq = 14;
static constexpr int NPq = 196;
static constexpr int OUTq = 1024;
static constexpr int DIq = 1536;
static constexpr int ROWS = NB * NPq;    // 3136
static constexpr int MPAD = 3200;        // 25*128, GEMM A-operand row padding

typedef __bf16 bf8_t __attribute__((ext_vector_type(8)));
typedef float f4_t __attribute__((ext_vector_type(4)));
typedef unsigned short us8 __attribute__((ext_vector_type(8)));
typedef const __attribute__((address_space(1))) unsigned int cgu32;
typedef __attribute__((address_space(3))) unsigned int lu32;

__device__ inline unsigned short f2bf(float x) {
    unsigned u = __builtin_bit_cast(unsigned, x);
    unsigned r = (u + 0x7FFFu + ((u >> 16) & 1u)) >> 16;
    return (unsigned short)r;
}
__device__ inline float bf2f(unsigned short v) {
    return __builtin_bit_cast(float, (unsigned)v << 16);
}
__device__ inline float fast_sig(float x) {
    return __builtin_amdgcn_rcpf(1.f + __expf(-x));
}

template<int CTRL>
__device__ inline float dpp_add(float x) {
    int v = __builtin_amdgcn_update_dpp(0, __builtin_bit_cast(int, x), CTRL, 0xF, 0xF, true);
    return x + __builtin_bit_cast(float, v);
}

// ---------------- K1a: channel avg/max ----------------
__global__ __launch_bounds__(256) void k_avgmax(const float* __restrict__ img, float* __restrict__ am) {
    int idx = blockIdx.x * 256 + threadIdx.x;
    if (idx >= NB * IMP / 4) return;
    int p4 = (idx % (IMP / 4)) * 4, b = idx / (IMP / 4);
    const float* ib = img + (size_t)b * NC * IMP + p4;
    float4 c0 = *(const float4*)ib;
    float4 c1 = *(const float4*)(ib + IMP);
    float4 c2 = *(const float4*)(ib + 2 * IMP);
    float4 av, mx;
    av.x = (c0.x + c1.x + c2.x) * (1.f / 3.f); mx.x = fmaxf(c0.x, fmaxf(c1.x, c2.x));
    av.y = (c0.y + c1.y + c2.y) * (1.f / 3.f); mx.y = fmaxf(c0.y, fmaxf(c1.y, c2.y));
    av.z = (c0.z + c1.z + c2.z) * (1.f / 3.f); mx.z = fmaxf(c0.z, fmaxf(c1.z, c2.z));
    av.w = (c0.w + c1.w + c2.w) * (1.f / 3.f); mx.w = fmaxf(c0.w, fmaxf(c1.w, c2.w));
    *(float4*)(am + (size_t)(b * 2 + 0) * IMP + p4) = av;
    *(float4*)(am + (size_t)(b * 2 + 1) * IMP + p4) = mx;
}

// ---------------- K1b: 7x7 conv gate + patchify ----------------
__global__ __launch_bounds__(256) void k_gatepatch(const float* __restrict__ img, const float* __restrict__ am,
                                                   const float* __restrict__ saw, unsigned short* __restrict__ G) {
    int quad = blockIdx.x * 256 + threadIdx.x;
    if (quad >= NB * IMP / 4) return;
    int pq = quad % (IMP / 4), b = quad / (IMP / 4);
    int x0 = (pq % 56) * 4;
    int y = pq / 56;
    float acc0 = 0.f, acc1 = 0.f, acc2 = 0.f, acc3 = 0.f;
    const bool lok = (x0 >= 4), rok = (x0 <= IM - 8);
    #pragma unroll
    for (int ci = 0; ci < 2; ci++) {
        const float* amc = am + (size_t)(b * 2 + ci) * IMP;
        const float* wc = saw + ci * 49;
        #pragma unroll
        for (int kh = 0; kh < 7; kh++) {
            int yy = y + kh - 3;
            if (yy < 0 || yy >= IM) continue;
            const float* rowp = amc + yy * IM;
            float4 lv = lok ? *(const float4*)(rowp + x0 - 4) : make_float4(0.f, 0.f, 0.f, 0.f);
            float4 mv = *(const float4*)(rowp + x0);
            float4 rv = rok ? *(const float4*)(rowp + x0 + 4) : make_float4(0.f, 0.f, 0.f, 0.f);
            float f[12] = {lv.x, lv.y, lv.z, lv.w, mv.x, mv.y, mv.z, mv.w, rv.x, rv.y, rv.z, rv.w};
            #pragma unroll
            for (int kw = 0; kw < 7; kw++) {
                float w = wc[kh * 7 + kw];
                acc0 = fmaf(w, f[kw + 1], acc0);
                acc1 = fmaf(w, f[kw + 2], acc1);
                acc2 = fmaf(w, f[kw + 3], acc2);
                acc3 = fmaf(w, f[kw + 4], acc3);
            }
        }
    }
    float s0 = fast_sig(acc0), s1 = fast_sig(acc1), s2 = fast_sig(acc2), s3 = fast_sig(acc3);
    const float* ib = img + (size_t)b * NC * IMP + y * IM + x0;
    float4 c0 = *(const float4*)ib;
    float4 c1 = *(const float4*)(ib + IMP);
    float4 c2 = *(const float4*)(ib + 2 * IMP);
    int hy = y >> 4, py = y & 15, hx = x0 >> 4, px0 = x0 & 15;
    size_t base = ((size_t)(b * NPq + hy * HPq + hx) * 768) + (size_t)(py * 16 + px0) * 3;
    ushort4 o0, o1, o2;
    o0.x = f2bf(c0.x * s0); o0.y = f2bf(c1.x * s0); o0.z = f2bf(c2.x * s0);
    o0.w = f2bf(c0.y * s1);
    o1.x = f2bf(c1.y * s1); o1.y = f2bf(c2.y * s1);
    o1.z = f2bf(c0.z * s2); o1.w = f2bf(c1.z * s2);
    o2.x = f2bf(c2.z * s2);
    o2.y = f2bf(c0.w * s3); o2.z = f2bf(c1.w * s3); o2.w = f2bf(c2.w * s3);
    *(ushort4*)(G + base + 0) = o0;
    *(ushort4*)(G + base + 4) = o1;
    *(ushort4*)(G + base + 8) = o2;
}

// ---------------- all weight transposes in ONE launch ----------------
// tile ranges (cumulative): pe 576 | in0 2880 | in1 5184 | ot0 6336 | ot1 7488 | em 8256 | at 9280
__global__ __launch_bounds__(256) void k_transpose_all(const float* pe_w, const float* in_w, const float* ot_w,
                                                       const float* em_w, const float* at_w,
                                                       unsigned short* wpe, unsigned short* win0, unsigned short* win1,
                                                       unsigned short* wot0, unsigned short* wot1,
                                                       unsigned short* wem, unsigned short* wat) {
    int bid = blockIdx.x;
    const float* W; unsigned short* Wt; int K, N, local;
    if (bid < 576)       { W = pe_w; Wt = wpe; K = 768; N = 768; local = bid; }
    else if (bid < 2880) { W = in_w; Wt = win0; K = 768; N = 3072; local = bid - 576; }
    else if (bid < 5184) { W = in_w + (size_t)768 * 3072; Wt = win1; K = 768; N = 3072; local = bid - 2880; }
    else if (bid < 6336) { W = ot_w; Wt = wot0; K = 1536; N = 768; local = bid - 5184; }
    else if (bid < 7488) { W = ot_w + (size_t)1536 * 768; Wt = wot1; K = 1536; N = 768; local = bid - 6336; }
    else if (bid < 8256) { W = em_w; Wt = wem; K = 768; N = 1024; local = bid - 7488; }
    else                 { W = at_w; Wt = wat; K = 1024; N = 1024; local = bid - 8256; }
    int gx = N / 32;
    int n0 = (local % gx) * 32, k0 = (local / gx) * 32;
    __shared__ float t[32][33];
    int c = threadIdx.x & 31, r8 = threadIdx.x >> 5;
    #pragma unroll
    for (int i = 0; i < 4; i++) {
        int r = r8 + i * 8;
        t[r][c] = W[(size_t)(k0 + r) * N + n0 + c];
    }
    __syncthreads();
    #pragma unroll
    for (int i = 0; i < 4; i++) {
        int r = r8 + i * 8;
        Wt[(size_t)(n0 + r) * K + k0 + c] = f2bf(t[c][r]);
    }
}

// ---------------- bf16 MFMA GEMM, BN=64 double-buffered (general shapes) ----------------
enum { EPI_NONE = 0, EPI_POSEMB = 1 };

template<int EPI, bool CBF>
__global__ __launch_bounds__(256) void k_gemm_bf(const unsigned short* __restrict__ A,
                                                 const unsigned short* __restrict__ Wt,
                                                 const float* __restrict__ bias,
                                                 void* __restrict__ Cv, int ldc,
                                                 int M, int N, int K,
                                                 const float* __restrict__ extra) {
    constexpr int BM = 128, BN = 64;
    __shared__ __align__(16) unsigned short As[2][BM * 64];
    __shared__ __align__(16) unsigned short Bs[2][BN * 64];
    const int bm = blockIdx.y * BM, bn = blockIdx.x * BN;
    const int tid = threadIdx.x;
    const int lane = tid & 63;
    const int wbase = tid & ~63;
    const int wr = ((tid >> 7) & 1) * 64;
    const int wc = ((tid >> 6) & 1) * 32;
    const int lr = lane & 15, lq = lane >> 4;

    f4_t acc[4][2] = {};

    auto stage = [&](int buf, int k0) {
        #pragma unroll
        for (int i = 0; i < 4; i++) {
            int gid2 = i * 256 + tid;
            int r = gid2 >> 3, g = gid2 & 7;
            const unsigned short* src = A + (size_t)(bm + r) * K + k0 + ((g ^ (r & 7)) * 8);
            __builtin_amdgcn_global_load_lds((cgu32*)src,
                (lu32*)&As[buf][(i * 256 + wbase) * 8], 16, 0, 0);
        }
        #pragma unroll
        for (int i = 0; i < 2; i++) {
            int gid2 = i * 256 + tid;
            int r = gid2 >> 3, g = gid2 & 7;
            const unsigned short* src = Wt + (size_t)(bn + r) * K + k0 + ((g ^ (r & 7)) * 8);
            __builtin_amdgcn_global_load_lds((cgu32*)src,
                (lu32*)&Bs[buf][(i * 256 + wbase) * 8], 16, 0, 0);
        }
    };

    stage(0, 0);
    __syncthreads();
    int cur = 0;
    for (int k0 = 0; k0 < K; k0 += 64) {
        if (k0 + 64 < K) stage(cur ^ 1, k0 + 64);
        #pragma unroll
        for (int h = 0; h < 2; h++) {
            bf8_t af[4], bfr[2];
            #pragma unroll
            for (int mb = 0; mb < 4; mb++) {
                int row = wr + mb * 16 + lr;
                int g = h * 4 + lq;
                af[mb] = *(const bf8_t*)&As[cur][row * 64 + ((g ^ (row & 7)) * 8)];
            }
            #pragma unroll
            for (int nb = 0; nb < 2; nb++) {
                int rn = wc + nb * 16 + lr;
                int g = h * 4 + lq;
                bfr[nb] = *(const bf8_t*)&Bs[cur][rn * 64 + ((g ^ (rn & 7)) * 8)];
            }
            #pragma unroll
            for (int mb = 0; mb < 4; mb++)
                #pragma unroll
                for (int nb = 0; nb < 2; nb++)
                    acc[mb][nb] = __builtin_amdgcn_mfma_f32_16x16x32_bf16(af[mb], bfr[nb], acc[mb][nb], 0, 0, 0);
        }
        __syncthreads();
        cur ^= 1;
    }

    #pragma unroll
    for (int mb = 0; mb < 4; mb++) {
        #pragma unroll
        for (int nb = 0; nb < 2; nb++) {
            int col = bn + wc + nb * 16 + lr;
            #pragma unroll
            for (int q = 0; q < 4; q++) {
                int row = bm + wr + mb * 16 + lq * 4 + q;
                if (row < M) {
                    float v = acc[mb][nb][q];
                    if (bias) v += bias[col];
                    if (EPI == EPI_POSEMB) v += extra[(size_t)(row % NPq) * N + col];
                    if (CBF) ((unsigned short*)Cv)[(size_t)row * ldc + col] = f2bf(v);
                    else     ((float*)Cv)[(size_t)row * ldc + col] = v;
                }
            }
        }
    }
}

// ---------------- 128x128 single-buffer GEMM (m97 structure), split epilogue ----------------
// xi half (col<1536) -> bf16 xr2; res half -> bf16 sres = silu(res)
__global__ __launch_bounds__(256) void k_gemm_bf2(const unsigned short* __restrict__ A,
                                                  const unsigned short* __restrict__ Wt,
                                                  const float* __restrict__ bias,
                                                  unsigned short* __restrict__ xr2,
                                                  unsigned short* __restrict__ sres,
                                                  int M, int K) {
    constexpr int BM = 128;
    __shared__ __align__(16) unsigned short As[BM * 64];
    __shared__ __align__(16) unsigned short Bs[BM * 64];
    const int bm = blockIdx.y * BM, bn = blockIdx.x * BM;
    const int tid = threadIdx.x;
    const int lane = tid & 63;
    const int wbase = tid & ~63;
    const int wid = tid >> 6;
    const int wr = (wid >> 1) * 64;
    const int wc = (wid & 1) * 64;
    const int lr = lane & 15, lq = lane >> 4;

    f4_t acc[4][4] = {};

    for (int k0 = 0; k0 < K; k0 += 64) {
        #pragma unroll
        for (int i = 0; i < 4; i++) {
            int gid2 = i * 256 + tid;
            int r = gid2 >> 3, g = gid2 & 7;
            const unsigned short* srcA = A + (size_t)(bm + r) * K + k0 + ((g ^ (r & 7)) * 8);
            __builtin_amdgcn_global_load_lds((cgu32*)srcA,
                (lu32*)&As[(i * 256 + wbase) * 8], 16, 0, 0);
            const unsigned short* srcB = Wt + (size_t)(bn + r) * K + k0 + ((g ^ (r & 7)) * 8);
            __builtin_amdgcn_global_load_lds((cgu32*)srcB,
                (lu32*)&Bs[(i * 256 + wbase) * 8], 16, 0, 0);
        }
        __syncthreads();
        #pragma unroll
        for (int h = 0; h < 2; h++) {
            bf8_t af[4], bfr[4];
            #pragma unroll
            for (int mb = 0; mb < 4; mb++) {
                int row = wr + mb * 16 + lr;
                int g = h * 4 + lq;
                af[mb] = *(const bf8_t*)&As[row * 64 + ((g ^ (row & 7)) * 8)];
            }
            #pragma unroll
            for (int nb = 0; nb < 4; nb++) {
                int rn = wc + nb * 16 + lr;
                int g = h * 4 + lq;
                bfr[nb] = *(const bf8_t*)&Bs[rn * 64 + ((g ^ (rn & 7)) * 8)];
            }
            #pragma unroll
            for (int mb = 0; mb < 4; mb++)
                #pragma unroll
                for (int nb = 0; nb < 4; nb++)
                    acc[mb][nb] = __builtin_amdgcn_mfma_f32_16x16x32_bf16(af[mb], bfr[nb], acc[mb][nb], 0, 0, 0);
        }
        __syncthreads();
    }

    #pragma unroll
    for (int mb = 0; mb < 4; mb++) {
        #pragma unroll
        for (int nb = 0; nb < 4; nb++) {
            int col = bn + wc + nb * 16 + lr;
            float bv = bias[col];
            #pragma unroll
            for (int q = 0; q < 4; q++) {
                int row = bm + wr + mb * 16 + lq * 4 + q;
                if (row < M) {
                    float v = acc[mb][nb][q] + bv;
                    if (col < DIq) xr2[(size_t)row * DIq + col] = f2bf(v);
                    else           sres[(size_t)row * DIq + (col - DIq)] = f2bf(v * fast_sig(v));
                }
            }
        }
    }
}

// ---------------- xproj split-K f32 GEMM (bf16 xi input) ----------------
static constexpr int XP_KS = 4;
static constexpr int XP_KC = 1536 / XP_KS;   // 384

__global__ __launch_bounds__(256) void k_xproj_part(const unsigned short* __restrict__ xi2b,
                                                    const float* __restrict__ W,
                                                    float* __restrict__ part) {
    __shared__ float As[32][65];
    __shared__ __align__(16) float Bs[64][80];
    int m0 = blockIdx.x * 32;
    int kc0 = blockIdx.y * XP_KC;
    int tid = threadIdx.x;
    int row = tid >> 3, cg = (tid & 7) * 10;
    float acc[10] = {};
    for (int k0 = 0; k0 < XP_KC; k0 += 64) {
        {
            int r = tid >> 3, c8 = (tid & 7) * 8;
            us8 v = *(const us8*)(xi2b + (size_t)(m0 + r) * 1536 + kc0 + k0 + c8);
            #pragma unroll
            for (int j = 0; j < 8; j++) As[r][c8 + j] = bf2f(v[j]);
        }
        #pragma unroll
        for (int i = 0; i < 5; i++) {
            int id = tid + i * 256;
            int r = id / 20, c4 = (id % 20) * 4;
            *(float4*)&Bs[r][c4] = *(const float4*)(W + (size_t)(kc0 + k0 + r) * 80 + c4);
        }
        __syncthreads();
        #pragma unroll
        for (int kk = 0; kk < 64; kk++) {
            float a = As[row][kk];
            #pragma unroll
            for (int j = 0; j < 10; j++)
                acc[j] = fmaf(a, Bs[kk][cg + j], acc[j]);
        }
        __syncthreads();
    }
    float* p = part + ((size_t)blockIdx.y * ROWS + m0 + row) * 80 + cg;
    #pragma unroll
    for (int j = 0; j < 10; j++) p[j] = acc[j];
}

// ---------------- merged xreduce + dt GEMM + softplus ----------------
static constexpr int DT_RPB = 4;
__global__ __launch_bounds__(384) void k_dtred(const float* __restrict__ part, const float* __restrict__ W,
                                               const float* __restrict__ bias, float* __restrict__ de,
                                               float* __restrict__ dbc) {
    int r0 = blockIdx.x * DT_RPB;
    int tid = threadIdx.x;
    __shared__ float ds[DT_RPB][80];
    if (tid < DT_RPB * 80) {
        int row = tid / 80, col = tid % 80;
        const int S = ROWS * 80;
        const float* p = part + (size_t)(r0 + row) * 80 + col;
        float s = p[0] + p[S] + p[2 * S] + p[3 * S];
        ds[row][col] = s;
        if (col >= 48) dbc[(size_t)(r0 + row) * 80 + col] = s;
    }
    __syncthreads();
    int j = tid * 4;
    float4 b = *(const float4*)(bias + j);
    float4 a0 = b, a1 = b, a2 = b, a3 = b;
    for (int k = 0; k < 48; k++) {
        float4 w = *(const float4*)(W + (size_t)k * 1536 + j);
        float d0 = ds[0][k], d1 = ds[1][k], d2 = ds[2][k], d3 = ds[3][k];
        a0.x = fmaf(d0, w.x, a0.x); a0.y = fmaf(d0, w.y, a0.y); a0.z = fmaf(d0, w.z, a0.z); a0.w = fmaf(d0, w.w, a0.w);
        a1.x = fmaf(d1, w.x, a1.x); a1.y = fmaf(d1, w.y, a1.y); a1.z = fmaf(d1, w.z, a1.z); a1.w = fmaf(d1, w.w, a1.w);
        a2.x = fmaf(d2, w.x, a2.x); a2.y = fmaf(d2, w.y, a2.y); a2.z = fmaf(d2, w.z, a2.z); a2.w = fmaf(d2, w.w, a2.w);
        a3.x = fmaf(d3, w.x, a3.x); a3.y = fmaf(d3, w.y, a3.y); a3.z = fmaf(d3, w.z, a3.z); a3.w = fmaf(d3, w.w, a3.w);
    }
    auto sp = [](float v) { return (v > 20.f) ? v : log1pf(expf(v)); };
    float4 o;
    o.x = sp(a0.x); o.y = sp(a0.y); o.z = sp(a0.z); o.w = sp(a0.w);
    *(float4*)(de + (size_t)(r0 + 0) * 1536 + j) = o;
    o.x = sp(a1.x); o.y = sp(a1.y); o.z = sp(a1.z); o.w = sp(a1.w);
    *(float4*)(de + (size_t)(r0 + 1) * 1536 + j) = o;
    o.x = sp(a2.x); o.y = sp(a2.y); o.z = sp(a2.z); o.w = sp(a2.w);
    *(float4*)(de + (size_t)(r0 + 2) * 1536 + j) = o;
    o.x = sp(a3.x); o.y = sp(a3.y); o.z = sp(a3.z); o.w = sp(a3.w);
    *(float4*)(de + (size_t)(r0 + 3) * 1536 + j) = o;
}

// ---------------- causal depthwise conv (DC=4) + silu, bf16 in/out ----------------
__global__ __launch_bounds__(256) void k_conv_silu(const unsigned short* __restrict__ xr2, const float* __restrict__ cw,
                                                   const float* __restrict__ cb, unsigned short* __restrict__ xi2b) {
    int idx4 = blockIdx.x * 256 + threadIdx.x;
    if (idx4 >= ROWS * DIq / 4) return;
    int d4 = (idx4 % (DIq / 4)) * 4;
    int bt = idx4 / (DIq / 4);
    int t = bt % NPq, b = bt / NPq;
    const unsigned short* base = xr2 + (size_t)b * NPq * DIq + d4;
    float4 s = *(const float4*)(cb + d4);
    float4 w0 = *(const float4*)(cw + (d4 + 0) * 4);
    float4 w1 = *(const float4*)(cw + (d4 + 1) * 4);
    float4 w2 = *(const float4*)(cw + (d4 + 2) * 4);
    float4 w3 = *(const float4*)(cw + (d4 + 3) * 4);
    if (t >= 3) {
        ushort4 v = *(const ushort4*)(base + (size_t)(t - 3) * DIq);
        s.x = fmaf(bf2f(v.x), w0.x, s.x); s.y = fmaf(bf2f(v.y), w1.x, s.y);
        s.z = fmaf(bf2f(v.z), w2.x, s.z); s.w = fmaf(bf2f(v.w), w3.x, s.w);
    }
    if (t >= 2) {
        ushort4 v = *(const ushort4*)(base + (size_t)(t - 2) * DIq);
        s.x = fmaf(bf2f(v.x), w0.y, s.x); s.y = fmaf(bf2f(v.y), w1.y, s.y);
        s.z = fmaf(bf2f(v.z), w2.y, s.z); s.w = fmaf(bf2f(v.w), w3.y, s.w);
    }
    if (t >= 1) {
        ushort4 v = *(const ushort4*)(base + (size_t)(t - 1) * DIq);
        s.x = fmaf(bf2f(v.x), w0.z, s.x); s.y = fmaf(bf2f(v.y), w1.z, s.y);
        s.z = fmaf(bf2f(v.z), w2.z, s.z); s.w = fmaf(bf2f(v.w), w3.z, s.w);
    }
    {
        ushort4 v = *(const ushort4*)(base + (size_t)t * DIq);
        s.x = fmaf(bf2f(v.x), w0.w, s.x); s.y = fmaf(bf2f(v.y), w1.w, s.y);
        s.z = fmaf(bf2f(v.z), w2.w, s.z); s.w = fmaf(bf2f(v.w), w3.w, s.w);
    }
    ushort4 xo;
    xo.x = f2bf(s.x * fast_sig(s.x)); xo.y = f2bf(s.y * fast_sig(s.y));
    xo.z = f2bf(s.z * fast_sig(s.z)); xo.w = f2bf(s.w * fast_sig(s.w));
    *(ushort4*)(xi2b + (size_t)bt * DIq + d4) = xo;
}

// ---------------- selective-scan, LDS double-buffered, packed b64 sdu ----------------
static constexpr int STB = 28;

__global__ __launch_bounds__(256) void k_scan(const float* __restrict__ delta, const unsigned short* __restrict__ xi2b,
                                              const float* __restrict__ dbc, const unsigned short* __restrict__ sresb,
                                              const float* __restrict__ Alog, const float* __restrict__ Dv,
                                              unsigned short* __restrict__ ys) {
    const int b = blockIdx.x;
    const int d0 = blockIdx.y * 32;
    const int tid = threadIdx.x;
    const int dl = tid >> 3;
    const int np = tid & 7;
    const int d = d0 + dl;
    const float A0 = -__expf(Alog[d * 16 + np]);
    const float A1 = -__expf(Alog[d * 16 + np + 8]);
    const float Dd = Dv[d];
    const int tr = tid >> 5;
    const int dls = tid & 31;

    __shared__ float2 sdu[2][STB][32];   // {de, pack(u,sr)} per d
    __shared__ float sbc[2][STB][32];    // [np*4 + {B0,B1,C0,C1}]

    const float* gde = delta + ((size_t)b * NPq + tr) * DIq + d0 + dls;
    const unsigned short* gu  = xi2b  + ((size_t)b * NPq + tr) * DIq + d0 + dls;
    const unsigned short* gsr = sresb + ((size_t)b * NPq + tr) * DIq + d0 + dls;
    const float* gbc = dbc + ((size_t)b * NPq + tr) * 80 + 48 + dls;
    unsigned short* gy = ys + (size_t)b * NPq * DIq + d;

    float rde[4], rbc[4];
    unsigned short ruu[4], rss[4];

    auto stageLoad = [&](int c) {
        const int t0 = c * STB;
        #pragma unroll
        for (int j = 0; j < 3; j++) {
            int off = (t0 + 8 * j) * DIq;
            rde[j] = gde[off];
            ruu[j] = gu[off];
            rss[j] = gsr[off];
            rbc[j] = gbc[(t0 + 8 * j) * 80];
        }
        if (tid < 128) {
            int off = (t0 + 24) * DIq;
            rde[3] = gde[off];
            ruu[3] = gu[off];
            rss[3] = gsr[off];
            rbc[3] = gbc[(t0 + 24) * 80];
        }
    };
    auto stageWrite = [&](int buf) {
        const int pi = (dls & 7) * 4 + (dls >> 3);
        #pragma unroll
        for (int j = 0; j < 3; j++) {
            int t = tr + 8 * j;
            unsigned pk = ((unsigned)ruu[j] << 16) | rss[j];
            sdu[buf][t][dls] = make_float2(rde[j], __builtin_bit_cast(float, pk));
            sbc[buf][t][pi] = rbc[j];
        }
        if (tid < 128) {
            int t = tr + 24;
            unsigned pk = ((unsigned)ruu[3] << 16) | rss[3];
            sdu[buf][t][dls] = make_float2(rde[3], __builtin_bit_cast(float, pk));
            sbc[buf][t][pi] = rbc[3];
        }
    };

    stageLoad(0);
    stageWrite(0);
    __syncthreads();

    float h0 = 0.f, h1 = 0.f;
    int cur = 0;
    for (int c = 0; c < 7; c++) {
        if (c < 6) stageLoad(c + 1);
        #pragma unroll 4
        for (int t = 0; t < STB; t++) {
            float2 duv = sdu[cur][t][dl];
            float4 bc = *(const float4*)&sbc[cur][t][np * 4];
            unsigned bits = __builtin_bit_cast(unsigned, duv.y);
            float u  = __builtin_bit_cast(float, bits & 0xFFFF0000u);
            float sr = __builtin_bit_cast(float, bits << 16);
            float a0 = __expf(duv.x * A0), a1 = __expf(duv.x * A1);
            float deu = duv.x * u;
            h0 = fmaf(a0, h0, deu * bc.x);
            h1 = fmaf(a1, h1, deu * bc.y);
            float p = fmaf(h1, bc.w, h0 * bc.z);
            p = dpp_add<0xB1>(p);    // += lane^1
            p = dpp_add<0x4E>(p);    // += lane^2
            p = dpp_add<0x141>(p);   // += other quad
            if (np == 0) gy[(size_t)(c * STB + t) * DIq] = f2bf(fmaf(Dd, u, p) * sr);
        }
        if (c < 6) stageWrite(cur ^ 1);
        __syncthreads();
        cur ^= 1;
    }
}

// ---------------- row LayerNorm (1024) + exact gelu; out f32 or bf16 ----------------
template<bool OBF>
__global__ __launch_bounds__(256) void k_ln_gelu(const float* __restrict__ in, const float* __restrict__ g,
                                                 const float* __restrict__ bt, void* __restrict__ outv) {
    int row = blockIdx.x;
    const float* x = in + (size_t)row * OUTq;
    float4 v = ((const float4*)x)[threadIdx.x];
    float s = v.x + v.y + v.z + v.w;
    float ss = v.x * v.x + v.y * v.y + v.z * v.z + v.w * v.w;
    #pragma unroll
    for (int off = 32; off >= 1; off >>= 1) { s += __shfl_down(s, off); ss += __shfl_down(ss, off); }
    __shared__ float sh[10];
    int wid = threadIdx.x >> 6, lid = threadIdx.x & 63;
    if (lid == 0) { sh[wid] = s; sh[4 + wid] = ss; }
    __syncthreads();
    if (threadIdx.x == 0) {
        float S = sh[0] + sh[1] + sh[2] + sh[3], SS = sh[4] + sh[5] + sh[6] + sh[7];
        float m = S * (1.f / OUTq);
        float var = SS * (1.f / OUTq) - m * m;
        sh[8] = m; sh[9] = rsqrtf(var + 1e-5f);
    }
    __syncthreads();
    float m = sh[8], rst = sh[9];
    float4 gv = ((const float4*)g)[threadIdx.x];
    float4 bv = ((const float4*)bt)[threadIdx.x];
    float4 o;
    float y0 = (v.x - m) * rst * gv.x + bv.x; o.x = 0.5f * y0 * (1.f + erff(y0 * 0.70710678118f));
    float y1 = (v.y - m) * rst * gv.y + bv.y; o.y = 0.5f * y1 * (1.f + erff(y1 * 0.70710678118f));
    float y2 = (v.z - m) * rst * gv.z + bv.z; o.z = 0.5f * y2 * (1.f + erff(y2 * 0.70710678118f));
    float y3 = (v.w - m) * rst * gv.w + bv.w; o.w = 0.5f * y3 * (1.f + erff(y3 * 0.70710678118f));
    if (OBF) {
        ushort4 o4;
        o4.x = f2bf(o.x); o4.y = f2bf(o.y); o4.z = f2bf(o.z); o4.w = f2bf(o.w);
        ((ushort4*)((unsigned short*)outv + (size_t)row * OUTq))[threadIdx.x] = o4;
    } else {
        ((float4*)((float*)outv + (size_t)row * OUTq))[threadIdx.x] = o;
    }
}

// ---------------- column softmax + pool, 4-way t-split ----------------
__global__ __launch_bounds__(256) void k_softpool(const float* __restrict__ gm, const unsigned short* __restrict__ ym,
                                                  float* __restrict__ pooled) {
    int b = blockIdx.y;
    int jl = threadIdx.x & 63;
    int j = blockIdx.x * 64 + jl;
    int tc = threadIdx.x >> 6;
    const float* gb = gm + (size_t)b * NPq * OUTq + j;
    const unsigned short* yb = ym + (size_t)b * NPq * OUTq + j;
    int t0 = tc * 49;
    float m = -1e30f, s = 0.f, ps = 0.f;
    for (int t = t0; t < t0 + 49; t++) {
        float g = gb[(size_t)t * OUTq];
        float y = bf2f(yb[(size_t)t * OUTq]);
        float mn = fmaxf(m, g);
        float sc = __expf(m - mn);
        float e = __expf(g - mn);
        s = fmaf(s, sc, e);
        ps = fmaf(ps, sc, y * e);
        m = mn;
    }
    __shared__ float sm[4][64], ssum[4][64], sps[4][64];
    sm[tc][jl] = m; ssum[tc][jl] = s; sps[tc][jl] = ps;
    __syncthreads();
    if (tc == 0) {
        float m0 = sm[0][jl], m1 = sm[1][jl], m2 = sm[2][jl], m3 = sm[3][jl];
        float mt = fmaxf(fmaxf(m0, m1), fmaxf(m2, m3));
        float e0 = __expf(m0 - mt), e1 = __expf(m1 - mt);
        float e2 = __expf(m2 - mt), e3 = __expf(m3 - mt);
        float st = ssum[0][jl] * e0 + ssum[1][jl] * e1 + ssum[2][jl] * e2 + ssum[3][jl] * e3;
        float pt = sps[0][jl] * e0 + sps[1][jl] * e1 + sps[2][jl] * e2 + sps[3][jl] * e3;
        pooled[b * OUTq + j] = pt / st;
    }
}

// ---------------- final LayerNorm ----------------
__global__ __launch_bounds__(256) void k_final_ln(const float* __restrict__ p, const float* __restrict__ g,
                                                  const float* __restrict__ bt, float* __restrict__ out) {
    int row = blockIdx.x;
    const float* x = p + (size_t)row * OUTq;
    float4 v = ((const float4*)x)[threadIdx.x];
    float s = v.x + v.y + v.z + v.w;
    float ss = v.x * v.x + v.y * v.y + v.z * v.z + v.w * v.w;
    #pragma unroll
    for (int off = 32; off >= 1; off >>= 1) { s += __shfl_down(s, off); ss += __shfl_down(ss, off); }
    __shared__ float sh[10];
    int wid = threadIdx.x >> 6, lid = threadIdx.x & 63;
    if (lid == 0) { sh[wid] = s; sh[4 + wid] = ss; }
    __syncthreads();
    if (threadIdx.x == 0) {
        float S = sh[0] + sh[1] + sh[2] + sh[3], SS = sh[4] + sh[5] + sh[6] + sh[7];
        float m = S * (1.f / OUTq);
        float var = SS * (1.f / OUTq) - m * m;
        sh[8] = m; sh[9] = rsqrtf(var + 1e-5f);
    }
    __syncthreads();
    float m = sh[8], rst = sh[9];
    float4 gv = ((const float4*)g)[threadIdx.x];
    float4 bv = ((const float4*)bt)[threadIdx.x];
    float4 o;
    o.x = (v.x - m) * rst * gv.x + bv.x;
    o.y = (v.y - m) * rst * gv.y + bv.y;
    o.z = (v.z - m) * rst * gv.z + bv.z;
    o.w = (v.w - m) * rst * gv.w + bv.w;
    ((float4*)(out + (size_t)row * OUTq))[threadIdx.x] = o;
}

extern "C" void kernel_launch(void* const* d_in, const int* in_sizes, int n_in,
                              void* d_out, int out_size, void* d_ws, size_t ws_size,
                              hipStream_t stream) {
    const float* img   = (const float*)d_in[0];
    const float* sa_w  = (const float*)d_in[1];
    const float* pe_w  = (const float*)d_in[2];
    const float* pe_b  = (const float*)d_in[3];
    const float* pos   = (const float*)d_in[4];
    const float* in_w  = (const float*)d_in[5];
    const float* in_b  = (const float*)d_in[6];
    const float* cv_w  = (const float*)d_in[7];
    const float* cv_b  = (const float*)d_in[8];
    const float* xp_w  = (const float*)d_in[9];
    const float* dt_w  = (const float*)d_in[10];
    const float* dt_b  = (const float*)d_in[11];
    const float* Alog  = (const float*)d_in[12];
    const float* Dv    = (const float*)d_in[13];
    const float* ot_w  = (const float*)d_in[14];
    const float* ot_b  = (const float*)d_in[15];
    const float* em_w  = (const float*)d_in[16];
    const float* em_b  = (const float*)d_in[17];
    const float* em_g  = (const float*)d_in[18];
    const float* em_bt = (const float*)d_in[19];
    const float* at_w  = (const float*)d_in[20];
    const float* at_b  = (const float*)d_in[21];
    const float* at_g  = (const float*)d_in[22];
    const float* at_bt = (const float*)d_in[23];
    const float* la_g  = (const float*)d_in[24];
    const float* la_bt = (const float*)d_in[25];

    char* ws = (char*)d_ws;
    auto al = [](size_t x) { return (x + 255) & ~(size_t)255; };
    size_t SZ_am   = (size_t)NB * 2 * IMP * 4;        // 6.4 MB
    size_t SZ_G    = (size_t)MPAD * 768 * 2;
    size_t SZ_x    = (size_t)MPAD * 768 * 2;
    size_t SZ_xr2  = (size_t)ROWS * DIq * 2;          // bf16
    size_t SZ_xi2  = (size_t)ROWS * DIq * 2;          // bf16 now
    size_t SZ_de   = (size_t)ROWS * DIq * 4;          // f32
    size_t SZ_dbc  = (size_t)ROWS * 80 * 4;
    size_t SZ_ys   = (size_t)MPAD * DIq * 2;
    size_t SZ_sres = (size_t)ROWS * DIq * 2;          // bf16 now
    size_t SZ_yem  = (size_t)MPAD * 1024 * 2;
    size_t SZ_pool = (size_t)NB * OUTq * 4;
    size_t SZ_part = (size_t)XP_KS * ROWS * 80 * 4;

    size_t o_am   = 0;
    size_t o_G    = al(o_am + SZ_am);
    size_t o_x    = al(o_G + SZ_G);
    size_t o_xr2  = al(o_x + SZ_x);
    size_t o_xi2  = al(o_xr2 + SZ_xr2);
    size_t o_de   = al(o_xi2 + SZ_xi2);
    size_t o_dbc  = al(o_de + SZ_de);
    size_t o_ys   = al(o_dbc + SZ_dbc);
    size_t o_sres = al(o_ys + SZ_ys);
    size_t o_yem  = al(o_sres + SZ_sres);
    size_t o_pool = al(o_yem + SZ_yem);
    size_t o_part = al(o_pool + SZ_pool);

    size_t o_wpe  = al(o_part + SZ_part);
    size_t o_win0 = al(o_wpe  + (size_t)768 * 768 * 2);
    size_t o_win1 = al(o_win0 + (size_t)3072 * 768 * 2);
    size_t o_wot0 = al(o_win1 + (size_t)3072 * 768 * 2);
    size_t o_wot1 = al(o_wot0 + (size_t)768 * 1536 * 2);
    size_t o_wem  = al(o_wot1 + (size_t)768 * 1536 * 2);
    size_t o_wat  = al(o_wem  + (size_t)1024 * 768 * 2);

    float* am    = (float*)(ws + o_am);
    unsigned short* G   = (unsigned short*)(ws + o_G);
    unsigned short* x   = (unsigned short*)(ws + o_x);
    unsigned short* xr2 = (unsigned short*)(ws + o_xr2);
    unsigned short* xi2b = (unsigned short*)(ws + o_xi2);
    float* de    = (float*)(ws + o_de);
    float* dbc   = (float*)(ws + o_dbc);
    unsigned short* ys = (unsigned short*)(ws + o_ys);
    unsigned short* sresb = (unsigned short*)(ws + o_sres);
    unsigned short* yem = (unsigned short*)(ws + o_yem);
    float* pool  = (float*)(ws + o_pool);
    float* part  = (float*)(ws + o_part);
    unsigned short* wpe  = (unsigned short*)(ws + o_wpe);
    unsigned short* win0 = (unsigned short*)(ws + o_win0);
    unsigned short* win1 = (unsigned short*)(ws + o_win1);
    unsigned short* wot0 = (unsigned short*)(ws + o_wot0);
    unsigned short* wot1 = (unsigned short*)(ws + o_wot1);
    unsigned short* wem  = (unsigned short*)(ws + o_wem);
    unsigned short* wat  = (unsigned short*)(ws + o_wat);
    // head-phase overlays (layer buffers dead):
    // t1 (12.8MB f32) over de (19.3MB); t2 over xr2+xi2 (19.2MB); gat over ys+sres (19.4MB)
    float* t1  = (float*)(ws + o_de);
    float* t2  = (float*)(ws + o_xr2);
    float* gat = (float*)(ws + o_ys);

    k_transpose_all<<<9280, 256, 0, stream>>>(pe_w, in_w, ot_w, em_w, at_w,
                                              wpe, win0, win1, wot0, wot1, wem, wat);

    int nq = NB * IMP / 4;
    k_avgmax<<<(nq + 255) / 256, 256, 0, stream>>>(img, am);
    k_gatepatch<<<(nq + 255) / 256, 256, 0, stream>>>(img, am, sa_w, G);

    dim3 blk(256);
    // patch embed: x(bf16) = G @ pe_w + pe_b + pos
    k_gemm_bf<EPI_POSEMB, true><<<dim3(12, 25), blk, 0, stream>>>(G, wpe, pe_b, x, 768, ROWS, 768, 768, pos);

    for (int l = 0; l < 2; l++) {
        const unsigned short* win = l ? win1 : win0;
        const unsigned short* wot = l ? wot1 : wot0;
        // in-proj (m97-structure 128x128): xi half -> bf16 xr2; res half -> bf16 sres
        k_gemm_bf2<<<dim3(24, 25), blk, 0, stream>>>(x, win, in_b + l * 3072, xr2, sresb, ROWS, 768);
        int nc4 = ROWS * DIq / 4;
        k_conv_silu<<<(nc4 + 255) / 256, 256, 0, stream>>>(xr2, cv_w + (size_t)l * DIq * 4, cv_b + l * DIq, xi2b);
        k_xproj_part<<<dim3(ROWS / 32, XP_KS), blk, 0, stream>>>(xi2b, xp_w + (size_t)l * 1536 * 80, part);
        k_dtred<<<ROWS / DT_RPB, 384, 0, stream>>>(part, dt_w + (size_t)l * 48 * 1536, dt_b + l * 1536, de, dbc);
        k_scan<<<dim3(16, 48), blk, 0, stream>>>(de, xi2b, dbc, sresb, Alog + (size_t)l * 1536 * 16,
                                                 Dv + l * 1536, ys);
        // x(bf16) = ys @ out_w + out_b
        k_gemm_bf<EPI_NONE, true><<<dim3(12, 25), blk, 0, stream>>>(ys, wot, ot_b + l * 768, x, 768,
                                                                    ROWS, 768, 1536, nullptr);
    }

    // head
    k_gemm_bf<EPI_NONE, false><<<dim3(16, 25), blk, 0, stream>>>(x, wem, em_b, t1, 1024, ROWS, 1024, 768, nullptr);
    k_ln_gelu<true><<<ROWS, 256, 0, stream>>>(t1, em_g, em_bt, yem);
    k_gemm_bf<EPI_NONE, false><<<dim3(16, 25), blk, 0, stream>>>(yem, wat, at_b, t2, 1024, ROWS, 1024, 1024, nullptr);
    k_ln_gelu<false><<<ROWS, 256, 0, stream>>>(t2, at_g, at_bt, gat);
    k_softpool<<<dim3(16, NB), 256, 0, stream>>>(gat, yem, pool);
    k_final_ln<<<NB, 256, 0, stream>>>(pool, la_g, la_bt, (float*)d_out);
}

// Round 11
// 436.478 us; speedup vs baseline: 5.7124x; 1.0702x over previous
//
#include <hip/hip_runtime.h>
#include <math.h>

static constexpr int NB = 16;
static constexpr int NC = 3;
static constexpr int IM = 224;
static constexpr int IMP = IM * IM;      // 50176
static constexpr int HPq = 14;
static constexpr int NPq = 196;
static constexpr int OUTq = 1024;
static constexpr int DIq = 1536;
static constexpr int ROWS = NB * NPq;    // 3136
static constexpr int MPAD = 3200;        // 25*128, GEMM A-operand row padding

typedef __bf16 bf8_t __attribute__((ext_vector_type(8)));
typedef float f4_t __attribute__((ext_vector_type(4)));
typedef unsigned short us8 __attribute__((ext_vector_type(8)));
typedef const __attribute__((address_space(1))) unsigned int cgu32;
typedef __attribute__((address_space(3))) unsigned int lu32;

__device__ inline unsigned short f2bf(float x) {
    unsigned u = __builtin_bit_cast(unsigned, x);
    unsigned r = (u + 0x7FFFu + ((u >> 16) & 1u)) >> 16;
    return (unsigned short)r;
}
__device__ inline float bf2f(unsigned short v) {
    return __builtin_bit_cast(float, (unsigned)v << 16);
}
__device__ inline float fast_sig(float x) {
    return __builtin_amdgcn_rcpf(1.f + __expf(-x));
}
// numerically stable fast softplus: max(v,0) + log(1+exp(-|v|))
__device__ inline float fast_softplus(float v) {
    return fmaxf(v, 0.f) + __logf(1.f + __expf(-fabsf(v)));
}

template<int CTRL>
__device__ inline float dpp_add(float x) {
    int v = __builtin_amdgcn_update_dpp(0, __builtin_bit_cast(int, x), CTRL, 0xF, 0xF, true);
    return x + __builtin_bit_cast(float, v);
}

// ---------------- K1a: channel avg/max ----------------
__global__ __launch_bounds__(256) void k_avgmax(const float* __restrict__ img, float* __restrict__ am) {
    int idx = blockIdx.x * 256 + threadIdx.x;
    if (idx >= NB * IMP / 4) return;
    int p4 = (idx % (IMP / 4)) * 4, b = idx / (IMP / 4);
    const float* ib = img + (size_t)b * NC * IMP + p4;
    float4 c0 = *(const float4*)ib;
    float4 c1 = *(const float4*)(ib + IMP);
    float4 c2 = *(const float4*)(ib + 2 * IMP);
    float4 av, mx;
    av.x = (c0.x + c1.x + c2.x) * (1.f / 3.f); mx.x = fmaxf(c0.x, fmaxf(c1.x, c2.x));
    av.y = (c0.y + c1.y + c2.y) * (1.f / 3.f); mx.y = fmaxf(c0.y, fmaxf(c1.y, c2.y));
    av.z = (c0.z + c1.z + c2.z) * (1.f / 3.f); mx.z = fmaxf(c0.z, fmaxf(c1.z, c2.z));
    av.w = (c0.w + c1.w + c2.w) * (1.f / 3.f); mx.w = fmaxf(c0.w, fmaxf(c1.w, c2.w));
    *(float4*)(am + (size_t)(b * 2 + 0) * IMP + p4) = av;
    *(float4*)(am + (size_t)(b * 2 + 1) * IMP + p4) = mx;
}

// ---------------- K1b: 7x7 conv gate + patchify ----------------
__global__ __launch_bounds__(256) void k_gatepatch(const float* __restrict__ img, const float* __restrict__ am,
                                                   const float* __restrict__ saw, unsigned short* __restrict__ G) {
    int quad = blockIdx.x * 256 + threadIdx.x;
    if (quad >= NB * IMP / 4) return;
    int pq = quad % (IMP / 4), b = quad / (IMP / 4);
    int x0 = (pq % 56) * 4;
    int y = pq / 56;
    float acc0 = 0.f, acc1 = 0.f, acc2 = 0.f, acc3 = 0.f;
    const bool lok = (x0 >= 4), rok = (x0 <= IM - 8);
    #pragma unroll
    for (int ci = 0; ci < 2; ci++) {
        const float* amc = am + (size_t)(b * 2 + ci) * IMP;
        const float* wc = saw + ci * 49;
        #pragma unroll
        for (int kh = 0; kh < 7; kh++) {
            int yy = y + kh - 3;
            if (yy < 0 || yy >= IM) continue;
            const float* rowp = amc + yy * IM;
            float4 lv = lok ? *(const float4*)(rowp + x0 - 4) : make_float4(0.f, 0.f, 0.f, 0.f);
            float4 mv = *(const float4*)(rowp + x0);
            float4 rv = rok ? *(const float4*)(rowp + x0 + 4) : make_float4(0.f, 0.f, 0.f, 0.f);
            float f[12] = {lv.x, lv.y, lv.z, lv.w, mv.x, mv.y, mv.z, mv.w, rv.x, rv.y, rv.z, rv.w};
            #pragma unroll
            for (int kw = 0; kw < 7; kw++) {
                float w = wc[kh * 7 + kw];
                acc0 = fmaf(w, f[kw + 1], acc0);
                acc1 = fmaf(w, f[kw + 2], acc1);
                acc2 = fmaf(w, f[kw + 3], acc2);
                acc3 = fmaf(w, f[kw + 4], acc3);
            }
        }
    }
    float s0 = fast_sig(acc0), s1 = fast_sig(acc1), s2 = fast_sig(acc2), s3 = fast_sig(acc3);
    const float* ib = img + (size_t)b * NC * IMP + y * IM + x0;
    float4 c0 = *(const float4*)ib;
    float4 c1 = *(const float4*)(ib + IMP);
    float4 c2 = *(const float4*)(ib + 2 * IMP);
    int hy = y >> 4, py = y & 15, hx = x0 >> 4, px0 = x0 & 15;
    size_t base = ((size_t)(b * NPq + hy * HPq + hx) * 768) + (size_t)(py * 16 + px0) * 3;
    ushort4 o0, o1, o2;
    o0.x = f2bf(c0.x * s0); o0.y = f2bf(c1.x * s0); o0.z = f2bf(c2.x * s0);
    o0.w = f2bf(c0.y * s1);
    o1.x = f2bf(c1.y * s1); o1.y = f2bf(c2.y * s1);
    o1.z = f2bf(c0.z * s2); o1.w = f2bf(c1.z * s2);
    o2.x = f2bf(c2.z * s2);
    o2.y = f2bf(c0.w * s3); o2.z = f2bf(c1.w * s3); o2.w = f2bf(c2.w * s3);
    *(ushort4*)(G + base + 0) = o0;
    *(ushort4*)(G + base + 4) = o1;
    *(ushort4*)(G + base + 8) = o2;
}

// ---------------- all weight transposes in ONE launch ----------------
__global__ __launch_bounds__(256) void k_transpose_all(const float* pe_w, const float* in_w, const float* ot_w,
                                                       const float* em_w, const float* at_w,
                                                       unsigned short* wpe, unsigned short* win0, unsigned short* win1,
                                                       unsigned short* wot0, unsigned short* wot1,
                                                       unsigned short* wem, unsigned short* wat) {
    int bid = blockIdx.x;
    const float* W; unsigned short* Wt; int K, N, local;
    if (bid < 576)       { W = pe_w; Wt = wpe; K = 768; N = 768; local = bid; }
    else if (bid < 2880) { W = in_w; Wt = win0; K = 768; N = 3072; local = bid - 576; }
    else if (bid < 5184) { W = in_w + (size_t)768 * 3072; Wt = win1; K = 768; N = 3072; local = bid - 2880; }
    else if (bid < 6336) { W = ot_w; Wt = wot0; K = 1536; N = 768; local = bid - 5184; }
    else if (bid < 7488) { W = ot_w + (size_t)1536 * 768; Wt = wot1; K = 1536; N = 768; local = bid - 6336; }
    else if (bid < 8256) { W = em_w; Wt = wem; K = 768; N = 1024; local = bid - 7488; }
    else                 { W = at_w; Wt = wat; K = 1024; N = 1024; local = bid - 8256; }
    int gx = N / 32;
    int n0 = (local % gx) * 32, k0 = (local / gx) * 32;
    __shared__ float t[32][33];
    int c = threadIdx.x & 31, r8 = threadIdx.x >> 5;
    #pragma unroll
    for (int i = 0; i < 4; i++) {
        int r = r8 + i * 8;
        t[r][c] = W[(size_t)(k0 + r) * N + n0 + c];
    }
    __syncthreads();
    #pragma unroll
    for (int i = 0; i < 4; i++) {
        int r = r8 + i * 8;
        Wt[(size_t)(n0 + r) * K + k0 + c] = f2bf(t[c][r]);
    }
}

// ---------------- bf16 MFMA GEMM, BN=64 double-buffered (general shapes) ----------------
enum { EPI_NONE = 0, EPI_POSEMB = 1 };

template<int EPI, bool CBF>
__global__ __launch_bounds__(256) void k_gemm_bf(const unsigned short* __restrict__ A,
                                                 const unsigned short* __restrict__ Wt,
                                                 const float* __restrict__ bias,
                                                 void* __restrict__ Cv, int ldc,
                                                 int M, int N, int K,
                                                 const float* __restrict__ extra) {
    constexpr int BM = 128, BN = 64;
    __shared__ __align__(16) unsigned short As[2][BM * 64];
    __shared__ __align__(16) unsigned short Bs[2][BN * 64];
    const int bm = blockIdx.y * BM, bn = blockIdx.x * BN;
    const int tid = threadIdx.x;
    const int lane = tid & 63;
    const int wbase = tid & ~63;
    const int wr = ((tid >> 7) & 1) * 64;
    const int wc = ((tid >> 6) & 1) * 32;
    const int lr = lane & 15, lq = lane >> 4;

    f4_t acc[4][2] = {};

    auto stage = [&](int buf, int k0) {
        #pragma unroll
        for (int i = 0; i < 4; i++) {
            int gid2 = i * 256 + tid;
            int r = gid2 >> 3, g = gid2 & 7;
            const unsigned short* src = A + (size_t)(bm + r) * K + k0 + ((g ^ (r & 7)) * 8);
            __builtin_amdgcn_global_load_lds((cgu32*)src,
                (lu32*)&As[buf][(i * 256 + wbase) * 8], 16, 0, 0);
        }
        #pragma unroll
        for (int i = 0; i < 2; i++) {
            int gid2 = i * 256 + tid;
            int r = gid2 >> 3, g = gid2 & 7;
            const unsigned short* src = Wt + (size_t)(bn + r) * K + k0 + ((g ^ (r & 7)) * 8);
            __builtin_amdgcn_global_load_lds((cgu32*)src,
                (lu32*)&Bs[buf][(i * 256 + wbase) * 8], 16, 0, 0);
        }
    };

    stage(0, 0);
    __syncthreads();
    int cur = 0;
    for (int k0 = 0; k0 < K; k0 += 64) {
        if (k0 + 64 < K) stage(cur ^ 1, k0 + 64);
        #pragma unroll
        for (int h = 0; h < 2; h++) {
            bf8_t af[4], bfr[2];
            #pragma unroll
            for (int mb = 0; mb < 4; mb++) {
                int row = wr + mb * 16 + lr;
                int g = h * 4 + lq;
                af[mb] = *(const bf8_t*)&As[cur][row * 64 + ((g ^ (row & 7)) * 8)];
            }
            #pragma unroll
            for (int nb = 0; nb < 2; nb++) {
                int rn = wc + nb * 16 + lr;
                int g = h * 4 + lq;
                bfr[nb] = *(const bf8_t*)&Bs[cur][rn * 64 + ((g ^ (rn & 7)) * 8)];
            }
            #pragma unroll
            for (int mb = 0; mb < 4; mb++)
                #pragma unroll
                for (int nb = 0; nb < 2; nb++)
                    acc[mb][nb] = __builtin_amdgcn_mfma_f32_16x16x32_bf16(af[mb], bfr[nb], acc[mb][nb], 0, 0, 0);
        }
        __syncthreads();
        cur ^= 1;
    }

    #pragma unroll
    for (int mb = 0; mb < 4; mb++) {
        #pragma unroll
        for (int nb = 0; nb < 2; nb++) {
            int col = bn + wc + nb * 16 + lr;
            #pragma unroll
            for (int q = 0; q < 4; q++) {
                int row = bm + wr + mb * 16 + lq * 4 + q;
                if (row < M) {
                    float v = acc[mb][nb][q];
                    if (bias) v += bias[col];
                    if (EPI == EPI_POSEMB) v += extra[(size_t)(row % NPq) * N + col];
                    if (CBF) ((unsigned short*)Cv)[(size_t)row * ldc + col] = f2bf(v);
                    else     ((float*)Cv)[(size_t)row * ldc + col] = v;
                }
            }
        }
    }
}

// ---------------- 128x128 single-buffer GEMM (m97 structure), split epilogue ----------------
__global__ __launch_bounds__(256) void k_gemm_bf2(const unsigned short* __restrict__ A,
                                                  const unsigned short* __restrict__ Wt,
                                                  const float* __restrict__ bias,
                                                  unsigned short* __restrict__ xr2,
                                                  unsigned short* __restrict__ sres,
                                                  int M, int K) {
    constexpr int BM = 128;
    __shared__ __align__(16) unsigned short As[BM * 64];
    __shared__ __align__(16) unsigned short Bs[BM * 64];
    const int bm = blockIdx.y * BM, bn = blockIdx.x * BM;
    const int tid = threadIdx.x;
    const int lane = tid & 63;
    const int wbase = tid & ~63;
    const int wid = tid >> 6;
    const int wr = (wid >> 1) * 64;
    const int wc = (wid & 1) * 64;
    const int lr = lane & 15, lq = lane >> 4;

    f4_t acc[4][4] = {};

    for (int k0 = 0; k0 < K; k0 += 64) {
        #pragma unroll
        for (int i = 0; i < 4; i++) {
            int gid2 = i * 256 + tid;
            int r = gid2 >> 3, g = gid2 & 7;
            const unsigned short* srcA = A + (size_t)(bm + r) * K + k0 + ((g ^ (r & 7)) * 8);
            __builtin_amdgcn_global_load_lds((cgu32*)srcA,
                (lu32*)&As[(i * 256 + wbase) * 8], 16, 0, 0);
            const unsigned short* srcB = Wt + (size_t)(bn + r) * K + k0 + ((g ^ (r & 7)) * 8);
            __builtin_amdgcn_global_load_lds((cgu32*)srcB,
                (lu32*)&Bs[(i * 256 + wbase) * 8], 16, 0, 0);
        }
        __syncthreads();
        #pragma unroll
        for (int h = 0; h < 2; h++) {
            bf8_t af[4], bfr[4];
            #pragma unroll
            for (int mb = 0; mb < 4; mb++) {
                int row = wr + mb * 16 + lr;
                int g = h * 4 + lq;
                af[mb] = *(const bf8_t*)&As[row * 64 + ((g ^ (row & 7)) * 8)];
            }
            #pragma unroll
            for (int nb = 0; nb < 4; nb++) {
                int rn = wc + nb * 16 + lr;
                int g = h * 4 + lq;
                bfr[nb] = *(const bf8_t*)&Bs[rn * 64 + ((g ^ (rn & 7)) * 8)];
            }
            #pragma unroll
            for (int mb = 0; mb < 4; mb++)
                #pragma unroll
                for (int nb = 0; nb < 4; nb++)
                    acc[mb][nb] = __builtin_amdgcn_mfma_f32_16x16x32_bf16(af[mb], bfr[nb], acc[mb][nb], 0, 0, 0);
        }
        __syncthreads();
    }

    #pragma unroll
    for (int mb = 0; mb < 4; mb++) {
        #pragma unroll
        for (int nb = 0; nb < 4; nb++) {
            int col = bn + wc + nb * 16 + lr;
            float bv = bias[col];
            #pragma unroll
            for (int q = 0; q < 4; q++) {
                int row = bm + wr + mb * 16 + lq * 4 + q;
                if (row < M) {
                    float v = acc[mb][nb][q] + bv;
                    if (col < DIq) xr2[(size_t)row * DIq + col] = f2bf(v);
                    else           sres[(size_t)row * DIq + (col - DIq)] = f2bf(v * fast_sig(v));
                }
            }
        }
    }
}

// ---------------- xproj split-K f32 GEMM (bf16 xi input) ----------------
static constexpr int XP_KS = 8;
static constexpr int XP_KC = 1536 / XP_KS;   // 192

__global__ __launch_bounds__(256) void k_xproj_part(const unsigned short* __restrict__ xi2b,
                                                    const float* __restrict__ W,
                                                    float* __restrict__ part) {
    __shared__ float As[32][65];
    __shared__ __align__(16) float Bs[64][80];
    int m0 = blockIdx.x * 32;
    int kc0 = blockIdx.y * XP_KC;
    int tid = threadIdx.x;
    int row = tid >> 3, cg = (tid & 7) * 10;
    float acc[10] = {};
    for (int k0 = 0; k0 < XP_KC; k0 += 64) {
        {
            int r = tid >> 3, c8 = (tid & 7) * 8;
            us8 v = *(const us8*)(xi2b + (size_t)(m0 + r) * 1536 + kc0 + k0 + c8);
            #pragma unroll
            for (int j = 0; j < 8; j++) As[r][c8 + j] = bf2f(v[j]);
        }
        #pragma unroll
        for (int i = 0; i < 5; i++) {
            int id = tid + i * 256;
            int r = id / 20, c4 = (id % 20) * 4;
            *(float4*)&Bs[r][c4] = *(const float4*)(W + (size_t)(kc0 + k0 + r) * 80 + c4);
        }
        __syncthreads();
        #pragma unroll
        for (int kk = 0; kk < 64; kk++) {
            float a = As[row][kk];
            #pragma unroll
            for (int j = 0; j < 10; j++)
                acc[j] = fmaf(a, Bs[kk][cg + j], acc[j]);
        }
        __syncthreads();
    }
    float* p = part + ((size_t)blockIdx.y * ROWS + m0 + row) * 80 + cg;
    #pragma unroll
    for (int j = 0; j < 10; j++) p[j] = acc[j];
}

// ---------------- merged xreduce + dt GEMM + fast softplus ----------------
static constexpr int DT_RPB = 4;
__global__ __launch_bounds__(384) void k_dtred(const float* __restrict__ part, const float* __restrict__ W,
                                               const float* __restrict__ bias, float* __restrict__ de,
                                               float* __restrict__ dbc) {
    int r0 = blockIdx.x * DT_RPB;
    int tid = threadIdx.x;
    __shared__ float ds[DT_RPB][80];
    if (tid < DT_RPB * 80) {
        int row = tid / 80, col = tid % 80;
        const int S = ROWS * 80;
        const float* p = part + (size_t)(r0 + row) * 80 + col;
        float s = 0.f;
        #pragma unroll
        for (int k = 0; k < XP_KS; k++) s += p[(size_t)k * S];
        ds[row][col] = s;
        if (col >= 48) dbc[(size_t)(r0 + row) * 80 + col] = s;
    }
    __syncthreads();
    int j = tid * 4;
    float4 b = *(const float4*)(bias + j);
    float4 a0 = b, a1 = b, a2 = b, a3 = b;
    for (int k = 0; k < 48; k++) {
        float4 w = *(const float4*)(W + (size_t)k * 1536 + j);
        float d0 = ds[0][k], d1 = ds[1][k], d2 = ds[2][k], d3 = ds[3][k];
        a0.x = fmaf(d0, w.x, a0.x); a0.y = fmaf(d0, w.y, a0.y); a0.z = fmaf(d0, w.z, a0.z); a0.w = fmaf(d0, w.w, a0.w);
        a1.x = fmaf(d1, w.x, a1.x); a1.y = fmaf(d1, w.y, a1.y); a1.z = fmaf(d1, w.z, a1.z); a1.w = fmaf(d1, w.w, a1.w);
        a2.x = fmaf(d2, w.x, a2.x); a2.y = fmaf(d2, w.y, a2.y); a2.z = fmaf(d2, w.z, a2.z); a2.w = fmaf(d2, w.w, a2.w);
        a3.x = fmaf(d3, w.x, a3.x); a3.y = fmaf(d3, w.y, a3.y); a3.z = fmaf(d3, w.z, a3.z); a3.w = fmaf(d3, w.w, a3.w);
    }
    float4 o;
    o.x = fast_softplus(a0.x); o.y = fast_softplus(a0.y); o.z = fast_softplus(a0.z); o.w = fast_softplus(a0.w);
    *(float4*)(de + (size_t)(r0 + 0) * 1536 + j) = o;
    o.x = fast_softplus(a1.x); o.y = fast_softplus(a1.y); o.z = fast_softplus(a1.z); o.w = fast_softplus(a1.w);
    *(float4*)(de + (size_t)(r0 + 1) * 1536 + j) = o;
    o.x = fast_softplus(a2.x); o.y = fast_softplus(a2.y); o.z = fast_softplus(a2.z); o.w = fast_softplus(a2.w);
    *(float4*)(de + (size_t)(r0 + 2) * 1536 + j) = o;
    o.x = fast_softplus(a3.x); o.y = fast_softplus(a3.y); o.z = fast_softplus(a3.z); o.w = fast_softplus(a3.w);
    *(float4*)(de + (size_t)(r0 + 3) * 1536 + j) = o;
}

// ---------------- causal depthwise conv (DC=4) + silu, bf16 in/out ----------------
__global__ __launch_bounds__(256) void k_conv_silu(const unsigned short* __restrict__ xr2, const float* __restrict__ cw,
                                                   const float* __restrict__ cb, unsigned short* __restrict__ xi2b) {
    int idx4 = blockIdx.x * 256 + threadIdx.x;
    if (idx4 >= ROWS * DIq / 4) return;
    int d4 = (idx4 % (DIq / 4)) * 4;
    int bt = idx4 / (DIq / 4);
    int t = bt % NPq, b = bt / NPq;
    const unsigned short* base = xr2 + (size_t)b * NPq * DIq + d4;
    float4 s = *(const float4*)(cb + d4);
    float4 w0 = *(const float4*)(cw + (d4 + 0) * 4);
    float4 w1 = *(const float4*)(cw + (d4 + 1) * 4);
    float4 w2 = *(const float4*)(cw + (d4 + 2) * 4);
    float4 w3 = *(const float4*)(cw + (d4 + 3) * 4);
    if (t >= 3) {
        ushort4 v = *(const ushort4*)(base + (size_t)(t - 3) * DIq);
        s.x = fmaf(bf2f(v.x), w0.x, s.x); s.y = fmaf(bf2f(v.y), w1.x, s.y);
        s.z = fmaf(bf2f(v.z), w2.x, s.z); s.w = fmaf(bf2f(v.w), w3.x, s.w);
    }
    if (t >= 2) {
        ushort4 v = *(const ushort4*)(base + (size_t)(t - 2) * DIq);
        s.x = fmaf(bf2f(v.x), w0.y, s.x); s.y = fmaf(bf2f(v.y), w1.y, s.y);
        s.z = fmaf(bf2f(v.z), w2.y, s.z); s.w = fmaf(bf2f(v.w), w3.y, s.w);
    }
    if (t >= 1) {
        ushort4 v = *(const ushort4*)(base + (size_t)(t - 1) * DIq);
        s.x = fmaf(bf2f(v.x), w0.z, s.x); s.y = fmaf(bf2f(v.y), w1.z, s.y);
        s.z = fmaf(bf2f(v.z), w2.z, s.z); s.w = fmaf(bf2f(v.w), w3.z, s.w);
    }
    {
        ushort4 v = *(const ushort4*)(base + (size_t)t * DIq);
        s.x = fmaf(bf2f(v.x), w0.w, s.x); s.y = fmaf(bf2f(v.y), w1.w, s.y);
        s.z = fmaf(bf2f(v.z), w2.w, s.z); s.w = fmaf(bf2f(v.w), w3.w, s.w);
    }
    ushort4 xo;
    xo.x = f2bf(s.x * fast_sig(s.x)); xo.y = f2bf(s.y * fast_sig(s.y));
    xo.z = f2bf(s.z * fast_sig(s.z)); xo.w = f2bf(s.w * fast_sig(s.w));
    *(ushort4*)(xi2b + (size_t)bt * DIq + d4) = xo;
}

// ---------------- selective-scan, LDS double-buffered, packed b64 sdu ----------------
static constexpr int STB = 28;

__global__ __launch_bounds__(256) void k_scan(const float* __restrict__ delta, const unsigned short* __restrict__ xi2b,
                                              const float* __restrict__ dbc, const unsigned short* __restrict__ sresb,
                                              const float* __restrict__ Alog, const float* __restrict__ Dv,
                                              unsigned short* __restrict__ ys) {
    const int b = blockIdx.x;
    const int d0 = blockIdx.y * 32;
    const int tid = threadIdx.x;
    const int dl = tid >> 3;
    const int np = tid & 7;
    const int d = d0 + dl;
    const float A0 = -__expf(Alog[d * 16 + np]);
    const float A1 = -__expf(Alog[d * 16 + np + 8]);
    const float Dd = Dv[d];
    const int tr = tid >> 5;
    const int dls = tid & 31;

    __shared__ float2 sdu[2][STB][32];   // {de, pack(u,sr)} per d
    __shared__ float sbc[2][STB][32];    // [np*4 + {B0,B1,C0,C1}]

    const float* gde = delta + ((size_t)b * NPq + tr) * DIq + d0 + dls;
    const unsigned short* gu  = xi2b  + ((size_t)b * NPq + tr) * DIq + d0 + dls;
    const unsigned short* gsr = sresb + ((size_t)b * NPq + tr) * DIq + d0 + dls;
    const float* gbc = dbc + ((size_t)b * NPq + tr) * 80 + 48 + dls;
    unsigned short* gy = ys + (size_t)b * NPq * DIq + d;

    float rde[4], rbc[4];
    unsigned short ruu[4], rss[4];

    auto stageLoad = [&](int c) {
        const int t0 = c * STB;
        #pragma unroll
        for (int j = 0; j < 3; j++) {
            int off = (t0 + 8 * j) * DIq;
            rde[j] = gde[off];
            ruu[j] = gu[off];
            rss[j] = gsr[off];
            rbc[j] = gbc[(t0 + 8 * j) * 80];
        }
        if (tid < 128) {
            int off = (t0 + 24) * DIq;
            rde[3] = gde[off];
            ruu[3] = gu[off];
            rss[3] = gsr[off];
            rbc[3] = gbc[(t0 + 24) * 80];
        }
    };
    auto stageWrite = [&](int buf) {
        const int pi = (dls & 7) * 4 + (dls >> 3);
        #pragma unroll
        for (int j = 0; j < 3; j++) {
            int t = tr + 8 * j;
            unsigned pk = ((unsigned)ruu[j] << 16) | rss[j];
            sdu[buf][t][dls] = make_float2(rde[j], __builtin_bit_cast(float, pk));
            sbc[buf][t][pi] = rbc[j];
        }
        if (tid < 128) {
            int t = tr + 24;
            unsigned pk = ((unsigned)ruu[3] << 16) | rss[3];
            sdu[buf][t][dls] = make_float2(rde[3], __builtin_bit_cast(float, pk));
            sbc[buf][t][pi] = rbc[3];
        }
    };

    stageLoad(0);
    stageWrite(0);
    __syncthreads();

    float h0 = 0.f, h1 = 0.f;
    int cur = 0;
    for (int c = 0; c < 7; c++) {
        if (c < 6) stageLoad(c + 1);
        #pragma unroll 4
        for (int t = 0; t < STB; t++) {
            float2 duv = sdu[cur][t][dl];
            float4 bc = *(const float4*)&sbc[cur][t][np * 4];
            unsigned bits = __builtin_bit_cast(unsigned, duv.y);
            float u  = __builtin_bit_cast(float, bits & 0xFFFF0000u);
            float sr = __builtin_bit_cast(float, bits << 16);
            float a0 = __expf(duv.x * A0), a1 = __expf(duv.x * A1);
            float deu = duv.x * u;
            h0 = fmaf(a0, h0, deu * bc.x);
            h1 = fmaf(a1, h1, deu * bc.y);
            float p = fmaf(h1, bc.w, h0 * bc.z);
            p = dpp_add<0xB1>(p);
            p = dpp_add<0x4E>(p);
            p = dpp_add<0x141>(p);
            if (np == 0) gy[(size_t)(c * STB + t) * DIq] = f2bf(fmaf(Dd, u, p) * sr);
        }
        if (c < 6) stageWrite(cur ^ 1);
        __syncthreads();
        cur ^= 1;
    }
}

// ---------------- row LayerNorm (1024) + exact gelu; out f32 or bf16 ----------------
template<bool OBF>
__global__ __launch_bounds__(256) void k_ln_gelu(const float* __restrict__ in, const float* __restrict__ g,
                                                 const float* __restrict__ bt, void* __restrict__ outv) {
    int row = blockIdx.x;
    const float* x = in + (size_t)row * OUTq;
    float4 v = ((const float4*)x)[threadIdx.x];
    float s = v.x + v.y + v.z + v.w;
    float ss = v.x * v.x + v.y * v.y + v.z * v.z + v.w * v.w;
    #pragma unroll
    for (int off = 32; off >= 1; off >>= 1) { s += __shfl_down(s, off); ss += __shfl_down(ss, off); }
    __shared__ float sh[10];
    int wid = threadIdx.x >> 6, lid = threadIdx.x & 63;
    if (lid == 0) { sh[wid] = s; sh[4 + wid] = ss; }
    __syncthreads();
    if (threadIdx.x == 0) {
        float S = sh[0] + sh[1] + sh[2] + sh[3], SS = sh[4] + sh[5] + sh[6] + sh[7];
        float m = S * (1.f / OUTq);
        float var = SS * (1.f / OUTq) - m * m;
        sh[8] = m; sh[9] = rsqrtf(var + 1e-5f);
    }
    __syncthreads();
    float m = sh[8], rst = sh[9];
    float4 gv = ((const float4*)g)[threadIdx.x];
    float4 bv = ((const float4*)bt)[threadIdx.x];
    float4 o;
    float y0 = (v.x - m) * rst * gv.x + bv.x; o.x = 0.5f * y0 * (1.f + erff(y0 * 0.70710678118f));
    float y1 = (v.y - m) * rst * gv.y + bv.y; o.y = 0.5f * y1 * (1.f + erff(y1 * 0.70710678118f));
    float y2 = (v.z - m) * rst * gv.z + bv.z; o.z = 0.5f * y2 * (1.f + erff(y2 * 0.70710678118f));
    float y3 = (v.w - m) * rst * gv.w + bv.w; o.w = 0.5f * y3 * (1.f + erff(y3 * 0.70710678118f));
    if (OBF) {
        ushort4 o4;
        o4.x = f2bf(o.x); o4.y = f2bf(o.y); o4.z = f2bf(o.z); o4.w = f2bf(o.w);
        ((ushort4*)((unsigned short*)outv + (size_t)row * OUTq))[threadIdx.x] = o4;
    } else {
        ((float4*)((float*)outv + (size_t)row * OUTq))[threadIdx.x] = o;
    }
}

// ---------------- column softmax + pool, 4-way t-split ----------------
__global__ __launch_bounds__(256) void k_softpool(const float* __restrict__ gm, const unsigned short* __restrict__ ym,
                                                  float* __restrict__ pooled) {
    int b = blockIdx.y;
    int jl = threadIdx.x & 63;
    int j = blockIdx.x * 64 + jl;
    int tc = threadIdx.x >> 6;
    const float* gb = gm + (size_t)b * NPq * OUTq + j;
    const unsigned short* yb = ym + (size_t)b * NPq * OUTq + j;
    int t0 = tc * 49;
    float m = -1e30f, s = 0.f, ps = 0.f;
    for (int t = t0; t < t0 + 49; t++) {
        float g = gb[(size_t)t * OUTq];
        float y = bf2f(yb[(size_t)t * OUTq]);
        float mn = fmaxf(m, g);
        float sc = __expf(m - mn);
        float e = __expf(g - mn);
        s = fmaf(s, sc, e);
        ps = fmaf(ps, sc, y * e);
        m = mn;
    }
    __shared__ float sm[4][64], ssum[4][64], sps[4][64];
    sm[tc][jl] = m; ssum[tc][jl] = s; sps[tc][jl] = ps;
    __syncthreads();
    if (tc == 0) {
        float m0 = sm[0][jl], m1 = sm[1][jl], m2 = sm[2][jl], m3 = sm[3][jl];
        float mt = fmaxf(fmaxf(m0, m1), fmaxf(m2, m3));
        float e0 = __expf(m0 - mt), e1 = __expf(m1 - mt);
        float e2 = __expf(m2 - mt), e3 = __expf(m3 - mt);
        float st = ssum[0][jl] * e0 + ssum[1][jl] * e1 + ssum[2][jl] * e2 + ssum[3][jl] * e3;
        float pt = sps[0][jl] * e0 + sps[1][jl] * e1 + sps[2][jl] * e2 + sps[3][jl] * e3;
        pooled[b * OUTq + j] = pt / st;
    }
}

// ---------------- final LayerNorm ----------------
__global__ __launch_bounds__(256) void k_final_ln(const float* __restrict__ p, const float* __restrict__ g,
                                                  const float* __restrict__ bt, float* __restrict__ out) {
    int row = blockIdx.x;
    const float* x = p + (size_t)row * OUTq;
    float4 v = ((const float4*)x)[threadIdx.x];
    float s = v.x + v.y + v.z + v.w;
    float ss = v.x * v.x + v.y * v.y + v.z * v.z + v.w * v.w;
    #pragma unroll
    for (int off = 32; off >= 1; off >>= 1) { s += __shfl_down(s, off); ss += __shfl_down(ss, off); }
    __shared__ float sh[10];
    int wid = threadIdx.x >> 6, lid = threadIdx.x & 63;
    if (lid == 0) { sh[wid] = s; sh[4 + wid] = ss; }
    __syncthreads();
    if (threadIdx.x == 0) {
        float S = sh[0] + sh[1] + sh[2] + sh[3], SS = sh[4] + sh[5] + sh[6] + sh[7];
        float m = S * (1.f / OUTq);
        float var = SS * (1.f / OUTq) - m * m;
        sh[8] = m; sh[9] = rsqrtf(var + 1e-5f);
    }
    __syncthreads();
    float m = sh[8], rst = sh[9];
    float4 gv = ((const float4*)g)[threadIdx.x];
    float4 bv = ((const float4*)bt)[threadIdx.x];
    float4 o;
    o.x = (v.x - m) * rst * gv.x + bv.x;
    o.y = (v.y - m) * rst * gv.y + bv.y;
    o.z = (v.z - m) * rst * gv.z + bv.z;
    o.w = (v.w - m) * rst * gv.w + bv.w;
    ((float4*)(out + (size_t)row * OUTq))[threadIdx.x] = o;
}

extern "C" void kernel_launch(void* const* d_in, const int* in_sizes, int n_in,
                              void* d_out, int out_size, void* d_ws, size_t ws_size,
                              hipStream_t stream) {
    const float* img   = (const float*)d_in[0];
    const float* sa_w  = (const float*)d_in[1];
    const float* pe_w  = (const float*)d_in[2];
    const float* pe_b  = (const float*)d_in[3];
    const float* pos   = (const float*)d_in[4];
    const float* in_w  = (const float*)d_in[5];
    const float* in_b  = (const float*)d_in[6];
    const float* cv_w  = (const float*)d_in[7];
    const float* cv_b  = (const float*)d_in[8];
    const float* xp_w  = (const float*)d_in[9];
    const float* dt_w  = (const float*)d_in[10];
    const float* dt_b  = (const float*)d_in[11];
    const float* Alog  = (const float*)d_in[12];
    const float* Dv    = (const float*)d_in[13];
    const float* ot_w  = (const float*)d_in[14];
    const float* ot_b  = (const float*)d_in[15];
    const float* em_w  = (const float*)d_in[16];
    const float* em_b  = (const float*)d_in[17];
    const float* em_g  = (const float*)d_in[18];
    const float* em_bt = (const float*)d_in[19];
    const float* at_w  = (const float*)d_in[20];
    const float* at_b  = (const float*)d_in[21];
    const float* at_g  = (const float*)d_in[22];
    const float* at_bt = (const float*)d_in[23];
    const float* la_g  = (const float*)d_in[24];
    const float* la_bt = (const float*)d_in[25];

    char* ws = (char*)d_ws;
    auto al = [](size_t x) { return (x + 255) & ~(size_t)255; };
    size_t SZ_am   = (size_t)NB * 2 * IMP * 4;
    size_t SZ_G    = (size_t)MPAD * 768 * 2;
    size_t SZ_x    = (size_t)MPAD * 768 * 2;
    size_t SZ_xr2  = (size_t)ROWS * DIq * 2;
    size_t SZ_xi2  = (size_t)ROWS * DIq * 2;
    size_t SZ_de   = (size_t)ROWS * DIq * 4;
    size_t SZ_dbc  = (size_t)ROWS * 80 * 4;
    size_t SZ_ys   = (size_t)MPAD * DIq * 2;
    size_t SZ_sres = (size_t)ROWS * DIq * 2;
    size_t SZ_yem  = (size_t)MPAD * 1024 * 2;
    size_t SZ_pool = (size_t)NB * OUTq * 4;
    size_t SZ_part = (size_t)XP_KS * ROWS * 80 * 4;   // 8 MB

    size_t o_am   = 0;
    size_t o_G    = al(o_am + SZ_am);
    size_t o_x    = al(o_G + SZ_G);
    size_t o_xr2  = al(o_x + SZ_x);
    size_t o_xi2  = al(o_xr2 + SZ_xr2);
    size_t o_de   = al(o_xi2 + SZ_xi2);
    size_t o_dbc  = al(o_de + SZ_de);
    size_t o_ys   = al(o_dbc + SZ_dbc);
    size_t o_sres = al(o_ys + SZ_ys);
    size_t o_yem  = al(o_sres + SZ_sres);
    size_t o_pool = al(o_yem + SZ_yem);
    size_t o_part = al(o_pool + SZ_pool);

    size_t o_wpe  = al(o_part + SZ_part);
    size_t o_win0 = al(o_wpe  + (size_t)768 * 768 * 2);
    size_t o_win1 = al(o_win0 + (size_t)3072 * 768 * 2);
    size_t o_wot0 = al(o_win1 + (size_t)3072 * 768 * 2);
    size_t o_wot1 = al(o_wot0 + (size_t)768 * 1536 * 2);
    size_t o_wem  = al(o_wot1 + (size_t)768 * 1536 * 2);
    size_t o_wat  = al(o_wem  + (size_t)1024 * 768 * 2);

    float* am    = (float*)(ws + o_am);
    unsigned short* G   = (unsigned short*)(ws + o_G);
    unsigned short* x   = (unsigned short*)(ws + o_x);
    unsigned short* xr2 = (unsigned short*)(ws + o_xr2);
    unsigned short* xi2b = (unsigned short*)(ws + o_xi2);
    float* de    = (float*)(ws + o_de);
    float* dbc   = (float*)(ws + o_dbc);
    unsigned short* ys = (unsigned short*)(ws + o_ys);
    unsigned short* sresb = (unsigned short*)(ws + o_sres);
    unsigned short* yem = (unsigned short*)(ws + o_yem);
    float* pool  = (float*)(ws + o_pool);
    float* part  = (float*)(ws + o_part);
    unsigned short* wpe  = (unsigned short*)(ws + o_wpe);
    unsigned short* win0 = (unsigned short*)(ws + o_win0);
    unsigned short* win1 = (unsigned short*)(ws + o_win1);
    unsigned short* wot0 = (unsigned short*)(ws + o_wot0);
    unsigned short* wot1 = (unsigned short*)(ws + o_wot1);
    unsigned short* wem  = (unsigned short*)(ws + o_wem);
    unsigned short* wat  = (unsigned short*)(ws + o_wat);
    // head-phase overlays
    float* t1  = (float*)(ws + o_de);
    float* t2  = (float*)(ws + o_xr2);
    float* gat = (float*)(ws + o_ys);

    k_transpose_all<<<9280, 256, 0, stream>>>(pe_w, in_w, ot_w, em_w, at_w,
                                              wpe, win0, win1, wot0, wot1, wem, wat);

    int nq = NB * IMP / 4;
    k_avgmax<<<(nq + 255) / 256, 256, 0, stream>>>(img, am);
    k_gatepatch<<<(nq + 255) / 256, 256, 0, stream>>>(img, am, sa_w, G);

    dim3 blk(256);
    k_gemm_bf<EPI_POSEMB, true><<<dim3(12, 25), blk, 0, stream>>>(G, wpe, pe_b, x, 768, ROWS, 768, 768, pos);

    for (int l = 0; l < 2; l++) {
        const unsigned short* win = l ? win1 : win0;
        const unsigned short* wot = l ? wot1 : wot0;
        k_gemm_bf2<<<dim3(24, 25), blk, 0, stream>>>(x, win, in_b + l * 3072, xr2, sresb, ROWS, 768);
        int nc4 = ROWS * DIq / 4;
        k_conv_silu<<<(nc4 + 255) / 256, 256, 0, stream>>>(xr2, cv_w + (size_t)l * DIq * 4, cv_b + l * DIq, xi2b);
        k_xproj_part<<<dim3(ROWS / 32, XP_KS), blk, 0, stream>>>(xi2b, xp_w + (size_t)l * 1536 * 80, part);
        k_dtred<<<ROWS / DT_RPB, 384, 0, stream>>>(part, dt_w + (size_t)l * 48 * 1536, dt_b + l * 1536, de, dbc);
        k_scan<<<dim3(16, 48), blk, 0, stream>>>(de, xi2b, dbc, sresb, Alog + (size_t)l * 1536 * 16,
                                                 Dv + l * 1536, ys);
        k_gemm_bf<EPI_NONE, true><<<dim3(12, 25), blk, 0, stream>>>(ys, wot, ot_b + l * 768, x, 768,
                                                                    ROWS, 768, 1536, nullptr);
    }

    // head
    k_gemm_bf<EPI_NONE, false><<<dim3(16, 25), blk, 0, stream>>>(x, wem, em_b, t1, 1024, ROWS, 1024, 768, nullptr);
    k_ln_gelu<true><<<ROWS, 256, 0, stream>>>(t1, em_g, em_bt, yem);
    k_gemm_bf<EPI_NONE, false><<<dim3(16, 25), blk, 0, stream>>>(yem, wat, at_b, t2, 1024, ROWS, 1024, 1024, nullptr);
    k_ln_gelu<false><<<ROWS, 256, 0, stream>>>(t2, at_g, at_bt, gat);
    k_softpool<<<dim3(16, NB), 256, 0, stream>>>(gat, yem, pool);
    k_final_ln<<<NB, 256, 0, stream>>>(pool, la_g, la_bt, (float*)d_out);
}

// Round 12
// 422.350 us; speedup vs baseline: 5.9034x; 1.0335x over previous
//
#include <hip/hip_runtime.h>
#include <math.h>

static constexpr int NB = 16;
static constexpr int NC = 3;
static constexpr int IM = 224;
static constexpr int IMP = IM * IM;      // 50176
static constexpr int HPq = 14;
static constexpr int NPq = 196;
static constexpr int OUTq = 1024;
static constexpr int DIq = 1536;
static constexpr int ROWS = NB * NPq;    // 3136
static constexpr int MPAD = 3200;        // 25*128, GEMM A-operand row padding

typedef __bf16 bf8_t __attribute__((ext_vector_type(8)));
typedef float f4_t __attribute__((ext_vector_type(4)));
typedef unsigned short us8 __attribute__((ext_vector_type(8)));
typedef const __attribute__((address_space(1))) unsigned int cgu32;
typedef __attribute__((address_space(3))) unsigned int lu32;

__device__ inline unsigned short f2bf(float x) {
    unsigned u = __builtin_bit_cast(unsigned, x);
    unsigned r = (u + 0x7FFFu + ((u >> 16) & 1u)) >> 16;
    return (unsigned short)r;
}
__device__ inline float bf2f(unsigned short v) {
    return __builtin_bit_cast(float, (unsigned)v << 16);
}
__device__ inline float fast_sig(float x) {
    return __builtin_amdgcn_rcpf(1.f + __expf(-x));
}
__device__ inline float fast_softplus(float v) {
    return fmaxf(v, 0.f) + __logf(1.f + __expf(-fabsf(v)));
}

template<int CTRL>
__device__ inline float dpp_add(float x) {
    int v = __builtin_amdgcn_update_dpp(0, __builtin_bit_cast(int, x), CTRL, 0xF, 0xF, true);
    return x + __builtin_bit_cast(float, v);
}

// ---------------- K1a: channel avg/max ----------------
__global__ __launch_bounds__(256) void k_avgmax(const float* __restrict__ img, float* __restrict__ am) {
    int idx = blockIdx.x * 256 + threadIdx.x;
    if (idx >= NB * IMP / 4) return;
    int p4 = (idx % (IMP / 4)) * 4, b = idx / (IMP / 4);
    const float* ib = img + (size_t)b * NC * IMP + p4;
    float4 c0 = *(const float4*)ib;
    float4 c1 = *(const float4*)(ib + IMP);
    float4 c2 = *(const float4*)(ib + 2 * IMP);
    float4 av, mx;
    av.x = (c0.x + c1.x + c2.x) * (1.f / 3.f); mx.x = fmaxf(c0.x, fmaxf(c1.x, c2.x));
    av.y = (c0.y + c1.y + c2.y) * (1.f / 3.f); mx.y = fmaxf(c0.y, fmaxf(c1.y, c2.y));
    av.z = (c0.z + c1.z + c2.z) * (1.f / 3.f); mx.z = fmaxf(c0.z, fmaxf(c1.z, c2.z));
    av.w = (c0.w + c1.w + c2.w) * (1.f / 3.f); mx.w = fmaxf(c0.w, fmaxf(c1.w, c2.w));
    *(float4*)(am + (size_t)(b * 2 + 0) * IMP + p4) = av;
    *(float4*)(am + (size_t)(b * 2 + 1) * IMP + p4) = mx;
}

// ---------------- K1b: 7x7 conv gate + patchify ----------------
__global__ __launch_bounds__(256) void k_gatepatch(const float* __restrict__ img, const float* __restrict__ am,
                                                   const float* __restrict__ saw, unsigned short* __restrict__ G) {
    int quad = blockIdx.x * 256 + threadIdx.x;
    if (quad >= NB * IMP / 4) return;
    int pq = quad % (IMP / 4), b = quad / (IMP / 4);
    int x0 = (pq % 56) * 4;
    int y = pq / 56;
    float acc0 = 0.f, acc1 = 0.f, acc2 = 0.f, acc3 = 0.f;
    const bool lok = (x0 >= 4), rok = (x0 <= IM - 8);
    #pragma unroll
    for (int ci = 0; ci < 2; ci++) {
        const float* amc = am + (size_t)(b * 2 + ci) * IMP;
        const float* wc = saw + ci * 49;
        #pragma unroll
        for (int kh = 0; kh < 7; kh++) {
            int yy = y + kh - 3;
            if (yy < 0 || yy >= IM) continue;
            const float* rowp = amc + yy * IM;
            float4 lv = lok ? *(const float4*)(rowp + x0 - 4) : make_float4(0.f, 0.f, 0.f, 0.f);
            float4 mv = *(const float4*)(rowp + x0);
            float4 rv = rok ? *(const float4*)(rowp + x0 + 4) : make_float4(0.f, 0.f, 0.f, 0.f);
            float f[12] = {lv.x, lv.y, lv.z, lv.w, mv.x, mv.y, mv.z, mv.w, rv.x, rv.y, rv.z, rv.w};
            #pragma unroll
            for (int kw = 0; kw < 7; kw++) {
                float w = wc[kh * 7 + kw];
                acc0 = fmaf(w, f[kw + 1], acc0);
                acc1 = fmaf(w, f[kw + 2], acc1);
                acc2 = fmaf(w, f[kw + 3], acc2);
                acc3 = fmaf(w, f[kw + 4], acc3);
            }
        }
    }
    float s0 = fast_sig(acc0), s1 = fast_sig(acc1), s2 = fast_sig(acc2), s3 = fast_sig(acc3);
    const float* ib = img + (size_t)b * NC * IMP + y * IM + x0;
    float4 c0 = *(const float4*)ib;
    float4 c1 = *(const float4*)(ib + IMP);
    float4 c2 = *(const float4*)(ib + 2 * IMP);
    int hy = y >> 4, py = y & 15, hx = x0 >> 4, px0 = x0 & 15;
    size_t base = ((size_t)(b * NPq + hy * HPq + hx) * 768) + (size_t)(py * 16 + px0) * 3;
    ushort4 o0, o1, o2;
    o0.x = f2bf(c0.x * s0); o0.y = f2bf(c1.x * s0); o0.z = f2bf(c2.x * s0);
    o0.w = f2bf(c0.y * s1);
    o1.x = f2bf(c1.y * s1); o1.y = f2bf(c2.y * s1);
    o1.z = f2bf(c0.z * s2); o1.w = f2bf(c1.z * s2);
    o2.x = f2bf(c2.z * s2);
    o2.y = f2bf(c0.w * s3); o2.z = f2bf(c1.w * s3); o2.w = f2bf(c2.w * s3);
    *(ushort4*)(G + base + 0) = o0;
    *(ushort4*)(G + base + 4) = o1;
    *(ushort4*)(G + base + 8) = o2;
}

// ---------------- all weight transposes in ONE launch ----------------
__global__ __launch_bounds__(256) void k_transpose_all(const float* pe_w, const float* in_w, const float* ot_w,
                                                       const float* em_w, const float* at_w,
                                                       unsigned short* wpe, unsigned short* win0, unsigned short* win1,
                                                       unsigned short* wot0, unsigned short* wot1,
                                                       unsigned short* wem, unsigned short* wat) {
    int bid = blockIdx.x;
    const float* W; unsigned short* Wt; int K, N, local;
    if (bid < 576)       { W = pe_w; Wt = wpe; K = 768; N = 768; local = bid; }
    else if (bid < 2880) { W = in_w; Wt = win0; K = 768; N = 3072; local = bid - 576; }
    else if (bid < 5184) { W = in_w + (size_t)768 * 3072; Wt = win1; K = 768; N = 3072; local = bid - 2880; }
    else if (bid < 6336) { W = ot_w; Wt = wot0; K = 1536; N = 768; local = bid - 5184; }
    else if (bid < 7488) { W = ot_w + (size_t)1536 * 768; Wt = wot1; K = 1536; N = 768; local = bid - 6336; }
    else if (bid < 8256) { W = em_w; Wt = wem; K = 768; N = 1024; local = bid - 7488; }
    else                 { W = at_w; Wt = wat; K = 1024; N = 1024; local = bid - 8256; }
    int gx = N / 32;
    int n0 = (local % gx) * 32, k0 = (local / gx) * 32;
    __shared__ float t[32][33];
    int c = threadIdx.x & 31, r8 = threadIdx.x >> 5;
    #pragma unroll
    for (int i = 0; i < 4; i++) {
        int r = r8 + i * 8;
        t[r][c] = W[(size_t)(k0 + r) * N + n0 + c];
    }
    __syncthreads();
    #pragma unroll
    for (int i = 0; i < 4; i++) {
        int r = r8 + i * 8;
        Wt[(size_t)(n0 + r) * K + k0 + c] = f2bf(t[c][r]);
    }
}

// ---------------- xproj weight: f32 [l][1536][80] -> bf16 [l][128][1536], zero-padded ----------------
__global__ __launch_bounds__(256) void k_xpw_t(const float* __restrict__ xp_w, unsigned short* __restrict__ xpt) {
    int idx = blockIdx.x * 256 + threadIdx.x;
    if (idx >= 2 * 128 * 1536) return;
    int k = idx % 1536;
    int n = (idx / 1536) % 128;
    int l = idx / (1536 * 128);
    unsigned short v = 0;
    if (n < 80) v = f2bf(xp_w[(size_t)l * 1536 * 80 + (size_t)k * 80 + n]);
    xpt[idx] = v;
}

// ---------------- bf16 MFMA GEMM, BN=64 double-buffered (general shapes) ----------------
enum { EPI_NONE = 0, EPI_POSEMB = 1 };

template<int EPI, bool CBF>
__global__ __launch_bounds__(256) void k_gemm_bf(const unsigned short* __restrict__ A,
                                                 const unsigned short* __restrict__ Wt,
                                                 const float* __restrict__ bias,
                                                 void* __restrict__ Cv, int ldc,
                                                 int M, int N, int K,
                                                 const float* __restrict__ extra) {
    constexpr int BM = 128, BN = 64;
    __shared__ __align__(16) unsigned short As[2][BM * 64];
    __shared__ __align__(16) unsigned short Bs[2][BN * 64];
    const int bm = blockIdx.y * BM, bn = blockIdx.x * BN;
    const int tid = threadIdx.x;
    const int lane = tid & 63;
    const int wbase = tid & ~63;
    const int wr = ((tid >> 7) & 1) * 64;
    const int wc = ((tid >> 6) & 1) * 32;
    const int lr = lane & 15, lq = lane >> 4;

    f4_t acc[4][2] = {};

    auto stage = [&](int buf, int k0) {
        #pragma unroll
        for (int i = 0; i < 4; i++) {
            int gid2 = i * 256 + tid;
            int r = gid2 >> 3, g = gid2 & 7;
            const unsigned short* src = A + (size_t)(bm + r) * K + k0 + ((g ^ (r & 7)) * 8);
            __builtin_amdgcn_global_load_lds((cgu32*)src,
                (lu32*)&As[buf][(i * 256 + wbase) * 8], 16, 0, 0);
        }
        #pragma unroll
        for (int i = 0; i < 2; i++) {
            int gid2 = i * 256 + tid;
            int r = gid2 >> 3, g = gid2 & 7;
            const unsigned short* src = Wt + (size_t)(bn + r) * K + k0 + ((g ^ (r & 7)) * 8);
            __builtin_amdgcn_global_load_lds((cgu32*)src,
                (lu32*)&Bs[buf][(i * 256 + wbase) * 8], 16, 0, 0);
        }
    };

    stage(0, 0);
    __syncthreads();
    int cur = 0;
    for (int k0 = 0; k0 < K; k0 += 64) {
        if (k0 + 64 < K) stage(cur ^ 1, k0 + 64);
        #pragma unroll
        for (int h = 0; h < 2; h++) {
            bf8_t af[4], bfr[2];
            #pragma unroll
            for (int mb = 0; mb < 4; mb++) {
                int row = wr + mb * 16 + lr;
                int g = h * 4 + lq;
                af[mb] = *(const bf8_t*)&As[cur][row * 64 + ((g ^ (row & 7)) * 8)];
            }
            #pragma unroll
            for (int nb = 0; nb < 2; nb++) {
                int rn = wc + nb * 16 + lr;
                int g = h * 4 + lq;
                bfr[nb] = *(const bf8_t*)&Bs[cur][rn * 64 + ((g ^ (rn & 7)) * 8)];
            }
            #pragma unroll
            for (int mb = 0; mb < 4; mb++)
                #pragma unroll
                for (int nb = 0; nb < 2; nb++)
                    acc[mb][nb] = __builtin_amdgcn_mfma_f32_16x16x32_bf16(af[mb], bfr[nb], acc[mb][nb], 0, 0, 0);
        }
        __syncthreads();
        cur ^= 1;
    }

    #pragma unroll
    for (int mb = 0; mb < 4; mb++) {
        #pragma unroll
        for (int nb = 0; nb < 2; nb++) {
            int col = bn + wc + nb * 16 + lr;
            #pragma unroll
            for (int q = 0; q < 4; q++) {
                int row = bm + wr + mb * 16 + lq * 4 + q;
                if (row < M) {
                    float v = acc[mb][nb][q];
                    if (bias) v += bias[col];
                    if (EPI == EPI_POSEMB) v += extra[(size_t)(row % NPq) * N + col];
                    if (CBF) ((unsigned short*)Cv)[(size_t)row * ldc + col] = f2bf(v);
                    else     ((float*)Cv)[(size_t)row * ldc + col] = v;
                }
            }
        }
    }
}

// ---------------- 128x128 single-buffer GEMM (m97 structure), split epilogue ----------------
__global__ __launch_bounds__(256) void k_gemm_bf2(const unsigned short* __restrict__ A,
                                                  const unsigned short* __restrict__ Wt,
                                                  const float* __restrict__ bias,
                                                  unsigned short* __restrict__ xr2,
                                                  unsigned short* __restrict__ sres,
                                                  int M, int K) {
    constexpr int BM = 128;
    __shared__ __align__(16) unsigned short As[BM * 64];
    __shared__ __align__(16) unsigned short Bs[BM * 64];
    const int bm = blockIdx.y * BM, bn = blockIdx.x * BM;
    const int tid = threadIdx.x;
    const int lane = tid & 63;
    const int wbase = tid & ~63;
    const int wid = tid >> 6;
    const int wr = (wid >> 1) * 64;
    const int wc = (wid & 1) * 64;
    const int lr = lane & 15, lq = lane >> 4;

    f4_t acc[4][4] = {};

    for (int k0 = 0; k0 < K; k0 += 64) {
        #pragma unroll
        for (int i = 0; i < 4; i++) {
            int gid2 = i * 256 + tid;
            int r = gid2 >> 3, g = gid2 & 7;
            const unsigned short* srcA = A + (size_t)(bm + r) * K + k0 + ((g ^ (r & 7)) * 8);
            __builtin_amdgcn_global_load_lds((cgu32*)srcA,
                (lu32*)&As[(i * 256 + wbase) * 8], 16, 0, 0);
            const unsigned short* srcB = Wt + (size_t)(bn + r) * K + k0 + ((g ^ (r & 7)) * 8);
            __builtin_amdgcn_global_load_lds((cgu32*)srcB,
                (lu32*)&Bs[(i * 256 + wbase) * 8], 16, 0, 0);
        }
        __syncthreads();
        #pragma unroll
        for (int h = 0; h < 2; h++) {
            bf8_t af[4], bfr[4];
            #pragma unroll
            for (int mb = 0; mb < 4; mb++) {
                int row = wr + mb * 16 + lr;
                int g = h * 4 + lq;
                af[mb] = *(const bf8_t*)&As[row * 64 + ((g ^ (row & 7)) * 8)];
            }
            #pragma unroll
            for (int nb = 0; nb < 4; nb++) {
                int rn = wc + nb * 16 + lr;
                int g = h * 4 + lq;
                bfr[nb] = *(const bf8_t*)&Bs[rn * 64 + ((g ^ (rn & 7)) * 8)];
            }
            #pragma unroll
            for (int mb = 0; mb < 4; mb++)
                #pragma unroll
                for (int nb = 0; nb < 4; nb++)
                    acc[mb][nb] = __builtin_amdgcn_mfma_f32_16x16x32_bf16(af[mb], bfr[nb], acc[mb][nb], 0, 0, 0);
        }
        __syncthreads();
    }

    #pragma unroll
    for (int mb = 0; mb < 4; mb++) {
        #pragma unroll
        for (int nb = 0; nb < 4; nb++) {
            int col = bn + wc + nb * 16 + lr;
            float bv = bias[col];
            #pragma unroll
            for (int q = 0; q < 4; q++) {
                int row = bm + wr + mb * 16 + lq * 4 + q;
                if (row < M) {
                    float v = acc[mb][nb][q] + bv;
                    if (col < DIq) xr2[(size_t)row * DIq + col] = f2bf(v);
                    else           sres[(size_t)row * DIq + (col - DIq)] = f2bf(v * fast_sig(v));
                }
            }
        }
    }
}

// ---------------- dt GEMM (K=48) + fast softplus; reads dbc128 directly ----------------
static constexpr int DT_RPB = 4;
__global__ __launch_bounds__(384) void k_dtred(const float* __restrict__ dbc128, const float* __restrict__ W,
                                               const float* __restrict__ bias, float* __restrict__ de) {
    int r0 = blockIdx.x * DT_RPB;
    int tid = threadIdx.x;
    __shared__ float ds[DT_RPB][48];
    if (tid < DT_RPB * 48) {
        int row = tid / 48, col = tid % 48;
        ds[row][col] = dbc128[(size_t)(r0 + row) * 128 + col];
    }
    __syncthreads();
    int j = tid * 4;
    float4 b = *(const float4*)(bias + j);
    float4 a0 = b, a1 = b, a2 = b, a3 = b;
    for (int k = 0; k < 48; k++) {
        float4 w = *(const float4*)(W + (size_t)k * 1536 + j);
        float d0 = ds[0][k], d1 = ds[1][k], d2 = ds[2][k], d3 = ds[3][k];
        a0.x = fmaf(d0, w.x, a0.x); a0.y = fmaf(d0, w.y, a0.y); a0.z = fmaf(d0, w.z, a0.z); a0.w = fmaf(d0, w.w, a0.w);
        a1.x = fmaf(d1, w.x, a1.x); a1.y = fmaf(d1, w.y, a1.y); a1.z = fmaf(d1, w.z, a1.z); a1.w = fmaf(d1, w.w, a1.w);
        a2.x = fmaf(d2, w.x, a2.x); a2.y = fmaf(d2, w.y, a2.y); a2.z = fmaf(d2, w.z, a2.z); a2.w = fmaf(d2, w.w, a2.w);
        a3.x = fmaf(d3, w.x, a3.x); a3.y = fmaf(d3, w.y, a3.y); a3.z = fmaf(d3, w.z, a3.z); a3.w = fmaf(d3, w.w, a3.w);
    }
    float4 o;
    o.x = fast_softplus(a0.x); o.y = fast_softplus(a0.y); o.z = fast_softplus(a0.z); o.w = fast_softplus(a0.w);
    *(float4*)(de + (size_t)(r0 + 0) * 1536 + j) = o;
    o.x = fast_softplus(a1.x); o.y = fast_softplus(a1.y); o.z = fast_softplus(a1.z); o.w = fast_softplus(a1.w);
    *(float4*)(de + (size_t)(r0 + 1) * 1536 + j) = o;
    o.x = fast_softplus(a2.x); o.y = fast_softplus(a2.y); o.z = fast_softplus(a2.z); o.w = fast_softplus(a2.w);
    *(float4*)(de + (size_t)(r0 + 2) * 1536 + j) = o;
    o.x = fast_softplus(a3.x); o.y = fast_softplus(a3.y); o.z = fast_softplus(a3.z); o.w = fast_softplus(a3.w);
    *(float4*)(de + (size_t)(r0 + 3) * 1536 + j) = o;
}

// ---------------- causal depthwise conv (DC=4) + silu, bf16 in/out ----------------
__global__ __launch_bounds__(256) void k_conv_silu(const unsigned short* __restrict__ xr2, const float* __restrict__ cw,
                                                   const float* __restrict__ cb, unsigned short* __restrict__ xi2b) {
    int idx4 = blockIdx.x * 256 + threadIdx.x;
    if (idx4 >= ROWS * DIq / 4) return;
    int d4 = (idx4 % (DIq / 4)) * 4;
    int bt = idx4 / (DIq / 4);
    int t = bt % NPq, b = bt / NPq;
    const unsigned short* base = xr2 + (size_t)b * NPq * DIq + d4;
    float4 s = *(const float4*)(cb + d4);
    float4 w0 = *(const float4*)(cw + (d4 + 0) * 4);
    float4 w1 = *(const float4*)(cw + (d4 + 1) * 4);
    float4 w2 = *(const float4*)(cw + (d4 + 2) * 4);
    float4 w3 = *(const float4*)(cw + (d4 + 3) * 4);
    if (t >= 3) {
        ushort4 v = *(const ushort4*)(base + (size_t)(t - 3) * DIq);
        s.x = fmaf(bf2f(v.x), w0.x, s.x); s.y = fmaf(bf2f(v.y), w1.x, s.y);
        s.z = fmaf(bf2f(v.z), w2.x, s.z); s.w = fmaf(bf2f(v.w), w3.x, s.w);
    }
    if (t >= 2) {
        ushort4 v = *(const ushort4*)(base + (size_t)(t - 2) * DIq);
        s.x = fmaf(bf2f(v.x), w0.y, s.x); s.y = fmaf(bf2f(v.y), w1.y, s.y);
        s.z = fmaf(bf2f(v.z), w2.y, s.z); s.w = fmaf(bf2f(v.w), w3.y, s.w);
    }
    if (t >= 1) {
        ushort4 v = *(const ushort4*)(base + (size_t)(t - 1) * DIq);
        s.x = fmaf(bf2f(v.x), w0.z, s.x); s.y = fmaf(bf2f(v.y), w1.z, s.y);
        s.z = fmaf(bf2f(v.z), w2.z, s.z); s.w = fmaf(bf2f(v.w), w3.z, s.w);
    }
    {
        ushort4 v = *(const ushort4*)(base + (size_t)t * DIq);
        s.x = fmaf(bf2f(v.x), w0.w, s.x); s.y = fmaf(bf2f(v.y), w1.w, s.y);
        s.z = fmaf(bf2f(v.z), w2.w, s.z); s.w = fmaf(bf2f(v.w), w3.w, s.w);
    }
    ushort4 xo;
    xo.x = f2bf(s.x * fast_sig(s.x)); xo.y = f2bf(s.y * fast_sig(s.y));
    xo.z = f2bf(s.z * fast_sig(s.z)); xo.w = f2bf(s.w * fast_sig(s.w));
    *(ushort4*)(xi2b + (size_t)bt * DIq + d4) = xo;
}

// ---------------- selective-scan, LDS double-buffered, packed b64 sdu, exp2 ----------------
static constexpr int STB = 28;

__global__ __launch_bounds__(256) void k_scan(const float* __restrict__ delta, const unsigned short* __restrict__ xi2b,
                                              const float* __restrict__ dbc128, const unsigned short* __restrict__ sresb,
                                              const float* __restrict__ Alog, const float* __restrict__ Dv,
                                              unsigned short* __restrict__ ys) {
    const int b = blockIdx.x;
    const int d0 = blockIdx.y * 32;
    const int tid = threadIdx.x;
    const int dl = tid >> 3;
    const int np = tid & 7;
    const int d = d0 + dl;
    const float A0p = -__expf(Alog[d * 16 + np]) * 1.44269504089f;
    const float A1p = -__expf(Alog[d * 16 + np + 8]) * 1.44269504089f;
    const float Dd = Dv[d];
    const int tr = tid >> 5;
    const int dls = tid & 31;

    __shared__ float2 sdu[2][STB][32];
    __shared__ float sbc[2][STB][32];

    const float* gde = delta + ((size_t)b * NPq + tr) * DIq + d0 + dls;
    const unsigned short* gu  = xi2b  + ((size_t)b * NPq + tr) * DIq + d0 + dls;
    const unsigned short* gsr = sresb + ((size_t)b * NPq + tr) * DIq + d0 + dls;
    const float* gbc = dbc128 + ((size_t)b * NPq + tr) * 128 + 48 + dls;
    unsigned short* gy = ys + (size_t)b * NPq * DIq + d;

    float rde[4], rbc[4];
    unsigned short ruu[4], rss[4];

    auto stageLoad = [&](int c) {
        const int t0 = c * STB;
        #pragma unroll
        for (int j = 0; j < 3; j++) {
            int off = (t0 + 8 * j) * DIq;
            rde[j] = gde[off];
            ruu[j] = gu[off];
            rss[j] = gsr[off];
            rbc[j] = gbc[(t0 + 8 * j) * 128];
        }
        if (tid < 128) {
            int off = (t0 + 24) * DIq;
            rde[3] = gde[off];
            ruu[3] = gu[off];
            rss[3] = gsr[off];
            rbc[3] = gbc[(t0 + 24) * 128];
        }
    };
    auto stageWrite = [&](int buf) {
        const int pi = (dls & 7) * 4 + (dls >> 3);
        #pragma unroll
        for (int j = 0; j < 3; j++) {
            int t = tr + 8 * j;
            unsigned pk = ((unsigned)ruu[j] << 16) | rss[j];
            sdu[buf][t][dls] = make_float2(rde[j], __builtin_bit_cast(float, pk));
            sbc[buf][t][pi] = rbc[j];
        }
        if (tid < 128) {
            int t = tr + 24;
            unsigned pk = ((unsigned)ruu[3] << 16) | rss[3];
            sdu[buf][t][dls] = make_float2(rde[3], __builtin_bit_cast(float, pk));
            sbc[buf][t][pi] = rbc[3];
        }
    };

    stageLoad(0);
    stageWrite(0);
    __syncthreads();

    float h0 = 0.f, h1 = 0.f;
    int cur = 0;
    for (int c = 0; c < 7; c++) {
        if (c < 6) stageLoad(c + 1);
        #pragma unroll 4
        for (int t = 0; t < STB; t++) {
            float2 duv = sdu[cur][t][dl];
            float4 bc = *(const float4*)&sbc[cur][t][np * 4];
            unsigned bits = __builtin_bit_cast(unsigned, duv.y);
            float u  = __builtin_bit_cast(float, bits & 0xFFFF0000u);
            float sr = __builtin_bit_cast(float, bits << 16);
            float a0 = exp2f(duv.x * A0p), a1 = exp2f(duv.x * A1p);
            float deu = duv.x * u;
            h0 = fmaf(a0, h0, deu * bc.x);
            h1 = fmaf(a1, h1, deu * bc.y);
            float p = fmaf(h1, bc.w, h0 * bc.z);
            p = dpp_add<0xB1>(p);
            p = dpp_add<0x4E>(p);
            p = dpp_add<0x141>(p);
            if (np == 0) gy[(size_t)(c * STB + t) * DIq] = f2bf(fmaf(Dd, u, p) * sr);
        }
        if (c < 6) stageWrite(cur ^ 1);
        __syncthreads();
        cur ^= 1;
    }
}

// ---------------- row LayerNorm (1024) + exact gelu; out f32 or bf16 ----------------
template<bool OBF>
__global__ __launch_bounds__(256) void k_ln_gelu(const float* __restrict__ in, const float* __restrict__ g,
                                                 const float* __restrict__ bt, void* __restrict__ outv) {
    int row = blockIdx.x;
    const float* x = in + (size_t)row * OUTq;
    float4 v = ((const float4*)x)[threadIdx.x];
    float s = v.x + v.y + v.z + v.w;
    float ss = v.x * v.x + v.y * v.y + v.z * v.z + v.w * v.w;
    #pragma unroll
    for (int off = 32; off >= 1; off >>= 1) { s += __shfl_down(s, off); ss += __shfl_down(ss, off); }
    __shared__ float sh[10];
    int wid = threadIdx.x >> 6, lid = threadIdx.x & 63;
    if (lid == 0) { sh[wid] = s; sh[4 + wid] = ss; }
    __syncthreads();
    if (threadIdx.x == 0) {
        float S = sh[0] + sh[1] + sh[2] + sh[3], SS = sh[4] + sh[5] + sh[6] + sh[7];
        float m = S * (1.f / OUTq);
        float var = SS * (1.f / OUTq) - m * m;
        sh[8] = m; sh[9] = rsqrtf(var + 1e-5f);
    }
    __syncthreads();
    float m = sh[8], rst = sh[9];
    float4 gv = ((const float4*)g)[threadIdx.x];
    float4 bv = ((const float4*)bt)[threadIdx.x];
    float4 o;
    float y0 = (v.x - m) * rst * gv.x + bv.x; o.x = 0.5f * y0 * (1.f + erff(y0 * 0.70710678118f));
    float y1 = (v.y - m) * rst * gv.y + bv.y; o.y = 0.5f * y1 * (1.f + erff(y1 * 0.70710678118f));
    float y2 = (v.z - m) * rst * gv.z + bv.z; o.z = 0.5f * y2 * (1.f + erff(y2 * 0.70710678118f));
    float y3 = (v.w - m) * rst * gv.w + bv.w; o.w = 0.5f * y3 * (1.f + erff(y3 * 0.70710678118f));
    if (OBF) {
        ushort4 o4;
        o4.x = f2bf(o.x); o4.y = f2bf(o.y); o4.z = f2bf(o.z); o4.w = f2bf(o.w);
        ((ushort4*)((unsigned short*)outv + (size_t)row * OUTq))[threadIdx.x] = o4;
    } else {
        ((float4*)((float*)outv + (size_t)row * OUTq))[threadIdx.x] = o;
    }
}

// ---------------- column softmax + pool, 4-way t-split ----------------
__global__ __launch_bounds__(256) void k_softpool(const float* __restrict__ gm, const unsigned short* __restrict__ ym,
                                                  float* __restrict__ pooled) {
    int b = blockIdx.y;
    int jl = threadIdx.x & 63;
    int j = blockIdx.x * 64 + jl;
    int tc = threadIdx.x >> 6;
    const float* gb = gm + (size_t)b * NPq * OUTq + j;
    const unsigned short* yb = ym + (size_t)b * NPq * OUTq + j;
    int t0 = tc * 49;
    float m = -1e30f, s = 0.f, ps = 0.f;
    for (int t = t0; t < t0 + 49; t++) {
        float g = gb[(size_t)t * OUTq];
        float y = bf2f(yb[(size_t)t * OUTq]);
        float mn = fmaxf(m, g);
        float sc = __expf(m - mn);
        float e = __expf(g - mn);
        s = fmaf(s, sc, e);
        ps = fmaf(ps, sc, y * e);
        m = mn;
    }
    __shared__ float sm[4][64], ssum[4][64], sps[4][64];
    sm[tc][jl] = m; ssum[tc][jl] = s; sps[tc][jl] = ps;
    __syncthreads();
    if (tc == 0) {
        float m0 = sm[0][jl], m1 = sm[1][jl], m2 = sm[2][jl], m3 = sm[3][jl];
        float mt = fmaxf(fmaxf(m0, m1), fmaxf(m2, m3));
        float e0 = __expf(m0 - mt), e1 = __expf(m1 - mt);
        float e2 = __expf(m2 - mt), e3 = __expf(m3 - mt);
        float st = ssum[0][jl] * e0 + ssum[1][jl] * e1 + ssum[2][jl] * e2 + ssum[3][jl] * e3;
        float pt = sps[0][jl] * e0 + sps[1][jl] * e1 + sps[2][jl] * e2 + sps[3][jl] * e3;
        pooled[b * OUTq + j] = pt / st;
    }
}

// ---------------- final LayerNorm ----------------
__global__ __launch_bounds__(256) void k_final_ln(const float* __restrict__ p, const float* __restrict__ g,
                                                  const float* __restrict__ bt, float* __restrict__ out) {
    int row = blockIdx.x;
    const float* x = p + (size_t)row * OUTq;
    float4 v = ((const float4*)x)[threadIdx.x];
    float s = v.x + v.y + v.z + v.w;
    float ss = v.x * v.x + v.y * v.y + v.z * v.z + v.w * v.w;
    #pragma unroll
    for (int off = 32; off >= 1; off >>= 1) { s += __shfl_down(s, off); ss += __shfl_down(ss, off); }
    __shared__ float sh[10];
    int wid = threadIdx.x >> 6, lid = threadIdx.x & 63;
    if (lid == 0) { sh[wid] = s; sh[4 + wid] = ss; }
    __syncthreads();
    if (threadIdx.x == 0) {
        float S = sh[0] + sh[1] + sh[2] + sh[3], SS = sh[4] + sh[5] + sh[6] + sh[7];
        float m = S * (1.f / OUTq);
        float var = SS * (1.f / OUTq) - m * m;
        sh[8] = m; sh[9] = rsqrtf(var + 1e-5f);
    }
    __syncthreads();
    float m = sh[8], rst = sh[9];
    float4 gv = ((const float4*)g)[threadIdx.x];
    float4 bv = ((const float4*)bt)[threadIdx.x];
    float4 o;
    o.x = (v.x - m) * rst * gv.x + bv.x;
    o.y = (v.y - m) * rst * gv.y + bv.y;
    o.z = (v.z - m) * rst * gv.z + bv.z;
    o.w = (v.w - m) * rst * gv.w + bv.w;
    ((float4*)(out + (size_t)row * OUTq))[threadIdx.x] = o;
}

extern "C" void kernel_launch(void* const* d_in, const int* in_sizes, int n_in,
                              void* d_out, int out_size, void* d_ws, size_t ws_size,
                              hipStream_t stream) {
    const float* img   = (const float*)d_in[0];
    const float* sa_w  = (const float*)d_in[1];
    const float* pe_w  = (const float*)d_in[2];
    const float* pe_b  = (const float*)d_in[3];
    const float* pos   = (const float*)d_in[4];
    const float* in_w  = (const float*)d_in[5];
    const float* in_b  = (const float*)d_in[6];
    const float* cv_w  = (const float*)d_in[7];
    const float* cv_b  = (const float*)d_in[8];
    const float* xp_w  = (const float*)d_in[9];
    const float* dt_w  = (const float*)d_in[10];
    const float* dt_b  = (const float*)d_in[11];
    const float* Alog  = (const float*)d_in[12];
    const float* Dv    = (const float*)d_in[13];
    const float* ot_w  = (const float*)d_in[14];
    const float* ot_b  = (const float*)d_in[15];
    const float* em_w  = (const float*)d_in[16];
    const float* em_b  = (const float*)d_in[17];
    const float* em_g  = (const float*)d_in[18];
    const float* em_bt = (const float*)d_in[19];
    const float* at_w  = (const float*)d_in[20];
    const float* at_b  = (const float*)d_in[21];
    const float* at_g  = (const float*)d_in[22];
    const float* at_bt = (const float*)d_in[23];
    const float* la_g  = (const float*)d_in[24];
    const float* la_bt = (const float*)d_in[25];

    char* ws = (char*)d_ws;
    auto al = [](size_t x) { return (x + 255) & ~(size_t)255; };
    size_t SZ_am   = (size_t)NB * 2 * IMP * 4;
    size_t SZ_G    = (size_t)MPAD * 768 * 2;
    size_t SZ_x    = (size_t)MPAD * 768 * 2;
    size_t SZ_xr2  = (size_t)ROWS * DIq * 2;
    size_t SZ_xi2  = (size_t)ROWS * DIq * 2;
    size_t SZ_de   = (size_t)ROWS * DIq * 4;
    size_t SZ_dbc  = (size_t)MPAD * 128 * 4;          // f32 [MPAD][128]
    size_t SZ_ys   = (size_t)MPAD * DIq * 2;
    size_t SZ_sres = (size_t)ROWS * DIq * 2;
    size_t SZ_yem  = (size_t)MPAD * 1024 * 2;
    size_t SZ_pool = (size_t)NB * OUTq * 4;

    size_t o_am   = 0;
    size_t o_G    = al(o_am + SZ_am);
    size_t o_x    = al(o_G + SZ_G);
    size_t o_xr2  = al(o_x + SZ_x);
    size_t o_xi2  = al(o_xr2 + SZ_xr2);
    size_t o_de   = al(o_xi2 + SZ_xi2);
    size_t o_dbc  = al(o_de + SZ_de);
    size_t o_ys   = al(o_dbc + SZ_dbc);
    size_t o_sres = al(o_ys + SZ_ys);
    size_t o_yem  = al(o_sres + SZ_sres);
    size_t o_pool = al(o_yem + SZ_yem);

    size_t o_wpe  = al(o_pool + SZ_pool);
    size_t o_win0 = al(o_wpe  + (size_t)768 * 768 * 2);
    size_t o_win1 = al(o_win0 + (size_t)3072 * 768 * 2);
    size_t o_wot0 = al(o_win1 + (size_t)3072 * 768 * 2);
    size_t o_wot1 = al(o_wot0 + (size_t)768 * 1536 * 2);
    size_t o_wem  = al(o_wot1 + (size_t)768 * 1536 * 2);
    size_t o_wat  = al(o_wem  + (size_t)1024 * 768 * 2);
    size_t o_xpt  = al(o_wat  + (size_t)1024 * 1024 * 2);

    float* am    = (float*)(ws + o_am);
    unsigned short* G   = (unsigned short*)(ws + o_G);
    unsigned short* x   = (unsigned short*)(ws + o_x);
    unsigned short* xr2 = (unsigned short*)(ws + o_xr2);
    unsigned short* xi2b = (unsigned short*)(ws + o_xi2);
    float* de    = (float*)(ws + o_de);
    float* dbc128 = (float*)(ws + o_dbc);
    unsigned short* ys = (unsigned short*)(ws + o_ys);
    unsigned short* sresb = (unsigned short*)(ws + o_sres);
    unsigned short* yem = (unsigned short*)(ws + o_yem);
    float* pool  = (float*)(ws + o_pool);
    unsigned short* wpe  = (unsigned short*)(ws + o_wpe);
    unsigned short* win0 = (unsigned short*)(ws + o_win0);
    unsigned short* win1 = (unsigned short*)(ws + o_win1);
    unsigned short* wot0 = (unsigned short*)(ws + o_wot0);
    unsigned short* wot1 = (unsigned short*)(ws + o_wot1);
    unsigned short* wem  = (unsigned short*)(ws + o_wem);
    unsigned short* wat  = (unsigned short*)(ws + o_wat);
    unsigned short* xpt  = (unsigned short*)(ws + o_xpt);
    // head-phase overlays
    float* t1  = (float*)(ws + o_de);
    float* t2  = (float*)(ws + o_xr2);
    float* gat = (float*)(ws + o_ys);

    k_transpose_all<<<9280, 256, 0, stream>>>(pe_w, in_w, ot_w, em_w, at_w,
                                              wpe, win0, win1, wot0, wot1, wem, wat);
    k_xpw_t<<<(2 * 128 * 1536 + 255) / 256, 256, 0, stream>>>(xp_w, xpt);

    int nq = NB * IMP / 4;
    k_avgmax<<<(nq + 255) / 256, 256, 0, stream>>>(img, am);
    k_gatepatch<<<(nq + 255) / 256, 256, 0, stream>>>(img, am, sa_w, G);

    dim3 blk(256);
    k_gemm_bf<EPI_POSEMB, true><<<dim3(12, 25), blk, 0, stream>>>(G, wpe, pe_b, x, 768, ROWS, 768, 768, pos);

    for (int l = 0; l < 2; l++) {
        const unsigned short* win = l ? win1 : win0;
        const unsigned short* wot = l ? wot1 : wot0;
        k_gemm_bf2<<<dim3(24, 25), blk, 0, stream>>>(x, win, in_b + l * 3072, xr2, sresb, ROWS, 768);
        int nc4 = ROWS * DIq / 4;
        k_conv_silu<<<(nc4 + 255) / 256, 256, 0, stream>>>(xr2, cv_w + (size_t)l * DIq * 4, cv_b + l * DIq, xi2b);
        // dbc128(f32) = xi2b @ xpt^T  (N=128, cols 80..127 = 0 by construction)
        k_gemm_bf<EPI_NONE, false><<<dim3(2, 25), blk, 0, stream>>>(xi2b, xpt + (size_t)l * 128 * 1536,
                                                                    nullptr, dbc128, 128, ROWS, 128, 1536, nullptr);
        k_dtred<<<ROWS / DT_RPB, 384, 0, stream>>>(dbc128, dt_w + (size_t)l * 48 * 1536, dt_b + l * 1536, de);
        k_scan<<<dim3(16, 48), blk, 0, stream>>>(de, xi2b, dbc128, sresb, Alog + (size_t)l * 1536 * 16,
                                                 Dv + l * 1536, ys);
        k_gemm_bf<EPI_NONE, true><<<dim3(12, 25), blk, 0, stream>>>(ys, wot, ot_b + l * 768, x, 768,
                                                                    ROWS, 768, 1536, nullptr);
    }

    // head
    k_gemm_bf<EPI_NONE, false><<<dim3(16, 25), blk, 0, stream>>>(x, wem, em_b, t1, 1024, ROWS, 1024, 768, nullptr);
    k_ln_gelu<true><<<ROWS, 256, 0, stream>>>(t1, em_g, em_bt, yem);
    k_gemm_bf<EPI_NONE, false><<<dim3(16, 25), blk, 0, stream>>>(yem, wat, at_b, t2, 1024, ROWS, 1024, 1024, nullptr);
    k_ln_gelu<false><<<ROWS, 256, 0, stream>>>(t2, at_g, at_bt, gat);
    k_softpool<<<dim3(16, NB), 256, 0, stream>>>(gat, yem, pool);
    k_final_ln<<<NB, 256, 0, stream>>>(pool, la_g, la_bt, (float*)d_out);
}

// Round 13
// 405.380 us; speedup vs baseline: 6.1506x; 1.0419x over previous
//
#include <hip/hip_runtime.h>
#include <math.h>

static constexpr int NB = 16;
static constexpr int NC = 3;
static constexpr int IM = 224;
static constexpr int IMP = IM * IM;      // 50176
static constexpr int HPq = 14;
static constexpr int NPq = 196;
static constexpr int OUTq = 1024;
static constexpr int DIq = 1536;
static constexpr int ROWS = NB * NPq;    // 3136
static constexpr int MPAD = 3200;        // 25*128, GEMM A-operand row padding

typedef __bf16 bf8_t __attribute__((ext_vector_type(8)));
typedef float f4_t __attribute__((ext_vector_type(4)));
typedef unsigned short us8 __attribute__((ext_vector_type(8)));
typedef const __attribute__((address_space(1))) unsigned int cgu32;
typedef __attribute__((address_space(3))) unsigned int lu32;

__device__ inline unsigned short f2bf(float x) {
    unsigned u = __builtin_bit_cast(unsigned, x);
    unsigned r = (u + 0x7FFFu + ((u >> 16) & 1u)) >> 16;
    return (unsigned short)r;
}
__device__ inline float bf2f(unsigned short v) {
    return __builtin_bit_cast(float, (unsigned)v << 16);
}
__device__ inline float fast_sig(float x) {
    return __builtin_amdgcn_rcpf(1.f + __expf(-x));
}
__device__ inline float fast_softplus(float v) {
    return fmaxf(v, 0.f) + __logf(1.f + __expf(-fabsf(v)));
}

template<int CTRL>
__device__ inline float dpp_add(float x) {
    int v = __builtin_amdgcn_update_dpp(0, __builtin_bit_cast(int, x), CTRL, 0xF, 0xF, true);
    return x + __builtin_bit_cast(float, v);
}

// ---------------- K1a: channel avg/max ----------------
__global__ __launch_bounds__(256) void k_avgmax(const float* __restrict__ img, float* __restrict__ am) {
    int idx = blockIdx.x * 256 + threadIdx.x;
    if (idx >= NB * IMP / 4) return;
    int p4 = (idx % (IMP / 4)) * 4, b = idx / (IMP / 4);
    const float* ib = img + (size_t)b * NC * IMP + p4;
    float4 c0 = *(const float4*)ib;
    float4 c1 = *(const float4*)(ib + IMP);
    float4 c2 = *(const float4*)(ib + 2 * IMP);
    float4 av, mx;
    av.x = (c0.x + c1.x + c2.x) * (1.f / 3.f); mx.x = fmaxf(c0.x, fmaxf(c1.x, c2.x));
    av.y = (c0.y + c1.y + c2.y) * (1.f / 3.f); mx.y = fmaxf(c0.y, fmaxf(c1.y, c2.y));
    av.z = (c0.z + c1.z + c2.z) * (1.f / 3.f); mx.z = fmaxf(c0.z, fmaxf(c1.z, c2.z));
    av.w = (c0.w + c1.w + c2.w) * (1.f / 3.f); mx.w = fmaxf(c0.w, fmaxf(c1.w, c2.w));
    *(float4*)(am + (size_t)(b * 2 + 0) * IMP + p4) = av;
    *(float4*)(am + (size_t)(b * 2 + 1) * IMP + p4) = mx;
}

// ---------------- K1b: 7x7 conv gate + patchify ----------------
__global__ __launch_bounds__(256) void k_gatepatch(const float* __restrict__ img, const float* __restrict__ am,
                                                   const float* __restrict__ saw, unsigned short* __restrict__ G) {
    int quad = blockIdx.x * 256 + threadIdx.x;
    if (quad >= NB * IMP / 4) return;
    int pq = quad % (IMP / 4), b = quad / (IMP / 4);
    int x0 = (pq % 56) * 4;
    int y = pq / 56;
    float acc0 = 0.f, acc1 = 0.f, acc2 = 0.f, acc3 = 0.f;
    const bool lok = (x0 >= 4), rok = (x0 <= IM - 8);
    #pragma unroll
    for (int ci = 0; ci < 2; ci++) {
        const float* amc = am + (size_t)(b * 2 + ci) * IMP;
        const float* wc = saw + ci * 49;
        #pragma unroll
        for (int kh = 0; kh < 7; kh++) {
            int yy = y + kh - 3;
            if (yy < 0 || yy >= IM) continue;
            const float* rowp = amc + yy * IM;
            float4 lv = lok ? *(const float4*)(rowp + x0 - 4) : make_float4(0.f, 0.f, 0.f, 0.f);
            float4 mv = *(const float4*)(rowp + x0);
            float4 rv = rok ? *(const float4*)(rowp + x0 + 4) : make_float4(0.f, 0.f, 0.f, 0.f);
            float f[12] = {lv.x, lv.y, lv.z, lv.w, mv.x, mv.y, mv.z, mv.w, rv.x, rv.y, rv.z, rv.w};
            #pragma unroll
            for (int kw = 0; kw < 7; kw++) {
                float w = wc[kh * 7 + kw];
                acc0 = fmaf(w, f[kw + 1], acc0);
                acc1 = fmaf(w, f[kw + 2], acc1);
                acc2 = fmaf(w, f[kw + 3], acc2);
                acc3 = fmaf(w, f[kw + 4], acc3);
            }
        }
    }
    float s0 = fast_sig(acc0), s1 = fast_sig(acc1), s2 = fast_sig(acc2), s3 = fast_sig(acc3);
    const float* ib = img + (size_t)b * NC * IMP + y * IM + x0;
    float4 c0 = *(const float4*)ib;
    float4 c1 = *(const float4*)(ib + IMP);
    float4 c2 = *(const float4*)(ib + 2 * IMP);
    int hy = y >> 4, py = y & 15, hx = x0 >> 4, px0 = x0 & 15;
    size_t base = ((size_t)(b * NPq + hy * HPq + hx) * 768) + (size_t)(py * 16 + px0) * 3;
    ushort4 o0, o1, o2;
    o0.x = f2bf(c0.x * s0); o0.y = f2bf(c1.x * s0); o0.z = f2bf(c2.x * s0);
    o0.w = f2bf(c0.y * s1);
    o1.x = f2bf(c1.y * s1); o1.y = f2bf(c2.y * s1);
    o1.z = f2bf(c0.z * s2); o1.w = f2bf(c1.z * s2);
    o2.x = f2bf(c2.z * s2);
    o2.y = f2bf(c0.w * s3); o2.z = f2bf(c1.w * s3); o2.w = f2bf(c2.w * s3);
    *(ushort4*)(G + base + 0) = o0;
    *(ushort4*)(G + base + 4) = o1;
    *(ushort4*)(G + base + 8) = o2;
}

// ---------------- all weight transposes in ONE launch ----------------
__global__ __launch_bounds__(256) void k_transpose_all(const float* pe_w, const float* in_w, const float* ot_w,
                                                       const float* em_w, const float* at_w,
                                                       unsigned short* wpe, unsigned short* win0, unsigned short* win1,
                                                       unsigned short* wot0, unsigned short* wot1,
                                                       unsigned short* wem, unsigned short* wat) {
    int bid = blockIdx.x;
    const float* W; unsigned short* Wt; int K, N, local;
    if (bid < 576)       { W = pe_w; Wt = wpe; K = 768; N = 768; local = bid; }
    else if (bid < 2880) { W = in_w; Wt = win0; K = 768; N = 3072; local = bid - 576; }
    else if (bid < 5184) { W = in_w + (size_t)768 * 3072; Wt = win1; K = 768; N = 3072; local = bid - 2880; }
    else if (bid < 6336) { W = ot_w; Wt = wot0; K = 1536; N = 768; local = bid - 5184; }
    else if (bid < 7488) { W = ot_w + (size_t)1536 * 768; Wt = wot1; K = 1536; N = 768; local = bid - 6336; }
    else if (bid < 8256) { W = em_w; Wt = wem; K = 768; N = 1024; local = bid - 7488; }
    else                 { W = at_w; Wt = wat; K = 1024; N = 1024; local = bid - 8256; }
    int gx = N / 32;
    int n0 = (local % gx) * 32, k0 = (local / gx) * 32;
    __shared__ float t[32][33];
    int c = threadIdx.x & 31, r8 = threadIdx.x >> 5;
    #pragma unroll
    for (int i = 0; i < 4; i++) {
        int r = r8 + i * 8;
        t[r][c] = W[(size_t)(k0 + r) * N + n0 + c];
    }
    __syncthreads();
    #pragma unroll
    for (int i = 0; i < 4; i++) {
        int r = r8 + i * 8;
        Wt[(size_t)(n0 + r) * K + k0 + c] = f2bf(t[c][r]);
    }
}

// ---------------- xproj weight: f32 [l][1536][80] -> bf16 [l][128][1536], zero-padded ----------------
__global__ __launch_bounds__(256) void k_xpw_t(const float* __restrict__ xp_w, unsigned short* __restrict__ xpt) {
    int idx = blockIdx.x * 256 + threadIdx.x;
    if (idx >= 2 * 128 * 1536) return;
    int k = idx % 1536;
    int n = (idx / 1536) % 128;
    int l = idx / (1536 * 128);
    unsigned short v = 0;
    if (n < 80) v = f2bf(xp_w[(size_t)l * 1536 * 80 + (size_t)k * 80 + n]);
    xpt[idx] = v;
}

// ---------------- bf16 MFMA GEMM, BN=64 double-buffered (general shapes) ----------------
enum { EPI_NONE = 0, EPI_POSEMB = 1 };

template<int EPI, bool CBF>
__global__ __launch_bounds__(256) void k_gemm_bf(const unsigned short* __restrict__ A,
                                                 const unsigned short* __restrict__ Wt,
                                                 const float* __restrict__ bias,
                                                 void* __restrict__ Cv, int ldc,
                                                 int M, int N, int K,
                                                 const float* __restrict__ extra) {
    constexpr int BM = 128, BN = 64;
    __shared__ __align__(16) unsigned short As[2][BM * 64];
    __shared__ __align__(16) unsigned short Bs[2][BN * 64];
    const int bm = blockIdx.y * BM, bn = blockIdx.x * BN;
    const int tid = threadIdx.x;
    const int lane = tid & 63;
    const int wbase = tid & ~63;
    const int wr = ((tid >> 7) & 1) * 64;
    const int wc = ((tid >> 6) & 1) * 32;
    const int lr = lane & 15, lq = lane >> 4;

    f4_t acc[4][2] = {};

    auto stage = [&](int buf, int k0) {
        #pragma unroll
        for (int i = 0; i < 4; i++) {
            int gid2 = i * 256 + tid;
            int r = gid2 >> 3, g = gid2 & 7;
            const unsigned short* src = A + (size_t)(bm + r) * K + k0 + ((g ^ (r & 7)) * 8);
            __builtin_amdgcn_global_load_lds((cgu32*)src,
                (lu32*)&As[buf][(i * 256 + wbase) * 8], 16, 0, 0);
        }
        #pragma unroll
        for (int i = 0; i < 2; i++) {
            int gid2 = i * 256 + tid;
            int r = gid2 >> 3, g = gid2 & 7;
            const unsigned short* src = Wt + (size_t)(bn + r) * K + k0 + ((g ^ (r & 7)) * 8);
            __builtin_amdgcn_global_load_lds((cgu32*)src,
                (lu32*)&Bs[buf][(i * 256 + wbase) * 8], 16, 0, 0);
        }
    };

    stage(0, 0);
    __syncthreads();
    int cur = 0;
    for (int k0 = 0; k0 < K; k0 += 64) {
        if (k0 + 64 < K) stage(cur ^ 1, k0 + 64);
        #pragma unroll
        for (int h = 0; h < 2; h++) {
            bf8_t af[4], bfr[2];
            #pragma unroll
            for (int mb = 0; mb < 4; mb++) {
                int row = wr + mb * 16 + lr;
                int g = h * 4 + lq;
                af[mb] = *(const bf8_t*)&As[cur][row * 64 + ((g ^ (row & 7)) * 8)];
            }
            #pragma unroll
            for (int nb = 0; nb < 2; nb++) {
                int rn = wc + nb * 16 + lr;
                int g = h * 4 + lq;
                bfr[nb] = *(const bf8_t*)&Bs[cur][rn * 64 + ((g ^ (rn & 7)) * 8)];
            }
            #pragma unroll
            for (int mb = 0; mb < 4; mb++)
                #pragma unroll
                for (int nb = 0; nb < 2; nb++)
                    acc[mb][nb] = __builtin_amdgcn_mfma_f32_16x16x32_bf16(af[mb], bfr[nb], acc[mb][nb], 0, 0, 0);
        }
        __syncthreads();
        cur ^= 1;
    }

    #pragma unroll
    for (int mb = 0; mb < 4; mb++) {
        #pragma unroll
        for (int nb = 0; nb < 2; nb++) {
            int col = bn + wc + nb * 16 + lr;
            #pragma unroll
            for (int q = 0; q < 4; q++) {
                int row = bm + wr + mb * 16 + lq * 4 + q;
                if (row < M) {
                    float v = acc[mb][nb][q];
                    if (bias) v += bias[col];
                    if (EPI == EPI_POSEMB) v += extra[(size_t)(row % NPq) * N + col];
                    if (CBF) ((unsigned short*)Cv)[(size_t)row * ldc + col] = f2bf(v);
                    else     ((float*)Cv)[(size_t)row * ldc + col] = v;
                }
            }
        }
    }
}

// ---------------- 128x128 single-buffer GEMM (m97 structure), split epilogue ----------------
__global__ __launch_bounds__(256) void k_gemm_bf2(const unsigned short* __restrict__ A,
                                                  const unsigned short* __restrict__ Wt,
                                                  const float* __restrict__ bias,
                                                  unsigned short* __restrict__ xr2,
                                                  unsigned short* __restrict__ sres,
                                                  int M, int K) {
    constexpr int BM = 128;
    __shared__ __align__(16) unsigned short As[BM * 64];
    __shared__ __align__(16) unsigned short Bs[BM * 64];
    const int bm = blockIdx.y * BM, bn = blockIdx.x * BM;
    const int tid = threadIdx.x;
    const int lane = tid & 63;
    const int wbase = tid & ~63;
    const int wid = tid >> 6;
    const int wr = (wid >> 1) * 64;
    const int wc = (wid & 1) * 64;
    const int lr = lane & 15, lq = lane >> 4;

    f4_t acc[4][4] = {};

    for (int k0 = 0; k0 < K; k0 += 64) {
        #pragma unroll
        for (int i = 0; i < 4; i++) {
            int gid2 = i * 256 + tid;
            int r = gid2 >> 3, g = gid2 & 7;
            const unsigned short* srcA = A + (size_t)(bm + r) * K + k0 + ((g ^ (r & 7)) * 8);
            __builtin_amdgcn_global_load_lds((cgu32*)srcA,
                (lu32*)&As[(i * 256 + wbase) * 8], 16, 0, 0);
            const unsigned short* srcB = Wt + (size_t)(bn + r) * K + k0 + ((g ^ (r & 7)) * 8);
            __builtin_amdgcn_global_load_lds((cgu32*)srcB,
                (lu32*)&Bs[(i * 256 + wbase) * 8], 16, 0, 0);
        }
        __syncthreads();
        #pragma unroll
        for (int h = 0; h < 2; h++) {
            bf8_t af[4], bfr[4];
            #pragma unroll
            for (int mb = 0; mb < 4; mb++) {
                int row = wr + mb * 16 + lr;
                int g = h * 4 + lq;
                af[mb] = *(const bf8_t*)&As[row * 64 + ((g ^ (row & 7)) * 8)];
            }
            #pragma unroll
            for (int nb = 0; nb < 4; nb++) {
                int rn = wc + nb * 16 + lr;
                int g = h * 4 + lq;
                bfr[nb] = *(const bf8_t*)&Bs[rn * 64 + ((g ^ (rn & 7)) * 8)];
            }
            #pragma unroll
            for (int mb = 0; mb < 4; mb++)
                #pragma unroll
                for (int nb = 0; nb < 4; nb++)
                    acc[mb][nb] = __builtin_amdgcn_mfma_f32_16x16x32_bf16(af[mb], bfr[nb], acc[mb][nb], 0, 0, 0);
        }
        __syncthreads();
    }

    #pragma unroll
    for (int mb = 0; mb < 4; mb++) {
        #pragma unroll
        for (int nb = 0; nb < 4; nb++) {
            int col = bn + wc + nb * 16 + lr;
            float bv = bias[col];
            #pragma unroll
            for (int q = 0; q < 4; q++) {
                int row = bm + wr + mb * 16 + lq * 4 + q;
                if (row < M) {
                    float v = acc[mb][nb][q] + bv;
                    if (col < DIq) xr2[(size_t)row * DIq + col] = f2bf(v);
                    else           sres[(size_t)row * DIq + (col - DIq)] = f2bf(v * fast_sig(v));
                }
            }
        }
    }
}

// ---------------- dt GEMM (K=48) + fast softplus; reads dbc128 directly ----------------
static constexpr int DT_RPB = 4;
__global__ __launch_bounds__(384) void k_dtred(const float* __restrict__ dbc128, const float* __restrict__ W,
                                               const float* __restrict__ bias, float* __restrict__ de) {
    int r0 = blockIdx.x * DT_RPB;
    int tid = threadIdx.x;
    __shared__ float ds[DT_RPB][48];
    if (tid < DT_RPB * 48) {
        int row = tid / 48, col = tid % 48;
        ds[row][col] = dbc128[(size_t)(r0 + row) * 128 + col];
    }
    __syncthreads();
    int j = tid * 4;
    float4 b = *(const float4*)(bias + j);
    float4 a0 = b, a1 = b, a2 = b, a3 = b;
    for (int k = 0; k < 48; k++) {
        float4 w = *(const float4*)(W + (size_t)k * 1536 + j);
        float d0 = ds[0][k], d1 = ds[1][k], d2 = ds[2][k], d3 = ds[3][k];
        a0.x = fmaf(d0, w.x, a0.x); a0.y = fmaf(d0, w.y, a0.y); a0.z = fmaf(d0, w.z, a0.z); a0.w = fmaf(d0, w.w, a0.w);
        a1.x = fmaf(d1, w.x, a1.x); a1.y = fmaf(d1, w.y, a1.y); a1.z = fmaf(d1, w.z, a1.z); a1.w = fmaf(d1, w.w, a1.w);
        a2.x = fmaf(d2, w.x, a2.x); a2.y = fmaf(d2, w.y, a2.y); a2.z = fmaf(d2, w.z, a2.z); a2.w = fmaf(d2, w.w, a2.w);
        a3.x = fmaf(d3, w.x, a3.x); a3.y = fmaf(d3, w.y, a3.y); a3.z = fmaf(d3, w.z, a3.z); a3.w = fmaf(d3, w.w, a3.w);
    }
    float4 o;
    o.x = fast_softplus(a0.x); o.y = fast_softplus(a0.y); o.z = fast_softplus(a0.z); o.w = fast_softplus(a0.w);
    *(float4*)(de + (size_t)(r0 + 0) * 1536 + j) = o;
    o.x = fast_softplus(a1.x); o.y = fast_softplus(a1.y); o.z = fast_softplus(a1.z); o.w = fast_softplus(a1.w);
    *(float4*)(de + (size_t)(r0 + 1) * 1536 + j) = o;
    o.x = fast_softplus(a2.x); o.y = fast_softplus(a2.y); o.z = fast_softplus(a2.z); o.w = fast_softplus(a2.w);
    *(float4*)(de + (size_t)(r0 + 2) * 1536 + j) = o;
    o.x = fast_softplus(a3.x); o.y = fast_softplus(a3.y); o.z = fast_softplus(a3.z); o.w = fast_softplus(a3.w);
    *(float4*)(de + (size_t)(r0 + 3) * 1536 + j) = o;
}

// ---------------- causal depthwise conv (DC=4) + silu, bf16 in/out ----------------
__global__ __launch_bounds__(256) void k_conv_silu(const unsigned short* __restrict__ xr2, const float* __restrict__ cw,
                                                   const float* __restrict__ cb, unsigned short* __restrict__ xi2b) {
    int idx4 = blockIdx.x * 256 + threadIdx.x;
    if (idx4 >= ROWS * DIq / 4) return;
    int d4 = (idx4 % (DIq / 4)) * 4;
    int bt = idx4 / (DIq / 4);
    int t = bt % NPq, b = bt / NPq;
    const unsigned short* base = xr2 + (size_t)b * NPq * DIq + d4;
    float4 s = *(const float4*)(cb + d4);
    float4 w0 = *(const float4*)(cw + (d4 + 0) * 4);
    float4 w1 = *(const float4*)(cw + (d4 + 1) * 4);
    float4 w2 = *(const float4*)(cw + (d4 + 2) * 4);
    float4 w3 = *(const float4*)(cw + (d4 + 3) * 4);
    if (t >= 3) {
        ushort4 v = *(const ushort4*)(base + (size_t)(t - 3) * DIq);
        s.x = fmaf(bf2f(v.x), w0.x, s.x); s.y = fmaf(bf2f(v.y), w1.x, s.y);
        s.z = fmaf(bf2f(v.z), w2.x, s.z); s.w = fmaf(bf2f(v.w), w3.x, s.w);
    }
    if (t >= 2) {
        ushort4 v = *(const ushort4*)(base + (size_t)(t - 2) * DIq);
        s.x = fmaf(bf2f(v.x), w0.y, s.x); s.y = fmaf(bf2f(v.y), w1.y, s.y);
        s.z = fmaf(bf2f(v.z), w2.y, s.z); s.w = fmaf(bf2f(v.w), w3.y, s.w);
    }
    if (t >= 1) {
        ushort4 v = *(const ushort4*)(base + (size_t)(t - 1) * DIq);
        s.x = fmaf(bf2f(v.x), w0.z, s.x); s.y = fmaf(bf2f(v.y), w1.z, s.y);
        s.z = fmaf(bf2f(v.z), w2.z, s.z); s.w = fmaf(bf2f(v.w), w3.z, s.w);
    }
    {
        ushort4 v = *(const ushort4*)(base + (size_t)t * DIq);
        s.x = fmaf(bf2f(v.x), w0.w, s.x); s.y = fmaf(bf2f(v.y), w1.w, s.y);
        s.z = fmaf(bf2f(v.z), w2.w, s.z); s.w = fmaf(bf2f(v.w), w3.w, s.w);
    }
    ushort4 xo;
    xo.x = f2bf(s.x * fast_sig(s.x)); xo.y = f2bf(s.y * fast_sig(s.y));
    xo.z = f2bf(s.z * fast_sig(s.z)); xo.w = f2bf(s.w * fast_sig(s.w));
    *(ushort4*)(xi2b + (size_t)bt * DIq + d4) = xo;
}

// ---------------- selective-scan, LDS double-buffered, packed b64 sdu, raw v_exp ----------------
static constexpr int STB = 28;

__global__ __launch_bounds__(256) void k_scan(const float* __restrict__ delta, const unsigned short* __restrict__ xi2b,
                                              const float* __restrict__ dbc128, const unsigned short* __restrict__ sresb,
                                              const float* __restrict__ Alog, const float* __restrict__ Dv,
                                              unsigned short* __restrict__ ys) {
    const int b = blockIdx.x;
    const int d0 = blockIdx.y * 32;
    const int tid = threadIdx.x;
    const int dl = tid >> 3;
    const int np = tid & 7;
    const int d = d0 + dl;
    const float A0p = -__expf(Alog[d * 16 + np]) * 1.44269504089f;
    const float A1p = -__expf(Alog[d * 16 + np + 8]) * 1.44269504089f;
    const float Dd = Dv[d];
    const int tr = tid >> 5;
    const int dls = tid & 31;

    __shared__ float2 sdu[2][STB][32];
    __shared__ float sbc[2][STB][32];

    const float* gde = delta + ((size_t)b * NPq + tr) * DIq + d0 + dls;
    const unsigned short* gu  = xi2b  + ((size_t)b * NPq + tr) * DIq + d0 + dls;
    const unsigned short* gsr = sresb + ((size_t)b * NPq + tr) * DIq + d0 + dls;
    const float* gbc = dbc128 + ((size_t)b * NPq + tr) * 128 + 48 + dls;
    unsigned short* gy = ys + (size_t)b * NPq * DIq + d;

    float rde[4], rbc[4];
    unsigned short ruu[4], rss[4];

    auto stageLoad = [&](int c) {
        const int t0 = c * STB;
        #pragma unroll
        for (int j = 0; j < 3; j++) {
            int off = (t0 + 8 * j) * DIq;
            rde[j] = gde[off];
            ruu[j] = gu[off];
            rss[j] = gsr[off];
            rbc[j] = gbc[(t0 + 8 * j) * 128];
        }
        if (tid < 128) {
            int off = (t0 + 24) * DIq;
            rde[3] = gde[off];
            ruu[3] = gu[off];
            rss[3] = gsr[off];
            rbc[3] = gbc[(t0 + 24) * 128];
        }
    };
    auto stageWrite = [&](int buf) {
        const int pi = (dls & 7) * 4 + (dls >> 3);
        #pragma unroll
        for (int j = 0; j < 3; j++) {
            int t = tr + 8 * j;
            unsigned pk = ((unsigned)ruu[j] << 16) | rss[j];
            sdu[buf][t][dls] = make_float2(rde[j], __builtin_bit_cast(float, pk));
            sbc[buf][t][pi] = rbc[j];
        }
        if (tid < 128) {
            int t = tr + 24;
            unsigned pk = ((unsigned)ruu[3] << 16) | rss[3];
            sdu[buf][t][dls] = make_float2(rde[3], __builtin_bit_cast(float, pk));
            sbc[buf][t][pi] = rbc[3];
        }
    };

    stageLoad(0);
    stageWrite(0);
    __syncthreads();

    float h0 = 0.f, h1 = 0.f;
    int cur = 0;
    for (int c = 0; c < 7; c++) {
        if (c < 6) stageLoad(c + 1);
        #pragma unroll 4
        for (int t = 0; t < STB; t++) {
            float2 duv = sdu[cur][t][dl];
            float4 bc = *(const float4*)&sbc[cur][t][np * 4];
            unsigned bits = __builtin_bit_cast(unsigned, duv.y);
            float u  = __builtin_bit_cast(float, bits & 0xFFFF0000u);
            float sr = __builtin_bit_cast(float, bits << 16);
            float a0 = __builtin_amdgcn_exp2f(duv.x * A0p);
            float a1 = __builtin_amdgcn_exp2f(duv.x * A1p);
            float deu = duv.x * u;
            h0 = fmaf(a0, h0, deu * bc.x);
            h1 = fmaf(a1, h1, deu * bc.y);
            float p = fmaf(h1, bc.w, h0 * bc.z);
            p = dpp_add<0xB1>(p);
            p = dpp_add<0x4E>(p);
            p = dpp_add<0x141>(p);
            if (np == 0) gy[(size_t)(c * STB + t) * DIq] = f2bf(fmaf(Dd, u, p) * sr);
        }
        if (c < 6) stageWrite(cur ^ 1);
        __syncthreads();
        cur ^= 1;
    }
}

// ---------------- row LayerNorm (1024) + exact gelu; out f32 or bf16 ----------------
template<bool OBF>
__global__ __launch_bounds__(256) void k_ln_gelu(const float* __restrict__ in, const float* __restrict__ g,
                                                 const float* __restrict__ bt, void* __restrict__ outv) {
    int row = blockIdx.x;
    const float* x = in + (size_t)row * OUTq;
    float4 v = ((const float4*)x)[threadIdx.x];
    float s = v.x + v.y + v.z + v.w;
    float ss = v.x * v.x + v.y * v.y + v.z * v.z + v.w * v.w;
    #pragma unroll
    for (int off = 32; off >= 1; off >>= 1) { s += __shfl_down(s, off); ss += __shfl_down(ss, off); }
    __shared__ float sh[10];
    int wid = threadIdx.x >> 6, lid = threadIdx.x & 63;
    if (lid == 0) { sh[wid] = s; sh[4 + wid] = ss; }
    __syncthreads();
    if (threadIdx.x == 0) {
        float S = sh[0] + sh[1] + sh[2] + sh[3], SS = sh[4] + sh[5] + sh[6] + sh[7];
        float m = S * (1.f / OUTq);
        float var = SS * (1.f / OUTq) - m * m;
        sh[8] = m; sh[9] = rsqrtf(var + 1e-5f);
    }
    __syncthreads();
    float m = sh[8], rst = sh[9];
    float4 gv = ((const float4*)g)[threadIdx.x];
    float4 bv = ((const float4*)bt)[threadIdx.x];
    float4 o;
    float y0 = (v.x - m) * rst * gv.x + bv.x; o.x = 0.5f * y0 * (1.f + erff(y0 * 0.70710678118f));
    float y1 = (v.y - m) * rst * gv.y + bv.y; o.y = 0.5f * y1 * (1.f + erff(y1 * 0.70710678118f));
    float y2 = (v.z - m) * rst * gv.z + bv.z; o.z = 0.5f * y2 * (1.f + erff(y2 * 0.70710678118f));
    float y3 = (v.w - m) * rst * gv.w + bv.w; o.w = 0.5f * y3 * (1.f + erff(y3 * 0.70710678118f));
    if (OBF) {
        ushort4 o4;
        o4.x = f2bf(o.x); o4.y = f2bf(o.y); o4.z = f2bf(o.z); o4.w = f2bf(o.w);
        ((ushort4*)((unsigned short*)outv + (size_t)row * OUTq))[threadIdx.x] = o4;
    } else {
        ((float4*)((float*)outv + (size_t)row * OUTq))[threadIdx.x] = o;
    }
}

// ---------------- column softmax + pool, 4-way t-split ----------------
__global__ __launch_bounds__(256) void k_softpool(const float* __restrict__ gm, const unsigned short* __restrict__ ym,
                                                  float* __restrict__ pooled) {
    int b = blockIdx.y;
    int jl = threadIdx.x & 63;
    int j = blockIdx.x * 64 + jl;
    int tc = threadIdx.x >> 6;
    const float* gb = gm + (size_t)b * NPq * OUTq + j;
    const unsigned short* yb = ym + (size_t)b * NPq * OUTq + j;
    int t0 = tc * 49;
    float m = -1e30f, s = 0.f, ps = 0.f;
    for (int t = t0; t < t0 + 49; t++) {
        float g = gb[(size_t)t * OUTq];
        float y = bf2f(yb[(size_t)t * OUTq]);
        float mn = fmaxf(m, g);
        float sc = __expf(m - mn);
        float e = __expf(g - mn);
        s = fmaf(s, sc, e);
        ps = fmaf(ps, sc, y * e);
        m = mn;
    }
    __shared__ float sm[4][64], ssum[4][64], sps[4][64];
    sm[tc][jl] = m; ssum[tc][jl] = s; sps[tc][jl] = ps;
    __syncthreads();
    if (tc == 0) {
        float m0 = sm[0][jl], m1 = sm[1][jl], m2 = sm[2][jl], m3 = sm[3][jl];
        float mt = fmaxf(fmaxf(m0, m1), fmaxf(m2, m3));
        float e0 = __expf(m0 - mt), e1 = __expf(m1 - mt);
        float e2 = __expf(m2 - mt), e3 = __expf(m3 - mt);
        float st = ssum[0][jl] * e0 + ssum[1][jl] * e1 + ssum[2][jl] * e2 + ssum[3][jl] * e3;
        float pt = sps[0][jl] * e0 + sps[1][jl] * e1 + sps[2][jl] * e2 + sps[3][jl] * e3;
        pooled[b * OUTq + j] = pt / st;
    }
}

// ---------------- final LayerNorm ----------------
__global__ __launch_bounds__(256) void k_final_ln(const float* __restrict__ p, const float* __restrict__ g,
                                                  const float* __restrict__ bt, float* __restrict__ out) {
    int row = blockIdx.x;
    const float* x = p + (size_t)row * OUTq;
    float4 v = ((const float4*)x)[threadIdx.x];
    float s = v.x + v.y + v.z + v.w;
    float ss = v.x * v.x + v.y * v.y + v.z * v.z + v.w * v.w;
    #pragma unroll
    for (int off = 32; off >= 1; off >>= 1) { s += __shfl_down(s, off); ss += __shfl_down(ss, off); }
    __shared__ float sh[10];
    int wid = threadIdx.x >> 6, lid = threadIdx.x & 63;
    if (lid == 0) { sh[wid] = s; sh[4 + wid] = ss; }
    __syncthreads();
    if (threadIdx.x == 0) {
        float S = sh[0] + sh[1] + sh[2] + sh[3], SS = sh[4] + sh[5] + sh[6] + sh[7];
        float m = S * (1.f / OUTq);
        float var = SS * (1.f / OUTq) - m * m;
        sh[8] = m; sh[9] = rsqrtf(var + 1e-5f);
    }
    __syncthreads();
    float m = sh[8], rst = sh[9];
    float4 gv = ((const float4*)g)[threadIdx.x];
    float4 bv = ((const float4*)bt)[threadIdx.x];
    float4 o;
    o.x = (v.x - m) * rst * gv.x + bv.x;
    o.y = (v.y - m) * rst * gv.y + bv.y;
    o.z = (v.z - m) * rst * gv.z + bv.z;
    o.w = (v.w - m) * rst * gv.w + bv.w;
    ((float4*)(out + (size_t)row * OUTq))[threadIdx.x] = o;
}

extern "C" void kernel_launch(void* const* d_in, const int* in_sizes, int n_in,
                              void* d_out, int out_size, void* d_ws, size_t ws_size,
                              hipStream_t stream) {
    const float* img   = (const float*)d_in[0];
    const float* sa_w  = (const float*)d_in[1];
    const float* pe_w  = (const float*)d_in[2];
    const float* pe_b  = (const float*)d_in[3];
    const float* pos   = (const float*)d_in[4];
    const float* in_w  = (const float*)d_in[5];
    const float* in_b  = (const float*)d_in[6];
    const float* cv_w  = (const float*)d_in[7];
    const float* cv_b  = (const float*)d_in[8];
    const float* xp_w  = (const float*)d_in[9];
    const float* dt_w  = (const float*)d_in[10];
    const float* dt_b  = (const float*)d_in[11];
    const float* Alog  = (const float*)d_in[12];
    const float* Dv    = (const float*)d_in[13];
    const float* ot_w  = (const float*)d_in[14];
    const float* ot_b  = (const float*)d_in[15];
    const float* em_w  = (const float*)d_in[16];
    const float* em_b  = (const float*)d_in[17];
    const float* em_g  = (const float*)d_in[18];
    const float* em_bt = (const float*)d_in[19];
    const float* at_w  = (const float*)d_in[20];
    const float* at_b  = (const float*)d_in[21];
    const float* at_g  = (const float*)d_in[22];
    const float* at_bt = (const float*)d_in[23];
    const float* la_g  = (const float*)d_in[24];
    const float* la_bt = (const float*)d_in[25];

    char* ws = (char*)d_ws;
    auto al = [](size_t x) { return (x + 255) & ~(size_t)255; };
    size_t SZ_am   = (size_t)NB * 2 * IMP * 4;
    size_t SZ_G    = (size_t)MPAD * 768 * 2;
    size_t SZ_x    = (size_t)MPAD * 768 * 2;
    size_t SZ_xr2  = (size_t)ROWS * DIq * 2;
    size_t SZ_xi2  = (size_t)ROWS * DIq * 2;
    size_t SZ_de   = (size_t)ROWS * DIq * 4;
    size_t SZ_dbc  = (size_t)MPAD * 128 * 4;
    size_t SZ_ys   = (size_t)MPAD * DIq * 2;
    size_t SZ_sres = (size_t)ROWS * DIq * 2;
    size_t SZ_yem  = (size_t)MPAD * 1024 * 2;
    size_t SZ_pool = (size_t)NB * OUTq * 4;

    size_t o_am   = 0;
    size_t o_G    = al(o_am + SZ_am);
    size_t o_x    = al(o_G + SZ_G);
    size_t o_xr2  = al(o_x + SZ_x);
    size_t o_xi2  = al(o_xr2 + SZ_xr2);
    size_t o_de   = al(o_xi2 + SZ_xi2);
    size_t o_dbc  = al(o_de + SZ_de);
    size_t o_ys   = al(o_dbc + SZ_dbc);
    size_t o_sres = al(o_ys + SZ_ys);
    size_t o_yem  = al(o_sres + SZ_sres);
    size_t o_pool = al(o_yem + SZ_yem);

    size_t o_wpe  = al(o_pool + SZ_pool);
    size_t o_win0 = al(o_wpe  + (size_t)768 * 768 * 2);
    size_t o_win1 = al(o_win0 + (size_t)3072 * 768 * 2);
    size_t o_wot0 = al(o_win1 + (size_t)3072 * 768 * 2);
    size_t o_wot1 = al(o_wot0 + (size_t)768 * 1536 * 2);
    size_t o_wem  = al(o_wot1 + (size_t)768 * 1536 * 2);
    size_t o_wat  = al(o_wem  + (size_t)1024 * 768 * 2);
    size_t o_xpt  = al(o_wat  + (size_t)1024 * 1024 * 2);

    float* am    = (float*)(ws + o_am);
    unsigned short* G   = (unsigned short*)(ws + o_G);
    unsigned short* x   = (unsigned short*)(ws + o_x);
    unsigned short* xr2 = (unsigned short*)(ws + o_xr2);
    unsigned short* xi2b = (unsigned short*)(ws + o_xi2);
    float* de    = (float*)(ws + o_de);
    float* dbc128 = (float*)(ws + o_dbc);
    unsigned short* ys = (unsigned short*)(ws + o_ys);
    unsigned short* sresb = (unsigned short*)(ws + o_sres);
    unsigned short* yem = (unsigned short*)(ws + o_yem);
    float* pool  = (float*)(ws + o_pool);
    unsigned short* wpe  = (unsigned short*)(ws + o_wpe);
    unsigned short* win0 = (unsigned short*)(ws + o_win0);
    unsigned short* win1 = (unsigned short*)(ws + o_win1);
    unsigned short* wot0 = (unsigned short*)(ws + o_wot0);
    unsigned short* wot1 = (unsigned short*)(ws + o_wot1);
    unsigned short* wem  = (unsigned short*)(ws + o_wem);
    unsigned short* wat  = (unsigned short*)(ws + o_wat);
    unsigned short* xpt  = (unsigned short*)(ws + o_xpt);
    // head-phase overlays
    float* t1  = (float*)(ws + o_de);
    float* t2  = (float*)(ws + o_xr2);
    float* gat = (float*)(ws + o_ys);

    k_transpose_all<<<9280, 256, 0, stream>>>(pe_w, in_w, ot_w, em_w, at_w,
                                              wpe, win0, win1, wot0, wot1, wem, wat);
    k_xpw_t<<<(2 * 128 * 1536 + 255) / 256, 256, 0, stream>>>(xp_w, xpt);

    int nq = NB * IMP / 4;
    k_avgmax<<<(nq + 255) / 256, 256, 0, stream>>>(img, am);
    k_gatepatch<<<(nq + 255) / 256, 256, 0, stream>>>(img, am, sa_w, G);

    dim3 blk(256);
    k_gemm_bf<EPI_POSEMB, true><<<dim3(12, 25), blk, 0, stream>>>(G, wpe, pe_b, x, 768, ROWS, 768, 768, pos);

    for (int l = 0; l < 2; l++) {
        const unsigned short* win = l ? win1 : win0;
        const unsigned short* wot = l ? wot1 : wot0;
        k_gemm_bf2<<<dim3(24, 25), blk, 0, stream>>>(x, win, in_b + l * 3072, xr2, sresb, ROWS, 768);
        int nc4 = ROWS * DIq / 4;
        k_conv_silu<<<(nc4 + 255) / 256, 256, 0, stream>>>(xr2, cv_w + (size_t)l * DIq * 4, cv_b + l * DIq, xi2b);
        k_gemm_bf<EPI_NONE, false><<<dim3(2, 25), blk, 0, stream>>>(xi2b, xpt + (size_t)l * 128 * 1536,
                                                                    nullptr, dbc128, 128, ROWS, 128, 1536, nullptr);
        k_dtred<<<ROWS / DT_RPB, 384, 0, stream>>>(dbc128, dt_w + (size_t)l * 48 * 1536, dt_b + l * 1536, de);
        k_scan<<<dim3(16, 48), blk, 0, stream>>>(de, xi2b, dbc128, sresb, Alog + (size_t)l * 1536 * 16,
                                                 Dv + l * 1536, ys);
        k_gemm_bf<EPI_NONE, true><<<dim3(12, 25), blk, 0, stream>>>(ys, wot, ot_b + l * 768, x, 768,
                                                                    ROWS, 768, 1536, nullptr);
    }

    // head
    k_gemm_bf<EPI_NONE, false><<<dim3(16, 25), blk, 0, stream>>>(x, wem, em_b, t1, 1024, ROWS, 1024, 768, nullptr);
    k_ln_gelu<true><<<ROWS, 256, 0, stream>>>(t1, em_g, em_bt, yem);
    k_gemm_bf<EPI_NONE, false><<<dim3(16, 25), blk, 0, stream>>>(yem, wat, at_b, t2, 1024, ROWS, 1024, 1024, nullptr);
    k_ln_gelu<false><<<ROWS, 256, 0, stream>>>(t2, at_g, at_bt, gat);
    k_softpool<<<dim3(16, NB), 256, 0, stream>>>(gat, yem, pool);
    k_final_ln<<<NB, 256, 0, stream>>>(pool, la_g, la_bt, (float*)d_out);
}